// Round 4
// baseline (4034.370 us; speedup 1.0000x reference)
//
#include <hip/hip_runtime.h>
#include <hip/hip_bf16.h>

constexpr int NNODES = 25000;
constexpr int NEDGES = 400000;
constexpr int DD = 64;
constexpr float BNEPS = 1e-5f;
constexpr float AGGEPS = 1e-6f;

typedef __attribute__((ext_vector_type(8))) short short8_t;
typedef __attribute__((ext_vector_type(4))) float float4_t;

// storage-type helpers (compute is always fp32)
__device__ __forceinline__ float ldv(const float* p, long i) { return p[i]; }
__device__ __forceinline__ float ldv(const __hip_bfloat16* p, long i) { return __bfloat162float(p[i]); }
__device__ __forceinline__ void stv(float* p, long i, float v) { p[i] = v; }
__device__ __forceinline__ void stv(__hip_bfloat16* p, long i, float v) { p[i] = __float2bfloat16(v); }

// float -> bf16 bits, RNE (finite inputs only)
__device__ __forceinline__ short f2bs(float f) {
    union { float f; unsigned u; } x; x.f = f;
    unsigned r = x.u + 0x7FFFu + ((x.u >> 16) & 1u);
    return (short)(r >> 16);
}
__device__ __forceinline__ float bs2f(short s) {
    union { unsigned u; float f; } x; x.u = ((unsigned)(unsigned short)s) << 16; return x.f;
}

// stage 8 consecutive elems from global into bf16 LDS (16B-aligned both sides)
__device__ __forceinline__ void stage8(const __hip_bfloat16* s, short* d) {
    *(short8_t*)d = *(const short8_t*)s;
}
__device__ __forceinline__ void stage8(const float* s, short* d) {
    float4_t a = *(const float4_t*)s;
    float4_t b = *(const float4_t*)(s + 4);
    short8_t v;
    v[0] = f2bs(a[0]); v[1] = f2bs(a[1]); v[2] = f2bs(a[2]); v[3] = f2bs(a[3]);
    v[4] = f2bs(b[0]); v[5] = f2bs(b[1]); v[6] = f2bs(b[2]); v[7] = f2bs(b[3]);
    *(short8_t*)d = v;
}

// ---------------------------------------------------------------------------
// LDS-tiled linear: Y[r][n] = bias[n] + sum_k X[r][k]*W[k][n] (+ optional
// fused gathered adds G1[g1[r]][n] + G2[g2[r]][n] — the gated-GCN edge update)
// ---------------------------------------------------------------------------
template<int K, int N, int JR, bool GADD, typename TX, typename TY>
__global__ __launch_bounds__(256) void linear_kernel(
    const TX* __restrict__ X, const float* __restrict__ W,
    const float* __restrict__ Bb, TY* __restrict__ Y,
    const float* __restrict__ G1, const int* __restrict__ g1,
    const float* __restrict__ G2, const int* __restrict__ g2,
    int rows)
{
    constexpr int SLOTS = 256 / N;
    constexpr int RPG = SLOTS * JR;   // rows per group
    __shared__ float wl[K * N];
    __shared__ float bl[N];
    __shared__ float xl[RPG * K];

    const int tid = threadIdx.x;
    for (int i = tid; i < K * N; i += 256) wl[i] = W[i];
    if (tid < N) bl[tid] = Bb ? Bb[tid] : 0.0f;

    const int col = tid % N;
    const int slot = tid / N;

    const int ngroups = (rows + RPG - 1) / RPG;
    for (int g = blockIdx.x; g < ngroups; g += gridDim.x) {
        const int rowBase = g * RPG;
        __syncthreads();
        for (int i = tid; i < RPG * K; i += 256) {
            int r = i / K, k = i - r * K;
            int row = rowBase + r;
            xl[i] = (row < rows) ? ldv(X, (long)row * K + k) : 0.0f;
        }
        __syncthreads();
        float acc[JR];
        #pragma unroll
        for (int j = 0; j < JR; ++j) acc[j] = bl[col];
        #pragma unroll 4
        for (int k = 0; k < K; ++k) {
            float w = wl[k * N + col];
            #pragma unroll
            for (int j = 0; j < JR; ++j)
                acc[j] += xl[(slot * JR + j) * K + k] * w;
        }
        #pragma unroll
        for (int j = 0; j < JR; ++j) {
            int row = rowBase + slot * JR + j;
            if (row < rows) {
                float v = acc[j];
                if (GADD) {
                    v += G1[(long)g1[row] * N + col];
                    v += G2[(long)g2[row] * N + col];
                }
                stv(Y, (long)row * N + col, v);
            }
        }
    }
}

// num[dst][c] += sig*Bh[src][c]; den[dst][c] += sig; fused BN stats of ehat
template<typename TH>
__global__ __launch_bounds__(256) void aggregate_kernel(
    const TH* __restrict__ ehat, const float* __restrict__ Bh,
    const int* __restrict__ src, const int* __restrict__ dst,
    float* __restrict__ num, float* __restrict__ den,
    float* __restrict__ stats, int rows)
{
    long total = (long)rows * DD;
    float ls = 0.0f, ls2 = 0.0f;
    for (long gid = (long)blockIdx.x * 256 + threadIdx.x; gid < total;
         gid += (long)gridDim.x * 256) {
        int i = (int)(gid >> 6), c = (int)(gid & 63);
        float v = ldv(ehat, gid);
        float s = 1.0f / (1.0f + __expf(-v));
        int sr = src[i], d = dst[i];
        atomicAdd(&den[(long)d * DD + c], s);
        atomicAdd(&num[(long)d * DD + c], s * Bh[(long)sr * DD + c]);
        ls += v; ls2 += v * v;
    }
    // column index is invariant per thread (stride % 64 == 0)
    __shared__ float sb[256], sb2[256];
    int tid = threadIdx.x;
    sb[tid] = ls; sb2[tid] = ls2;
    __syncthreads();
    if (tid < 64) {
        float s  = sb[tid] + sb[tid + 64] + sb[tid + 128] + sb[tid + 192];
        float s2 = sb2[tid] + sb2[tid + 64] + sb2[tid + 128] + sb2[tid + 192];
        atomicAdd(&stats[tid], s);
        atomicAdd(&stats[64 + tid], s2);
    }
}

// hhat = Ah + num/(den+eps); fused BN stats of hhat
__global__ __launch_bounds__(256) void hhat_kernel(
    const float* __restrict__ Ah, const float* __restrict__ num,
    const float* __restrict__ den, float* __restrict__ hhat,
    float* __restrict__ stats, long total)
{
    float ls = 0.0f, ls2 = 0.0f;
    for (long gid = (long)blockIdx.x * 256 + threadIdx.x; gid < total;
         gid += (long)gridDim.x * 256) {
        float v = Ah[gid] + num[gid] / (den[gid] + AGGEPS);
        hhat[gid] = v;
        ls += v; ls2 += v * v;
    }
    __shared__ float sb[256], sb2[256];
    int tid = threadIdx.x;
    sb[tid] = ls; sb2[tid] = ls2;
    __syncthreads();
    if (tid < 64) {
        float s  = sb[tid] + sb[tid + 64] + sb[tid + 128] + sb[tid + 192];
        float s2 = sb2[tid] + sb2[tid + 64] + sb2[tid + 128] + sb2[tid + 192];
        atomicAdd(&stats[tid], s);
        atomicAdd(&stats[64 + tid], s2);
    }
}

// base += relu((xhat - mu)*rstd*g + b)
template<typename TB, typename TX>
__global__ __launch_bounds__(256) void bn_apply_kernel(
    TB* __restrict__ base, const TX* __restrict__ xhat,
    const float* __restrict__ stats, const float* __restrict__ g,
    const float* __restrict__ b, int rows)
{
    long total = (long)rows * DD;
    float inv = 1.0f / (float)rows;
    for (long gid = (long)blockIdx.x * 256 + threadIdx.x; gid < total;
         gid += (long)gridDim.x * 256) {
        int c = (int)(gid & 63);
        float mu = stats[c] * inv;
        float var = stats[64 + c] * inv - mu * mu;
        float rstd = rsqrtf(var + BNEPS);
        float v = (ldv(xhat, gid) - mu) * rstd * g[c] + b[c];
        stv(base, gid, ldv(base, gid) + fmaxf(v, 0.0f));
    }
}

// one-shot: W0 (256x128) -> W0T bf16 [n=128][k=256]; W1 (128x64) -> W1T [64][128]
__global__ __launch_bounds__(256) void transpose_w_kernel(
    const float* __restrict__ W0, const float* __restrict__ W1,
    short* __restrict__ W0T, short* __restrict__ W1T)
{
    int id = blockIdx.x * 256 + threadIdx.x;
    if (id < 256 * 128) {
        int k = id >> 7, n = id & 127;
        W0T[n * 256 + k] = f2bs(W0[id]);
    }
    if (id < 128 * 64) {
        int k = id >> 6, n = id & 63;
        W1T[n * 128 + k] = f2bs(W1[id]);
    }
}

// ---------------------------------------------------------------------------
// MFMA MLP readout: out = relu(relu(feat@W0+b0)@W1+b1)@W2+b2,
// feat = [e, e[rev], h[src], h[dst]]. 64-edge tiles, 4 waves, bf16 MFMA
// 16x16x32. Layouts (HW-verified): A[m=lane&15][k=quad*8+j],
// D[col=lane&15][row=quad*4+reg]. LDS rows padded to 72/136 elems (16B-aligned
// b128, 8 lanes/bank-quad = structural minimum).
// ---------------------------------------------------------------------------
template<typename TE>
__global__ __launch_bounds__(256) void readout_mfma_kernel(
    const TE* __restrict__ e, const float* __restrict__ h,
    const int* __restrict__ src, const int* __restrict__ dst,
    const int* __restrict__ rev,
    const short* __restrict__ W0T, const short* __restrict__ W1T,
    const float* __restrict__ b0, const float* __restrict__ b1,
    const float* __restrict__ W2, const float* __restrict__ b2,
    float* __restrict__ out)
{
    __shared__ short feat[64 * 72];    // feat slice (also reused as x1 tile)
    __shared__ short wtile[128 * 72];  // W0T slice [128][72]; reused as W1T [64][136]
    __shared__ short x0t[64 * 136];    // x0 tile bf16 (A-operand of phase 2)
    __shared__ float smallb[322];      // b0[128] | b1[64] | W2[128] | b2[2]

    const int tid = threadIdx.x;
    const int wave = tid >> 6;
    const int lane = tid & 63;
    const int r = lane & 15;
    const int q = lane >> 4;

    if (tid < 128) smallb[tid] = b0[tid];
    if (tid < 64)  smallb[128 + tid] = b1[tid];
    if (tid < 128) smallb[192 + tid] = W2[tid];
    if (tid < 2)   smallb[320 + tid] = b2[tid];

    constexpr int NTILES = NEDGES / 64;   // 6250, exact
    for (int t = blockIdx.x; t < NTILES; t += gridDim.x) {
        const int rowBase = t * 64;
        float4_t acc0[8];
        #pragma unroll
        for (int i = 0; i < 8; ++i) acc0[i] = (float4_t)0.0f;

        for (int s = 0; s < 4; ++s) {
            __syncthreads();   // protects feat/wtile (prev slice / prev tile x1+W1)
            for (int i = tid; i < 512; i += 256) {     // 64 rows x 8 octets
                int row = i >> 3, oct = i & 7;
                int er = rowBase + row;
                short* d = feat + row * 72 + oct * 8;
                if (s == 0)      stage8(e + (long)er * 64 + oct * 8, d);
                else if (s == 1) stage8(e + (long)rev[er] * 64 + oct * 8, d);
                else if (s == 2) stage8(h + (long)src[er] * 64 + oct * 8, d);
                else             stage8(h + (long)dst[er] * 64 + oct * 8, d);
            }
            for (int i = tid; i < 1024; i += 256) {    // W0T slice: 128 n x 8 octets
                int n = i >> 3, oct = i & 7;
                *(short8_t*)(wtile + n * 72 + oct * 8) =
                    *(const short8_t*)(W0T + (long)n * 256 + s * 64 + oct * 8);
            }
            __syncthreads();
            #pragma unroll
            for (int kk = 0; kk < 2; ++kk) {
                short8_t a = *(const short8_t*)(feat + (wave * 16 + r) * 72 + kk * 32 + q * 8);
                #pragma unroll
                for (int nt = 0; nt < 8; ++nt) {
                    short8_t b = *(const short8_t*)(wtile + (nt * 16 + r) * 72 + kk * 32 + q * 8);
                    acc0[nt] = __builtin_amdgcn_mfma_f32_16x16x32_bf16(a, b, acc0[nt], 0, 0, 0);
                }
            }
        }
        // epilogue 1: x0 = relu(acc0 + b0) -> x0t (bf16); rows are wave-private
        #pragma unroll
        for (int nt = 0; nt < 8; ++nt) {
            int col = nt * 16 + r;
            #pragma unroll
            for (int i2 = 0; i2 < 4; ++i2) {
                int row = wave * 16 + q * 4 + i2;
                x0t[row * 136 + col] = f2bs(fmaxf(acc0[nt][i2] + smallb[col], 0.0f));
            }
        }
        __syncthreads();   // wtile slice-3 reads done; x0t visible
        for (int i = tid; i < 1024; i += 256) {        // W1T: 64 n x 16 octets
            int n = i >> 4, oct = i & 15;
            *(short8_t*)(wtile + n * 136 + oct * 8) =
                *(const short8_t*)(W1T + (long)n * 128 + oct * 8);
        }
        __syncthreads();
        // phase 2: x1 = relu(x0 @ W1 + b1), K=128
        float4_t acc1[4];
        #pragma unroll
        for (int i = 0; i < 4; ++i) acc1[i] = (float4_t)0.0f;
        #pragma unroll
        for (int kk = 0; kk < 4; ++kk) {
            short8_t a = *(const short8_t*)(x0t + (wave * 16 + r) * 136 + kk * 32 + q * 8);
            #pragma unroll
            for (int nt = 0; nt < 4; ++nt) {
                short8_t b = *(const short8_t*)(wtile + (nt * 16 + r) * 136 + kk * 32 + q * 8);
                acc1[nt] = __builtin_amdgcn_mfma_f32_16x16x32_bf16(a, b, acc1[nt], 0, 0, 0);
            }
        }
        // epilogue 2: x1 -> feat buffer (bf16, stride 72)
        #pragma unroll
        for (int nt = 0; nt < 4; ++nt) {
            int col = nt * 16 + r;
            #pragma unroll
            for (int i2 = 0; i2 < 4; ++i2) {
                int row = wave * 16 + q * 4 + i2;
                feat[row * 72 + col] = f2bs(fmaxf(acc1[nt][i2] + smallb[128 + col], 0.0f));
            }
        }
        __syncthreads();
        // phase 3: out = x1 @ W2 + b2   (64 rows x 2 classes)
        if (tid < 128) {
            int row = tid >> 1, cls = tid & 1;
            float a = smallb[320 + cls];
            #pragma unroll 8
            for (int k = 0; k < 64; ++k)
                a += bs2f(feat[row * 72 + k]) * smallb[192 + k * 2 + cls];
            out[(long)(rowBase + row) * 2 + cls] = a;
        }
    }
}

// ---------------------------------------------------------------------------
static inline int igrid(long total, int block, int cap) {
    long g = (total + block - 1) / block;
    return (int)(g < cap ? g : cap);
}

template<typename TE, typename TH>
static void run_net(void* const* d_in, float* f, TE* e, TH* ehat,
                    float* out, hipStream_t stream)
{
    const float* h_in   = (const float*)d_in[0];
    const float* e_in   = (const float*)d_in[1];
    const int*   src    = (const int*)d_in[2];
    const int*   dst    = (const int*)d_in[3];
    const int*   rev    = (const int*)d_in[4];
    const float* emb_h_w = (const float*)d_in[5];
    const float* emb_h_b = (const float*)d_in[6];
    const float* emb_e_w = (const float*)d_in[7];
    const float* emb_e_b = (const float*)d_in[8];
    const float* A_w = (const float*)d_in[9];  const float* A_b = (const float*)d_in[10];
    const float* B_w = (const float*)d_in[11]; const float* B_b = (const float*)d_in[12];
    const float* C_w = (const float*)d_in[13]; const float* C_b = (const float*)d_in[14];
    const float* D_w = (const float*)d_in[15]; const float* D_b = (const float*)d_in[16];
    const float* E_w = (const float*)d_in[17]; const float* E_b = (const float*)d_in[18];
    // F/G (19..22) and bn_u (27,28) are dead: u never reaches the output.
    const float* bn_h_g = (const float*)d_in[23]; const float* bn_h_b = (const float*)d_in[24];
    const float* bn_e_g = (const float*)d_in[25]; const float* bn_e_b = (const float*)d_in[26];
    const float* W0 = (const float*)d_in[29]; const float* b0 = (const float*)d_in[30];
    const float* W1 = (const float*)d_in[31]; const float* b1 = (const float*)d_in[32];
    const float* W2 = (const float*)d_in[33]; const float* b2 = (const float*)d_in[34];

    const size_t NH = (size_t)NNODES * DD;
    float* h    = f;
    float* Ah   = f + NH;
    float* Bh   = f + 2 * NH;
    float* Dh   = f + 3 * NH;      // hhat aliases Dh (Dh dead after C-linear)
    float* Eh   = f + 4 * NH;
    float* num  = f + 5 * NH;
    float* den  = f + 6 * NH;
    float* stats= f + 7 * NH;      // 256 floats
    float* hhat = Dh;
    // W0T/W1T (bf16) live in the num region, used only after the last layer
    short* W0T = (short*)num;
    short* W1T = W0T + 256 * 128;

    const int GE = 4096;
    const int GN = 1563;
    const int EW = igrid((long)NEDGES * DD, 256, 16384);
    const int NW = igrid((long)NNODES * DD, 256, 16384);

    // embeddings
    linear_kernel<64, 64, 4, false, float, float><<<GN, 256, 0, stream>>>(
        h_in, emb_h_w, emb_h_b, h, nullptr, nullptr, nullptr, nullptr, NNODES);
    linear_kernel<16, 64, 4, false, float, TE><<<GE, 256, 0, stream>>>(
        e_in, emb_e_w, emb_e_b, e, nullptr, nullptr, nullptr, nullptr, NEDGES);

    for (int l = 0; l < 4; ++l) {
        const float* Awl = A_w + (size_t)l * DD * DD; const float* Abl = A_b + l * DD;
        const float* Bwl = B_w + (size_t)l * DD * DD; const float* Bbl = B_b + l * DD;
        const float* Cwl = C_w + (size_t)l * DD * DD; const float* Cbl = C_b + l * DD;
        const float* Dwl = D_w + (size_t)l * DD * DD; const float* Dbl = D_b + l * DD;
        const float* Ewl = E_w + (size_t)l * DD * DD; const float* Ebl = E_b + l * DD;

        linear_kernel<64, 64, 4, false, float, float><<<GN, 256, 0, stream>>>(
            h, Awl, Abl, Ah, nullptr, nullptr, nullptr, nullptr, NNODES);
        linear_kernel<64, 64, 4, false, float, float><<<GN, 256, 0, stream>>>(
            h, Bwl, Bbl, Bh, nullptr, nullptr, nullptr, nullptr, NNODES);
        linear_kernel<64, 64, 4, false, float, float><<<GN, 256, 0, stream>>>(
            h, Dwl, Dbl, Dh, nullptr, nullptr, nullptr, nullptr, NNODES);
        linear_kernel<64, 64, 4, false, float, float><<<GN, 256, 0, stream>>>(
            h, Ewl, Ebl, Eh, nullptr, nullptr, nullptr, nullptr, NNODES);

        // e_hat = e@C + Cb + Dh[src] + Eh[dst]   (gather fused into epilogue)
        linear_kernel<64, 64, 4, true, TE, TH><<<GE, 256, 0, stream>>>(
            e, Cwl, Cbl, ehat, Dh, src, Eh, dst, NEDGES);

        // aggregation + fused BN stats
        hipMemsetAsync(num, 0, 2 * NH * sizeof(float), stream);   // num+den contiguous
        hipMemsetAsync(stats, 0, 256 * sizeof(float), stream);
        aggregate_kernel<TH><<<EW, 256, 0, stream>>>(ehat, Bh, src, dst, num, den,
                                                     stats + 128, NEDGES);
        hhat_kernel<<<NW, 256, 0, stream>>>(Ah, num, den, hhat, stats, (long)NH);

        // BN apply + relu + residual
        bn_apply_kernel<float, float><<<NW, 256, 0, stream>>>(
            h, hhat, stats, bn_h_g + l * DD, bn_h_b + l * DD, NNODES);
        bn_apply_kernel<TE, TH><<<EW, 256, 0, stream>>>(
            e, ehat, stats + 128, bn_e_g + l * DD, bn_e_b + l * DD, NEDGES);
    }

    // MFMA readout (W transposed to bf16 scratch in the dead num region)
    transpose_w_kernel<<<128, 256, 0, stream>>>(W0, W1, W0T, W1T);
    readout_mfma_kernel<TE><<<2048, 256, 0, stream>>>(e, h, src, dst, rev,
                                                      W0T, W1T, b0, b1, W2, b2, out);
}

extern "C" void kernel_launch(void* const* d_in, const int* in_sizes, int n_in,
                              void* d_out, int out_size, void* d_ws, size_t ws_size,
                              hipStream_t stream)
{
    const size_t NH = (size_t)NNODES * DD;       // 1.6M floats
    const size_t NE = (size_t)NEDGES * DD;       // 25.6M elems
    const size_t baseB = (7 * NH + 256) * sizeof(float);   // 44.8 MB node region

    char* base = (char*)d_ws;
    char* edge = base + baseB;
    float* out = (float*)d_out;

    const size_t needA = baseB + NE * 4 * 2;          // fp32 e + fp32 ehat
    const size_t needB = baseB + NE * 4 + NE * 2;     // fp32 e + bf16 ehat
    const size_t needC = baseB + NE * 2 * 2;          // bf16 e + bf16 ehat

    if (ws_size >= needA) {
        run_net<float, float>(d_in, (float*)base, (float*)edge,
                              (float*)(edge + NE * 4), out, stream);
    } else if (ws_size >= needB) {
        run_net<float, __hip_bfloat16>(d_in, (float*)base, (float*)edge,
                                       (__hip_bfloat16*)(edge + NE * 4), out, stream);
    } else if (ws_size >= needC) {
        run_net<__hip_bfloat16, __hip_bfloat16>(d_in, (float*)base, (__hip_bfloat16*)edge,
                                                (__hip_bfloat16*)(edge + NE * 2), out, stream);
    } else {
        // diagnostic fallback: workspace too small — emit zeros, don't fault
        hipMemsetAsync(d_out, 0, (size_t)out_size * sizeof(float), stream);
    }
}

// Round 5
// 1868.902 us; speedup vs baseline: 2.1587x; 2.1587x over previous
//
#include <hip/hip_runtime.h>
#include <hip/hip_bf16.h>

constexpr int NNODES = 25000;
constexpr int NEDGES = 400000;
constexpr int DD = 64;
constexpr float BNEPS = 1e-5f;
constexpr float AGGEPS = 1e-6f;

typedef __attribute__((ext_vector_type(8))) short short8_t;
typedef __attribute__((ext_vector_type(4))) float float4_t;

// storage-type helpers (compute is always fp32)
__device__ __forceinline__ float ldv(const float* p, long i) { return p[i]; }
__device__ __forceinline__ float ldv(const __hip_bfloat16* p, long i) { return __bfloat162float(p[i]); }
__device__ __forceinline__ void stv(float* p, long i, float v) { p[i] = v; }
__device__ __forceinline__ void stv(__hip_bfloat16* p, long i, float v) { p[i] = __float2bfloat16(v); }

// float -> bf16 bits, RNE (finite inputs only)
__device__ __forceinline__ short f2bs(float f) {
    union { float f; unsigned u; } x; x.f = f;
    unsigned r = x.u + 0x7FFFu + ((x.u >> 16) & 1u);
    return (short)(r >> 16);
}
__device__ __forceinline__ float bs2f(short s) {
    union { unsigned u; float f; } x; x.u = ((unsigned)(unsigned short)s) << 16; return x.f;
}

// stage 8 consecutive elems from global into bf16 LDS (16B-aligned both sides)
__device__ __forceinline__ void stage8(const __hip_bfloat16* s, short* d) {
    *(short8_t*)d = *(const short8_t*)s;
}
__device__ __forceinline__ void stage8(const float* s, short* d) {
    float4_t a = *(const float4_t*)s;
    float4_t b = *(const float4_t*)(s + 4);
    short8_t v;
    v[0] = f2bs(a[0]); v[1] = f2bs(a[1]); v[2] = f2bs(a[2]); v[3] = f2bs(a[3]);
    v[4] = f2bs(b[0]); v[5] = f2bs(b[1]); v[6] = f2bs(b[2]); v[7] = f2bs(b[3]);
    *(short8_t*)d = v;
}

// ---------------------------------------------------------------------------
// LDS-tiled linear: Y[r][n] = bias[n] + sum_k X[r][k]*W[k][n] (+ optional
// fused gathered adds G1[g1[r]][n] + G2[g2[r]][n] — the gated-GCN edge update)
// ---------------------------------------------------------------------------
template<int K, int N, int JR, bool GADD, typename TX, typename TY>
__global__ __launch_bounds__(256) void linear_kernel(
    const TX* __restrict__ X, const float* __restrict__ W,
    const float* __restrict__ Bb, TY* __restrict__ Y,
    const float* __restrict__ G1, const int* __restrict__ g1,
    const float* __restrict__ G2, const int* __restrict__ g2,
    int rows)
{
    constexpr int SLOTS = 256 / N;
    constexpr int RPG = SLOTS * JR;   // rows per group
    __shared__ float wl[K * N];
    __shared__ float bl[N];
    __shared__ float xl[RPG * K];

    const int tid = threadIdx.x;
    for (int i = tid; i < K * N; i += 256) wl[i] = W[i];
    if (tid < N) bl[tid] = Bb ? Bb[tid] : 0.0f;

    const int col = tid % N;
    const int slot = tid / N;

    const int ngroups = (rows + RPG - 1) / RPG;
    for (int g = blockIdx.x; g < ngroups; g += gridDim.x) {
        const int rowBase = g * RPG;
        __syncthreads();
        for (int i = tid; i < RPG * K; i += 256) {
            int r = i / K, k = i - r * K;
            int row = rowBase + r;
            xl[i] = (row < rows) ? ldv(X, (long)row * K + k) : 0.0f;
        }
        __syncthreads();
        float acc[JR];
        #pragma unroll
        for (int j = 0; j < JR; ++j) acc[j] = bl[col];
        #pragma unroll 4
        for (int k = 0; k < K; ++k) {
            float w = wl[k * N + col];
            #pragma unroll
            for (int j = 0; j < JR; ++j)
                acc[j] += xl[(slot * JR + j) * K + k] * w;
        }
        #pragma unroll
        for (int j = 0; j < JR; ++j) {
            int row = rowBase + slot * JR + j;
            if (row < rows) {
                float v = acc[j];
                if (GADD) {
                    v += G1[(long)g1[row] * N + col];
                    v += G2[(long)g2[row] * N + col];
                }
                stv(Y, (long)row * N + col, v);
            }
        }
    }
}

// ---------------------------------------------------------------------------
// CSR build (graph is static within one call): histogram -> scan -> scatter
// ---------------------------------------------------------------------------
__global__ __launch_bounds__(256) void deg_hist_kernel(
    const int* __restrict__ dst, int* __restrict__ rowptr, int rows)
{
    int e = blockIdx.x * 256 + threadIdx.x;
    if (e < rows) atomicAdd(&rowptr[dst[e] + 1], 1);
}

// single-block inclusive scan (Hillis-Steele over 1024-chunks with carry)
__global__ __launch_bounds__(1024) void scan_kernel(int* __restrict__ data, int n)
{
    __shared__ int buf[1024];
    __shared__ int carry;
    if (threadIdx.x == 0) carry = 0;
    __syncthreads();
    for (int base = 0; base < n; base += 1024) {
        int i = base + threadIdx.x;
        int v = (i < n) ? data[i] : 0;
        buf[threadIdx.x] = v;
        __syncthreads();
        for (int off = 1; off < 1024; off <<= 1) {
            int t = (threadIdx.x >= off) ? buf[threadIdx.x - off] : 0;
            __syncthreads();
            buf[threadIdx.x] += t;
            __syncthreads();
        }
        if (i < n) data[i] = buf[threadIdx.x] + carry;
        __syncthreads();
        if (threadIdx.x == 0) carry += buf[1023];
        __syncthreads();
    }
}

__global__ __launch_bounds__(256) void scatter_kernel(
    const int* __restrict__ dst, const int* __restrict__ rowptr,
    int* __restrict__ cursor, int* __restrict__ eid, int rows)
{
    int e = blockIdx.x * 256 + threadIdx.x;
    if (e < rows) {
        int d = dst[e];
        int pos = atomicAdd(&cursor[d], 1);
        eid[rowptr[d] + pos] = e;
    }
}

// ---------------------------------------------------------------------------
// CSR aggregation: one wave per node, lane = column. No float atomics.
// hhat[n] = Ah[n] + sum_e(sig*Bh[src[e]]) / (sum_e(sig)+eps), fused.
// ---------------------------------------------------------------------------
template<typename TH>
__global__ __launch_bounds__(256) void agg_csr_kernel(
    const TH* __restrict__ ehat, const float* __restrict__ Bh,
    const int* __restrict__ src,
    const int* __restrict__ rowptr, const int* __restrict__ eid,
    const float* __restrict__ Ah, float* __restrict__ hhat)
{
    const int node = blockIdx.x * 4 + (threadIdx.x >> 6);
    const int lane = threadIdx.x & 63;
    const int s0 = rowptr[node], s1 = rowptr[node + 1];
    float den = 0.0f, num = 0.0f;
    for (int p = s0; p < s1; ++p) {
        int e = eid[p];
        float v = ldv(ehat, (long)e * DD + lane);
        float s = 1.0f / (1.0f + __expf(-v));
        den += s;
        num += s * Bh[(long)src[e] * DD + lane];
    }
    hhat[(long)node * DD + lane] = Ah[(long)node * DD + lane] + num / (den + AGGEPS);
}

// per-column sum & sumsq via block reduce + atomics (stats zeroed beforehand)
template<typename TX>
__global__ __launch_bounds__(256) void bn_stats_kernel(
    const TX* __restrict__ X, float* __restrict__ stats, int rows)
{
    __shared__ float sb[256], sb2[256];
    int tid = threadIdx.x;
    int c = tid & 63, slot = tid >> 6;
    float s = 0.0f, s2 = 0.0f;
    for (int r = blockIdx.x * 4 + slot; r < rows; r += gridDim.x * 4) {
        float x = ldv(X, (long)r * DD + c);
        s += x; s2 += x * x;
    }
    sb[tid] = s; sb2[tid] = s2;
    __syncthreads();
    if (tid < 64) {
        s  = sb[tid] + sb[tid + 64] + sb[tid + 128] + sb[tid + 192];
        s2 = sb2[tid] + sb2[tid + 64] + sb2[tid + 128] + sb2[tid + 192];
        atomicAdd(&stats[tid], s);
        atomicAdd(&stats[64 + tid], s2);
    }
}

// base += relu((xhat - mu)*rstd*g + b)
template<typename TB, typename TX>
__global__ __launch_bounds__(256) void bn_apply_kernel(
    TB* __restrict__ base, const TX* __restrict__ xhat,
    const float* __restrict__ stats, const float* __restrict__ g,
    const float* __restrict__ b, int rows)
{
    long total = (long)rows * DD;
    float inv = 1.0f / (float)rows;
    for (long gid = (long)blockIdx.x * 256 + threadIdx.x; gid < total;
         gid += (long)gridDim.x * 256) {
        int c = (int)(gid & 63);
        float mu = stats[c] * inv;
        float var = stats[64 + c] * inv - mu * mu;
        float rstd = rsqrtf(var + BNEPS);
        float v = (ldv(xhat, gid) - mu) * rstd * g[c] + b[c];
        stv(base, gid, ldv(base, gid) + fmaxf(v, 0.0f));
    }
}

// one-shot: W0 (256x128) -> W0T bf16 [n=128][k=256]; W1 (128x64) -> W1T [64][128]
__global__ __launch_bounds__(256) void transpose_w_kernel(
    const float* __restrict__ W0, const float* __restrict__ W1,
    short* __restrict__ W0T, short* __restrict__ W1T)
{
    int id = blockIdx.x * 256 + threadIdx.x;
    if (id < 256 * 128) {
        int k = id >> 7, n = id & 127;
        W0T[n * 256 + k] = f2bs(W0[id]);
    }
    if (id < 128 * 64) {
        int k = id >> 6, n = id & 63;
        W1T[n * 128 + k] = f2bs(W1[id]);
    }
}

// ---------------------------------------------------------------------------
// MFMA MLP readout: out = relu(relu(feat@W0+b0)@W1+b1)@W2+b2,
// feat = [e, e[rev], h[src], h[dst]]. 64-edge tiles, 4 waves, bf16 MFMA
// 16x16x32. A[m=lane&15][k=quad*8+j], D[col=lane&15][row=quad*4+reg].
// ---------------------------------------------------------------------------
template<typename TE>
__global__ __launch_bounds__(256) void readout_mfma_kernel(
    const TE* __restrict__ e, const float* __restrict__ h,
    const int* __restrict__ src, const int* __restrict__ dst,
    const int* __restrict__ rev,
    const short* __restrict__ W0T, const short* __restrict__ W1T,
    const float* __restrict__ b0, const float* __restrict__ b1,
    const float* __restrict__ W2, const float* __restrict__ b2,
    float* __restrict__ out)
{
    __shared__ short feat[64 * 72];    // feat slice (also reused as x1 tile)
    __shared__ short wtile[128 * 72];  // W0T slice [128][72]; reused as W1T [64][136]
    __shared__ short x0t[64 * 136];    // x0 tile bf16 (A-operand of phase 2)
    __shared__ float smallb[322];      // b0[128] | b1[64] | W2[128] | b2[2]

    const int tid = threadIdx.x;
    const int wave = tid >> 6;
    const int lane = tid & 63;
    const int r = lane & 15;
    const int q = lane >> 4;

    if (tid < 128) smallb[tid] = b0[tid];
    if (tid < 64)  smallb[128 + tid] = b1[tid];
    if (tid < 128) smallb[192 + tid] = W2[tid];
    if (tid < 2)   smallb[320 + tid] = b2[tid];

    constexpr int NTILES = NEDGES / 64;   // 6250, exact
    for (int t = blockIdx.x; t < NTILES; t += gridDim.x) {
        const int rowBase = t * 64;
        float4_t acc0[8];
        #pragma unroll
        for (int i = 0; i < 8; ++i) acc0[i] = (float4_t)0.0f;

        for (int s = 0; s < 4; ++s) {
            __syncthreads();   // protects feat/wtile (prev slice / prev tile x1+W1)
            for (int i = tid; i < 512; i += 256) {     // 64 rows x 8 octets
                int row = i >> 3, oct = i & 7;
                int er = rowBase + row;
                short* d = feat + row * 72 + oct * 8;
                if (s == 0)      stage8(e + (long)er * 64 + oct * 8, d);
                else if (s == 1) stage8(e + (long)rev[er] * 64 + oct * 8, d);
                else if (s == 2) stage8(h + (long)src[er] * 64 + oct * 8, d);
                else             stage8(h + (long)dst[er] * 64 + oct * 8, d);
            }
            for (int i = tid; i < 1024; i += 256) {    // W0T slice: 128 n x 8 octets
                int n = i >> 3, oct = i & 7;
                *(short8_t*)(wtile + n * 72 + oct * 8) =
                    *(const short8_t*)(W0T + (long)n * 256 + s * 64 + oct * 8);
            }
            __syncthreads();
            #pragma unroll
            for (int kk = 0; kk < 2; ++kk) {
                short8_t a = *(const short8_t*)(feat + (wave * 16 + r) * 72 + kk * 32 + q * 8);
                #pragma unroll
                for (int nt = 0; nt < 8; ++nt) {
                    short8_t b = *(const short8_t*)(wtile + (nt * 16 + r) * 72 + kk * 32 + q * 8);
                    acc0[nt] = __builtin_amdgcn_mfma_f32_16x16x32_bf16(a, b, acc0[nt], 0, 0, 0);
                }
            }
        }
        // epilogue 1: x0 = relu(acc0 + b0) -> x0t (bf16); rows are wave-private
        #pragma unroll
        for (int nt = 0; nt < 8; ++nt) {
            int col = nt * 16 + r;
            #pragma unroll
            for (int i2 = 0; i2 < 4; ++i2) {
                int row = wave * 16 + q * 4 + i2;
                x0t[row * 136 + col] = f2bs(fmaxf(acc0[nt][i2] + smallb[col], 0.0f));
            }
        }
        __syncthreads();   // wtile slice-3 reads done; x0t visible
        for (int i = tid; i < 1024; i += 256) {        // W1T: 64 n x 16 octets
            int n = i >> 4, oct = i & 15;
            *(short8_t*)(wtile + n * 136 + oct * 8) =
                *(const short8_t*)(W1T + (long)n * 128 + oct * 8);
        }
        __syncthreads();
        // phase 2: x1 = relu(x0 @ W1 + b1), K=128
        float4_t acc1[4];
        #pragma unroll
        for (int i = 0; i < 4; ++i) acc1[i] = (float4_t)0.0f;
        #pragma unroll
        for (int kk = 0; kk < 4; ++kk) {
            short8_t a = *(const short8_t*)(x0t + (wave * 16 + r) * 136 + kk * 32 + q * 8);
            #pragma unroll
            for (int nt = 0; nt < 4; ++nt) {
                short8_t b = *(const short8_t*)(wtile + (nt * 16 + r) * 136 + kk * 32 + q * 8);
                acc1[nt] = __builtin_amdgcn_mfma_f32_16x16x32_bf16(a, b, acc1[nt], 0, 0, 0);
            }
        }
        // epilogue 2: x1 -> feat buffer (bf16, stride 72)
        #pragma unroll
        for (int nt = 0; nt < 4; ++nt) {
            int col = nt * 16 + r;
            #pragma unroll
            for (int i2 = 0; i2 < 4; ++i2) {
                int row = wave * 16 + q * 4 + i2;
                feat[row * 72 + col] = f2bs(fmaxf(acc1[nt][i2] + smallb[128 + col], 0.0f));
            }
        }
        __syncthreads();
        // phase 3: out = x1 @ W2 + b2   (64 rows x 2 classes)
        if (tid < 128) {
            int row = tid >> 1, cls = tid & 1;
            float a = smallb[320 + cls];
            #pragma unroll 8
            for (int k = 0; k < 64; ++k)
                a += bs2f(feat[row * 72 + k]) * smallb[192 + k * 2 + cls];
            out[(long)(rowBase + row) * 2 + cls] = a;
        }
    }
}

// ---------------------------------------------------------------------------
static inline int igrid(long total, int block, int cap) {
    long g = (total + block - 1) / block;
    return (int)(g < cap ? g : cap);
}

template<typename TE, typename TH>
static void run_net(void* const* d_in, float* f, TE* e, TH* ehat,
                    float* out, hipStream_t stream)
{
    const float* h_in   = (const float*)d_in[0];
    const float* e_in   = (const float*)d_in[1];
    const int*   src    = (const int*)d_in[2];
    const int*   dst    = (const int*)d_in[3];
    const int*   rev    = (const int*)d_in[4];
    const float* emb_h_w = (const float*)d_in[5];
    const float* emb_h_b = (const float*)d_in[6];
    const float* emb_e_w = (const float*)d_in[7];
    const float* emb_e_b = (const float*)d_in[8];
    const float* A_w = (const float*)d_in[9];  const float* A_b = (const float*)d_in[10];
    const float* B_w = (const float*)d_in[11]; const float* B_b = (const float*)d_in[12];
    const float* C_w = (const float*)d_in[13]; const float* C_b = (const float*)d_in[14];
    const float* D_w = (const float*)d_in[15]; const float* D_b = (const float*)d_in[16];
    const float* E_w = (const float*)d_in[17]; const float* E_b = (const float*)d_in[18];
    // F/G (19..22) and bn_u (27,28) are dead: u never reaches the output.
    const float* bn_h_g = (const float*)d_in[23]; const float* bn_h_b = (const float*)d_in[24];
    const float* bn_e_g = (const float*)d_in[25]; const float* bn_e_b = (const float*)d_in[26];
    const float* W0 = (const float*)d_in[29]; const float* b0 = (const float*)d_in[30];
    const float* W1 = (const float*)d_in[31]; const float* b1 = (const float*)d_in[32];
    const float* W2 = (const float*)d_in[33]; const float* b2 = (const float*)d_in[34];

    const size_t NH = (size_t)NNODES * DD;
    float* h    = f;
    float* Ah   = f + NH;
    float* Bh   = f + 2 * NH;
    float* Dh   = f + 3 * NH;      // hhat aliases Dh (Dh dead after C-linear)
    float* Eh   = f + 4 * NH;
    float* stats= f + 7 * NH;      // 256 floats
    float* hhat = Dh;
    // CSR arrays live in the old num region (f+5NH, 6.4 MB — need 1.8 MB)
    int* rowptr = (int*)(f + 5 * NH);           // 25001 ints
    int* cursor = rowptr + NNODES + 1;          // 25000 ints
    int* eid    = cursor + NNODES;              // 400000 ints
    // W0T/W1T (bf16) in the old den region (f+6NH), used only after layers
    short* W0T = (short*)(f + 6 * NH);
    short* W1T = W0T + 256 * 128;

    const int GE = 4096;
    const int GN = 1563;
    const int EW = igrid((long)NEDGES * DD, 256, 16384);
    const int NW = igrid((long)NNODES * DD, 256, 16384);
    const int GEDGE = (NEDGES + 255) / 256;     // 1563

    // CSR build (once per call; graph static within the call)
    hipMemsetAsync(rowptr, 0, (2 * NNODES + 1) * sizeof(int), stream);  // rowptr+cursor
    deg_hist_kernel<<<GEDGE, 256, 0, stream>>>(dst, rowptr, NEDGES);
    scan_kernel<<<1, 1024, 0, stream>>>(rowptr, NNODES + 1);
    scatter_kernel<<<GEDGE, 256, 0, stream>>>(dst, rowptr, cursor, eid, NEDGES);

    // embeddings
    linear_kernel<64, 64, 4, false, float, float><<<GN, 256, 0, stream>>>(
        h_in, emb_h_w, emb_h_b, h, nullptr, nullptr, nullptr, nullptr, NNODES);
    linear_kernel<16, 64, 4, false, float, TE><<<GE, 256, 0, stream>>>(
        e_in, emb_e_w, emb_e_b, e, nullptr, nullptr, nullptr, nullptr, NEDGES);

    for (int l = 0; l < 4; ++l) {
        const float* Awl = A_w + (size_t)l * DD * DD; const float* Abl = A_b + l * DD;
        const float* Bwl = B_w + (size_t)l * DD * DD; const float* Bbl = B_b + l * DD;
        const float* Cwl = C_w + (size_t)l * DD * DD; const float* Cbl = C_b + l * DD;
        const float* Dwl = D_w + (size_t)l * DD * DD; const float* Dbl = D_b + l * DD;
        const float* Ewl = E_w + (size_t)l * DD * DD; const float* Ebl = E_b + l * DD;

        linear_kernel<64, 64, 4, false, float, float><<<GN, 256, 0, stream>>>(
            h, Awl, Abl, Ah, nullptr, nullptr, nullptr, nullptr, NNODES);
        linear_kernel<64, 64, 4, false, float, float><<<GN, 256, 0, stream>>>(
            h, Bwl, Bbl, Bh, nullptr, nullptr, nullptr, nullptr, NNODES);
        linear_kernel<64, 64, 4, false, float, float><<<GN, 256, 0, stream>>>(
            h, Dwl, Dbl, Dh, nullptr, nullptr, nullptr, nullptr, NNODES);
        linear_kernel<64, 64, 4, false, float, float><<<GN, 256, 0, stream>>>(
            h, Ewl, Ebl, Eh, nullptr, nullptr, nullptr, nullptr, NNODES);

        // e_hat = e@C + Cb + Dh[src] + Eh[dst]   (gather fused into epilogue)
        linear_kernel<64, 64, 4, true, TE, TH><<<GE, 256, 0, stream>>>(
            e, Cwl, Cbl, ehat, Dh, src, Eh, dst, NEDGES);

        // CSR aggregation, fused hhat (no float atomics, no num/den buffers)
        agg_csr_kernel<TH><<<NNODES / 4, 256, 0, stream>>>(
            ehat, Bh, src, rowptr, eid, Ah, hhat);

        // BN (1024-block stats — small atomic tails) + apply + relu + residual
        hipMemsetAsync(stats, 0, 256 * sizeof(float), stream);
        bn_stats_kernel<float><<<1024, 256, 0, stream>>>(hhat, stats, NNODES);
        bn_apply_kernel<float, float><<<NW, 256, 0, stream>>>(
            h, hhat, stats, bn_h_g + l * DD, bn_h_b + l * DD, NNODES);
        bn_stats_kernel<TH><<<1024, 256, 0, stream>>>(ehat, stats + 128, NEDGES);
        bn_apply_kernel<TE, TH><<<EW, 256, 0, stream>>>(
            e, ehat, stats + 128, bn_e_g + l * DD, bn_e_b + l * DD, NEDGES);
    }

    // MFMA readout (W transposed to bf16 scratch)
    transpose_w_kernel<<<128, 256, 0, stream>>>(W0, W1, W0T, W1T);
    readout_mfma_kernel<TE><<<2048, 256, 0, stream>>>(e, h, src, dst, rev,
                                                      W0T, W1T, b0, b1, W2, b2, out);
}

extern "C" void kernel_launch(void* const* d_in, const int* in_sizes, int n_in,
                              void* d_out, int out_size, void* d_ws, size_t ws_size,
                              hipStream_t stream)
{
    const size_t NH = (size_t)NNODES * DD;       // 1.6M floats
    const size_t NE = (size_t)NEDGES * DD;       // 25.6M elems
    const size_t baseB = (7 * NH + 256) * sizeof(float);   // 44.8 MB node region

    char* base = (char*)d_ws;
    char* edge = base + baseB;
    float* out = (float*)d_out;

    const size_t needA = baseB + NE * 4 * 2;          // fp32 e + fp32 ehat
    const size_t needB = baseB + NE * 4 + NE * 2;     // fp32 e + bf16 ehat
    const size_t needC = baseB + NE * 2 * 2;          // bf16 e + bf16 ehat

    if (ws_size >= needA) {
        run_net<float, float>(d_in, (float*)base, (float*)edge,
                              (float*)(edge + NE * 4), out, stream);
    } else if (ws_size >= needB) {
        run_net<float, __hip_bfloat16>(d_in, (float*)base, (float*)edge,
                                       (__hip_bfloat16*)(edge + NE * 4), out, stream);
    } else if (ws_size >= needC) {
        run_net<__hip_bfloat16, __hip_bfloat16>(d_in, (float*)base, (__hip_bfloat16*)edge,
                                                (__hip_bfloat16*)(edge + NE * 2), out, stream);
    } else {
        // diagnostic fallback: workspace too small — emit zeros, don't fault
        hipMemsetAsync(d_out, 0, (size_t)out_size * sizeof(float), stream);
    }
}

// Round 6
// 1377.573 us; speedup vs baseline: 2.9286x; 1.3567x over previous
//
#include <hip/hip_runtime.h>
#include <hip/hip_bf16.h>

constexpr int NNODES = 25000;
constexpr int NEDGES = 400000;
constexpr int DD = 64;
constexpr float BNEPS = 1e-5f;
constexpr float AGGEPS = 1e-6f;

typedef __attribute__((ext_vector_type(8))) short short8_t;
typedef __attribute__((ext_vector_type(4))) short short4_t;
typedef __attribute__((ext_vector_type(4))) float float4_t;

// storage-type helpers (compute is always fp32)
__device__ __forceinline__ float ldv(const float* p, long i) { return p[i]; }
__device__ __forceinline__ float ldv(const __hip_bfloat16* p, long i) { return __bfloat162float(p[i]); }
__device__ __forceinline__ void stv(float* p, long i, float v) { p[i] = v; }
__device__ __forceinline__ void stv(__hip_bfloat16* p, long i, float v) { p[i] = __float2bfloat16(v); }

// float -> bf16 bits, RNE (finite inputs only)
__device__ __forceinline__ short f2bs(float f) {
    union { float f; unsigned u; } x; x.f = f;
    unsigned r = x.u + 0x7FFFu + ((x.u >> 16) & 1u);
    return (short)(r >> 16);
}
__device__ __forceinline__ float bs2f(short s) {
    union { unsigned u; float f; } x; x.u = ((unsigned)(unsigned short)s) << 16; return x.f;
}

// vector load/store of 4 elems (fp32: 16B; bf16: 8B)
__device__ __forceinline__ float4_t ldv4(const float* p, long i) {
    return *(const float4_t*)(p + i);
}
__device__ __forceinline__ float4_t ldv4(const __hip_bfloat16* p, long i) {
    short4_t s = *(const short4_t*)(p + i);
    float4_t r;
    #pragma unroll
    for (int c = 0; c < 4; ++c) r[c] = bs2f(s[c]);
    return r;
}
__device__ __forceinline__ void stv4(float* p, long i, float4_t v) {
    *(float4_t*)(p + i) = v;
}
__device__ __forceinline__ void stv4(__hip_bfloat16* p, long i, float4_t v) {
    short4_t s;
    #pragma unroll
    for (int c = 0; c < 4; ++c) s[c] = f2bs(v[c]);
    *(short4_t*)(p + i) = s;
}

// stage 8 consecutive elems from global into bf16 LDS (16B-aligned both sides)
__device__ __forceinline__ void stage8(const __hip_bfloat16* s, short* d) {
    *(short8_t*)d = *(const short8_t*)s;
}
__device__ __forceinline__ void stage8(const float* s, short* d) {
    float4_t a = *(const float4_t*)s;
    float4_t b = *(const float4_t*)(s + 4);
    short8_t v;
    v[0] = f2bs(a[0]); v[1] = f2bs(a[1]); v[2] = f2bs(a[2]); v[3] = f2bs(a[3]);
    v[4] = f2bs(b[0]); v[5] = f2bs(b[1]); v[6] = f2bs(b[2]); v[7] = f2bs(b[3]);
    *(short8_t*)d = v;
}

// ---------------------------------------------------------------------------
// Generic LDS-tiled linear (embeddings): Y[r][n] = b[n] + sum_k X[r][k]W[k][n]
// ---------------------------------------------------------------------------
template<int K, int N, int JR, typename TX, typename TY>
__global__ __launch_bounds__(256) void linear_kernel(
    const TX* __restrict__ X, const float* __restrict__ W,
    const float* __restrict__ Bb, TY* __restrict__ Y, int rows)
{
    constexpr int SLOTS = 256 / N;
    constexpr int RPG = SLOTS * JR;
    __shared__ float wl[K * N];
    __shared__ float bl[N];
    __shared__ float xl[RPG * K];

    const int tid = threadIdx.x;
    for (int i = tid; i < K * N; i += 256) wl[i] = W[i];
    if (tid < N) bl[tid] = Bb[tid];

    const int col = tid % N;
    const int slot = tid / N;

    const int ngroups = (rows + RPG - 1) / RPG;
    for (int g = blockIdx.x; g < ngroups; g += gridDim.x) {
        const int rowBase = g * RPG;
        __syncthreads();
        for (int i = tid; i < RPG * K; i += 256) {
            int r = i / K, k = i - r * K;
            int row = rowBase + r;
            xl[i] = (row < rows) ? ldv(X, (long)row * K + k) : 0.0f;
        }
        __syncthreads();
        float acc[JR];
        #pragma unroll
        for (int j = 0; j < JR; ++j) acc[j] = bl[col];
        #pragma unroll 4
        for (int k = 0; k < K; ++k) {
            float w = wl[k * N + col];
            #pragma unroll
            for (int j = 0; j < JR; ++j)
                acc[j] += xl[(slot * JR + j) * K + k] * w;
        }
        #pragma unroll
        for (int j = 0; j < JR; ++j) {
            int row = rowBase + slot * JR + j;
            if (row < rows) stv(Y, (long)row * N + col, acc[j]);
        }
    }
}

// ---------------------------------------------------------------------------
// Dual linear (node path): stage X once, two weight sets, two outputs.
// ---------------------------------------------------------------------------
template<int K, int N, int JR>
__global__ __launch_bounds__(256) void linear2_kernel(
    const float* __restrict__ X,
    const float* __restrict__ Wa, const float* __restrict__ Ba, float* __restrict__ Ya,
    const float* __restrict__ Wb, const float* __restrict__ Bb, float* __restrict__ Yb,
    int rows)
{
    constexpr int SLOTS = 256 / N;
    constexpr int RPG = SLOTS * JR;
    __shared__ float wa[K * N], wb[K * N];
    __shared__ float bla[N], blb[N];
    __shared__ float xl[RPG * K];

    const int tid = threadIdx.x;
    for (int i = tid; i < K * N; i += 256) { wa[i] = Wa[i]; wb[i] = Wb[i]; }
    if (tid < N) { bla[tid] = Ba[tid]; blb[tid] = Bb[tid]; }

    const int col = tid % N;
    const int slot = tid / N;

    const int ngroups = (rows + RPG - 1) / RPG;
    for (int g = blockIdx.x; g < ngroups; g += gridDim.x) {
        const int rowBase = g * RPG;
        __syncthreads();
        for (int i = tid; i < RPG * K / 4; i += 256) {
            int r = (i * 4) / K, k0 = (i * 4) % K;
            int row = rowBase + r;
            float4_t v = (float4_t)0.0f;
            if (row < rows) v = ldv4(X, (long)row * K + k0);
            *(float4_t*)(xl + r * K + k0) = v;
        }
        __syncthreads();
        float aa[JR], ab[JR];
        #pragma unroll
        for (int j = 0; j < JR; ++j) { aa[j] = bla[col]; ab[j] = blb[col]; }
        #pragma unroll 2
        for (int k = 0; k < K; ++k) {
            float w1 = wa[k * N + col], w2 = wb[k * N + col];
            #pragma unroll
            for (int j = 0; j < JR; ++j) {
                float x = xl[(slot * JR + j) * K + k];
                aa[j] += x * w1; ab[j] += x * w2;
            }
        }
        #pragma unroll
        for (int j = 0; j < JR; ++j) {
            int row = rowBase + slot * JR + j;
            if (row < rows) {
                Ya[(long)row * N + col] = aa[j];
                Yb[(long)row * N + col] = ab[j];
            }
        }
    }
}

// ---------------------------------------------------------------------------
// Edge update (the per-layer workhorse):
//   if BNIN: e_new = e + relu(bn(ehat_prev; stats_prev,g,b))  [in-place, also
//            feeds the staged matmul input]
//   ehat_new = e_new @ Cw + Cb + Dh[src] + Eh[dst]            [in-place over
//            ehat_prev; block owns its rows]
//   block-level BN partial sums of ehat_new -> partial[block][128]
// ---------------------------------------------------------------------------
template<int JR, bool BNIN, typename TE, typename TH>
__global__ __launch_bounds__(256) void edge_update_kernel(
    TE* __restrict__ e, TH* __restrict__ ehat,
    const float* __restrict__ W, const float* __restrict__ Bb,
    const float* __restrict__ Dh, const int* __restrict__ src,
    const float* __restrict__ Eh, const int* __restrict__ dst,
    const float* __restrict__ stats_prev, const float* __restrict__ gprev,
    const float* __restrict__ bprev,
    float* __restrict__ partial, int rows)
{
    constexpr int RPG = 4 * JR;
    __shared__ float wl[64 * 64];
    __shared__ float bl[64];
    __shared__ float scale[64], shift[64];
    __shared__ float xl[RPG * 64];
    __shared__ float sb[256], sb2[256];

    const int tid = threadIdx.x;
    for (int i = tid; i < 4096; i += 256) wl[i] = W[i];
    if (tid < 64) {
        bl[tid] = Bb[tid];
        if (BNIN) {
            float inv = 1.0f / (float)NEDGES;
            float mu = stats_prev[tid] * inv;
            float var = stats_prev[64 + tid] * inv - mu * mu;
            float rs = rsqrtf(var + BNEPS);
            float sc = rs * gprev[tid];
            scale[tid] = sc;
            shift[tid] = bprev[tid] - mu * sc;
        }
    }
    const int col = tid & 63;
    const int slot = tid >> 6;
    float ls = 0.0f, ls2 = 0.0f;

    const int ngroups = (rows + RPG - 1) / RPG;
    for (int g = blockIdx.x; g < ngroups; g += gridDim.x) {
        const int rowBase = g * RPG;
        __syncthreads();
        for (int i = tid; i < RPG * 16; i += 256) {   // RPG*64/4 float4s
            int r = i >> 4, k0 = (i & 15) * 4;
            int row = rowBase + r;
            float4_t ev = (float4_t)0.0f;
            if (row < rows) {
                long idx = (long)row * 64 + k0;
                ev = ldv4(e, idx);
                if (BNIN) {
                    float4_t hv = ldv4(ehat, idx);
                    #pragma unroll
                    for (int c = 0; c < 4; ++c)
                        ev[c] += fmaxf(hv[c] * scale[k0 + c] + shift[k0 + c], 0.0f);
                    stv4(e, idx, ev);   // residual+BN materialized for later use
                }
            }
            *(float4_t*)(xl + r * 64 + k0) = ev;
        }
        __syncthreads();
        float acc[JR];
        #pragma unroll
        for (int j = 0; j < JR; ++j) acc[j] = bl[col];
        #pragma unroll 4
        for (int k = 0; k < 64; ++k) {
            float w = wl[k * 64 + col];
            #pragma unroll
            for (int j = 0; j < JR; ++j)
                acc[j] += xl[(slot * JR + j) * 64 + k] * w;
        }
        #pragma unroll
        for (int j = 0; j < JR; ++j) {
            int row = rowBase + slot * JR + j;
            if (row < rows) {
                float v = acc[j] + Dh[(long)src[row] * 64 + col]
                                 + Eh[(long)dst[row] * 64 + col];
                stv(ehat, (long)row * 64 + col, v);
                ls += v; ls2 += v * v;
            }
        }
    }
    // per-block BN partials (col is thread-invariant)
    __syncthreads();
    sb[tid] = ls; sb2[tid] = ls2;
    __syncthreads();
    if (tid < 64) {
        float s  = sb[tid] + sb[tid + 64] + sb[tid + 128] + sb[tid + 192];
        float s2 = sb2[tid] + sb2[tid + 64] + sb2[tid + 128] + sb2[tid + 192];
        partial[(long)blockIdx.x * 128 + tid] = s;
        partial[(long)blockIdx.x * 128 + 64 + tid] = s2;
    }
}

// ---------------------------------------------------------------------------
// CSR build (graph static within one call): histogram -> scan -> scatter
// ---------------------------------------------------------------------------
__global__ __launch_bounds__(256) void deg_hist_kernel(
    const int* __restrict__ dst, int* __restrict__ rowptr, int rows)
{
    int e = blockIdx.x * 256 + threadIdx.x;
    if (e < rows) atomicAdd(&rowptr[dst[e] + 1], 1);
}

__global__ __launch_bounds__(1024) void scan_kernel(int* __restrict__ data, int n)
{
    __shared__ int buf[1024];
    __shared__ int carry;
    if (threadIdx.x == 0) carry = 0;
    __syncthreads();
    for (int base = 0; base < n; base += 1024) {
        int i = base + threadIdx.x;
        int v = (i < n) ? data[i] : 0;
        buf[threadIdx.x] = v;
        __syncthreads();
        for (int off = 1; off < 1024; off <<= 1) {
            int t = (threadIdx.x >= off) ? buf[threadIdx.x - off] : 0;
            __syncthreads();
            buf[threadIdx.x] += t;
            __syncthreads();
        }
        if (i < n) data[i] = buf[threadIdx.x] + carry;
        __syncthreads();
        if (threadIdx.x == 0) carry += buf[1023];
        __syncthreads();
    }
}

__global__ __launch_bounds__(256) void scatter_kernel(
    const int* __restrict__ dst, const int* __restrict__ rowptr,
    int* __restrict__ cursor, int* __restrict__ eid, int rows)
{
    int e = blockIdx.x * 256 + threadIdx.x;
    if (e < rows) {
        int d = dst[e];
        int pos = atomicAdd(&cursor[d], 1);
        eid[rowptr[d] + pos] = e;
    }
}

// ---------------------------------------------------------------------------
// CSR aggregation, float4 lanes, 4 edges per wave-iteration, no atomics.
// hhat[n] = Ah[n] + sum(sig*Bh[src]) / (sum(sig)+eps); fused hhat BN partials.
// ---------------------------------------------------------------------------
template<typename TH>
__global__ __launch_bounds__(256) void agg_csr_kernel(
    const TH* __restrict__ ehat, const float* __restrict__ Bh,
    const int* __restrict__ src,
    const int* __restrict__ rowptr, const int* __restrict__ eid,
    const float* __restrict__ Ah, float* __restrict__ hhat,
    float* __restrict__ partial)
{
    __shared__ float ps[64], ps2[64];
    const int tid = threadIdx.x;
    if (tid < 64) { ps[tid] = 0.0f; ps2[tid] = 0.0f; }
    __syncthreads();

    const int node = blockIdx.x * 4 + (tid >> 6);
    const int lane = tid & 63;
    const int sub = lane >> 4;          // 0..3: which edge of the quad
    const int c4 = (lane & 15) * 4;     // 4 columns per lane
    const int s0 = rowptr[node], s1 = rowptr[node + 1];

    float4_t den = (float4_t)0.0f, num = (float4_t)0.0f;
    for (int p = s0 + sub; p < s1; p += 4) {
        int e = eid[p];
        float4_t v = ldv4(ehat, (long)e * 64 + c4);
        float4_t bh = ldv4(Bh, (long)src[e] * 64 + c4);
        #pragma unroll
        for (int c = 0; c < 4; ++c) {
            float s = 1.0f / (1.0f + __expf(-v[c]));
            den[c] += s;
            num[c] += s * bh[c];
        }
    }
    // reduce the 4 sub-groups (lanes differing in bits 4,5)
    #pragma unroll
    for (int m = 16; m <= 32; m <<= 1) {
        #pragma unroll
        for (int c = 0; c < 4; ++c) {
            den[c] += __shfl_xor(den[c], m, 64);
            num[c] += __shfl_xor(num[c], m, 64);
        }
    }
    if (sub == 0) {
        float4_t av = ldv4(Ah, (long)node * 64 + c4);
        float4_t hh;
        #pragma unroll
        for (int c = 0; c < 4; ++c) {
            hh[c] = av[c] + num[c] / (den[c] + AGGEPS);
            atomicAdd(&ps[c4 + c], hh[c]);
            atomicAdd(&ps2[c4 + c], hh[c] * hh[c]);
        }
        stv4(hhat, (long)node * 64 + c4, hh);
    }
    __syncthreads();
    if (tid < 64) {
        partial[(long)blockIdx.x * 128 + tid] = ps[tid];
        partial[(long)blockIdx.x * 128 + 64 + tid] = ps2[tid];
    }
}

// stats[c] = sum over blocks of partial[b][c]; grid = 128
__global__ __launch_bounds__(256) void reduce_stats_kernel(
    const float* __restrict__ partial, int nblk, float* __restrict__ stats)
{
    __shared__ float sb[256];
    int tid = threadIdx.x;
    float s = 0.0f;
    for (int i = tid; i < nblk; i += 256) s += partial[(long)i * 128 + blockIdx.x];
    sb[tid] = s;
    __syncthreads();
    for (int off = 128; off > 0; off >>= 1) {
        if (tid < off) sb[tid] += sb[tid + off];
        __syncthreads();
    }
    if (tid == 0) stats[blockIdx.x] = sb[0];
}

// base += relu((xhat-mu)*rstd*g + b), float4 per thread
template<typename TB, typename TX>
__global__ __launch_bounds__(256) void bn_apply4_kernel(
    TB* __restrict__ base, const TX* __restrict__ xhat,
    const float* __restrict__ stats, const float* __restrict__ g,
    const float* __restrict__ b, int rows)
{
    long total4 = (long)rows * 16;
    float inv = 1.0f / (float)rows;
    for (long q = (long)blockIdx.x * 256 + threadIdx.x; q < total4;
         q += (long)gridDim.x * 256) {
        long idx = q * 4;
        int c = (int)(idx & 63);
        float4_t x = ldv4(xhat, idx);
        float4_t bs = ldv4(base, idx);
        #pragma unroll
        for (int j = 0; j < 4; ++j) {
            float mu = stats[c + j] * inv;
            float var = stats[64 + c + j] * inv - mu * mu;
            float rs = rsqrtf(var + BNEPS);
            float v = (x[j] - mu) * rs * g[c + j] + b[c + j];
            bs[j] += fmaxf(v, 0.0f);
        }
        stv4(base, idx, bs);
    }
}

// one-shot: W0 (256x128) -> W0T bf16 [n=128][k=256]; W1 (128x64) -> W1T [64][128]
__global__ __launch_bounds__(256) void transpose_w_kernel(
    const float* __restrict__ W0, const float* __restrict__ W1,
    short* __restrict__ W0T, short* __restrict__ W1T)
{
    int id = blockIdx.x * 256 + threadIdx.x;
    if (id < 256 * 128) {
        int k = id >> 7, n = id & 127;
        W0T[n * 256 + k] = f2bs(W0[id]);
    }
    if (id < 128 * 64) {
        int k = id >> 6, n = id & 63;
        W1T[n * 128 + k] = f2bs(W1[id]);
    }
}

// ---------------------------------------------------------------------------
// MFMA MLP readout (unchanged from R5): 64-edge tiles, bf16 16x16x32.
// ---------------------------------------------------------------------------
template<typename TE>
__global__ __launch_bounds__(256) void readout_mfma_kernel(
    const TE* __restrict__ e, const float* __restrict__ h,
    const int* __restrict__ src, const int* __restrict__ dst,
    const int* __restrict__ rev,
    const short* __restrict__ W0T, const short* __restrict__ W1T,
    const float* __restrict__ b0, const float* __restrict__ b1,
    const float* __restrict__ W2, const float* __restrict__ b2,
    float* __restrict__ out)
{
    __shared__ short feat[64 * 72];
    __shared__ short wtile[128 * 72];
    __shared__ short x0t[64 * 136];
    __shared__ float smallb[322];

    const int tid = threadIdx.x;
    const int wave = tid >> 6;
    const int lane = tid & 63;
    const int r = lane & 15;
    const int q = lane >> 4;

    if (tid < 128) smallb[tid] = b0[tid];
    if (tid < 64)  smallb[128 + tid] = b1[tid];
    if (tid < 128) smallb[192 + tid] = W2[tid];
    if (tid < 2)   smallb[320 + tid] = b2[tid];

    constexpr int NTILES = NEDGES / 64;
    for (int t = blockIdx.x; t < NTILES; t += gridDim.x) {
        const int rowBase = t * 64;
        float4_t acc0[8];
        #pragma unroll
        for (int i = 0; i < 8; ++i) acc0[i] = (float4_t)0.0f;

        for (int s = 0; s < 4; ++s) {
            __syncthreads();
            for (int i = tid; i < 512; i += 256) {
                int row = i >> 3, oct = i & 7;
                int er = rowBase + row;
                short* d = feat + row * 72 + oct * 8;
                if (s == 0)      stage8(e + (long)er * 64 + oct * 8, d);
                else if (s == 1) stage8(e + (long)rev[er] * 64 + oct * 8, d);
                else if (s == 2) stage8(h + (long)src[er] * 64 + oct * 8, d);
                else             stage8(h + (long)dst[er] * 64 + oct * 8, d);
            }
            for (int i = tid; i < 1024; i += 256) {
                int n = i >> 3, oct = i & 7;
                *(short8_t*)(wtile + n * 72 + oct * 8) =
                    *(const short8_t*)(W0T + (long)n * 256 + s * 64 + oct * 8);
            }
            __syncthreads();
            #pragma unroll
            for (int kk = 0; kk < 2; ++kk) {
                short8_t a = *(const short8_t*)(feat + (wave * 16 + r) * 72 + kk * 32 + q * 8);
                #pragma unroll
                for (int nt = 0; nt < 8; ++nt) {
                    short8_t b = *(const short8_t*)(wtile + (nt * 16 + r) * 72 + kk * 32 + q * 8);
                    acc0[nt] = __builtin_amdgcn_mfma_f32_16x16x32_bf16(a, b, acc0[nt], 0, 0, 0);
                }
            }
        }
        #pragma unroll
        for (int nt = 0; nt < 8; ++nt) {
            int col = nt * 16 + r;
            #pragma unroll
            for (int i2 = 0; i2 < 4; ++i2) {
                int row = wave * 16 + q * 4 + i2;
                x0t[row * 136 + col] = f2bs(fmaxf(acc0[nt][i2] + smallb[col], 0.0f));
            }
        }
        __syncthreads();
        for (int i = tid; i < 1024; i += 256) {
            int n = i >> 4, oct = i & 15;
            *(short8_t*)(wtile + n * 136 + oct * 8) =
                *(const short8_t*)(W1T + (long)n * 128 + oct * 8);
        }
        __syncthreads();
        float4_t acc1[4];
        #pragma unroll
        for (int i = 0; i < 4; ++i) acc1[i] = (float4_t)0.0f;
        #pragma unroll
        for (int kk = 0; kk < 4; ++kk) {
            short8_t a = *(const short8_t*)(x0t + (wave * 16 + r) * 136 + kk * 32 + q * 8);
            #pragma unroll
            for (int nt = 0; nt < 4; ++nt) {
                short8_t b = *(const short8_t*)(wtile + (nt * 16 + r) * 136 + kk * 32 + q * 8);
                acc1[nt] = __builtin_amdgcn_mfma_f32_16x16x32_bf16(a, b, acc1[nt], 0, 0, 0);
            }
        }
        #pragma unroll
        for (int nt = 0; nt < 4; ++nt) {
            int col = nt * 16 + r;
            #pragma unroll
            for (int i2 = 0; i2 < 4; ++i2) {
                int row = wave * 16 + q * 4 + i2;
                feat[row * 72 + col] = f2bs(fmaxf(acc1[nt][i2] + smallb[128 + col], 0.0f));
            }
        }
        __syncthreads();
        if (tid < 128) {
            int row = tid >> 1, cls = tid & 1;
            float a = smallb[320 + cls];
            #pragma unroll 8
            for (int k = 0; k < 64; ++k)
                a += bs2f(feat[row * 72 + k]) * smallb[192 + k * 2 + cls];
            out[(long)(rowBase + row) * 2 + cls] = a;
        }
    }
}

// ---------------------------------------------------------------------------
static inline int igrid(long total, int block, int cap) {
    long g = (total + block - 1) / block;
    return (int)(g < cap ? g : cap);
}

constexpr int GE_EDGE = 4096;    // edge_update grid (partial_e rows)
constexpr int GA_AGG  = NNODES / 4;  // 6250 (partial_h rows)

template<typename TE, typename TH>
static void run_net(void* const* d_in, float* f, TE* e, TH* ehat,
                    float* out, hipStream_t stream)
{
    const float* h_in   = (const float*)d_in[0];
    const float* e_in   = (const float*)d_in[1];
    const int*   src    = (const int*)d_in[2];
    const int*   dst    = (const int*)d_in[3];
    const int*   rev    = (const int*)d_in[4];
    const float* emb_h_w = (const float*)d_in[5];
    const float* emb_h_b = (const float*)d_in[6];
    const float* emb_e_w = (const float*)d_in[7];
    const float* emb_e_b = (const float*)d_in[8];
    const float* A_w = (const float*)d_in[9];  const float* A_b = (const float*)d_in[10];
    const float* B_w = (const float*)d_in[11]; const float* B_b = (const float*)d_in[12];
    const float* C_w = (const float*)d_in[13]; const float* C_b = (const float*)d_in[14];
    const float* D_w = (const float*)d_in[15]; const float* D_b = (const float*)d_in[16];
    const float* E_w = (const float*)d_in[17]; const float* E_b = (const float*)d_in[18];
    // F/G (19..22) and bn_u (27,28) are dead: u never reaches the output.
    const float* bn_h_g = (const float*)d_in[23]; const float* bn_h_b = (const float*)d_in[24];
    const float* bn_e_g = (const float*)d_in[25]; const float* bn_e_b = (const float*)d_in[26];
    const float* W0 = (const float*)d_in[29]; const float* b0 = (const float*)d_in[30];
    const float* W1 = (const float*)d_in[31]; const float* b1 = (const float*)d_in[32];
    const float* W2 = (const float*)d_in[33]; const float* b2 = (const float*)d_in[34];

    const size_t NH = (size_t)NNODES * DD;
    float* h    = f;
    float* Ah   = f + NH;
    float* Bh   = f + 2 * NH;
    float* Dh   = f + 3 * NH;      // hhat aliases Dh (Dh dead after edge_update)
    float* Eh   = f + 4 * NH;
    float* hhat = Dh;
    float* stats_h  = f + 5 * NH;           // 128
    float* stats_e  = stats_h + 128;        // 128
    float* partial_e = f + 5 * NH + 512;    // 4096*128
    float* partial_h = partial_e + (size_t)GE_EDGE * 128;   // 6250*128
    int* rowptr = (int*)(partial_h + (size_t)GA_AGG * 128); // 25001
    int* cursor = rowptr + NNODES + 1;      // 25000
    int* eid    = cursor + NNODES;          // 400000
    short* W0T  = (short*)(eid + NEDGES);
    short* W1T  = W0T + 256 * 128;

    const int GN = 1563;
    const int GEDGE = (NEDGES + 255) / 256;

    // CSR build (once per call)
    hipMemsetAsync(rowptr, 0, (2 * NNODES + 1) * sizeof(int), stream);
    deg_hist_kernel<<<GEDGE, 256, 0, stream>>>(dst, rowptr, NEDGES);
    scan_kernel<<<1, 1024, 0, stream>>>(rowptr, NNODES + 1);
    scatter_kernel<<<GEDGE, 256, 0, stream>>>(dst, rowptr, cursor, eid, NEDGES);

    // embeddings
    linear_kernel<64, 64, 4, float, float><<<GN, 256, 0, stream>>>(
        h_in, emb_h_w, emb_h_b, h, NNODES);
    linear_kernel<16, 64, 4, float, TE><<<4096, 256, 0, stream>>>(
        e_in, emb_e_w, emb_e_b, e, NEDGES);

    for (int l = 0; l < 4; ++l) {
        const size_t o = (size_t)l * DD * DD;
        // node linears, batched 2x
        linear2_kernel<64, 64, 4><<<GN, 256, 0, stream>>>(
            h, A_w + o, A_b + l * DD, Ah, B_w + o, B_b + l * DD, Bh, NNODES);
        linear2_kernel<64, 64, 4><<<GN, 256, 0, stream>>>(
            h, D_w + o, D_b + l * DD, Dh, E_w + o, E_b + l * DD, Eh, NNODES);

        // edge update: (BN_e of prev layer fused in) + C-matmul + gathers + stats
        if (l == 0)
            edge_update_kernel<8, false, TE, TH><<<GE_EDGE, 256, 0, stream>>>(
                e, ehat, C_w + o, C_b + l * DD, Dh, src, Eh, dst,
                nullptr, nullptr, nullptr, partial_e, NEDGES);
        else
            edge_update_kernel<8, true, TE, TH><<<GE_EDGE, 256, 0, stream>>>(
                e, ehat, C_w + o, C_b + l * DD, Dh, src, Eh, dst,
                stats_e, bn_e_g + (l - 1) * DD, bn_e_b + (l - 1) * DD,
                partial_e, NEDGES);
        reduce_stats_kernel<<<128, 256, 0, stream>>>(partial_e, GE_EDGE, stats_e);

        // CSR aggregation + fused hhat + hhat BN partials
        agg_csr_kernel<TH><<<GA_AGG, 256, 0, stream>>>(
            ehat, Bh, src, rowptr, eid, Ah, hhat, partial_h);
        reduce_stats_kernel<<<128, 256, 0, stream>>>(partial_h, GA_AGG, stats_h);

        // h += relu(bn(hhat))
        bn_apply4_kernel<float, float><<<igrid((long)NNODES * 16, 256, 8192), 256, 0, stream>>>(
            h, hhat, stats_h, bn_h_g + l * DD, bn_h_b + l * DD, NNODES);
    }
    // final e update (layer-3 BN never got folded into a next layer)
    bn_apply4_kernel<TE, TH><<<igrid((long)NEDGES * 16, 256, 8192), 256, 0, stream>>>(
        e, ehat, stats_e, bn_e_g + 3 * DD, bn_e_b + 3 * DD, NEDGES);

    // MFMA readout
    transpose_w_kernel<<<128, 256, 0, stream>>>(W0, W1, W0T, W1T);
    readout_mfma_kernel<TE><<<2048, 256, 0, stream>>>(e, h, src, dst, rev,
                                                      W0T, W1T, b0, b1, W2, b2, out);
}

extern "C" void kernel_launch(void* const* d_in, const int* in_sizes, int n_in,
                              void* d_out, int out_size, void* d_ws, size_t ws_size,
                              hipStream_t stream)
{
    const size_t NH = (size_t)NNODES * DD;       // 1.6M floats
    const size_t NE = (size_t)NEDGES * DD;       // 25.6M elems
    const size_t baseB = (7 * NH + 256) * sizeof(float);   // 44.8 MB node region
    // internal layout uses ~39.4 MB of baseB: 5*NH + 512 + partials(4096+6250)*128
    // + CSR ints (450001) + W0T/W1T shorts

    char* base = (char*)d_ws;
    char* edge = base + baseB;
    float* out = (float*)d_out;

    const size_t needA = baseB + NE * 4 * 2;          // fp32 e + fp32 ehat
    const size_t needB = baseB + NE * 4 + NE * 2;     // fp32 e + bf16 ehat
    const size_t needC = baseB + NE * 2 * 2;          // bf16 e + bf16 ehat

    if (ws_size >= needA) {
        run_net<float, float>(d_in, (float*)base, (float*)edge,
                              (float*)(edge + NE * 4), out, stream);
    } else if (ws_size >= needB) {
        run_net<float, __hip_bfloat16>(d_in, (float*)base, (float*)edge,
                                       (__hip_bfloat16*)(edge + NE * 4), out, stream);
    } else if (ws_size >= needC) {
        run_net<__hip_bfloat16, __hip_bfloat16>(d_in, (float*)base, (__hip_bfloat16*)edge,
                                                (__hip_bfloat16*)(edge + NE * 2), out, stream);
    } else {
        // diagnostic fallback: workspace too small — emit zeros, don't fault
        hipMemsetAsync(d_out, 0, (size_t)out_size * sizeof(float), stream);
    }
}

// Round 7
// 1220.121 us; speedup vs baseline: 3.3065x; 1.1290x over previous
//
#include <hip/hip_runtime.h>
#include <hip/hip_bf16.h>

constexpr int NNODES = 25000;
constexpr int NEDGES = 400000;
constexpr int DD = 64;
constexpr float BNEPS = 1e-5f;
constexpr float AGGEPS = 1e-6f;

typedef __attribute__((ext_vector_type(8))) short short8_t;
typedef __attribute__((ext_vector_type(4))) short short4_t;
typedef __attribute__((ext_vector_type(4))) float float4_t;

// storage-type helpers (compute is always fp32)
__device__ __forceinline__ float ldv(const float* p, long i) { return p[i]; }
__device__ __forceinline__ float ldv(const __hip_bfloat16* p, long i) { return __bfloat162float(p[i]); }
__device__ __forceinline__ void stv(float* p, long i, float v) { p[i] = v; }
__device__ __forceinline__ void stv(__hip_bfloat16* p, long i, float v) { p[i] = __float2bfloat16(v); }

// float -> bf16 bits, RNE (finite inputs only)
__device__ __forceinline__ short f2bs(float f) {
    union { float f; unsigned u; } x; x.f = f;
    unsigned r = x.u + 0x7FFFu + ((x.u >> 16) & 1u);
    return (short)(r >> 16);
}
__device__ __forceinline__ float bs2f(short s) {
    union { unsigned u; float f; } x; x.u = ((unsigned)(unsigned short)s) << 16; return x.f;
}

// vector load/store of 4 elems (fp32: 16B; bf16: 8B)
__device__ __forceinline__ float4_t ldv4(const float* p, long i) {
    return *(const float4_t*)(p + i);
}
__device__ __forceinline__ float4_t ldv4(const __hip_bfloat16* p, long i) {
    short4_t s = *(const short4_t*)(p + i);
    float4_t r;
    #pragma unroll
    for (int c = 0; c < 4; ++c) r[c] = bs2f(s[c]);
    return r;
}
__device__ __forceinline__ void stv4(float* p, long i, float4_t v) {
    *(float4_t*)(p + i) = v;
}
__device__ __forceinline__ void stv4(__hip_bfloat16* p, long i, float4_t v) {
    short4_t s;
    #pragma unroll
    for (int c = 0; c < 4; ++c) s[c] = f2bs(v[c]);
    *(short4_t*)(p + i) = s;
}

// stage 8 consecutive elems from global into bf16 LDS (16B-aligned both sides)
__device__ __forceinline__ void stage8(const __hip_bfloat16* s, short* d) {
    *(short8_t*)d = *(const short8_t*)s;
}
__device__ __forceinline__ void stage8(const float* s, short* d) {
    float4_t a = *(const float4_t*)s;
    float4_t b = *(const float4_t*)(s + 4);
    short8_t v;
    v[0] = f2bs(a[0]); v[1] = f2bs(a[1]); v[2] = f2bs(a[2]); v[3] = f2bs(a[3]);
    v[4] = f2bs(b[0]); v[5] = f2bs(b[1]); v[6] = f2bs(b[2]); v[7] = f2bs(b[3]);
    *(short8_t*)d = v;
}

// ---------------------------------------------------------------------------
// Generic LDS-tiled linear (embeddings): Y[r][n] = b[n] + sum_k X[r][k]W[k][n]
// ---------------------------------------------------------------------------
template<int K, int N, int JR, typename TX, typename TY>
__global__ __launch_bounds__(256) void linear_kernel(
    const TX* __restrict__ X, const float* __restrict__ W,
    const float* __restrict__ Bb, TY* __restrict__ Y, int rows)
{
    constexpr int SLOTS = 256 / N;
    constexpr int RPG = SLOTS * JR;
    __shared__ float wl[K * N];
    __shared__ float bl[N];
    __shared__ float xl[RPG * K];

    const int tid = threadIdx.x;
    for (int i = tid; i < K * N; i += 256) wl[i] = W[i];
    if (tid < N) bl[tid] = Bb[tid];

    const int col = tid % N;
    const int slot = tid / N;

    const int ngroups = (rows + RPG - 1) / RPG;
    for (int g = blockIdx.x; g < ngroups; g += gridDim.x) {
        const int rowBase = g * RPG;
        __syncthreads();
        for (int i = tid; i < RPG * K; i += 256) {
            int r = i / K, k = i - r * K;
            int row = rowBase + r;
            xl[i] = (row < rows) ? ldv(X, (long)row * K + k) : 0.0f;
        }
        __syncthreads();
        float acc[JR];
        #pragma unroll
        for (int j = 0; j < JR; ++j) acc[j] = bl[col];
        #pragma unroll 4
        for (int k = 0; k < K; ++k) {
            float w = wl[k * N + col];
            #pragma unroll
            for (int j = 0; j < JR; ++j)
                acc[j] += xl[(slot * JR + j) * K + k] * w;
        }
        #pragma unroll
        for (int j = 0; j < JR; ++j) {
            int row = rowBase + slot * JR + j;
            if (row < rows) stv(Y, (long)row * N + col, acc[j]);
        }
    }
}

// ---------------------------------------------------------------------------
// Dual linear (node path): stage X once, two weight sets, two outputs.
// ---------------------------------------------------------------------------
template<int K, int N, int JR>
__global__ __launch_bounds__(256) void linear2_kernel(
    const float* __restrict__ X,
    const float* __restrict__ Wa, const float* __restrict__ Ba, float* __restrict__ Ya,
    const float* __restrict__ Wb, const float* __restrict__ Bb, float* __restrict__ Yb,
    int rows)
{
    constexpr int SLOTS = 256 / N;
    constexpr int RPG = SLOTS * JR;
    __shared__ float wa[K * N], wb[K * N];
    __shared__ float bla[N], blb[N];
    __shared__ float xl[RPG * K];

    const int tid = threadIdx.x;
    for (int i = tid; i < K * N; i += 256) { wa[i] = Wa[i]; wb[i] = Wb[i]; }
    if (tid < N) { bla[tid] = Ba[tid]; blb[tid] = Bb[tid]; }

    const int col = tid % N;
    const int slot = tid / N;

    const int ngroups = (rows + RPG - 1) / RPG;
    for (int g = blockIdx.x; g < ngroups; g += gridDim.x) {
        const int rowBase = g * RPG;
        __syncthreads();
        for (int i = tid; i < RPG * K / 4; i += 256) {
            int r = (i * 4) / K, k0 = (i * 4) % K;
            int row = rowBase + r;
            float4_t v = (float4_t)0.0f;
            if (row < rows) v = ldv4(X, (long)row * K + k0);
            *(float4_t*)(xl + r * K + k0) = v;
        }
        __syncthreads();
        float aa[JR], ab[JR];
        #pragma unroll
        for (int j = 0; j < JR; ++j) { aa[j] = bla[col]; ab[j] = blb[col]; }
        #pragma unroll 2
        for (int k = 0; k < K; ++k) {
            float w1 = wa[k * N + col], w2 = wb[k * N + col];
            #pragma unroll
            for (int j = 0; j < JR; ++j) {
                float x = xl[(slot * JR + j) * K + k];
                aa[j] += x * w1; ab[j] += x * w2;
            }
        }
        #pragma unroll
        for (int j = 0; j < JR; ++j) {
            int row = rowBase + slot * JR + j;
            if (row < rows) {
                Ya[(long)row * N + col] = aa[j];
                Yb[(long)row * N + col] = ab[j];
            }
        }
    }
}

// ---------------------------------------------------------------------------
// MFMA edge update (per-layer workhorse):
//   if BNIN: e = e + relu(bn(ehat_prev))   [in-place, feeds staged matmul]
//   ehat = e @ C + Cb + Dh[src] + Eh[dst]  [in-place over ehat_prev]
//   + per-block BN partials of new ehat.
// 64-edge tiles, 4 waves, bf16 16x16x32 MFMA; CT is bf16 [n][k] (B-fragment
// pattern identical to the validated readout kernel).
// ---------------------------------------------------------------------------
template<bool BNIN, typename TE, typename TH>
__global__ __launch_bounds__(256) void edge_update_mfma_kernel(
    TE* __restrict__ e, TH* __restrict__ ehat,
    const short* __restrict__ CT, const float* __restrict__ Cb,
    const float* __restrict__ Dh, const int* __restrict__ src,
    const float* __restrict__ Eh, const int* __restrict__ dst,
    const float* __restrict__ stats_prev, const float* __restrict__ gprev,
    const float* __restrict__ bprev, float* __restrict__ partial)
{
    __shared__ short ct[64 * 72];
    __shared__ short xs[64 * 72];
    __shared__ float bl[64], scale[64], shift[64];
    __shared__ float ps[128];

    const int tid = threadIdx.x;
    const int wave = tid >> 6;
    const int lane = tid & 63;
    const int r = lane & 15;
    const int q = lane >> 4;

    for (int i = tid; i < 512; i += 256) {        // CT tile, reused all tiles
        int n = i >> 3, oct = i & 7;
        *(short8_t*)(ct + n * 72 + oct * 8) = *(const short8_t*)(CT + n * 64 + oct * 8);
    }
    if (tid < 64) {
        bl[tid] = Cb[tid];
        if (BNIN) {
            float inv = 1.0f / (float)NEDGES;
            float mu = stats_prev[tid] * inv;
            float var = stats_prev[64 + tid] * inv - mu * mu;
            float rs = rsqrtf(var + BNEPS);
            float sc = rs * gprev[tid];
            scale[tid] = sc;
            shift[tid] = bprev[tid] - mu * sc;
        }
    }
    if (tid < 128) ps[tid] = 0.0f;
    float lsum[4] = {0, 0, 0, 0}, lsum2[4] = {0, 0, 0, 0};

    constexpr int NTILES = NEDGES / 64;           // 6250, exact
    for (int t = blockIdx.x; t < NTILES; t += gridDim.x) {
        const int rowBase = t * 64;
        __syncthreads();                          // xs reuse from prev tile
        for (int i = tid; i < 512; i += 256) {    // stage 64 rows x 8 octets
            int row = i >> 3, oct = i & 7;
            long idx = (long)(rowBase + row) * 64 + oct * 8;
            float4_t a = ldv4(e, idx), b = ldv4(e, idx + 4);
            if (BNIN) {
                float4_t ha = ldv4(ehat, idx), hb = ldv4(ehat, idx + 4);
                int k0 = oct * 8;
                #pragma unroll
                for (int c = 0; c < 4; ++c) {
                    a[c] += fmaxf(ha[c] * scale[k0 + c] + shift[k0 + c], 0.0f);
                    b[c] += fmaxf(hb[c] * scale[k0 + 4 + c] + shift[k0 + 4 + c], 0.0f);
                }
                stv4(e, idx, a); stv4(e, idx + 4, b);   // residual materialized
            }
            short8_t v;
            v[0] = f2bs(a[0]); v[1] = f2bs(a[1]); v[2] = f2bs(a[2]); v[3] = f2bs(a[3]);
            v[4] = f2bs(b[0]); v[5] = f2bs(b[1]); v[6] = f2bs(b[2]); v[7] = f2bs(b[3]);
            *(short8_t*)(xs + row * 72 + oct * 8) = v;
        }
        __syncthreads();
        float4_t acc[4];
        #pragma unroll
        for (int i = 0; i < 4; ++i) acc[i] = (float4_t)0.0f;
        #pragma unroll
        for (int kk = 0; kk < 2; ++kk) {
            short8_t a = *(const short8_t*)(xs + (wave * 16 + r) * 72 + kk * 32 + q * 8);
            #pragma unroll
            for (int nt = 0; nt < 4; ++nt) {
                short8_t b = *(const short8_t*)(ct + (nt * 16 + r) * 72 + kk * 32 + q * 8);
                acc[nt] = __builtin_amdgcn_mfma_f32_16x16x32_bf16(a, b, acc[nt], 0, 0, 0);
            }
        }
        // epilogue: bias + Dh[src]/Eh[dst] gathers + store + BN partials
        #pragma unroll
        for (int i2 = 0; i2 < 4; ++i2) {
            int row = wave * 16 + q * 4 + i2;
            int er = rowBase + row;
            int s = src[er], d = dst[er];
            #pragma unroll
            for (int nt = 0; nt < 4; ++nt) {
                int col = nt * 16 + r;
                float v = acc[nt][i2] + bl[col]
                        + Dh[(long)s * 64 + col] + Eh[(long)d * 64 + col];
                stv(ehat, (long)er * 64 + col, v);
                lsum[nt] += v; lsum2[nt] += v * v;
            }
        }
    }
    __syncthreads();
    #pragma unroll
    for (int nt = 0; nt < 4; ++nt) {
        atomicAdd(&ps[nt * 16 + r], lsum[nt]);
        atomicAdd(&ps[64 + nt * 16 + r], lsum2[nt]);
    }
    __syncthreads();
    if (tid < 128) partial[(long)blockIdx.x * 128 + tid] = ps[tid];
}

// ---------------------------------------------------------------------------
// CSR build (graph static within one call): histogram -> scan -> scatter
// ---------------------------------------------------------------------------
__global__ __launch_bounds__(256) void deg_hist_kernel(
    const int* __restrict__ dst, int* __restrict__ rowptr, int rows)
{
    int e = blockIdx.x * 256 + threadIdx.x;
    if (e < rows) atomicAdd(&rowptr[dst[e] + 1], 1);
}

__global__ __launch_bounds__(1024) void scan_kernel(int* __restrict__ data, int n)
{
    __shared__ int buf[1024];
    __shared__ int carry;
    if (threadIdx.x == 0) carry = 0;
    __syncthreads();
    for (int base = 0; base < n; base += 1024) {
        int i = base + threadIdx.x;
        int v = (i < n) ? data[i] : 0;
        buf[threadIdx.x] = v;
        __syncthreads();
        for (int off = 1; off < 1024; off <<= 1) {
            int t = (threadIdx.x >= off) ? buf[threadIdx.x - off] : 0;
            __syncthreads();
            buf[threadIdx.x] += t;
            __syncthreads();
        }
        if (i < n) data[i] = buf[threadIdx.x] + carry;
        __syncthreads();
        if (threadIdx.x == 0) carry += buf[1023];
        __syncthreads();
    }
}

__global__ __launch_bounds__(256) void scatter_kernel(
    const int* __restrict__ dst, const int* __restrict__ rowptr,
    int* __restrict__ cursor, int* __restrict__ eid, int rows)
{
    int e = blockIdx.x * 256 + threadIdx.x;
    if (e < rows) {
        int d = dst[e];
        int pos = atomicAdd(&cursor[d], 1);
        eid[rowptr[d] + pos] = e;
    }
}

// ---------------------------------------------------------------------------
// CSR aggregation, float4 lanes, 4 edges per wave-iteration, no atomics.
// hhat[n] = Ah[n] + sum(sig*Bh[src]) / (sum(sig)+eps); fused hhat BN partials.
// ---------------------------------------------------------------------------
template<typename TH>
__global__ __launch_bounds__(256) void agg_csr_kernel(
    const TH* __restrict__ ehat, const float* __restrict__ Bh,
    const int* __restrict__ src,
    const int* __restrict__ rowptr, const int* __restrict__ eid,
    const float* __restrict__ Ah, float* __restrict__ hhat,
    float* __restrict__ partial)
{
    __shared__ float ps[64], ps2[64];
    const int tid = threadIdx.x;
    if (tid < 64) { ps[tid] = 0.0f; ps2[tid] = 0.0f; }
    __syncthreads();

    const int node = blockIdx.x * 4 + (tid >> 6);
    const int lane = tid & 63;
    const int sub = lane >> 4;
    const int c4 = (lane & 15) * 4;
    const int s0 = rowptr[node], s1 = rowptr[node + 1];

    float4_t den = (float4_t)0.0f, num = (float4_t)0.0f;
    for (int p = s0 + sub; p < s1; p += 4) {
        int e = eid[p];
        float4_t v = ldv4(ehat, (long)e * 64 + c4);
        float4_t bh = ldv4(Bh, (long)src[e] * 64 + c4);
        #pragma unroll
        for (int c = 0; c < 4; ++c) {
            float s = 1.0f / (1.0f + __expf(-v[c]));
            den[c] += s;
            num[c] += s * bh[c];
        }
    }
    #pragma unroll
    for (int m = 16; m <= 32; m <<= 1) {
        #pragma unroll
        for (int c = 0; c < 4; ++c) {
            den[c] += __shfl_xor(den[c], m, 64);
            num[c] += __shfl_xor(num[c], m, 64);
        }
    }
    if (sub == 0) {
        float4_t av = ldv4(Ah, (long)node * 64 + c4);
        float4_t hh;
        #pragma unroll
        for (int c = 0; c < 4; ++c) {
            hh[c] = av[c] + num[c] / (den[c] + AGGEPS);
            atomicAdd(&ps[c4 + c], hh[c]);
            atomicAdd(&ps2[c4 + c], hh[c] * hh[c]);
        }
        stv4(hhat, (long)node * 64 + c4, hh);
    }
    __syncthreads();
    if (tid < 64) {
        partial[(long)blockIdx.x * 128 + tid] = ps[tid];
        partial[(long)blockIdx.x * 128 + 64 + tid] = ps2[tid];
    }
}

// stats[c] = sum over blocks of partial[b][c]; grid = 128
__global__ __launch_bounds__(256) void reduce_stats_kernel(
    const float* __restrict__ partial, int nblk, float* __restrict__ stats)
{
    __shared__ float sb[256];
    int tid = threadIdx.x;
    float s = 0.0f;
    for (int i = tid; i < nblk; i += 256) s += partial[(long)i * 128 + blockIdx.x];
    sb[tid] = s;
    __syncthreads();
    for (int off = 128; off > 0; off >>= 1) {
        if (tid < off) sb[tid] += sb[tid + off];
        __syncthreads();
    }
    if (tid == 0) stats[blockIdx.x] = sb[0];
}

// base += relu((xhat-mu)*rstd*g + b), float4 per thread
template<typename TB, typename TX>
__global__ __launch_bounds__(256) void bn_apply4_kernel(
    TB* __restrict__ base, const TX* __restrict__ xhat,
    const float* __restrict__ stats, const float* __restrict__ g,
    const float* __restrict__ b, int rows)
{
    long total4 = (long)rows * 16;
    float inv = 1.0f / (float)rows;
    for (long q = (long)blockIdx.x * 256 + threadIdx.x; q < total4;
         q += (long)gridDim.x * 256) {
        long idx = q * 4;
        int c = (int)(idx & 63);
        float4_t x = ldv4(xhat, idx);
        float4_t bs = ldv4(base, idx);
        #pragma unroll
        for (int j = 0; j < 4; ++j) {
            float mu = stats[c + j] * inv;
            float var = stats[64 + c + j] * inv - mu * mu;
            float rs = rsqrtf(var + BNEPS);
            float v = (x[j] - mu) * rs * g[c + j] + b[c + j];
            bs[j] += fmaxf(v, 0.0f);
        }
        stv4(base, idx, bs);
    }
}

// one-shot: W0 -> W0T bf16 [128][256]; W1 -> W1T [64][128]; C_w[l] -> CT [l][n][k]
__global__ __launch_bounds__(256) void transpose_w_kernel(
    const float* __restrict__ W0, const float* __restrict__ W1,
    const float* __restrict__ C_w,
    short* __restrict__ W0T, short* __restrict__ W1T, short* __restrict__ CT)
{
    int id = blockIdx.x * 256 + threadIdx.x;
    if (id < 256 * 128) {
        int k = id >> 7, n = id & 127;
        W0T[n * 256 + k] = f2bs(W0[id]);
    }
    if (id < 128 * 64) {
        int k = id >> 6, n = id & 63;
        W1T[n * 128 + k] = f2bs(W1[id]);
    }
    if (id < 4 * 64 * 64) {
        int l = id >> 12, rem = id & 4095, k = rem >> 6, n = rem & 63;
        CT[l * 4096 + n * 64 + k] = f2bs(C_w[l * 4096 + k * 64 + n]);
    }
}

// ---------------------------------------------------------------------------
// MFMA MLP readout (validated in R4): 64-edge tiles, bf16 16x16x32.
// ---------------------------------------------------------------------------
template<typename TE>
__global__ __launch_bounds__(256) void readout_mfma_kernel(
    const TE* __restrict__ e, const float* __restrict__ h,
    const int* __restrict__ src, const int* __restrict__ dst,
    const int* __restrict__ rev,
    const short* __restrict__ W0T, const short* __restrict__ W1T,
    const float* __restrict__ b0, const float* __restrict__ b1,
    const float* __restrict__ W2, const float* __restrict__ b2,
    float* __restrict__ out)
{
    __shared__ short feat[64 * 72];
    __shared__ short wtile[128 * 72];
    __shared__ short x0t[64 * 136];
    __shared__ float smallb[322];

    const int tid = threadIdx.x;
    const int wave = tid >> 6;
    const int lane = tid & 63;
    const int r = lane & 15;
    const int q = lane >> 4;

    if (tid < 128) smallb[tid] = b0[tid];
    if (tid < 64)  smallb[128 + tid] = b1[tid];
    if (tid < 128) smallb[192 + tid] = W2[tid];
    if (tid < 2)   smallb[320 + tid] = b2[tid];

    constexpr int NTILES = NEDGES / 64;
    for (int t = blockIdx.x; t < NTILES; t += gridDim.x) {
        const int rowBase = t * 64;
        float4_t acc0[8];
        #pragma unroll
        for (int i = 0; i < 8; ++i) acc0[i] = (float4_t)0.0f;

        for (int s = 0; s < 4; ++s) {
            __syncthreads();
            for (int i = tid; i < 512; i += 256) {
                int row = i >> 3, oct = i & 7;
                int er = rowBase + row;
                short* d = feat + row * 72 + oct * 8;
                if (s == 0)      stage8(e + (long)er * 64 + oct * 8, d);
                else if (s == 1) stage8(e + (long)rev[er] * 64 + oct * 8, d);
                else if (s == 2) stage8(h + (long)src[er] * 64 + oct * 8, d);
                else             stage8(h + (long)dst[er] * 64 + oct * 8, d);
            }
            for (int i = tid; i < 1024; i += 256) {
                int n = i >> 3, oct = i & 7;
                *(short8_t*)(wtile + n * 72 + oct * 8) =
                    *(const short8_t*)(W0T + (long)n * 256 + s * 64 + oct * 8);
            }
            __syncthreads();
            #pragma unroll
            for (int kk = 0; kk < 2; ++kk) {
                short8_t a = *(const short8_t*)(feat + (wave * 16 + r) * 72 + kk * 32 + q * 8);
                #pragma unroll
                for (int nt = 0; nt < 8; ++nt) {
                    short8_t b = *(const short8_t*)(wtile + (nt * 16 + r) * 72 + kk * 32 + q * 8);
                    acc0[nt] = __builtin_amdgcn_mfma_f32_16x16x32_bf16(a, b, acc0[nt], 0, 0, 0);
                }
            }
        }
        #pragma unroll
        for (int nt = 0; nt < 8; ++nt) {
            int col = nt * 16 + r;
            #pragma unroll
            for (int i2 = 0; i2 < 4; ++i2) {
                int row = wave * 16 + q * 4 + i2;
                x0t[row * 136 + col] = f2bs(fmaxf(acc0[nt][i2] + smallb[col], 0.0f));
            }
        }
        __syncthreads();
        for (int i = tid; i < 1024; i += 256) {
            int n = i >> 4, oct = i & 15;
            *(short8_t*)(wtile + n * 136 + oct * 8) =
                *(const short8_t*)(W1T + (long)n * 128 + oct * 8);
        }
        __syncthreads();
        float4_t acc1[4];
        #pragma unroll
        for (int i = 0; i < 4; ++i) acc1[i] = (float4_t)0.0f;
        #pragma unroll
        for (int kk = 0; kk < 4; ++kk) {
            short8_t a = *(const short8_t*)(x0t + (wave * 16 + r) * 136 + kk * 32 + q * 8);
            #pragma unroll
            for (int nt = 0; nt < 4; ++nt) {
                short8_t b = *(const short8_t*)(wtile + (nt * 16 + r) * 136 + kk * 32 + q * 8);
                acc1[nt] = __builtin_amdgcn_mfma_f32_16x16x32_bf16(a, b, acc1[nt], 0, 0, 0);
            }
        }
        #pragma unroll
        for (int nt = 0; nt < 4; ++nt) {
            int col = nt * 16 + r;
            #pragma unroll
            for (int i2 = 0; i2 < 4; ++i2) {
                int row = wave * 16 + q * 4 + i2;
                feat[row * 72 + col] = f2bs(fmaxf(acc1[nt][i2] + smallb[128 + col], 0.0f));
            }
        }
        __syncthreads();
        if (tid < 128) {
            int row = tid >> 1, cls = tid & 1;
            float a = smallb[320 + cls];
            #pragma unroll 8
            for (int k = 0; k < 64; ++k)
                a += bs2f(feat[row * 72 + k]) * smallb[192 + k * 2 + cls];
            out[(long)(rowBase + row) * 2 + cls] = a;
        }
    }
}

// ---------------------------------------------------------------------------
static inline int igrid(long total, int block, int cap) {
    long g = (total + block - 1) / block;
    return (int)(g < cap ? g : cap);
}

constexpr int GE_EDGE = 2048;        // edge_update_mfma grid (partial_e rows)
constexpr int GA_AGG  = NNODES / 4;  // 6250 (partial_h rows)

template<typename TE, typename TH>
static void run_net(void* const* d_in, float* f, TE* e, TH* ehat,
                    float* out, hipStream_t stream)
{
    const float* h_in   = (const float*)d_in[0];
    const float* e_in   = (const float*)d_in[1];
    const int*   src    = (const int*)d_in[2];
    const int*   dst    = (const int*)d_in[3];
    const int*   rev    = (const int*)d_in[4];
    const float* emb_h_w = (const float*)d_in[5];
    const float* emb_h_b = (const float*)d_in[6];
    const float* emb_e_w = (const float*)d_in[7];
    const float* emb_e_b = (const float*)d_in[8];
    const float* A_w = (const float*)d_in[9];  const float* A_b = (const float*)d_in[10];
    const float* B_w = (const float*)d_in[11]; const float* B_b = (const float*)d_in[12];
    const float* C_w = (const float*)d_in[13]; const float* C_b = (const float*)d_in[14];
    const float* D_w = (const float*)d_in[15]; const float* D_b = (const float*)d_in[16];
    const float* E_w = (const float*)d_in[17]; const float* E_b = (const float*)d_in[18];
    // F/G (19..22) and bn_u (27,28) are dead: u never reaches the output.
    const float* bn_h_g = (const float*)d_in[23]; const float* bn_h_b = (const float*)d_in[24];
    const float* bn_e_g = (const float*)d_in[25]; const float* bn_e_b = (const float*)d_in[26];
    const float* W0 = (const float*)d_in[29]; const float* b0 = (const float*)d_in[30];
    const float* W1 = (const float*)d_in[31]; const float* b1 = (const float*)d_in[32];
    const float* W2 = (const float*)d_in[33]; const float* b2 = (const float*)d_in[34];

    const size_t NH = (size_t)NNODES * DD;
    float* h    = f;
    float* Ah   = f + NH;
    float* Bh   = f + 2 * NH;
    float* Dh   = f + 3 * NH;      // hhat aliases Dh (Dh dead after edge_update)
    float* Eh   = f + 4 * NH;
    float* hhat = Dh;
    float* stats_h  = f + 5 * NH;           // 128
    float* stats_e  = stats_h + 128;        // 128
    float* partial_e = f + 5 * NH + 512;    // 2048*128
    float* partial_h = partial_e + (size_t)GE_EDGE * 128;   // 6250*128
    int* rowptr = (int*)(partial_h + (size_t)GA_AGG * 128); // 25001
    int* cursor = rowptr + NNODES + 1;      // 25000
    int* eid    = cursor + NNODES;          // 400000
    short* W0T  = (short*)(eid + NEDGES);   // 32768 shorts
    short* W1T  = W0T + 256 * 128;          // 8192
    short* CT   = W1T + 128 * 64;           // 4*4096 shorts

    const int GN = 1563;
    const int GEDGE = (NEDGES + 255) / 256;

    // CSR build + weight transposes (once per call)
    hipMemsetAsync(rowptr, 0, (2 * NNODES + 1) * sizeof(int), stream);
    deg_hist_kernel<<<GEDGE, 256, 0, stream>>>(dst, rowptr, NEDGES);
    scan_kernel<<<1, 1024, 0, stream>>>(rowptr, NNODES + 1);
    scatter_kernel<<<GEDGE, 256, 0, stream>>>(dst, rowptr, cursor, eid, NEDGES);
    transpose_w_kernel<<<128, 256, 0, stream>>>(W0, W1, C_w, W0T, W1T, CT);

    // embeddings
    linear_kernel<64, 64, 4, float, float><<<GN, 256, 0, stream>>>(
        h_in, emb_h_w, emb_h_b, h, NNODES);
    linear_kernel<16, 64, 4, float, TE><<<4096, 256, 0, stream>>>(
        e_in, emb_e_w, emb_e_b, e, NEDGES);

    for (int l = 0; l < 4; ++l) {
        const size_t o = (size_t)l * DD * DD;
        // node linears, batched 2x
        linear2_kernel<64, 64, 4><<<GN, 256, 0, stream>>>(
            h, A_w + o, A_b + l * DD, Ah, B_w + o, B_b + l * DD, Bh, NNODES);
        linear2_kernel<64, 64, 4><<<GN, 256, 0, stream>>>(
            h, D_w + o, D_b + l * DD, Dh, E_w + o, E_b + l * DD, Eh, NNODES);

        // MFMA edge update: (prev BN_e fused) + C-matmul + gathers + stats
        if (l == 0)
            edge_update_mfma_kernel<false, TE, TH><<<GE_EDGE, 256, 0, stream>>>(
                e, ehat, CT + o, C_b + l * DD, Dh, src, Eh, dst,
                nullptr, nullptr, nullptr, partial_e);
        else
            edge_update_mfma_kernel<true, TE, TH><<<GE_EDGE, 256, 0, stream>>>(
                e, ehat, CT + o, C_b + l * DD, Dh, src, Eh, dst,
                stats_e, bn_e_g + (l - 1) * DD, bn_e_b + (l - 1) * DD, partial_e);
        reduce_stats_kernel<<<128, 256, 0, stream>>>(partial_e, GE_EDGE, stats_e);

        // CSR aggregation + fused hhat + hhat BN partials
        agg_csr_kernel<TH><<<GA_AGG, 256, 0, stream>>>(
            ehat, Bh, src, rowptr, eid, Ah, hhat, partial_h);
        reduce_stats_kernel<<<128, 256, 0, stream>>>(partial_h, GA_AGG, stats_h);

        // h += relu(bn(hhat))
        bn_apply4_kernel<float, float><<<igrid((long)NNODES * 16, 256, 8192), 256, 0, stream>>>(
            h, hhat, stats_h, bn_h_g + l * DD, bn_h_b + l * DD, NNODES);
    }
    // final e update (layer-3 BN never folded into a next layer)
    bn_apply4_kernel<TE, TH><<<igrid((long)NEDGES * 16, 256, 8192), 256, 0, stream>>>(
        e, ehat, stats_e, bn_e_g + 3 * DD, bn_e_b + 3 * DD, NEDGES);

    // MFMA readout
    readout_mfma_kernel<TE><<<2048, 256, 0, stream>>>(e, h, src, dst, rev,
                                                      W0T, W1T, b0, b1, W2, b2, out);
}

extern "C" void kernel_launch(void* const* d_in, const int* in_sizes, int n_in,
                              void* d_out, int out_size, void* d_ws, size_t ws_size,
                              hipStream_t stream)
{
    const size_t NH = (size_t)NNODES * DD;       // 1.6M floats
    const size_t NE = (size_t)NEDGES * DD;       // 25.6M elems
    const size_t baseB = (7 * NH + 256) * sizeof(float);   // 44.8 MB node region
    // internal layout uses ~5*NH + 512 + partials (2048+6250)*128 + CSR ints
    // (450001) + W0T/W1T/CT shorts (57344) — fits within baseB.

    char* base = (char*)d_ws;
    char* edge = base + baseB;
    float* out = (float*)d_out;

    const size_t needA = baseB + NE * 4 * 2;          // fp32 e + fp32 ehat
    const size_t needB = baseB + NE * 4 + NE * 2;     // fp32 e + bf16 ehat
    const size_t needC = baseB + NE * 2 * 2;          // bf16 e + bf16 ehat

    if (ws_size >= needA) {
        run_net<float, float>(d_in, (float*)base, (float*)edge,
                              (float*)(edge + NE * 4), out, stream);
    } else if (ws_size >= needB) {
        run_net<float, __hip_bfloat16>(d_in, (float*)base, (float*)edge,
                                       (__hip_bfloat16*)(edge + NE * 4), out, stream);
    } else if (ws_size >= needC) {
        run_net<__hip_bfloat16, __hip_bfloat16>(d_in, (float*)base, (__hip_bfloat16*)edge,
                                                (__hip_bfloat16*)(edge + NE * 2), out, stream);
    } else {
        // diagnostic fallback: workspace too small — emit zeros, don't fault
        hipMemsetAsync(d_out, 0, (size_t)out_size * sizeof(float), stream);
    }
}

// Round 8
// 1094.340 us; speedup vs baseline: 3.6866x; 1.1149x over previous
//
#include <hip/hip_runtime.h>
#include <hip/hip_bf16.h>

constexpr int NNODES = 25000;
constexpr int NEDGES = 400000;
constexpr int DD = 64;
constexpr float BNEPS = 1e-5f;
constexpr float AGGEPS = 1e-6f;

typedef __attribute__((ext_vector_type(8))) short short8_t;
typedef __attribute__((ext_vector_type(4))) short short4_t;
typedef __attribute__((ext_vector_type(4))) float float4_t;

// storage-type helpers (compute is always fp32)
__device__ __forceinline__ float ldv(const float* p, long i) { return p[i]; }
__device__ __forceinline__ float ldv(const __hip_bfloat16* p, long i) { return __bfloat162float(p[i]); }
__device__ __forceinline__ void stv(float* p, long i, float v) { p[i] = v; }
__device__ __forceinline__ void stv(__hip_bfloat16* p, long i, float v) { p[i] = __float2bfloat16(v); }

// float -> bf16 bits, RNE (finite inputs only)
__device__ __forceinline__ short f2bs(float f) {
    union { float f; unsigned u; } x; x.f = f;
    unsigned r = x.u + 0x7FFFu + ((x.u >> 16) & 1u);
    return (short)(r >> 16);
}
__device__ __forceinline__ float bs2f(short s) {
    union { unsigned u; float f; } x; x.u = ((unsigned)(unsigned short)s) << 16; return x.f;
}

// vector load/store of 4 elems (fp32: 16B; bf16: 8B)
__device__ __forceinline__ float4_t ldv4(const float* p, long i) {
    return *(const float4_t*)(p + i);
}
__device__ __forceinline__ float4_t ldv4(const __hip_bfloat16* p, long i) {
    short4_t s = *(const short4_t*)(p + i);
    float4_t r;
    #pragma unroll
    for (int c = 0; c < 4; ++c) r[c] = bs2f(s[c]);
    return r;
}
__device__ __forceinline__ void stv4(float* p, long i, float4_t v) {
    *(float4_t*)(p + i) = v;
}
__device__ __forceinline__ void stv4(__hip_bfloat16* p, long i, float4_t v) {
    short4_t s;
    #pragma unroll
    for (int c = 0; c < 4; ++c) s[c] = f2bs(v[c]);
    *(short4_t*)(p + i) = s;
}

// stage 8 consecutive elems from global into bf16 LDS (16B-aligned both sides)
__device__ __forceinline__ void stage8(const __hip_bfloat16* s, short* d) {
    *(short8_t*)d = *(const short8_t*)s;
}
__device__ __forceinline__ void stage8(const float* s, short* d) {
    float4_t a = *(const float4_t*)s;
    float4_t b = *(const float4_t*)(s + 4);
    short8_t v;
    v[0] = f2bs(a[0]); v[1] = f2bs(a[1]); v[2] = f2bs(a[2]); v[3] = f2bs(a[3]);
    v[4] = f2bs(b[0]); v[5] = f2bs(b[1]); v[6] = f2bs(b[2]); v[7] = f2bs(b[3]);
    *(short8_t*)d = v;
}

// ---------------------------------------------------------------------------
// Generic LDS-tiled linear (embeddings), optional row-gather on X.
// ---------------------------------------------------------------------------
template<int K, int N, int JR, typename TX, typename TY>
__global__ __launch_bounds__(256) void linear_kernel(
    const TX* __restrict__ X, const float* __restrict__ W,
    const float* __restrict__ Bb, TY* __restrict__ Y,
    const int* __restrict__ gather, int rows)
{
    constexpr int SLOTS = 256 / N;
    constexpr int RPG = SLOTS * JR;
    __shared__ float wl[K * N];
    __shared__ float bl[N];
    __shared__ float xl[RPG * K];

    const int tid = threadIdx.x;
    for (int i = tid; i < K * N; i += 256) wl[i] = W[i];
    if (tid < N) bl[tid] = Bb[tid];

    const int col = tid % N;
    const int slot = tid / N;

    const int ngroups = (rows + RPG - 1) / RPG;
    for (int g = blockIdx.x; g < ngroups; g += gridDim.x) {
        const int rowBase = g * RPG;
        __syncthreads();
        for (int i = tid; i < RPG * K; i += 256) {
            int r = i / K, k = i - r * K;
            int row = rowBase + r;
            float v = 0.0f;
            if (row < rows) {
                int sr = gather ? gather[row] : row;
                v = ldv(X, (long)sr * K + k);
            }
            xl[i] = v;
        }
        __syncthreads();
        float acc[JR];
        #pragma unroll
        for (int j = 0; j < JR; ++j) acc[j] = bl[col];
        #pragma unroll 4
        for (int k = 0; k < K; ++k) {
            float w = wl[k * N + col];
            #pragma unroll
            for (int j = 0; j < JR; ++j)
                acc[j] += xl[(slot * JR + j) * K + k] * w;
        }
        #pragma unroll
        for (int j = 0; j < JR; ++j) {
            int row = rowBase + slot * JR + j;
            if (row < rows) stv(Y, (long)row * N + col, acc[j]);
        }
    }
}

// ---------------------------------------------------------------------------
// Quad node linear, MFMA: {Ah,Bh,Dh,Eh} = h @ {A,B,D,E} + biases in one pass.
// NT: bf16 [n=256][k=64], n = mat*64+col. 64-row tiles, 4 waves.
// ---------------------------------------------------------------------------
__global__ __launch_bounds__(256) void node_linear4_mfma_kernel(
    const float* __restrict__ h, const short* __restrict__ NT,
    const float* __restrict__ Ab, const float* __restrict__ Bb,
    const float* __restrict__ Db, const float* __restrict__ Eb,
    float* __restrict__ Ah, float* __restrict__ Bh,
    float* __restrict__ Dh, float* __restrict__ Eh)
{
    __shared__ short wt[256 * 72];
    __shared__ short xs[64 * 72];
    __shared__ float bl[256];

    const int tid = threadIdx.x;
    const int wave = tid >> 6;
    const int lane = tid & 63;
    const int r = lane & 15;
    const int q = lane >> 4;

    for (int i = tid; i < 2048; i += 256) {       // 256 n x 8 octets, resident
        int n = i >> 3, oct = i & 7;
        *(short8_t*)(wt + n * 72 + oct * 8) = *(const short8_t*)(NT + n * 64 + oct * 8);
    }
    if (tid < 64) bl[tid] = Ab[tid];
    else if (tid < 128) bl[tid] = Bb[tid - 64];
    else if (tid < 192) bl[tid] = Db[tid - 128];
    else bl[tid] = Eb[tid - 192];

    const int ntiles = (NNODES + 63) / 64;        // 391
    for (int t = blockIdx.x; t < ntiles; t += gridDim.x) {
        const int rowBase = t * 64;
        __syncthreads();
        for (int i = tid; i < 512; i += 256) {
            int row = i >> 3, oct = i & 7;
            int nr = rowBase + row;
            if (nr < NNODES) stage8(h + (long)nr * 64 + oct * 8, xs + row * 72 + oct * 8);
            else *(short8_t*)(xs + row * 72 + oct * 8) = (short8_t)0;
        }
        __syncthreads();
        float4_t acc[16];
        #pragma unroll
        for (int i = 0; i < 16; ++i) acc[i] = (float4_t)0.0f;
        #pragma unroll
        for (int kk = 0; kk < 2; ++kk) {
            short8_t a = *(const short8_t*)(xs + (wave * 16 + r) * 72 + kk * 32 + q * 8);
            #pragma unroll
            for (int nt = 0; nt < 16; ++nt) {
                short8_t b = *(const short8_t*)(wt + (nt * 16 + r) * 72 + kk * 32 + q * 8);
                acc[nt] = __builtin_amdgcn_mfma_f32_16x16x32_bf16(a, b, acc[nt], 0, 0, 0);
            }
        }
        #pragma unroll
        for (int nt = 0; nt < 16; ++nt) {
            float* Y = (nt < 4) ? Ah : (nt < 8) ? Bh : (nt < 12) ? Dh : Eh;
            int c = (nt & 3) * 16 + r;
            int n = nt * 16 + r;
            #pragma unroll
            for (int i2 = 0; i2 < 4; ++i2) {
                int row = rowBase + wave * 16 + q * 4 + i2;
                if (row < NNODES) Y[(long)row * 64 + c] = acc[nt][i2] + bl[n];
            }
        }
    }
}

// ---------------------------------------------------------------------------
// MFMA edge update (edges in dst-sorted order):
//   if BNIN: e = e + relu(bn(ehat_prev))   [in-place, feeds staged matmul]
//   ehat = e @ C + Cb + Dh[srcS] + Eh[dstS]  (Eh gather near-sequential)
//   + per-block BN partials of new ehat.
// ---------------------------------------------------------------------------
template<bool BNIN, typename TE, typename TH>
__global__ __launch_bounds__(256) void edge_update_mfma_kernel(
    TE* __restrict__ e, TH* __restrict__ ehat,
    const short* __restrict__ CT, const float* __restrict__ Cb,
    const float* __restrict__ Dh, const int* __restrict__ srcS,
    const float* __restrict__ Eh, const int* __restrict__ dstS,
    const float* __restrict__ stats_prev, const float* __restrict__ gprev,
    const float* __restrict__ bprev, float* __restrict__ partial)
{
    __shared__ short ct[64 * 72];
    __shared__ short xs[64 * 72];
    __shared__ float bl[64], scale[64], shift[64];
    __shared__ float ps[128];

    const int tid = threadIdx.x;
    const int wave = tid >> 6;
    const int lane = tid & 63;
    const int r = lane & 15;
    const int q = lane >> 4;

    for (int i = tid; i < 512; i += 256) {
        int n = i >> 3, oct = i & 7;
        *(short8_t*)(ct + n * 72 + oct * 8) = *(const short8_t*)(CT + n * 64 + oct * 8);
    }
    if (tid < 64) {
        bl[tid] = Cb[tid];
        if (BNIN) {
            float inv = 1.0f / (float)NEDGES;
            float mu = stats_prev[tid] * inv;
            float var = stats_prev[64 + tid] * inv - mu * mu;
            float rs = rsqrtf(var + BNEPS);
            float sc = rs * gprev[tid];
            scale[tid] = sc;
            shift[tid] = bprev[tid] - mu * sc;
        }
    }
    if (tid < 128) ps[tid] = 0.0f;
    float lsum[4] = {0, 0, 0, 0}, lsum2[4] = {0, 0, 0, 0};

    constexpr int NTILES = NEDGES / 64;
    for (int t = blockIdx.x; t < NTILES; t += gridDim.x) {
        const int rowBase = t * 64;
        __syncthreads();
        for (int i = tid; i < 512; i += 256) {
            int row = i >> 3, oct = i & 7;
            long idx = (long)(rowBase + row) * 64 + oct * 8;
            float4_t a = ldv4(e, idx), b = ldv4(e, idx + 4);
            if (BNIN) {
                float4_t ha = ldv4(ehat, idx), hb = ldv4(ehat, idx + 4);
                int k0 = oct * 8;
                #pragma unroll
                for (int c = 0; c < 4; ++c) {
                    a[c] += fmaxf(ha[c] * scale[k0 + c] + shift[k0 + c], 0.0f);
                    b[c] += fmaxf(hb[c] * scale[k0 + 4 + c] + shift[k0 + 4 + c], 0.0f);
                }
                stv4(e, idx, a); stv4(e, idx + 4, b);
            }
            short8_t v;
            v[0] = f2bs(a[0]); v[1] = f2bs(a[1]); v[2] = f2bs(a[2]); v[3] = f2bs(a[3]);
            v[4] = f2bs(b[0]); v[5] = f2bs(b[1]); v[6] = f2bs(b[2]); v[7] = f2bs(b[3]);
            *(short8_t*)(xs + row * 72 + oct * 8) = v;
        }
        __syncthreads();
        float4_t acc[4];
        #pragma unroll
        for (int i = 0; i < 4; ++i) acc[i] = (float4_t)0.0f;
        #pragma unroll
        for (int kk = 0; kk < 2; ++kk) {
            short8_t a = *(const short8_t*)(xs + (wave * 16 + r) * 72 + kk * 32 + q * 8);
            #pragma unroll
            for (int nt = 0; nt < 4; ++nt) {
                short8_t b = *(const short8_t*)(ct + (nt * 16 + r) * 72 + kk * 32 + q * 8);
                acc[nt] = __builtin_amdgcn_mfma_f32_16x16x32_bf16(a, b, acc[nt], 0, 0, 0);
            }
        }
        #pragma unroll
        for (int i2 = 0; i2 < 4; ++i2) {
            int row = wave * 16 + q * 4 + i2;
            int er = rowBase + row;
            int s = srcS[er], d = dstS[er];
            #pragma unroll
            for (int nt = 0; nt < 4; ++nt) {
                int col = nt * 16 + r;
                float v = acc[nt][i2] + bl[col]
                        + Dh[(long)s * 64 + col] + Eh[(long)d * 64 + col];
                stv(ehat, (long)er * 64 + col, v);
                lsum[nt] += v; lsum2[nt] += v * v;
            }
        }
    }
    __syncthreads();
    #pragma unroll
    for (int nt = 0; nt < 4; ++nt) {
        atomicAdd(&ps[nt * 16 + r], lsum[nt]);
        atomicAdd(&ps[64 + nt * 16 + r], lsum2[nt]);
    }
    __syncthreads();
    if (tid < 128) partial[(long)blockIdx.x * 128 + tid] = ps[tid];
}

// ---------------------------------------------------------------------------
// CSR build + edge permutation (graph static within a call)
// ---------------------------------------------------------------------------
__global__ __launch_bounds__(256) void deg_hist_kernel(
    const int* __restrict__ dst, int* __restrict__ rowptr, int rows)
{
    int e = blockIdx.x * 256 + threadIdx.x;
    if (e < rows) atomicAdd(&rowptr[dst[e] + 1], 1);
}

__global__ __launch_bounds__(1024) void scan_kernel(int* __restrict__ data, int n)
{
    __shared__ int buf[1024];
    __shared__ int carry;
    if (threadIdx.x == 0) carry = 0;
    __syncthreads();
    for (int base = 0; base < n; base += 1024) {
        int i = base + threadIdx.x;
        int v = (i < n) ? data[i] : 0;
        buf[threadIdx.x] = v;
        __syncthreads();
        for (int off = 1; off < 1024; off <<= 1) {
            int t = (threadIdx.x >= off) ? buf[threadIdx.x - off] : 0;
            __syncthreads();
            buf[threadIdx.x] += t;
            __syncthreads();
        }
        if (i < n) data[i] = buf[threadIdx.x] + carry;
        __syncthreads();
        if (threadIdx.x == 0) carry += buf[1023];
        __syncthreads();
    }
}

__global__ __launch_bounds__(256) void scatter_kernel(
    const int* __restrict__ dst, const int* __restrict__ rowptr,
    int* __restrict__ cursor, int* __restrict__ eid, int rows)
{
    int e = blockIdx.x * 256 + threadIdx.x;
    if (e < rows) {
        int d = dst[e];
        int pos = atomicAdd(&cursor[d], 1);
        eid[rowptr[d] + pos] = e;
    }
}

// inv/src/dst remap (pass 1), then rev remap (pass 2, needs complete inv)
__global__ __launch_bounds__(256) void remap1_kernel(
    const int* __restrict__ eid, const int* __restrict__ src,
    const int* __restrict__ dst, int* __restrict__ inv,
    int* __restrict__ srcS, int* __restrict__ dstS, int rows)
{
    int p = blockIdx.x * 256 + threadIdx.x;
    if (p < rows) {
        int orig = eid[p];
        inv[orig] = p;
        srcS[p] = src[orig];
        dstS[p] = dst[orig];
    }
}
__global__ __launch_bounds__(256) void remap2_kernel(
    const int* __restrict__ eid, const int* __restrict__ rev,
    const int* __restrict__ inv, int* __restrict__ revS, int rows)
{
    int p = blockIdx.x * 256 + threadIdx.x;
    if (p < rows) revS[p] = inv[rev[eid[p]]];
}

// ---------------------------------------------------------------------------
// Aggregation over dst-sorted edges: contiguous ehat rows per node.
// hhat[n] = Ah[n] + sum(sig*Bh[srcS]) / (sum(sig)+eps); fused BN partials.
// ---------------------------------------------------------------------------
template<typename TH>
__global__ __launch_bounds__(256) void agg_sorted_kernel(
    const TH* __restrict__ ehat, const float* __restrict__ Bh,
    const int* __restrict__ srcS, const int* __restrict__ rowptr,
    const float* __restrict__ Ah, float* __restrict__ hhat,
    float* __restrict__ partial)
{
    __shared__ float ps[64], ps2[64];
    const int tid = threadIdx.x;
    if (tid < 64) { ps[tid] = 0.0f; ps2[tid] = 0.0f; }
    __syncthreads();

    const int node = blockIdx.x * 4 + (tid >> 6);
    const int lane = tid & 63;
    const int sub = lane >> 4;
    const int c4 = (lane & 15) * 4;
    const int s0 = rowptr[node], s1 = rowptr[node + 1];

    float4_t den = (float4_t)0.0f, num = (float4_t)0.0f;
    for (int p = s0 + sub; p < s1; p += 4) {
        float4_t v = ldv4(ehat, (long)p * 64 + c4);
        float4_t bh = ldv4(Bh, (long)srcS[p] * 64 + c4);
        #pragma unroll
        for (int c = 0; c < 4; ++c) {
            float s = 1.0f / (1.0f + __expf(-v[c]));
            den[c] += s;
            num[c] += s * bh[c];
        }
    }
    #pragma unroll
    for (int m = 16; m <= 32; m <<= 1) {
        #pragma unroll
        for (int c = 0; c < 4; ++c) {
            den[c] += __shfl_xor(den[c], m, 64);
            num[c] += __shfl_xor(num[c], m, 64);
        }
    }
    if (sub == 0) {
        float4_t av = ldv4(Ah, (long)node * 64 + c4);
        float4_t hh;
        #pragma unroll
        for (int c = 0; c < 4; ++c) {
            hh[c] = av[c] + num[c] / (den[c] + AGGEPS);
            atomicAdd(&ps[c4 + c], hh[c]);
            atomicAdd(&ps2[c4 + c], hh[c] * hh[c]);
        }
        stv4(hhat, (long)node * 64 + c4, hh);
    }
    __syncthreads();
    if (tid < 64) {
        partial[(long)blockIdx.x * 128 + tid] = ps[tid];
        partial[(long)blockIdx.x * 128 + 64 + tid] = ps2[tid];
    }
}

// stats[c] = sum over blocks of partial[b][c]; grid = 128
__global__ __launch_bounds__(256) void reduce_stats_kernel(
    const float* __restrict__ partial, int nblk, float* __restrict__ stats)
{
    __shared__ float sb[256];
    int tid = threadIdx.x;
    float s = 0.0f;
    for (int i = tid; i < nblk; i += 256) s += partial[(long)i * 128 + blockIdx.x];
    sb[tid] = s;
    __syncthreads();
    for (int off = 128; off > 0; off >>= 1) {
        if (tid < off) sb[tid] += sb[tid + off];
        __syncthreads();
    }
    if (tid == 0) stats[blockIdx.x] = sb[0];
}

// base += relu((xhat-mu)*rstd*g + b), float4 per thread
template<typename TB, typename TX>
__global__ __launch_bounds__(256) void bn_apply4_kernel(
    TB* __restrict__ base, const TX* __restrict__ xhat,
    const float* __restrict__ stats, const float* __restrict__ g,
    const float* __restrict__ b, int rows)
{
    long total4 = (long)rows * 16;
    float inv = 1.0f / (float)rows;
    for (long q = (long)blockIdx.x * 256 + threadIdx.x; q < total4;
         q += (long)gridDim.x * 256) {
        long idx = q * 4;
        int c = (int)(idx & 63);
        float4_t x = ldv4(xhat, idx);
        float4_t bs = ldv4(base, idx);
        #pragma unroll
        for (int j = 0; j < 4; ++j) {
            float mu = stats[c + j] * inv;
            float var = stats[64 + c + j] * inv - mu * mu;
            float rs = rsqrtf(var + BNEPS);
            float v = (x[j] - mu) * rs * g[c + j] + b[c + j];
            bs[j] += fmaxf(v, 0.0f);
        }
        stv4(base, idx, bs);
    }
}

// one-shot weight prep: W0T [128][256], W1T [64][128], CT [l][64][64],
// NT [l][256][64] (A|B|D|E packed) — all bf16 transposed [n][k]
__global__ __launch_bounds__(256) void transpose_w_kernel(
    const float* __restrict__ W0, const float* __restrict__ W1,
    const float* __restrict__ C_w,
    const float* __restrict__ A_w, const float* __restrict__ B_w,
    const float* __restrict__ D_w, const float* __restrict__ E_w,
    short* __restrict__ W0T, short* __restrict__ W1T,
    short* __restrict__ CT, short* __restrict__ NT)
{
    int id = blockIdx.x * 256 + threadIdx.x;
    if (id < 256 * 128) {
        int k = id >> 7, n = id & 127;
        W0T[n * 256 + k] = f2bs(W0[id]);
    }
    if (id < 128 * 64) {
        int k = id >> 6, n = id & 63;
        W1T[n * 128 + k] = f2bs(W1[id]);
    }
    if (id < 4 * 64 * 64) {
        int l = id >> 12, rem = id & 4095, k = rem >> 6, n = rem & 63;
        CT[l * 4096 + n * 64 + k] = f2bs(C_w[l * 4096 + k * 64 + n]);
    }
    if (id < 4 * 256 * 64) {
        int l = id >> 14, rem = id & 16383, n = rem >> 6, k = rem & 63;
        int mat = n >> 6, c = n & 63;
        const float* Wm = (mat == 0) ? A_w : (mat == 1) ? B_w : (mat == 2) ? D_w : E_w;
        NT[l * 16384 + n * 64 + k] = f2bs(Wm[l * 4096 + k * 64 + c]);
    }
}

// ---------------------------------------------------------------------------
// MFMA MLP readout (edges in sorted order; out scatter-written via eid).
// ---------------------------------------------------------------------------
template<typename TE>
__global__ __launch_bounds__(256) void readout_mfma_kernel(
    const TE* __restrict__ e, const float* __restrict__ h,
    const int* __restrict__ srcS, const int* __restrict__ dstS,
    const int* __restrict__ revS, const int* __restrict__ eid,
    const short* __restrict__ W0T, const short* __restrict__ W1T,
    const float* __restrict__ b0, const float* __restrict__ b1,
    const float* __restrict__ W2, const float* __restrict__ b2,
    float* __restrict__ out)
{
    __shared__ short feat[64 * 72];
    __shared__ short wtile[128 * 72];
    __shared__ short x0t[64 * 136];
    __shared__ float smallb[322];

    const int tid = threadIdx.x;
    const int wave = tid >> 6;
    const int lane = tid & 63;
    const int r = lane & 15;
    const int q = lane >> 4;

    if (tid < 128) smallb[tid] = b0[tid];
    if (tid < 64)  smallb[128 + tid] = b1[tid];
    if (tid < 128) smallb[192 + tid] = W2[tid];
    if (tid < 2)   smallb[320 + tid] = b2[tid];

    constexpr int NTILES = NEDGES / 64;
    for (int t = blockIdx.x; t < NTILES; t += gridDim.x) {
        const int rowBase = t * 64;
        float4_t acc0[8];
        #pragma unroll
        for (int i = 0; i < 8; ++i) acc0[i] = (float4_t)0.0f;

        for (int s = 0; s < 4; ++s) {
            __syncthreads();
            for (int i = tid; i < 512; i += 256) {
                int row = i >> 3, oct = i & 7;
                int er = rowBase + row;
                short* d = feat + row * 72 + oct * 8;
                if (s == 0)      stage8(e + (long)er * 64 + oct * 8, d);
                else if (s == 1) stage8(e + (long)revS[er] * 64 + oct * 8, d);
                else if (s == 2) stage8(h + (long)srcS[er] * 64 + oct * 8, d);
                else             stage8(h + (long)dstS[er] * 64 + oct * 8, d);
            }
            for (int i = tid; i < 1024; i += 256) {
                int n = i >> 3, oct = i & 7;
                *(short8_t*)(wtile + n * 72 + oct * 8) =
                    *(const short8_t*)(W0T + (long)n * 256 + s * 64 + oct * 8);
            }
            __syncthreads();
            #pragma unroll
            for (int kk = 0; kk < 2; ++kk) {
                short8_t a = *(const short8_t*)(feat + (wave * 16 + r) * 72 + kk * 32 + q * 8);
                #pragma unroll
                for (int nt = 0; nt < 8; ++nt) {
                    short8_t b = *(const short8_t*)(wtile + (nt * 16 + r) * 72 + kk * 32 + q * 8);
                    acc0[nt] = __builtin_amdgcn_mfma_f32_16x16x32_bf16(a, b, acc0[nt], 0, 0, 0);
                }
            }
        }
        #pragma unroll
        for (int nt = 0; nt < 8; ++nt) {
            int col = nt * 16 + r;
            #pragma unroll
            for (int i2 = 0; i2 < 4; ++i2) {
                int row = wave * 16 + q * 4 + i2;
                x0t[row * 136 + col] = f2bs(fmaxf(acc0[nt][i2] + smallb[col], 0.0f));
            }
        }
        __syncthreads();
        for (int i = tid; i < 1024; i += 256) {
            int n = i >> 4, oct = i & 15;
            *(short8_t*)(wtile + n * 136 + oct * 8) =
                *(const short8_t*)(W1T + (long)n * 128 + oct * 8);
        }
        __syncthreads();
        float4_t acc1[4];
        #pragma unroll
        for (int i = 0; i < 4; ++i) acc1[i] = (float4_t)0.0f;
        #pragma unroll
        for (int kk = 0; kk < 4; ++kk) {
            short8_t a = *(const short8_t*)(x0t + (wave * 16 + r) * 136 + kk * 32 + q * 8);
            #pragma unroll
            for (int nt = 0; nt < 4; ++nt) {
                short8_t b = *(const short8_t*)(wtile + (nt * 16 + r) * 136 + kk * 32 + q * 8);
                acc1[nt] = __builtin_amdgcn_mfma_f32_16x16x32_bf16(a, b, acc1[nt], 0, 0, 0);
            }
        }
        #pragma unroll
        for (int nt = 0; nt < 4; ++nt) {
            int col = nt * 16 + r;
            #pragma unroll
            for (int i2 = 0; i2 < 4; ++i2) {
                int row = wave * 16 + q * 4 + i2;
                feat[row * 72 + col] = f2bs(fmaxf(acc1[nt][i2] + smallb[128 + col], 0.0f));
            }
        }
        __syncthreads();
        if (tid < 128) {
            int row = tid >> 1, cls = tid & 1;
            float a = smallb[320 + cls];
            #pragma unroll 8
            for (int k = 0; k < 64; ++k)
                a += bs2f(feat[row * 72 + k]) * smallb[192 + k * 2 + cls];
            out[(long)eid[rowBase + row] * 2 + cls] = a;
        }
    }
}

// ---------------------------------------------------------------------------
static inline int igrid(long total, int block, int cap) {
    long g = (total + block - 1) / block;
    return (int)(g < cap ? g : cap);
}

constexpr int GE_EDGE = 2048;
constexpr int GA_AGG  = NNODES / 4;  // 6250

template<typename TE, typename TH>
static void run_net(void* const* d_in, float* f, TE* e, TH* ehat,
                    float* out, hipStream_t stream)
{
    const float* h_in   = (const float*)d_in[0];
    const float* e_in   = (const float*)d_in[1];
    const int*   src    = (const int*)d_in[2];
    const int*   dst    = (const int*)d_in[3];
    const int*   rev    = (const int*)d_in[4];
    const float* emb_h_w = (const float*)d_in[5];
    const float* emb_h_b = (const float*)d_in[6];
    const float* emb_e_w = (const float*)d_in[7];
    const float* emb_e_b = (const float*)d_in[8];
    const float* A_w = (const float*)d_in[9];  const float* A_b = (const float*)d_in[10];
    const float* B_w = (const float*)d_in[11]; const float* B_b = (const float*)d_in[12];
    const float* C_w = (const float*)d_in[13]; const float* C_b = (const float*)d_in[14];
    const float* D_w = (const float*)d_in[15]; const float* D_b = (const float*)d_in[16];
    const float* E_w = (const float*)d_in[17]; const float* E_b = (const float*)d_in[18];
    // F/G (19..22) and bn_u (27,28) are dead: u never reaches the output.
    const float* bn_h_g = (const float*)d_in[23]; const float* bn_h_b = (const float*)d_in[24];
    const float* bn_e_g = (const float*)d_in[25]; const float* bn_e_b = (const float*)d_in[26];
    const float* W0 = (const float*)d_in[29]; const float* b0 = (const float*)d_in[30];
    const float* W1 = (const float*)d_in[31]; const float* b1 = (const float*)d_in[32];
    const float* W2 = (const float*)d_in[33]; const float* b2 = (const float*)d_in[34];

    const size_t NH = (size_t)NNODES * DD;
    float* h    = f;
    float* Ah   = f + NH;
    float* Bh   = f + 2 * NH;
    float* Dh   = f + 3 * NH;      // hhat aliases Dh (Dh dead after edge_update)
    float* Eh   = f + 4 * NH;
    float* hhat = Dh;
    float* stats_h  = f + 5 * NH;           // 128
    float* stats_e  = stats_h + 128;        // 128
    float* partial_e = f + 5 * NH + 512;    // 2048*128
    float* partial_h = partial_e + (size_t)GE_EDGE * 128;   // 6250*128
    int* rowptr = (int*)(partial_h + (size_t)GA_AGG * 128); // 25001
    int* cursor = rowptr + NNODES + 1;      // 25000
    int* eid    = cursor + NNODES;          // 400000 (the dst-sort permutation)
    int* inv    = eid + NEDGES;             // 400000
    int* srcS   = inv + NEDGES;             // 400000
    int* dstS   = srcS + NEDGES;            // 400000
    int* revS   = dstS + NEDGES;            // 400000
    short* W0T  = (short*)(revS + NEDGES);  // 32768 shorts
    short* W1T  = W0T + 256 * 128;          // 8192
    short* CT   = W1T + 128 * 64;           // 16384
    short* NT   = CT + 4 * 4096;            // 65536

    const int GN = 1563;
    const int GEDGE = (NEDGES + 255) / 256;

    // CSR + permutation + weight prep (once per call; graph static)
    hipMemsetAsync(rowptr, 0, (2 * NNODES + 1) * sizeof(int), stream);
    deg_hist_kernel<<<GEDGE, 256, 0, stream>>>(dst, rowptr, NEDGES);
    scan_kernel<<<1, 1024, 0, stream>>>(rowptr, NNODES + 1);
    scatter_kernel<<<GEDGE, 256, 0, stream>>>(dst, rowptr, cursor, eid, NEDGES);
    remap1_kernel<<<GEDGE, 256, 0, stream>>>(eid, src, dst, inv, srcS, dstS, NEDGES);
    remap2_kernel<<<GEDGE, 256, 0, stream>>>(eid, rev, inv, revS, NEDGES);
    transpose_w_kernel<<<256, 256, 0, stream>>>(W0, W1, C_w, A_w, B_w, D_w, E_w,
                                                W0T, W1T, CT, NT);

    // embeddings (e in dst-sorted order via eid gather)
    linear_kernel<64, 64, 4, float, float><<<GN, 256, 0, stream>>>(
        h_in, emb_h_w, emb_h_b, h, nullptr, NNODES);
    linear_kernel<16, 64, 4, float, TE><<<4096, 256, 0, stream>>>(
        e_in, emb_e_w, emb_e_b, e, eid, NEDGES);

    for (int l = 0; l < 4; ++l) {
        const size_t o = (size_t)l * DD * DD;
        // all 4 node linears in one MFMA pass
        node_linear4_mfma_kernel<<<391, 256, 0, stream>>>(
            h, NT + (size_t)l * 16384,
            A_b + l * DD, B_b + l * DD, D_b + l * DD, E_b + l * DD,
            Ah, Bh, Dh, Eh);

        // MFMA edge update: (prev BN_e fused) + C-matmul + gathers + stats
        if (l == 0)
            edge_update_mfma_kernel<false, TE, TH><<<GE_EDGE, 256, 0, stream>>>(
                e, ehat, CT + o, C_b + l * DD, Dh, srcS, Eh, dstS,
                nullptr, nullptr, nullptr, partial_e);
        else
            edge_update_mfma_kernel<true, TE, TH><<<GE_EDGE, 256, 0, stream>>>(
                e, ehat, CT + o, C_b + l * DD, Dh, srcS, Eh, dstS,
                stats_e, bn_e_g + (l - 1) * DD, bn_e_b + (l - 1) * DD, partial_e);
        reduce_stats_kernel<<<128, 256, 0, stream>>>(partial_e, GE_EDGE, stats_e);

        // sorted aggregation (contiguous ehat) + fused hhat + BN partials
        agg_sorted_kernel<TH><<<GA_AGG, 256, 0, stream>>>(
            ehat, Bh, srcS, rowptr, Ah, hhat, partial_h);
        reduce_stats_kernel<<<128, 256, 0, stream>>>(partial_h, GA_AGG, stats_h);

        // h += relu(bn(hhat))
        bn_apply4_kernel<float, float><<<igrid((long)NNODES * 16, 256, 8192), 256, 0, stream>>>(
            h, hhat, stats_h, bn_h_g + l * DD, bn_h_b + l * DD, NNODES);
    }
    // final e update
    bn_apply4_kernel<TE, TH><<<igrid((long)NEDGES * 16, 256, 8192), 256, 0, stream>>>(
        e, ehat, stats_e, bn_e_g + 3 * DD, bn_e_b + 3 * DD, NEDGES);

    // MFMA readout (scatter-writes out back to original edge order)
    readout_mfma_kernel<TE><<<2048, 256, 0, stream>>>(e, h, srcS, dstS, revS, eid,
                                                      W0T, W1T, b0, b1, W2, b2, out);
}

extern "C" void kernel_launch(void* const* d_in, const int* in_sizes, int n_in,
                              void* d_out, int out_size, void* d_ws, size_t ws_size,
                              hipStream_t stream)
{
    const size_t NH = (size_t)NNODES * DD;       // 1.6M floats
    const size_t NE = (size_t)NEDGES * DD;       // 25.6M elems
    const size_t baseB = (7 * NH + 256) * sizeof(float);   // 44.8 MB node region
    // internal: 5NH + 512 + partials (2048+6250)*128 + ints (5*400000+50001)
    // + shorts 122880 ≈ 44.7 MB — fits baseB.

    char* base = (char*)d_ws;
    char* edge = base + baseB;
    float* out = (float*)d_out;

    const size_t needA = baseB + NE * 4 * 2;          // fp32 e + fp32 ehat
    const size_t needB = baseB + NE * 4 + NE * 2;     // fp32 e + bf16 ehat
    const size_t needC = baseB + NE * 2 * 2;          // bf16 e + bf16 ehat

    if (ws_size >= needA) {
        run_net<float, float>(d_in, (float*)base, (float*)edge,
                              (float*)(edge + NE * 4), out, stream);
    } else if (ws_size >= needB) {
        run_net<float, __hip_bfloat16>(d_in, (float*)base, (float*)edge,
                                       (__hip_bfloat16*)(edge + NE * 4), out, stream);
    } else if (ws_size >= needC) {
        run_net<__hip_bfloat16, __hip_bfloat16>(d_in, (float*)base, (__hip_bfloat16*)edge,
                                                (__hip_bfloat16*)(edge + NE * 2), out, stream);
    } else {
        // diagnostic fallback: workspace too small — emit zeros, don't fault
        hipMemsetAsync(d_out, 0, (size_t)out_size * sizeof(float), stream);
    }
}

// Round 9
// 1051.341 us; speedup vs baseline: 3.8374x; 1.0409x over previous
//
#include <hip/hip_runtime.h>
#include <hip/hip_bf16.h>

constexpr int NNODES = 25000;
constexpr int NEDGES = 400000;
constexpr int DD = 64;
constexpr float BNEPS = 1e-5f;
constexpr float AGGEPS = 1e-6f;

typedef __attribute__((ext_vector_type(8))) short short8_t;
typedef __attribute__((ext_vector_type(4))) short short4_t;
typedef __attribute__((ext_vector_type(4))) float float4_t;

// storage-type helpers (compute is always fp32)
__device__ __forceinline__ float ldv(const float* p, long i) { return p[i]; }
__device__ __forceinline__ float ldv(const __hip_bfloat16* p, long i) { return __bfloat162float(p[i]); }
__device__ __forceinline__ void stv(float* p, long i, float v) { p[i] = v; }
__device__ __forceinline__ void stv(__hip_bfloat16* p, long i, float v) { p[i] = __float2bfloat16(v); }

__device__ __forceinline__ short f2bs(float f) {
    union { float f; unsigned u; } x; x.f = f;
    unsigned r = x.u + 0x7FFFu + ((x.u >> 16) & 1u);
    return (short)(r >> 16);
}
__device__ __forceinline__ float bs2f(short s) {
    union { unsigned u; float f; } x; x.u = ((unsigned)(unsigned short)s) << 16; return x.f;
}

__device__ __forceinline__ float4_t ldv4(const float* p, long i) {
    return *(const float4_t*)(p + i);
}
__device__ __forceinline__ float4_t ldv4(const __hip_bfloat16* p, long i) {
    short4_t s = *(const short4_t*)(p + i);
    float4_t r;
    #pragma unroll
    for (int c = 0; c < 4; ++c) r[c] = bs2f(s[c]);
    return r;
}
__device__ __forceinline__ void stv4(float* p, long i, float4_t v) {
    *(float4_t*)(p + i) = v;
}
__device__ __forceinline__ void stv4(__hip_bfloat16* p, long i, float4_t v) {
    short4_t s;
    #pragma unroll
    for (int c = 0; c < 4; ++c) s[c] = f2bs(v[c]);
    *(short4_t*)(p + i) = s;
}

__device__ __forceinline__ void stage8(const __hip_bfloat16* s, short* d) {
    *(short8_t*)d = *(const short8_t*)s;
}
__device__ __forceinline__ void stage8(const float* s, short* d) {
    float4_t a = *(const float4_t*)s;
    float4_t b = *(const float4_t*)(s + 4);
    short8_t v;
    v[0] = f2bs(a[0]); v[1] = f2bs(a[1]); v[2] = f2bs(a[2]); v[3] = f2bs(a[3]);
    v[4] = f2bs(b[0]); v[5] = f2bs(b[1]); v[6] = f2bs(b[2]); v[7] = f2bs(b[3]);
    *(short8_t*)d = v;
}

// ---------------------------------------------------------------------------
// Generic LDS-tiled linear (embeddings), optional row-gather on X.
// ---------------------------------------------------------------------------
template<int K, int N, int JR, typename TX, typename TY>
__global__ __launch_bounds__(256) void linear_kernel(
    const TX* __restrict__ X, const float* __restrict__ W,
    const float* __restrict__ Bb, TY* __restrict__ Y,
    const int* __restrict__ gather, int rows)
{
    constexpr int SLOTS = 256 / N;
    constexpr int RPG = SLOTS * JR;
    __shared__ float wl[K * N];
    __shared__ float bl[N];
    __shared__ float xl[RPG * K];

    const int tid = threadIdx.x;
    for (int i = tid; i < K * N; i += 256) wl[i] = W[i];
    if (tid < N) bl[tid] = Bb[tid];

    const int col = tid % N;
    const int slot = tid / N;

    const int ngroups = (rows + RPG - 1) / RPG;
    for (int g = blockIdx.x; g < ngroups; g += gridDim.x) {
        const int rowBase = g * RPG;
        __syncthreads();
        for (int i = tid; i < RPG * K; i += 256) {
            int r = i / K, k = i - r * K;
            int row = rowBase + r;
            float v = 0.0f;
            if (row < rows) {
                int sr = gather ? gather[row] : row;
                v = ldv(X, (long)sr * K + k);
            }
            xl[i] = v;
        }
        __syncthreads();
        float acc[JR];
        #pragma unroll
        for (int j = 0; j < JR; ++j) acc[j] = bl[col];
        #pragma unroll 4
        for (int k = 0; k < K; ++k) {
            float w = wl[k * N + col];
            #pragma unroll
            for (int j = 0; j < JR; ++j)
                acc[j] += xl[(slot * JR + j) * K + k] * w;
        }
        #pragma unroll
        for (int j = 0; j < JR; ++j) {
            int row = rowBase + slot * JR + j;
            if (row < rows) stv(Y, (long)row * N + col, acc[j]);
        }
    }
}

// ---------------------------------------------------------------------------
// Quad node linear, MFMA: {Ah,Bh,Dh,Eh} = h @ {A,B,D,E} + biases.
// If BNIN: h = h + relu(bn(hhat; stats_prev)) in place first (feeds matmul).
// ---------------------------------------------------------------------------
template<bool BNIN>
__global__ __launch_bounds__(256) void node_linear4_mfma_kernel(
    float* __restrict__ h, const float* __restrict__ hhat,
    const short* __restrict__ NT,
    const float* __restrict__ Ab, const float* __restrict__ Bb,
    const float* __restrict__ Db, const float* __restrict__ Eb,
    const float* __restrict__ stats_prev, const float* __restrict__ gprev,
    const float* __restrict__ bprev,
    float* __restrict__ Ah, float* __restrict__ Bh,
    float* __restrict__ Dh, float* __restrict__ Eh)
{
    __shared__ short wt[256 * 72];
    __shared__ short xs[64 * 72];
    __shared__ float bl[256];
    __shared__ float scale[64], shift[64];

    const int tid = threadIdx.x;
    const int wave = tid >> 6;
    const int lane = tid & 63;
    const int r = lane & 15;
    const int q = lane >> 4;

    for (int i = tid; i < 2048; i += 256) {
        int n = i >> 3, oct = i & 7;
        *(short8_t*)(wt + n * 72 + oct * 8) = *(const short8_t*)(NT + n * 64 + oct * 8);
    }
    if (tid < 64) bl[tid] = Ab[tid];
    else if (tid < 128) bl[tid] = Bb[tid - 64];
    else if (tid < 192) bl[tid] = Db[tid - 128];
    else bl[tid] = Eb[tid - 192];
    if (BNIN && tid < 64) {
        float inv = 1.0f / (float)NNODES;
        float mu = stats_prev[tid] * inv;
        float var = stats_prev[64 + tid] * inv - mu * mu;
        float rs = rsqrtf(var + BNEPS);
        float sc = rs * gprev[tid];
        scale[tid] = sc;
        shift[tid] = bprev[tid] - mu * sc;
    }

    const int ntiles = (NNODES + 63) / 64;        // 391
    for (int t = blockIdx.x; t < ntiles; t += gridDim.x) {
        const int rowBase = t * 64;
        __syncthreads();
        for (int i = tid; i < 512; i += 256) {
            int row = i >> 3, oct = i & 7;
            int nr = rowBase + row;
            if (nr < NNODES) {
                long idx = (long)nr * 64 + oct * 8;
                float4_t a = ldv4(h, idx), b = ldv4(h, idx + 4);
                if (BNIN) {
                    float4_t ha = ldv4(hhat, idx), hb = ldv4(hhat, idx + 4);
                    int k0 = oct * 8;
                    #pragma unroll
                    for (int c = 0; c < 4; ++c) {
                        a[c] += fmaxf(ha[c] * scale[k0 + c] + shift[k0 + c], 0.0f);
                        b[c] += fmaxf(hb[c] * scale[k0 + 4 + c] + shift[k0 + 4 + c], 0.0f);
                    }
                    stv4(h, idx, a); stv4(h, idx + 4, b);
                }
                short8_t v;
                v[0] = f2bs(a[0]); v[1] = f2bs(a[1]); v[2] = f2bs(a[2]); v[3] = f2bs(a[3]);
                v[4] = f2bs(b[0]); v[5] = f2bs(b[1]); v[6] = f2bs(b[2]); v[7] = f2bs(b[3]);
                *(short8_t*)(xs + row * 72 + oct * 8) = v;
            } else {
                *(short8_t*)(xs + row * 72 + oct * 8) = (short8_t)0;
            }
        }
        __syncthreads();
        float4_t acc[16];
        #pragma unroll
        for (int i = 0; i < 16; ++i) acc[i] = (float4_t)0.0f;
        #pragma unroll
        for (int kk = 0; kk < 2; ++kk) {
            short8_t a = *(const short8_t*)(xs + (wave * 16 + r) * 72 + kk * 32 + q * 8);
            #pragma unroll
            for (int nt = 0; nt < 16; ++nt) {
                short8_t b = *(const short8_t*)(wt + (nt * 16 + r) * 72 + kk * 32 + q * 8);
                acc[nt] = __builtin_amdgcn_mfma_f32_16x16x32_bf16(a, b, acc[nt], 0, 0, 0);
            }
        }
        #pragma unroll
        for (int nt = 0; nt < 16; ++nt) {
            float* Y = (nt < 4) ? Ah : (nt < 8) ? Bh : (nt < 12) ? Dh : Eh;
            int c = (nt & 3) * 16 + r;
            int n = nt * 16 + r;
            #pragma unroll
            for (int i2 = 0; i2 < 4; ++i2) {
                int row = rowBase + wave * 16 + q * 4 + i2;
                if (row < NNODES) Y[(long)row * 64 + c] = acc[nt][i2] + bl[n];
            }
        }
    }
}

// ---------------------------------------------------------------------------
// MFMA edge update (edges in dst-sorted order) — validated in R7/R8.
// ---------------------------------------------------------------------------
template<bool BNIN, typename TE, typename TH>
__global__ __launch_bounds__(256) void edge_update_mfma_kernel(
    TE* __restrict__ e, TH* __restrict__ ehat,
    const short* __restrict__ CT, const float* __restrict__ Cb,
    const float* __restrict__ Dh, const int* __restrict__ srcS,
    const float* __restrict__ Eh, const int* __restrict__ dstS,
    const float* __restrict__ stats_prev, const float* __restrict__ gprev,
    const float* __restrict__ bprev, float* __restrict__ partial)
{
    __shared__ short ct[64 * 72];
    __shared__ short xs[64 * 72];
    __shared__ float bl[64], scale[64], shift[64];
    __shared__ float ps[128];

    const int tid = threadIdx.x;
    const int wave = tid >> 6;
    const int lane = tid & 63;
    const int r = lane & 15;
    const int q = lane >> 4;

    for (int i = tid; i < 512; i += 256) {
        int n = i >> 3, oct = i & 7;
        *(short8_t*)(ct + n * 72 + oct * 8) = *(const short8_t*)(CT + n * 64 + oct * 8);
    }
    if (tid < 64) {
        bl[tid] = Cb[tid];
        if (BNIN) {
            float inv = 1.0f / (float)NEDGES;
            float mu = stats_prev[tid] * inv;
            float var = stats_prev[64 + tid] * inv - mu * mu;
            float rs = rsqrtf(var + BNEPS);
            float sc = rs * gprev[tid];
            scale[tid] = sc;
            shift[tid] = bprev[tid] - mu * sc;
        }
    }
    if (tid < 128) ps[tid] = 0.0f;
    float lsum[4] = {0, 0, 0, 0}, lsum2[4] = {0, 0, 0, 0};

    constexpr int NTILES = NEDGES / 64;
    for (int t = blockIdx.x; t < NTILES; t += gridDim.x) {
        const int rowBase = t * 64;
        __syncthreads();
        for (int i = tid; i < 512; i += 256) {
            int row = i >> 3, oct = i & 7;
            long idx = (long)(rowBase + row) * 64 + oct * 8;
            float4_t a = ldv4(e, idx), b = ldv4(e, idx + 4);
            if (BNIN) {
                float4_t ha = ldv4(ehat, idx), hb = ldv4(ehat, idx + 4);
                int k0 = oct * 8;
                #pragma unroll
                for (int c = 0; c < 4; ++c) {
                    a[c] += fmaxf(ha[c] * scale[k0 + c] + shift[k0 + c], 0.0f);
                    b[c] += fmaxf(hb[c] * scale[k0 + 4 + c] + shift[k0 + 4 + c], 0.0f);
                }
                stv4(e, idx, a); stv4(e, idx + 4, b);
            }
            short8_t v;
            v[0] = f2bs(a[0]); v[1] = f2bs(a[1]); v[2] = f2bs(a[2]); v[3] = f2bs(a[3]);
            v[4] = f2bs(b[0]); v[5] = f2bs(b[1]); v[6] = f2bs(b[2]); v[7] = f2bs(b[3]);
            *(short8_t*)(xs + row * 72 + oct * 8) = v;
        }
        __syncthreads();
        float4_t acc[4];
        #pragma unroll
        for (int i = 0; i < 4; ++i) acc[i] = (float4_t)0.0f;
        #pragma unroll
        for (int kk = 0; kk < 2; ++kk) {
            short8_t a = *(const short8_t*)(xs + (wave * 16 + r) * 72 + kk * 32 + q * 8);
            #pragma unroll
            for (int nt = 0; nt < 4; ++nt) {
                short8_t b = *(const short8_t*)(ct + (nt * 16 + r) * 72 + kk * 32 + q * 8);
                acc[nt] = __builtin_amdgcn_mfma_f32_16x16x32_bf16(a, b, acc[nt], 0, 0, 0);
            }
        }
        #pragma unroll
        for (int i2 = 0; i2 < 4; ++i2) {
            int row = wave * 16 + q * 4 + i2;
            int er = rowBase + row;
            int s = srcS[er], d = dstS[er];
            #pragma unroll
            for (int nt = 0; nt < 4; ++nt) {
                int col = nt * 16 + r;
                float v = acc[nt][i2] + bl[col]
                        + Dh[(long)s * 64 + col] + Eh[(long)d * 64 + col];
                stv(ehat, (long)er * 64 + col, v);
                lsum[nt] += v; lsum2[nt] += v * v;
            }
        }
    }
    __syncthreads();
    #pragma unroll
    for (int nt = 0; nt < 4; ++nt) {
        atomicAdd(&ps[nt * 16 + r], lsum[nt]);
        atomicAdd(&ps[64 + nt * 16 + r], lsum2[nt]);
    }
    __syncthreads();
    if (tid < 128) partial[(long)blockIdx.x * 128 + tid] = ps[tid];
}

// ---------------------------------------------------------------------------
// CSR build + edge permutation
// ---------------------------------------------------------------------------
__global__ __launch_bounds__(256) void deg_hist_kernel(
    const int* __restrict__ dst, int* __restrict__ rowptr, int rows)
{
    int e = blockIdx.x * 256 + threadIdx.x;
    if (e < rows) atomicAdd(&rowptr[dst[e] + 1], 1);
}

__global__ __launch_bounds__(1024) void scan_kernel(int* __restrict__ data, int n)
{
    __shared__ int buf[1024];
    __shared__ int carry;
    if (threadIdx.x == 0) carry = 0;
    __syncthreads();
    for (int base = 0; base < n; base += 1024) {
        int i = base + threadIdx.x;
        int v = (i < n) ? data[i] : 0;
        buf[threadIdx.x] = v;
        __syncthreads();
        for (int off = 1; off < 1024; off <<= 1) {
            int t = (threadIdx.x >= off) ? buf[threadIdx.x - off] : 0;
            __syncthreads();
            buf[threadIdx.x] += t;
            __syncthreads();
        }
        if (i < n) data[i] = buf[threadIdx.x] + carry;
        __syncthreads();
        if (threadIdx.x == 0) carry += buf[1023];
        __syncthreads();
    }
}

__global__ __launch_bounds__(256) void scatter_kernel(
    const int* __restrict__ dst, const int* __restrict__ rowptr,
    int* __restrict__ cursor, int* __restrict__ eid, int rows)
{
    int e = blockIdx.x * 256 + threadIdx.x;
    if (e < rows) {
        int d = dst[e];
        int pos = atomicAdd(&cursor[d], 1);
        eid[rowptr[d] + pos] = e;
    }
}

__global__ __launch_bounds__(256) void remap1_kernel(
    const int* __restrict__ eid, const int* __restrict__ src,
    const int* __restrict__ dst, int* __restrict__ inv,
    int* __restrict__ srcS, int* __restrict__ dstS, int rows)
{
    int p = blockIdx.x * 256 + threadIdx.x;
    if (p < rows) {
        int orig = eid[p];
        inv[orig] = p;
        srcS[p] = src[orig];
        dstS[p] = dst[orig];
    }
}

// ---------------------------------------------------------------------------
// Sorted aggregation + fused hhat + BN partials — validated in R8.
// ---------------------------------------------------------------------------
template<typename TH>
__global__ __launch_bounds__(256) void agg_sorted_kernel(
    const TH* __restrict__ ehat, const float* __restrict__ Bh,
    const int* __restrict__ srcS, const int* __restrict__ rowptr,
    const float* __restrict__ Ah, float* __restrict__ hhat,
    float* __restrict__ partial)
{
    __shared__ float ps[64], ps2[64];
    const int tid = threadIdx.x;
    if (tid < 64) { ps[tid] = 0.0f; ps2[tid] = 0.0f; }
    __syncthreads();

    const int node = blockIdx.x * 4 + (tid >> 6);
    const int lane = tid & 63;
    const int sub = lane >> 4;
    const int c4 = (lane & 15) * 4;
    const int s0 = rowptr[node], s1 = rowptr[node + 1];

    float4_t den = (float4_t)0.0f, num = (float4_t)0.0f;
    for (int p = s0 + sub; p < s1; p += 4) {
        float4_t v = ldv4(ehat, (long)p * 64 + c4);
        float4_t bh = ldv4(Bh, (long)srcS[p] * 64 + c4);
        #pragma unroll
        for (int c = 0; c < 4; ++c) {
            float s = 1.0f / (1.0f + __expf(-v[c]));
            den[c] += s;
            num[c] += s * bh[c];
        }
    }
    #pragma unroll
    for (int m = 16; m <= 32; m <<= 1) {
        #pragma unroll
        for (int c = 0; c < 4; ++c) {
            den[c] += __shfl_xor(den[c], m, 64);
            num[c] += __shfl_xor(num[c], m, 64);
        }
    }
    if (sub == 0) {
        float4_t av = ldv4(Ah, (long)node * 64 + c4);
        float4_t hh;
        #pragma unroll
        for (int c = 0; c < 4; ++c) {
            hh[c] = av[c] + num[c] / (den[c] + AGGEPS);
            atomicAdd(&ps[c4 + c], hh[c]);
            atomicAdd(&ps2[c4 + c], hh[c] * hh[c]);
        }
        stv4(hhat, (long)node * 64 + c4, hh);
    }
    __syncthreads();
    if (tid < 64) {
        partial[(long)blockIdx.x * 128 + tid] = ps[tid];
        partial[(long)blockIdx.x * 128 + 64 + tid] = ps2[tid];
    }
}

// merged stats reduce: blocks 0..127 -> stats_e, 128..255 -> stats_h
__global__ __launch_bounds__(256) void reduce_stats2_kernel(
    const float* __restrict__ pe, int ne, float* __restrict__ se,
    const float* __restrict__ ph, int nh, float* __restrict__ sh)
{
    __shared__ float sb[256];
    const float* partial; int nblk; float* stats; int col;
    if (blockIdx.x < 128) { partial = pe; nblk = ne; stats = se; col = blockIdx.x; }
    else                  { partial = ph; nblk = nh; stats = sh; col = blockIdx.x - 128; }
    int tid = threadIdx.x;
    float s = 0.0f;
    for (int i = tid; i < nblk; i += 256) s += partial[(long)i * 128 + col];
    sb[tid] = s;
    __syncthreads();
    for (int off = 128; off > 0; off >>= 1) {
        if (tid < off) sb[tid] += sb[tid + off];
        __syncthreads();
    }
    if (tid == 0) stats[col] = sb[0];
}

// base += relu((xhat-mu)*rstd*g + b), float4 per thread (in place)
template<typename TB, typename TX>
__global__ __launch_bounds__(256) void bn_apply4_kernel(
    TB* __restrict__ base, const TX* __restrict__ xhat,
    const float* __restrict__ stats, const float* __restrict__ g,
    const float* __restrict__ b, int rows)
{
    long total4 = (long)rows * 16;
    float inv = 1.0f / (float)rows;
    for (long q = (long)blockIdx.x * 256 + threadIdx.x; q < total4;
         q += (long)gridDim.x * 256) {
        long idx = q * 4;
        int c = (int)(idx & 63);
        float4_t x = ldv4(xhat, idx);
        float4_t bs = ldv4(base, idx);
        #pragma unroll
        for (int j = 0; j < 4; ++j) {
            float mu = stats[c + j] * inv;
            float var = stats[64 + c + j] * inv - mu * mu;
            float rs = rsqrtf(var + BNEPS);
            float v = (x[j] - mu) * rs * g[c + j] + b[c + j];
            bs[j] += fmaxf(v, 0.0f);
        }
        stv4(base, idx, bs);
    }
}

// fused final e update + scatter to original order (dedicated eorig buffer):
// eorig[eid[p]] = bf16(e[p] + relu(bn(ehat[p])))
template<typename TE, typename TH>
__global__ __launch_bounds__(256) void bnfinal_scatter_kernel(
    const TE* __restrict__ e, const TH* __restrict__ ehat,
    const int* __restrict__ eid, const float* __restrict__ stats,
    const float* __restrict__ g, const float* __restrict__ b,
    __hip_bfloat16* __restrict__ eorig)
{
    __shared__ float scale[64], shift[64];
    const int tid = threadIdx.x;
    if (tid < 64) {
        float inv = 1.0f / (float)NEDGES;
        float mu = stats[tid] * inv;
        float var = stats[64 + tid] * inv - mu * mu;
        float rs = rsqrtf(var + BNEPS);
        float sc = rs * g[tid];
        scale[tid] = sc;
        shift[tid] = b[tid] - mu * sc;
    }
    __syncthreads();
    long total = (long)NEDGES * 8;
    for (long i = (long)blockIdx.x * 256 + tid; i < total; i += (long)gridDim.x * 256) {
        int p = (int)(i >> 3), oct = (int)(i & 7);
        int k0 = oct * 8;
        long idx = (long)p * 64 + k0;
        float4_t a = ldv4(e, idx), b4 = ldv4(e, idx + 4);
        float4_t ha = ldv4(ehat, idx), hb = ldv4(ehat, idx + 4);
        short8_t v;
        #pragma unroll
        for (int c = 0; c < 4; ++c) {
            v[c]     = f2bs(a[c]  + fmaxf(ha[c] * scale[k0 + c]     + shift[k0 + c], 0.0f));
            v[4 + c] = f2bs(b4[c] + fmaxf(hb[c] * scale[k0 + 4 + c] + shift[k0 + 4 + c], 0.0f));
        }
        *(short8_t*)((short*)eorig + (long)eid[p] * 64 + k0) = v;
    }
}

// two-pass fallback: permute updated e (sorted) -> bf16 eorig (original order)
template<typename TE>
__global__ __launch_bounds__(256) void permute_e_kernel(
    const TE* __restrict__ e, const int* __restrict__ eid,
    __hip_bfloat16* __restrict__ eorig)
{
    long total = (long)NEDGES * 8;
    for (long i = (long)blockIdx.x * 256 + threadIdx.x; i < total;
         i += (long)gridDim.x * 256) {
        int p = (int)(i >> 3), oct = (int)(i & 7);
        long idx = (long)p * 64 + oct * 8;
        float4_t a = ldv4(e, idx), b = ldv4(e, idx + 4);
        short8_t v;
        #pragma unroll
        for (int c = 0; c < 4; ++c) { v[c] = f2bs(a[c]); v[4 + c] = f2bs(b[c]); }
        *(short8_t*)((short*)eorig + (long)eid[p] * 64 + oct * 8) = v;
    }
}

// Hs = h_fin @ W0c + b0, Hd = h_fin @ W0d, with h_fin = h + relu(bn(hhat))
// computed on the fly (no h writeback; h is dead afterwards).
__global__ __launch_bounds__(256) void precompute_H_kernel(
    const float* __restrict__ h, const float* __restrict__ hhat,
    const float* __restrict__ stats, const float* __restrict__ g,
    const float* __restrict__ b,
    const short* __restrict__ HT, const float* __restrict__ b0,
    float* __restrict__ Hs, float* __restrict__ Hd)
{
    __shared__ short wt[256 * 72];
    __shared__ short xs[64 * 72];
    __shared__ float bl[256];
    __shared__ float scale[64], shift[64];

    const int tid = threadIdx.x;
    const int wave = tid >> 6;
    const int lane = tid & 63;
    const int r = lane & 15;
    const int q = lane >> 4;

    for (int i = tid; i < 2048; i += 256) {
        int n = i >> 3, oct = i & 7;
        *(short8_t*)(wt + n * 72 + oct * 8) = *(const short8_t*)(HT + n * 64 + oct * 8);
    }
    bl[tid] = (tid < 128) ? b0[tid] : 0.0f;
    if (tid < 64) {
        float inv = 1.0f / (float)NNODES;
        float mu = stats[tid] * inv;
        float var = stats[64 + tid] * inv - mu * mu;
        float rs = rsqrtf(var + BNEPS);
        float sc = rs * g[tid];
        scale[tid] = sc;
        shift[tid] = b[tid] - mu * sc;
    }

    const int ntiles = (NNODES + 63) / 64;
    for (int t = blockIdx.x; t < ntiles; t += gridDim.x) {
        const int rowBase = t * 64;
        __syncthreads();
        for (int i = tid; i < 512; i += 256) {
            int row = i >> 3, oct = i & 7;
            int nr = rowBase + row;
            if (nr < NNODES) {
                long idx = (long)nr * 64 + oct * 8;
                float4_t a = ldv4(h, idx), bb = ldv4(h, idx + 4);
                float4_t ha = ldv4(hhat, idx), hb = ldv4(hhat, idx + 4);
                int k0 = oct * 8;
                #pragma unroll
                for (int c = 0; c < 4; ++c) {
                    a[c]  += fmaxf(ha[c] * scale[k0 + c]     + shift[k0 + c], 0.0f);
                    bb[c] += fmaxf(hb[c] * scale[k0 + 4 + c] + shift[k0 + 4 + c], 0.0f);
                }
                short8_t v;
                v[0] = f2bs(a[0]); v[1] = f2bs(a[1]); v[2] = f2bs(a[2]); v[3] = f2bs(a[3]);
                v[4] = f2bs(bb[0]); v[5] = f2bs(bb[1]); v[6] = f2bs(bb[2]); v[7] = f2bs(bb[3]);
                *(short8_t*)(xs + row * 72 + oct * 8) = v;
            } else {
                *(short8_t*)(xs + row * 72 + oct * 8) = (short8_t)0;
            }
        }
        __syncthreads();
        float4_t acc[16];
        #pragma unroll
        for (int i = 0; i < 16; ++i) acc[i] = (float4_t)0.0f;
        #pragma unroll
        for (int kk = 0; kk < 2; ++kk) {
            short8_t a = *(const short8_t*)(xs + (wave * 16 + r) * 72 + kk * 32 + q * 8);
            #pragma unroll
            for (int nt = 0; nt < 16; ++nt) {
                short8_t b2 = *(const short8_t*)(wt + (nt * 16 + r) * 72 + kk * 32 + q * 8);
                acc[nt] = __builtin_amdgcn_mfma_f32_16x16x32_bf16(a, b2, acc[nt], 0, 0, 0);
            }
        }
        #pragma unroll
        for (int nt = 0; nt < 16; ++nt) {
            float* Y = (nt < 8) ? Hs : Hd;
            int c = (nt & 7) * 16 + r;
            int n = nt * 16 + r;
            #pragma unroll
            for (int i2 = 0; i2 < 4; ++i2) {
                int row = rowBase + wave * 16 + q * 4 + i2;
                if (row < NNODES) Y[(long)row * 128 + c] = acc[nt][i2] + bl[n];
            }
        }
    }
}

// one-shot weight prep (bf16 [n][k]): W0T [128][256], W1T [64][128],
// CT [l][64][64], NT [l][256][64] (A|B|D|E), HT [256][64] (W0c|W0d)
__global__ __launch_bounds__(256) void transpose_w_kernel(
    const float* __restrict__ W0, const float* __restrict__ W1,
    const float* __restrict__ C_w,
    const float* __restrict__ A_w, const float* __restrict__ B_w,
    const float* __restrict__ D_w, const float* __restrict__ E_w,
    short* __restrict__ W0T, short* __restrict__ W1T,
    short* __restrict__ CT, short* __restrict__ NT, short* __restrict__ HT)
{
    int id = blockIdx.x * 256 + threadIdx.x;
    if (id < 256 * 128) {
        int k = id >> 7, n = id & 127;
        W0T[n * 256 + k] = f2bs(W0[id]);
    }
    if (id < 128 * 64) {
        int k = id >> 6, n = id & 63;
        W1T[n * 128 + k] = f2bs(W1[id]);
    }
    if (id < 4 * 64 * 64) {
        int l = id >> 12, rem = id & 4095, k = rem >> 6, n = rem & 63;
        CT[l * 4096 + n * 64 + k] = f2bs(C_w[l * 4096 + k * 64 + n]);
    }
    if (id < 4 * 256 * 64) {
        int l = id >> 14, rem = id & 16383, n = rem >> 6, k = rem & 63;
        int mat = n >> 6, c = n & 63;
        const float* Wm = (mat == 0) ? A_w : (mat == 1) ? B_w : (mat == 2) ? D_w : E_w;
        NT[l * 16384 + n * 64 + k] = f2bs(Wm[l * 4096 + k * 64 + c]);
    }
    if (id < 256 * 64) {
        int n = id >> 6, k = id & 63;
        int mat = n >> 7, col = n & 127;
        HT[n * 64 + k] = f2bs(W0[(128 + mat * 64 + k) * 128 + col]);
    }
}

// ---------------------------------------------------------------------------
// MFMA MLP readout v2 — ORIGINAL edge order, pure streaming:
//   x0 = e@W0a + e[rev]@W0b (MFMA, 2 phases) + Hs[src] + Hd[dst] (epilogue)
//   out = relu(x0)@W1 ... @W2, written sequentially.
// rev accesses are sequential (rev[i] = i±NEDGES/2; tiles never straddle).
// ---------------------------------------------------------------------------
__global__ __launch_bounds__(256) void readout_mfma2_kernel(
    const __hip_bfloat16* __restrict__ eorig, const int* __restrict__ rev,
    const float* __restrict__ Hs, const float* __restrict__ Hd,
    const int* __restrict__ src, const int* __restrict__ dst,
    const short* __restrict__ W0T, const short* __restrict__ W1T,
    const float* __restrict__ b1, const float* __restrict__ W2,
    const float* __restrict__ b2, float* __restrict__ out)
{
    __shared__ short feat[64 * 72];    // e / e_rev tile; reused as x1 tile
    __shared__ short wtile[128 * 72];  // W0 slice [128][72]; reused as W1T [64][136]
    __shared__ short x0t[64 * 136];    // x0 tile bf16
    __shared__ float smallb[194];      // b1[64] | W2[128] | b2[2]

    const int tid = threadIdx.x;
    const int wave = tid >> 6;
    const int lane = tid & 63;
    const int r = lane & 15;
    const int q = lane >> 4;

    if (tid < 64)  smallb[tid] = b1[tid];
    if (tid < 128) smallb[64 + tid] = W2[tid];
    if (tid < 2)   smallb[192 + tid] = b2[tid];

    constexpr int NTILES = NEDGES / 64;   // 6250
    for (int t = blockIdx.x; t < NTILES; t += gridDim.x) {
        const int rowBase = t * 64;
        float4_t acc0[8];
        #pragma unroll
        for (int i = 0; i < 8; ++i) acc0[i] = (float4_t)0.0f;

        for (int s = 0; s < 2; ++s) {
            __syncthreads();
            for (int i = tid; i < 512; i += 256) {
                int row = i >> 3, oct = i & 7;
                int er = rowBase + row;
                int srow = (s == 0) ? er : rev[er];   // sequential either way
                *(short8_t*)(feat + row * 72 + oct * 8) =
                    *(const short8_t*)((const short*)eorig + (long)srow * 64 + oct * 8);
            }
            for (int i = tid; i < 1024; i += 256) {
                int n = i >> 3, oct = i & 7;
                *(short8_t*)(wtile + n * 72 + oct * 8) =
                    *(const short8_t*)(W0T + (long)n * 256 + s * 64 + oct * 8);
            }
            __syncthreads();
            #pragma unroll
            for (int kk = 0; kk < 2; ++kk) {
                short8_t a = *(const short8_t*)(feat + (wave * 16 + r) * 72 + kk * 32 + q * 8);
                #pragma unroll
                for (int nt = 0; nt < 8; ++nt) {
                    short8_t b = *(const short8_t*)(wtile + (nt * 16 + r) * 72 + kk * 32 + q * 8);
                    acc0[nt] = __builtin_amdgcn_mfma_f32_16x16x32_bf16(a, b, acc0[nt], 0, 0, 0);
                }
            }
        }
        // epilogue 1: x0 = relu(acc0 + Hs[src] + Hd[dst]) -> x0t (b0 folded into Hs)
        #pragma unroll
        for (int i2 = 0; i2 < 4; ++i2) {
            int row = wave * 16 + q * 4 + i2;
            int er = rowBase + row;
            int sN = src[er], dN = dst[er];
            #pragma unroll
            for (int nt = 0; nt < 8; ++nt) {
                int col = nt * 16 + r;
                float v = acc0[nt][i2] + Hs[(long)sN * 128 + col] + Hd[(long)dN * 128 + col];
                x0t[row * 136 + col] = f2bs(fmaxf(v, 0.0f));
            }
        }
        __syncthreads();
        for (int i = tid; i < 1024; i += 256) {       // W1T -> wtile as [64][136]
            int n = i >> 4, oct = i & 15;
            *(short8_t*)(wtile + n * 136 + oct * 8) =
                *(const short8_t*)(W1T + (long)n * 128 + oct * 8);
        }
        __syncthreads();
        float4_t acc1[4];
        #pragma unroll
        for (int i = 0; i < 4; ++i) acc1[i] = (float4_t)0.0f;
        #pragma unroll
        for (int kk = 0; kk < 4; ++kk) {
            short8_t a = *(const short8_t*)(x0t + (wave * 16 + r) * 136 + kk * 32 + q * 8);
            #pragma unroll
            for (int nt = 0; nt < 4; ++nt) {
                short8_t b = *(const short8_t*)(wtile + (nt * 16 + r) * 136 + kk * 32 + q * 8);
                acc1[nt] = __builtin_amdgcn_mfma_f32_16x16x32_bf16(a, b, acc1[nt], 0, 0, 0);
            }
        }
        #pragma unroll
        for (int nt = 0; nt < 4; ++nt) {
            int col = nt * 16 + r;
            #pragma unroll
            for (int i2 = 0; i2 < 4; ++i2) {
                int row = wave * 16 + q * 4 + i2;
                feat[row * 72 + col] = f2bs(fmaxf(acc1[nt][i2] + smallb[col], 0.0f));
            }
        }
        __syncthreads();
        if (tid < 128) {
            int row = tid >> 1, cls = tid & 1;
            float a = smallb[192 + cls];
            #pragma unroll 8
            for (int k = 0; k < 64; ++k)
                a += bs2f(feat[row * 72 + k]) * smallb[64 + k * 2 + cls];
            out[(long)(rowBase + row) * 2 + cls] = a;
        }
    }
}

// ---------------------------------------------------------------------------
static inline int igrid(long total, int block, int cap) {
    long g = (total + block - 1) / block;
    return (int)(g < cap ? g : cap);
}

constexpr int GE_EDGE = 2048;
constexpr int GA_AGG  = NNODES / 4;  // 6250
constexpr size_t NINTS_PAD = 25001 + 25000 + 5 * (size_t)NEDGES + 2;  // pad to 4-int multiple

template<typename TE, typename TH>
static void run_net(void* const* d_in, float* f, TE* e, TH* ehat,
                    __hip_bfloat16* eorig, bool fusedFinal,
                    float* out, hipStream_t stream)
{
    const float* h_in   = (const float*)d_in[0];
    const float* e_in   = (const float*)d_in[1];
    const int*   src    = (const int*)d_in[2];
    const int*   dst    = (const int*)d_in[3];
    const int*   rev    = (const int*)d_in[4];
    const float* emb_h_w = (const float*)d_in[5];
    const float* emb_h_b = (const float*)d_in[6];
    const float* emb_e_w = (const float*)d_in[7];
    const float* emb_e_b = (const float*)d_in[8];
    const float* A_w = (const float*)d_in[9];  const float* A_b = (const float*)d_in[10];
    const float* B_w = (const float*)d_in[11]; const float* B_b = (const float*)d_in[12];
    const float* C_w = (const float*)d_in[13]; const float* C_b = (const float*)d_in[14];
    const float* D_w = (const float*)d_in[15]; const float* D_b = (const float*)d_in[16];
    const float* E_w = (const float*)d_in[17]; const float* E_b = (const float*)d_in[18];
    // F/G (19..22) and bn_u (27,28) are dead: u never reaches the output.
    const float* bn_h_g = (const float*)d_in[23]; const float* bn_h_b = (const float*)d_in[24];
    const float* bn_e_g = (const float*)d_in[25]; const float* bn_e_b = (const float*)d_in[26];
    const float* W0 = (const float*)d_in[29]; const float* b0 = (const float*)d_in[30];
    const float* W1 = (const float*)d_in[31]; const float* b1 = (const float*)d_in[32];
    const float* W2 = (const float*)d_in[33]; const float* b2 = (const float*)d_in[34];

    const size_t NH = (size_t)NNODES * DD;
    float* h    = f;
    float* Ah   = f + NH;
    float* Bh   = f + 2 * NH;
    float* Dh   = f + 3 * NH;      // = hhat
    float* Eh   = f + 4 * NH;
    float* hhat = Dh;
    float* scratch = f + 5 * NH;
    float* partial_e = scratch;                              // 2048*128 = 262144
    float* partial_h = partial_e + (size_t)GE_EDGE * 128;    // 800000
    int*   rowptr = (int*)(partial_h + (size_t)GA_AGG * 128);
    int*   cursor = rowptr + NNODES + 1;
    int*   eid    = cursor + NNODES;
    int*   inv    = eid + NEDGES;
    int*   srcS   = inv + NEDGES;
    int*   dstS   = srcS + NEDGES;
    int*   revS_pad = dstS + NEDGES;   // revS no longer needed; keep slot for layout
    short* W0T = (short*)(rowptr + NINTS_PAD);   // 16B-aligned (ints padded)
    short* W1T = W0T + 256 * 128;
    short* CT  = W1T + 128 * 64;
    short* NT  = CT + 4 * 4096;
    short* HT  = NT + 4 * 16384;
    float* stats_h = (float*)(HT + 256 * 64);
    float* stats_e = stats_h + 128;
    // after final layer: Hs reuses Ah+Bh (2NH), Hd reuses Eh + dead scratch (2NH)
    float* Hs = f + NH;
    float* Hd = f + 4 * NH;
    (void)revS_pad;

    const int GN = 1563;
    const int GEDGE = (NEDGES + 255) / 256;

    // CSR + permutation + weight prep (once per call; graph static)
    hipMemsetAsync(rowptr, 0, (2 * NNODES + 1) * sizeof(int), stream);
    deg_hist_kernel<<<GEDGE, 256, 0, stream>>>(dst, rowptr, NEDGES);
    scan_kernel<<<1, 1024, 0, stream>>>(rowptr, NNODES + 1);
    scatter_kernel<<<GEDGE, 256, 0, stream>>>(dst, rowptr, cursor, eid, NEDGES);
    remap1_kernel<<<GEDGE, 256, 0, stream>>>(eid, src, dst, inv, srcS, dstS, NEDGES);
    transpose_w_kernel<<<256, 256, 0, stream>>>(W0, W1, C_w, A_w, B_w, D_w, E_w,
                                                W0T, W1T, CT, NT, HT);

    // embeddings (e in dst-sorted order via eid gather)
    linear_kernel<64, 64, 4, float, float><<<GN, 256, 0, stream>>>(
        h_in, emb_h_w, emb_h_b, h, nullptr, NNODES);
    linear_kernel<16, 64, 4, float, TE><<<4096, 256, 0, stream>>>(
        e_in, emb_e_w, emb_e_b, e, eid, NEDGES);

    for (int l = 0; l < 4; ++l) {
        const size_t o = (size_t)l * DD * DD;
        // node linears (4-in-1 MFMA) with fused h-update from previous layer
        if (l == 0)
            node_linear4_mfma_kernel<false><<<391, 256, 0, stream>>>(
                h, hhat, NT + (size_t)l * 16384,
                A_b + l * DD, B_b + l * DD, D_b + l * DD, E_b + l * DD,
                nullptr, nullptr, nullptr, Ah, Bh, Dh, Eh);
        else
            node_linear4_mfma_kernel<true><<<391, 256, 0, stream>>>(
                h, hhat, NT + (size_t)l * 16384,
                A_b + l * DD, B_b + l * DD, D_b + l * DD, E_b + l * DD,
                stats_h, bn_h_g + (l - 1) * DD, bn_h_b + (l - 1) * DD,
                Ah, Bh, Dh, Eh);

        // MFMA edge update with fused e-update from previous layer
        if (l == 0)
            edge_update_mfma_kernel<false, TE, TH><<<GE_EDGE, 256, 0, stream>>>(
                e, ehat, CT + o, C_b + l * DD, Dh, srcS, Eh, dstS,
                nullptr, nullptr, nullptr, partial_e);
        else
            edge_update_mfma_kernel<true, TE, TH><<<GE_EDGE, 256, 0, stream>>>(
                e, ehat, CT + o, C_b + l * DD, Dh, srcS, Eh, dstS,
                stats_e, bn_e_g + (l - 1) * DD, bn_e_b + (l - 1) * DD, partial_e);

        // sorted aggregation + fused hhat + BN partials, then both reduces
        agg_sorted_kernel<TH><<<GA_AGG, 256, 0, stream>>>(
            ehat, Bh, srcS, rowptr, Ah, hhat, partial_h);
        reduce_stats2_kernel<<<256, 256, 0, stream>>>(
            partial_e, GE_EDGE, stats_e, partial_h, GA_AGG, stats_h);
    }

    // final e update -> bf16 eorig in ORIGINAL edge order (uses eid; must run
    // before precompute_H which reuses the eid/scratch region as Hd)
    if (fusedFinal) {
        bnfinal_scatter_kernel<TE, TH><<<8192, 256, 0, stream>>>(
            e, ehat, eid, stats_e, bn_e_g + 3 * DD, bn_e_b + 3 * DD, eorig);
    } else {
        bn_apply4_kernel<TE, TH><<<8192, 256, 0, stream>>>(
            e, ehat, stats_e, bn_e_g + 3 * DD, bn_e_b + 3 * DD, NEDGES);
        permute_e_kernel<TE><<<8192, 256, 0, stream>>>(e, eid, eorig);
    }

    // Hs/Hd precompute with fused final h-update (no h writeback)
    precompute_H_kernel<<<391, 256, 0, stream>>>(
        h, hhat, stats_h, bn_h_g + 3 * DD, bn_h_b + 3 * DD, HT, b0, Hs, Hd);

    // streaming readout in original order
    readout_mfma2_kernel<<<2048, 256, 0, stream>>>(
        eorig, rev, Hs, Hd, src, dst, W0T, W1T, b1, W2, b2, out);
}

extern "C" void kernel_launch(void* const* d_in, const int* in_sizes, int n_in,
                              void* d_out, int out_size, void* d_ws, size_t ws_size,
                              hipStream_t stream)
{
    const size_t NH = (size_t)NNODES * DD;       // 1.6M floats
    const size_t NE = (size_t)NEDGES * DD;       // 25.6M elems
    const size_t baseB = (7 * NH + 256) * sizeof(float);   // 44.8 MB node region

    char* base = (char*)d_ws;
    char* edge = base + baseB;
    float* out = (float*)d_out;

    const size_t needA2 = baseB + NE * 4 * 2 + NE * 2;  // + dedicated bf16 eorig
    const size_t needA  = baseB + NE * 4 * 2;           // fp32 e + fp32 ehat
    const size_t needB  = baseB + NE * 4 + NE * 2;      // fp32 e + bf16 ehat
    const size_t needC  = baseB + NE * 2 * 2;           // bf16 e + bf16 ehat

    if (ws_size >= needA2) {
        float* e = (float*)edge;
        float* ehat = (float*)(edge + NE * 4);
        __hip_bfloat16* eorig = (__hip_bfloat16*)(edge + NE * 8);
        run_net<float, float>(d_in, (float*)base, e, ehat, eorig, true, out, stream);
    } else if (ws_size >= needA) {
        float* e = (float*)edge;
        float* ehat = (float*)(edge + NE * 4);
        // two-pass: eorig overlays ehat storage (race-free across kernels)
        run_net<float, float>(d_in, (float*)base, e, ehat,
                              (__hip_bfloat16*)ehat, false, out, stream);
    } else if (ws_size >= needB) {
        float* e = (float*)edge;
        __hip_bfloat16* ehat = (__hip_bfloat16*)(edge + NE * 4);
        run_net<float, __hip_bfloat16>(d_in, (float*)base, e, ehat,
                                       (__hip_bfloat16*)ehat, false, out, stream);
    } else if (ws_size >= needC) {
        __hip_bfloat16* e = (__hip_bfloat16*)edge;
        __hip_bfloat16* ehat = (__hip_bfloat16*)(edge + NE * 2);
        run_net<__hip_bfloat16, __hip_bfloat16>(d_in, (float*)base, e, ehat,
                                                ehat, false, out, stream);
    } else {
        hipMemsetAsync(d_out, 0, (size_t)out_size * sizeof(float), stream);
    }
}

// Round 10
// 932.955 us; speedup vs baseline: 4.3243x; 1.1269x over previous
//
#include <hip/hip_runtime.h>
#include <hip/hip_bf16.h>

constexpr int NNODES = 25000;
constexpr int NEDGES = 400000;
constexpr int DD = 64;
constexpr float BNEPS = 1e-5f;
constexpr float AGGEPS = 1e-6f;

typedef __attribute__((ext_vector_type(8))) short short8_t;
typedef __attribute__((ext_vector_type(4))) short short4_t;
typedef __attribute__((ext_vector_type(4))) float float4_t;

// storage-type helpers (compute is always fp32)
__device__ __forceinline__ float ldv(const float* p, long i) { return p[i]; }
__device__ __forceinline__ float ldv(const __hip_bfloat16* p, long i) { return __bfloat162float(p[i]); }
__device__ __forceinline__ void stv(float* p, long i, float v) { p[i] = v; }
__device__ __forceinline__ void stv(__hip_bfloat16* p, long i, float v) { p[i] = __float2bfloat16(v); }

__device__ __forceinline__ short f2bs(float f) {
    union { float f; unsigned u; } x; x.f = f;
    unsigned r = x.u + 0x7FFFu + ((x.u >> 16) & 1u);
    return (short)(r >> 16);
}
__device__ __forceinline__ float bs2f(short s) {
    union { unsigned u; float f; } x; x.u = ((unsigned)(unsigned short)s) << 16; return x.f;
}

__device__ __forceinline__ float4_t ldv4(const float* p, long i) {
    return *(const float4_t*)(p + i);
}
__device__ __forceinline__ float4_t ldv4(const __hip_bfloat16* p, long i) {
    short4_t s = *(const short4_t*)(p + i);
    float4_t r;
    #pragma unroll
    for (int c = 0; c < 4; ++c) r[c] = bs2f(s[c]);
    return r;
}
__device__ __forceinline__ void stv4(float* p, long i, float4_t v) {
    *(float4_t*)(p + i) = v;
}
__device__ __forceinline__ void stv4(__hip_bfloat16* p, long i, float4_t v) {
    short4_t s;
    #pragma unroll
    for (int c = 0; c < 4; ++c) s[c] = f2bs(v[c]);
    *(short4_t*)(p + i) = s;
}

__device__ __forceinline__ void stage8(const __hip_bfloat16* s, short* d) {
    *(short8_t*)d = *(const short8_t*)s;
}
__device__ __forceinline__ void stage8(const float* s, short* d) {
    float4_t a = *(const float4_t*)s;
    float4_t b = *(const float4_t*)(s + 4);
    short8_t v;
    v[0] = f2bs(a[0]); v[1] = f2bs(a[1]); v[2] = f2bs(a[2]); v[3] = f2bs(a[3]);
    v[4] = f2bs(b[0]); v[5] = f2bs(b[1]); v[6] = f2bs(b[2]); v[7] = f2bs(b[3]);
    *(short8_t*)d = v;
}

// ---------------------------------------------------------------------------
// Generic LDS-tiled linear (embeddings), optional row-gather on X.
// ---------------------------------------------------------------------------
template<int K, int N, int JR, typename TX, typename TY>
__global__ __launch_bounds__(256) void linear_kernel(
    const TX* __restrict__ X, const float* __restrict__ W,
    const float* __restrict__ Bb, TY* __restrict__ Y,
    const int* __restrict__ gather, int rows)
{
    constexpr int SLOTS = 256 / N;
    constexpr int RPG = SLOTS * JR;
    __shared__ float wl[K * N];
    __shared__ float bl[N];
    __shared__ float xl[RPG * K];

    const int tid = threadIdx.x;
    for (int i = tid; i < K * N; i += 256) wl[i] = W[i];
    if (tid < N) bl[tid] = Bb[tid];

    const int col = tid % N;
    const int slot = tid / N;

    const int ngroups = (rows + RPG - 1) / RPG;
    for (int g = blockIdx.x; g < ngroups; g += gridDim.x) {
        const int rowBase = g * RPG;
        __syncthreads();
        for (int i = tid; i < RPG * K; i += 256) {
            int r = i / K, k = i - r * K;
            int row = rowBase + r;
            float v = 0.0f;
            if (row < rows) {
                int sr = gather ? gather[row] : row;
                v = ldv(X, (long)sr * K + k);
            }
            xl[i] = v;
        }
        __syncthreads();
        float acc[JR];
        #pragma unroll
        for (int j = 0; j < JR; ++j) acc[j] = bl[col];
        #pragma unroll 4
        for (int k = 0; k < K; ++k) {
            float w = wl[k * N + col];
            #pragma unroll
            for (int j = 0; j < JR; ++j)
                acc[j] += xl[(slot * JR + j) * K + k] * w;
        }
        #pragma unroll
        for (int j = 0; j < JR; ++j) {
            int row = rowBase + slot * JR + j;
            if (row < rows) stv(Y, (long)row * N + col, acc[j]);
        }
    }
}

// ---------------------------------------------------------------------------
// Quad node linear, MFMA: {Ah,Bh,Dh,Eh} = h @ {A,B,D,E} + biases.
// If BNIN: h = h + relu(bn(hhat; stats_prev)) in place first (feeds matmul).
// ---------------------------------------------------------------------------
template<bool BNIN>
__global__ __launch_bounds__(256) void node_linear4_mfma_kernel(
    float* __restrict__ h, const float* __restrict__ hhat,
    const short* __restrict__ NT,
    const float* __restrict__ Ab, const float* __restrict__ Bb,
    const float* __restrict__ Db, const float* __restrict__ Eb,
    const float* __restrict__ stats_prev, const float* __restrict__ gprev,
    const float* __restrict__ bprev,
    float* __restrict__ Ah, float* __restrict__ Bh,
    float* __restrict__ Dh, float* __restrict__ Eh)
{
    __shared__ short wt[256 * 72];
    __shared__ short xs[64 * 72];
    __shared__ float bl[256];
    __shared__ float scale[64], shift[64];

    const int tid = threadIdx.x;
    const int wave = tid >> 6;
    const int lane = tid & 63;
    const int r = lane & 15;
    const int q = lane >> 4;

    for (int i = tid; i < 2048; i += 256) {
        int n = i >> 3, oct = i & 7;
        *(short8_t*)(wt + n * 72 + oct * 8) = *(const short8_t*)(NT + n * 64 + oct * 8);
    }
    if (tid < 64) bl[tid] = Ab[tid];
    else if (tid < 128) bl[tid] = Bb[tid - 64];
    else if (tid < 192) bl[tid] = Db[tid - 128];
    else bl[tid] = Eb[tid - 192];
    if (BNIN && tid < 64) {
        float inv = 1.0f / (float)NNODES;
        float mu = stats_prev[tid] * inv;
        float var = stats_prev[64 + tid] * inv - mu * mu;
        float rs = rsqrtf(var + BNEPS);
        float sc = rs * gprev[tid];
        scale[tid] = sc;
        shift[tid] = bprev[tid] - mu * sc;
    }

    const int ntiles = (NNODES + 63) / 64;        // 391
    for (int t = blockIdx.x; t < ntiles; t += gridDim.x) {
        const int rowBase = t * 64;
        __syncthreads();
        for (int i = tid; i < 512; i += 256) {
            int row = i >> 3, oct = i & 7;
            int nr = rowBase + row;
            if (nr < NNODES) {
                long idx = (long)nr * 64 + oct * 8;
                float4_t a = ldv4(h, idx), b = ldv4(h, idx + 4);
                if (BNIN) {
                    float4_t ha = ldv4(hhat, idx), hb = ldv4(hhat, idx + 4);
                    int k0 = oct * 8;
                    #pragma unroll
                    for (int c = 0; c < 4; ++c) {
                        a[c] += fmaxf(ha[c] * scale[k0 + c] + shift[k0 + c], 0.0f);
                        b[c] += fmaxf(hb[c] * scale[k0 + 4 + c] + shift[k0 + 4 + c], 0.0f);
                    }
                    stv4(h, idx, a); stv4(h, idx + 4, b);
                }
                short8_t v;
                v[0] = f2bs(a[0]); v[1] = f2bs(a[1]); v[2] = f2bs(a[2]); v[3] = f2bs(a[3]);
                v[4] = f2bs(b[0]); v[5] = f2bs(b[1]); v[6] = f2bs(b[2]); v[7] = f2bs(b[3]);
                *(short8_t*)(xs + row * 72 + oct * 8) = v;
            } else {
                *(short8_t*)(xs + row * 72 + oct * 8) = (short8_t)0;
            }
        }
        __syncthreads();
        float4_t acc[16];
        #pragma unroll
        for (int i = 0; i < 16; ++i) acc[i] = (float4_t)0.0f;
        #pragma unroll
        for (int kk = 0; kk < 2; ++kk) {
            short8_t a = *(const short8_t*)(xs + (wave * 16 + r) * 72 + kk * 32 + q * 8);
            #pragma unroll
            for (int nt = 0; nt < 16; ++nt) {
                short8_t b = *(const short8_t*)(wt + (nt * 16 + r) * 72 + kk * 32 + q * 8);
                acc[nt] = __builtin_amdgcn_mfma_f32_16x16x32_bf16(a, b, acc[nt], 0, 0, 0);
            }
        }
        #pragma unroll
        for (int nt = 0; nt < 16; ++nt) {
            float* Y = (nt < 4) ? Ah : (nt < 8) ? Bh : (nt < 12) ? Dh : Eh;
            int c = (nt & 3) * 16 + r;
            int n = nt * 16 + r;
            #pragma unroll
            for (int i2 = 0; i2 < 4; ++i2) {
                int row = rowBase + wave * 16 + q * 4 + i2;
                if (row < NNODES) Y[(long)row * 64 + c] = acc[nt][i2] + bl[n];
            }
        }
    }
}

// ---------------------------------------------------------------------------
// MFMA edge update (edges in dst-sorted order) — validated in R7/R8.
// BN stats are accumulated from fp32 values BEFORE ehat storage rounding.
// ---------------------------------------------------------------------------
template<bool BNIN, typename TE, typename TH>
__global__ __launch_bounds__(256) void edge_update_mfma_kernel(
    TE* __restrict__ e, TH* __restrict__ ehat,
    const short* __restrict__ CT, const float* __restrict__ Cb,
    const float* __restrict__ Dh, const int* __restrict__ srcS,
    const float* __restrict__ Eh, const int* __restrict__ dstS,
    const float* __restrict__ stats_prev, const float* __restrict__ gprev,
    const float* __restrict__ bprev, float* __restrict__ partial)
{
    __shared__ short ct[64 * 72];
    __shared__ short xs[64 * 72];
    __shared__ float bl[64], scale[64], shift[64];
    __shared__ float ps[128];

    const int tid = threadIdx.x;
    const int wave = tid >> 6;
    const int lane = tid & 63;
    const int r = lane & 15;
    const int q = lane >> 4;

    for (int i = tid; i < 512; i += 256) {
        int n = i >> 3, oct = i & 7;
        *(short8_t*)(ct + n * 72 + oct * 8) = *(const short8_t*)(CT + n * 64 + oct * 8);
    }
    if (tid < 64) {
        bl[tid] = Cb[tid];
        if (BNIN) {
            float inv = 1.0f / (float)NEDGES;
            float mu = stats_prev[tid] * inv;
            float var = stats_prev[64 + tid] * inv - mu * mu;
            float rs = rsqrtf(var + BNEPS);
            float sc = rs * gprev[tid];
            scale[tid] = sc;
            shift[tid] = bprev[tid] - mu * sc;
        }
    }
    if (tid < 128) ps[tid] = 0.0f;
    float lsum[4] = {0, 0, 0, 0}, lsum2[4] = {0, 0, 0, 0};

    constexpr int NTILES = NEDGES / 64;
    for (int t = blockIdx.x; t < NTILES; t += gridDim.x) {
        const int rowBase = t * 64;
        __syncthreads();
        for (int i = tid; i < 512; i += 256) {
            int row = i >> 3, oct = i & 7;
            long idx = (long)(rowBase + row) * 64 + oct * 8;
            float4_t a = ldv4(e, idx), b = ldv4(e, idx + 4);
            if (BNIN) {
                float4_t ha = ldv4(ehat, idx), hb = ldv4(ehat, idx + 4);
                int k0 = oct * 8;
                #pragma unroll
                for (int c = 0; c < 4; ++c) {
                    a[c] += fmaxf(ha[c] * scale[k0 + c] + shift[k0 + c], 0.0f);
                    b[c] += fmaxf(hb[c] * scale[k0 + 4 + c] + shift[k0 + 4 + c], 0.0f);
                }
                stv4(e, idx, a); stv4(e, idx + 4, b);
            }
            short8_t v;
            v[0] = f2bs(a[0]); v[1] = f2bs(a[1]); v[2] = f2bs(a[2]); v[3] = f2bs(a[3]);
            v[4] = f2bs(b[0]); v[5] = f2bs(b[1]); v[6] = f2bs(b[2]); v[7] = f2bs(b[3]);
            *(short8_t*)(xs + row * 72 + oct * 8) = v;
        }
        __syncthreads();
        float4_t acc[4];
        #pragma unroll
        for (int i = 0; i < 4; ++i) acc[i] = (float4_t)0.0f;
        #pragma unroll
        for (int kk = 0; kk < 2; ++kk) {
            short8_t a = *(const short8_t*)(xs + (wave * 16 + r) * 72 + kk * 32 + q * 8);
            #pragma unroll
            for (int nt = 0; nt < 4; ++nt) {
                short8_t b = *(const short8_t*)(ct + (nt * 16 + r) * 72 + kk * 32 + q * 8);
                acc[nt] = __builtin_amdgcn_mfma_f32_16x16x32_bf16(a, b, acc[nt], 0, 0, 0);
            }
        }
        #pragma unroll
        for (int i2 = 0; i2 < 4; ++i2) {
            int row = wave * 16 + q * 4 + i2;
            int er = rowBase + row;
            int s = srcS[er], d = dstS[er];
            #pragma unroll
            for (int nt = 0; nt < 4; ++nt) {
                int col = nt * 16 + r;
                float v = acc[nt][i2] + bl[col]
                        + Dh[(long)s * 64 + col] + Eh[(long)d * 64 + col];
                stv(ehat, (long)er * 64 + col, v);
                lsum[nt] += v; lsum2[nt] += v * v;
            }
        }
    }
    __syncthreads();
    #pragma unroll
    for (int nt = 0; nt < 4; ++nt) {
        atomicAdd(&ps[nt * 16 + r], lsum[nt]);
        atomicAdd(&ps[64 + nt * 16 + r], lsum2[nt]);
    }
    __syncthreads();
    if (tid < 128) partial[(long)blockIdx.x * 128 + tid] = ps[tid];
}

// ---------------------------------------------------------------------------
// CSR build + edge permutation
// ---------------------------------------------------------------------------
__global__ __launch_bounds__(256) void deg_hist_kernel(
    const int* __restrict__ dst, int* __restrict__ rowptr, int rows)
{
    int e = blockIdx.x * 256 + threadIdx.x;
    if (e < rows) atomicAdd(&rowptr[dst[e] + 1], 1);
}

__global__ __launch_bounds__(1024) void scan_kernel(int* __restrict__ data, int n)
{
    __shared__ int buf[1024];
    __shared__ int carry;
    if (threadIdx.x == 0) carry = 0;
    __syncthreads();
    for (int base = 0; base < n; base += 1024) {
        int i = base + threadIdx.x;
        int v = (i < n) ? data[i] : 0;
        buf[threadIdx.x] = v;
        __syncthreads();
        for (int off = 1; off < 1024; off <<= 1) {
            int t = (threadIdx.x >= off) ? buf[threadIdx.x - off] : 0;
            __syncthreads();
            buf[threadIdx.x] += t;
            __syncthreads();
        }
        if (i < n) data[i] = buf[threadIdx.x] + carry;
        __syncthreads();
        if (threadIdx.x == 0) carry += buf[1023];
        __syncthreads();
    }
}

__global__ __launch_bounds__(256) void scatter_kernel(
    const int* __restrict__ dst, const int* __restrict__ rowptr,
    int* __restrict__ cursor, int* __restrict__ eid, int rows)
{
    int e = blockIdx.x * 256 + threadIdx.x;
    if (e < rows) {
        int d = dst[e];
        int pos = atomicAdd(&cursor[d], 1);
        eid[rowptr[d] + pos] = e;
    }
}

__global__ __launch_bounds__(256) void remap1_kernel(
    const int* __restrict__ eid, const int* __restrict__ src,
    const int* __restrict__ dst, int* __restrict__ inv,
    int* __restrict__ srcS, int* __restrict__ dstS, int rows)
{
    int p = blockIdx.x * 256 + threadIdx.x;
    if (p < rows) {
        int orig = eid[p];
        inv[orig] = p;
        srcS[p] = src[orig];
        dstS[p] = dst[orig];
    }
}

// ---------------------------------------------------------------------------
// Sorted aggregation + fused hhat + BN partials — validated in R8.
// ---------------------------------------------------------------------------
template<typename TH>
__global__ __launch_bounds__(256) void agg_sorted_kernel(
    const TH* __restrict__ ehat, const float* __restrict__ Bh,
    const int* __restrict__ srcS, const int* __restrict__ rowptr,
    const float* __restrict__ Ah, float* __restrict__ hhat,
    float* __restrict__ partial)
{
    __shared__ float ps[64], ps2[64];
    const int tid = threadIdx.x;
    if (tid < 64) { ps[tid] = 0.0f; ps2[tid] = 0.0f; }
    __syncthreads();

    const int node = blockIdx.x * 4 + (tid >> 6);
    const int lane = tid & 63;
    const int sub = lane >> 4;
    const int c4 = (lane & 15) * 4;
    const int s0 = rowptr[node], s1 = rowptr[node + 1];

    float4_t den = (float4_t)0.0f, num = (float4_t)0.0f;
    for (int p = s0 + sub; p < s1; p += 4) {
        float4_t v = ldv4(ehat, (long)p * 64 + c4);
        float4_t bh = ldv4(Bh, (long)srcS[p] * 64 + c4);
        #pragma unroll
        for (int c = 0; c < 4; ++c) {
            float s = 1.0f / (1.0f + __expf(-v[c]));
            den[c] += s;
            num[c] += s * bh[c];
        }
    }
    #pragma unroll
    for (int m = 16; m <= 32; m <<= 1) {
        #pragma unroll
        for (int c = 0; c < 4; ++c) {
            den[c] += __shfl_xor(den[c], m, 64);
            num[c] += __shfl_xor(num[c], m, 64);
        }
    }
    if (sub == 0) {
        float4_t av = ldv4(Ah, (long)node * 64 + c4);
        float4_t hh;
        #pragma unroll
        for (int c = 0; c < 4; ++c) {
            hh[c] = av[c] + num[c] / (den[c] + AGGEPS);
            atomicAdd(&ps[c4 + c], hh[c]);
            atomicAdd(&ps2[c4 + c], hh[c] * hh[c]);
        }
        stv4(hhat, (long)node * 64 + c4, hh);
    }
    __syncthreads();
    if (tid < 64) {
        partial[(long)blockIdx.x * 128 + tid] = ps[tid];
        partial[(long)blockIdx.x * 128 + 64 + tid] = ps2[tid];
    }
}

// merged stats reduce: blocks 0..127 -> stats_e, 128..255 -> stats_h
__global__ __launch_bounds__(256) void reduce_stats2_kernel(
    const float* __restrict__ pe, int ne, float* __restrict__ se,
    const float* __restrict__ ph, int nh, float* __restrict__ sh)
{
    __shared__ float sb[256];
    const float* partial; int nblk; float* stats; int col;
    if (blockIdx.x < 128) { partial = pe; nblk = ne; stats = se; col = blockIdx.x; }
    else                  { partial = ph; nblk = nh; stats = sh; col = blockIdx.x - 128; }
    int tid = threadIdx.x;
    float s = 0.0f;
    for (int i = tid; i < nblk; i += 256) s += partial[(long)i * 128 + col];
    sb[tid] = s;
    __syncthreads();
    for (int off = 128; off > 0; off >>= 1) {
        if (tid < off) sb[tid] += sb[tid + off];
        __syncthreads();
    }
    if (tid == 0) stats[col] = sb[0];
}

// base += relu((xhat-mu)*rstd*g + b), float4 per thread (in place)
template<typename TB, typename TX>
__global__ __launch_bounds__(256) void bn_apply4_kernel(
    TB* __restrict__ base, const TX* __restrict__ xhat,
    const float* __restrict__ stats, const float* __restrict__ g,
    const float* __restrict__ b, int rows)
{
    long total4 = (long)rows * 16;
    float inv = 1.0f / (float)rows;
    for (long q = (long)blockIdx.x * 256 + threadIdx.x; q < total4;
         q += (long)gridDim.x * 256) {
        long idx = q * 4;
        int c = (int)(idx & 63);
        float4_t x = ldv4(xhat, idx);
        float4_t bs = ldv4(base, idx);
        #pragma unroll
        for (int j = 0; j < 4; ++j) {
            float mu = stats[c + j] * inv;
            float var = stats[64 + c + j] * inv - mu * mu;
            float rs = rsqrtf(var + BNEPS);
            float v = (x[j] - mu) * rs * g[c + j] + b[c + j];
            bs[j] += fmaxf(v, 0.0f);
        }
        stv4(base, idx, bs);
    }
}

// fused final e update + scatter to original order (dedicated eorig buffer):
// eorig[eid[p]] = bf16(e[p] + relu(bn(ehat[p])))
template<typename TE, typename TH>
__global__ __launch_bounds__(256) void bnfinal_scatter_kernel(
    const TE* __restrict__ e, const TH* __restrict__ ehat,
    const int* __restrict__ eid, const float* __restrict__ stats,
    const float* __restrict__ g, const float* __restrict__ b,
    __hip_bfloat16* __restrict__ eorig)
{
    __shared__ float scale[64], shift[64];
    const int tid = threadIdx.x;
    if (tid < 64) {
        float inv = 1.0f / (float)NEDGES;
        float mu = stats[tid] * inv;
        float var = stats[64 + tid] * inv - mu * mu;
        float rs = rsqrtf(var + BNEPS);
        float sc = rs * g[tid];
        scale[tid] = sc;
        shift[tid] = b[tid] - mu * sc;
    }
    __syncthreads();
    long total = (long)NEDGES * 8;
    for (long i = (long)blockIdx.x * 256 + tid; i < total; i += (long)gridDim.x * 256) {
        int p = (int)(i >> 3), oct = (int)(i & 7);
        int k0 = oct * 8;
        long idx = (long)p * 64 + k0;
        float4_t a = ldv4(e, idx), b4 = ldv4(e, idx + 4);
        float4_t ha = ldv4(ehat, idx), hb = ldv4(ehat, idx + 4);
        short8_t v;
        #pragma unroll
        for (int c = 0; c < 4; ++c) {
            v[c]     = f2bs(a[c]  + fmaxf(ha[c] * scale[k0 + c]     + shift[k0 + c], 0.0f));
            v[4 + c] = f2bs(b4[c] + fmaxf(hb[c] * scale[k0 + 4 + c] + shift[k0 + 4 + c], 0.0f));
        }
        *(short8_t*)((short*)eorig + (long)eid[p] * 64 + k0) = v;
    }
}

// two-pass fallback: permute updated e (sorted) -> bf16 eorig (original order)
template<typename TE>
__global__ __launch_bounds__(256) void permute_e_kernel(
    const TE* __restrict__ e, const int* __restrict__ eid,
    __hip_bfloat16* __restrict__ eorig)
{
    long total = (long)NEDGES * 8;
    for (long i = (long)blockIdx.x * 256 + threadIdx.x; i < total;
         i += (long)gridDim.x * 256) {
        int p = (int)(i >> 3), oct = (int)(i & 7);
        long idx = (long)p * 64 + oct * 8;
        float4_t a = ldv4(e, idx), b = ldv4(e, idx + 4);
        short8_t v;
        #pragma unroll
        for (int c = 0; c < 4; ++c) { v[c] = f2bs(a[c]); v[4 + c] = f2bs(b[c]); }
        *(short8_t*)((short*)eorig + (long)eid[p] * 64 + oct * 8) = v;
    }
}

// Hs = h_fin @ W0c + b0, Hd = h_fin @ W0d (bf16 outputs), with
// h_fin = h + relu(bn(hhat)) computed on the fly (no h writeback).
__global__ __launch_bounds__(256) void precompute_H_kernel(
    const float* __restrict__ h, const float* __restrict__ hhat,
    const float* __restrict__ stats, const float* __restrict__ g,
    const float* __restrict__ b,
    const short* __restrict__ HT, const float* __restrict__ b0,
    __hip_bfloat16* __restrict__ Hs, __hip_bfloat16* __restrict__ Hd)
{
    __shared__ short wt[256 * 72];
    __shared__ short xs[64 * 72];
    __shared__ float bl[256];
    __shared__ float scale[64], shift[64];

    const int tid = threadIdx.x;
    const int wave = tid >> 6;
    const int lane = tid & 63;
    const int r = lane & 15;
    const int q = lane >> 4;

    for (int i = tid; i < 2048; i += 256) {
        int n = i >> 3, oct = i & 7;
        *(short8_t*)(wt + n * 72 + oct * 8) = *(const short8_t*)(HT + n * 64 + oct * 8);
    }
    bl[tid] = (tid < 128) ? b0[tid] : 0.0f;
    if (tid < 64) {
        float inv = 1.0f / (float)NNODES;
        float mu = stats[tid] * inv;
        float var = stats[64 + tid] * inv - mu * mu;
        float rs = rsqrtf(var + BNEPS);
        float sc = rs * g[tid];
        scale[tid] = sc;
        shift[tid] = b[tid] - mu * sc;
    }

    const int ntiles = (NNODES + 63) / 64;
    for (int t = blockIdx.x; t < ntiles; t += gridDim.x) {
        const int rowBase = t * 64;
        __syncthreads();
        for (int i = tid; i < 512; i += 256) {
            int row = i >> 3, oct = i & 7;
            int nr = rowBase + row;
            if (nr < NNODES) {
                long idx = (long)nr * 64 + oct * 8;
                float4_t a = ldv4(h, idx), bb = ldv4(h, idx + 4);
                float4_t ha = ldv4(hhat, idx), hb = ldv4(hhat, idx + 4);
                int k0 = oct * 8;
                #pragma unroll
                for (int c = 0; c < 4; ++c) {
                    a[c]  += fmaxf(ha[c] * scale[k0 + c]     + shift[k0 + c], 0.0f);
                    bb[c] += fmaxf(hb[c] * scale[k0 + 4 + c] + shift[k0 + 4 + c], 0.0f);
                }
                short8_t v;
                v[0] = f2bs(a[0]); v[1] = f2bs(a[1]); v[2] = f2bs(a[2]); v[3] = f2bs(a[3]);
                v[4] = f2bs(bb[0]); v[5] = f2bs(bb[1]); v[6] = f2bs(bb[2]); v[7] = f2bs(bb[3]);
                *(short8_t*)(xs + row * 72 + oct * 8) = v;
            } else {
                *(short8_t*)(xs + row * 72 + oct * 8) = (short8_t)0;
            }
        }
        __syncthreads();
        float4_t acc[16];
        #pragma unroll
        for (int i = 0; i < 16; ++i) acc[i] = (float4_t)0.0f;
        #pragma unroll
        for (int kk = 0; kk < 2; ++kk) {
            short8_t a = *(const short8_t*)(xs + (wave * 16 + r) * 72 + kk * 32 + q * 8);
            #pragma unroll
            for (int nt = 0; nt < 16; ++nt) {
                short8_t b2 = *(const short8_t*)(wt + (nt * 16 + r) * 72 + kk * 32 + q * 8);
                acc[nt] = __builtin_amdgcn_mfma_f32_16x16x32_bf16(a, b2, acc[nt], 0, 0, 0);
            }
        }
        #pragma unroll
        for (int nt = 0; nt < 16; ++nt) {
            __hip_bfloat16* Y = (nt < 8) ? Hs : Hd;
            int c = (nt & 7) * 16 + r;
            int n = nt * 16 + r;
            #pragma unroll
            for (int i2 = 0; i2 < 4; ++i2) {
                int row = rowBase + wave * 16 + q * 4 + i2;
                if (row < NNODES) stv(Y, (long)row * 128 + c, acc[nt][i2] + bl[n]);
            }
        }
    }
}

// one-shot weight prep (bf16 [n][k]): W0T [128][256], W1T [64][128],
// CT [l][64][64], NT [l][256][64] (A|B|D|E), HT [256][64] (W0c|W0d)
__global__ __launch_bounds__(256) void transpose_w_kernel(
    const float* __restrict__ W0, const float* __restrict__ W1,
    const float* __restrict__ C_w,
    const float* __restrict__ A_w, const float* __restrict__ B_w,
    const float* __restrict__ D_w, const float* __restrict__ E_w,
    short* __restrict__ W0T, short* __restrict__ W1T,
    short* __restrict__ CT, short* __restrict__ NT, short* __restrict__ HT)
{
    int id = blockIdx.x * 256 + threadIdx.x;
    if (id < 256 * 128) {
        int k = id >> 7, n = id & 127;
        W0T[n * 256 + k] = f2bs(W0[id]);
    }
    if (id < 128 * 64) {
        int k = id >> 6, n = id & 63;
        W1T[n * 128 + k] = f2bs(W1[id]);
    }
    if (id < 4 * 64 * 64) {
        int l = id >> 12, rem = id & 4095, k = rem >> 6, n = rem & 63;
        CT[l * 4096 + n * 64 + k] = f2bs(C_w[l * 4096 + k * 64 + n]);
    }
    if (id < 4 * 256 * 64) {
        int l = id >> 14, rem = id & 16383, n = rem >> 6, k = rem & 63;
        int mat = n >> 6, c = n & 63;
        const float* Wm = (mat == 0) ? A_w : (mat == 1) ? B_w : (mat == 2) ? D_w : E_w;
        NT[l * 16384 + n * 64 + k] = f2bs(Wm[l * 4096 + k * 64 + c]);
    }
    if (id < 256 * 64) {
        int n = id >> 6, k = id & 63;
        int mat = n >> 7, col = n & 127;
        HT[n * 64 + k] = f2bs(W0[(128 + mat * 64 + k) * 128 + col]);
    }
}

// ---------------------------------------------------------------------------
// MFMA MLP readout v2 — ORIGINAL edge order, pure streaming; Hs/Hd bf16.
// ---------------------------------------------------------------------------
__global__ __launch_bounds__(256) void readout_mfma2_kernel(
    const __hip_bfloat16* __restrict__ eorig, const int* __restrict__ rev,
    const __hip_bfloat16* __restrict__ Hs, const __hip_bfloat16* __restrict__ Hd,
    const int* __restrict__ src, const int* __restrict__ dst,
    const short* __restrict__ W0T, const short* __restrict__ W1T,
    const float* __restrict__ b1, const float* __restrict__ W2,
    const float* __restrict__ b2, float* __restrict__ out)
{
    __shared__ short feat[64 * 72];    // e / e_rev tile; reused as x1 tile
    __shared__ short wtile[128 * 72];  // W0 slice [128][72]; reused as W1T [64][136]
    __shared__ short x0t[64 * 136];    // x0 tile bf16
    __shared__ float smallb[194];      // b1[64] | W2[128] | b2[2]

    const int tid = threadIdx.x;
    const int wave = tid >> 6;
    const int lane = tid & 63;
    const int r = lane & 15;
    const int q = lane >> 4;

    if (tid < 64)  smallb[tid] = b1[tid];
    if (tid < 128) smallb[64 + tid] = W2[tid];
    if (tid < 2)   smallb[192 + tid] = b2[tid];

    constexpr int NTILES = NEDGES / 64;   // 6250
    for (int t = blockIdx.x; t < NTILES; t += gridDim.x) {
        const int rowBase = t * 64;
        float4_t acc0[8];
        #pragma unroll
        for (int i = 0; i < 8; ++i) acc0[i] = (float4_t)0.0f;

        for (int s = 0; s < 2; ++s) {
            __syncthreads();
            for (int i = tid; i < 512; i += 256) {
                int row = i >> 3, oct = i & 7;
                int er = rowBase + row;
                int srow = (s == 0) ? er : rev[er];   // sequential either way
                *(short8_t*)(feat + row * 72 + oct * 8) =
                    *(const short8_t*)((const short*)eorig + (long)srow * 64 + oct * 8);
            }
            for (int i = tid; i < 1024; i += 256) {
                int n = i >> 3, oct = i & 7;
                *(short8_t*)(wtile + n * 72 + oct * 8) =
                    *(const short8_t*)(W0T + (long)n * 256 + s * 64 + oct * 8);
            }
            __syncthreads();
            #pragma unroll
            for (int kk = 0; kk < 2; ++kk) {
                short8_t a = *(const short8_t*)(feat + (wave * 16 + r) * 72 + kk * 32 + q * 8);
                #pragma unroll
                for (int nt = 0; nt < 8; ++nt) {
                    short8_t b = *(const short8_t*)(wtile + (nt * 16 + r) * 72 + kk * 32 + q * 8);
                    acc0[nt] = __builtin_amdgcn_mfma_f32_16x16x32_bf16(a, b, acc0[nt], 0, 0, 0);
                }
            }
        }
        // epilogue 1: x0 = relu(acc0 + Hs[src] + Hd[dst]) (b0 folded into Hs)
        #pragma unroll
        for (int i2 = 0; i2 < 4; ++i2) {
            int row = wave * 16 + q * 4 + i2;
            int er = rowBase + row;
            int sN = src[er], dN = dst[er];
            #pragma unroll
            for (int nt = 0; nt < 8; ++nt) {
                int col = nt * 16 + r;
                float v = acc0[nt][i2] + ldv(Hs, (long)sN * 128 + col)
                                       + ldv(Hd, (long)dN * 128 + col);
                x0t[row * 136 + col] = f2bs(fmaxf(v, 0.0f));
            }
        }
        __syncthreads();
        for (int i = tid; i < 1024; i += 256) {       // W1T -> wtile as [64][136]
            int n = i >> 4, oct = i & 15;
            *(short8_t*)(wtile + n * 136 + oct * 8) =
                *(const short8_t*)(W1T + (long)n * 128 + oct * 8);
        }
        __syncthreads();
        float4_t acc1[4];
        #pragma unroll
        for (int i = 0; i < 4; ++i) acc1[i] = (float4_t)0.0f;
        #pragma unroll
        for (int kk = 0; kk < 4; ++kk) {
            short8_t a = *(const short8_t*)(x0t + (wave * 16 + r) * 136 + kk * 32 + q * 8);
            #pragma unroll
            for (int nt = 0; nt < 4; ++nt) {
                short8_t b = *(const short8_t*)(wtile + (nt * 16 + r) * 136 + kk * 32 + q * 8);
                acc1[nt] = __builtin_amdgcn_mfma_f32_16x16x32_bf16(a, b, acc1[nt], 0, 0, 0);
            }
        }
        #pragma unroll
        for (int nt = 0; nt < 4; ++nt) {
            int col = nt * 16 + r;
            #pragma unroll
            for (int i2 = 0; i2 < 4; ++i2) {
                int row = wave * 16 + q * 4 + i2;
                feat[row * 72 + col] = f2bs(fmaxf(acc1[nt][i2] + smallb[col], 0.0f));
            }
        }
        __syncthreads();
        if (tid < 128) {
            int row = tid >> 1, cls = tid & 1;
            float a = smallb[192 + cls];
            #pragma unroll 8
            for (int k = 0; k < 64; ++k)
                a += bs2f(feat[row * 72 + k]) * smallb[64 + k * 2 + cls];
            out[(long)(rowBase + row) * 2 + cls] = a;
        }
    }
}

// ---------------------------------------------------------------------------
static inline int igrid(long total, int block, int cap) {
    long g = (total + block - 1) / block;
    return (int)(g < cap ? g : cap);
}

constexpr int GE_EDGE = 2048;
constexpr int GA_AGG  = NNODES / 4;  // 6250
constexpr size_t NINTS_PAD = 25001 + 25000 + 5 * (size_t)NEDGES + 2;

template<typename TE, typename TH>
static void run_net(void* const* d_in, float* f, TE* e, TH* ehat,
                    __hip_bfloat16* eorig, bool fusedFinal,
                    float* out, hipStream_t stream)
{
    const float* h_in   = (const float*)d_in[0];
    const float* e_in   = (const float*)d_in[1];
    const int*   src    = (const int*)d_in[2];
    const int*   dst    = (const int*)d_in[3];
    const int*   rev    = (const int*)d_in[4];
    const float* emb_h_w = (const float*)d_in[5];
    const float* emb_h_b = (const float*)d_in[6];
    const float* emb_e_w = (const float*)d_in[7];
    const float* emb_e_b = (const float*)d_in[8];
    const float* A_w = (const float*)d_in[9];  const float* A_b = (const float*)d_in[10];
    const float* B_w = (const float*)d_in[11]; const float* B_b = (const float*)d_in[12];
    const float* C_w = (const float*)d_in[13]; const float* C_b = (const float*)d_in[14];
    const float* D_w = (const float*)d_in[15]; const float* D_b = (const float*)d_in[16];
    const float* E_w = (const float*)d_in[17]; const float* E_b = (const float*)d_in[18];
    // F/G (19..22) and bn_u (27,28) are dead: u never reaches the output.
    const float* bn_h_g = (const float*)d_in[23]; const float* bn_h_b = (const float*)d_in[24];
    const float* bn_e_g = (const float*)d_in[25]; const float* bn_e_b = (const float*)d_in[26];
    const float* W0 = (const float*)d_in[29]; const float* b0 = (const float*)d_in[30];
    const float* W1 = (const float*)d_in[31]; const float* b1 = (const float*)d_in[32];
    const float* W2 = (const float*)d_in[33]; const float* b2 = (const float*)d_in[34];

    const size_t NH = (size_t)NNODES * DD;
    float* h    = f;
    float* Ah   = f + NH;
    float* Bh   = f + 2 * NH;
    float* Dh   = f + 3 * NH;      // = hhat
    float* Eh   = f + 4 * NH;
    float* hhat = Dh;
    float* scratch = f + 5 * NH;
    float* partial_e = scratch;                              // 2048*128
    float* partial_h = partial_e + (size_t)GE_EDGE * 128;    // 6250*128
    int*   rowptr = (int*)(partial_h + (size_t)GA_AGG * 128);
    int*   cursor = rowptr + NNODES + 1;
    int*   eid    = cursor + NNODES;
    int*   inv    = eid + NEDGES;
    int*   srcS   = inv + NEDGES;
    int*   dstS   = srcS + NEDGES;
    short* W0T = (short*)(rowptr + NINTS_PAD);   // 16B-aligned (ints padded)
    short* W1T = W0T + 256 * 128;
    short* CT  = W1T + 128 * 64;
    short* NT  = CT + 4 * 4096;
    short* HT  = NT + 4 * 16384;
    float* stats_h = (float*)(HT + 256 * 64);
    float* stats_e = stats_h + 128;
    // Hs/Hd bf16 (6.4 MB each) reuse Ah / Bh regions (both dead after last agg)
    __hip_bfloat16* Hs = (__hip_bfloat16*)(f + NH);
    __hip_bfloat16* Hd = (__hip_bfloat16*)(f + 2 * NH);

    const int GN = 1563;
    const int GEDGE = (NEDGES + 255) / 256;

    // CSR + permutation + weight prep (once per call; graph static)
    hipMemsetAsync(rowptr, 0, (2 * NNODES + 1) * sizeof(int), stream);
    deg_hist_kernel<<<GEDGE, 256, 0, stream>>>(dst, rowptr, NEDGES);
    scan_kernel<<<1, 1024, 0, stream>>>(rowptr, NNODES + 1);
    scatter_kernel<<<GEDGE, 256, 0, stream>>>(dst, rowptr, cursor, eid, NEDGES);
    remap1_kernel<<<GEDGE, 256, 0, stream>>>(eid, src, dst, inv, srcS, dstS, NEDGES);
    transpose_w_kernel<<<256, 256, 0, stream>>>(W0, W1, C_w, A_w, B_w, D_w, E_w,
                                                W0T, W1T, CT, NT, HT);

    // embeddings (e in dst-sorted order via eid gather)
    linear_kernel<64, 64, 4, float, float><<<GN, 256, 0, stream>>>(
        h_in, emb_h_w, emb_h_b, h, nullptr, NNODES);
    linear_kernel<16, 64, 4, float, TE><<<4096, 256, 0, stream>>>(
        e_in, emb_e_w, emb_e_b, e, eid, NEDGES);

    for (int l = 0; l < 4; ++l) {
        const size_t o = (size_t)l * DD * DD;
        if (l == 0)
            node_linear4_mfma_kernel<false><<<391, 256, 0, stream>>>(
                h, hhat, NT + (size_t)l * 16384,
                A_b + l * DD, B_b + l * DD, D_b + l * DD, E_b + l * DD,
                nullptr, nullptr, nullptr, Ah, Bh, Dh, Eh);
        else
            node_linear4_mfma_kernel<true><<<391, 256, 0, stream>>>(
                h, hhat, NT + (size_t)l * 16384,
                A_b + l * DD, B_b + l * DD, D_b + l * DD, E_b + l * DD,
                stats_h, bn_h_g + (l - 1) * DD, bn_h_b + (l - 1) * DD,
                Ah, Bh, Dh, Eh);

        if (l == 0)
            edge_update_mfma_kernel<false, TE, TH><<<GE_EDGE, 256, 0, stream>>>(
                e, ehat, CT + o, C_b + l * DD, Dh, srcS, Eh, dstS,
                nullptr, nullptr, nullptr, partial_e);
        else
            edge_update_mfma_kernel<true, TE, TH><<<GE_EDGE, 256, 0, stream>>>(
                e, ehat, CT + o, C_b + l * DD, Dh, srcS, Eh, dstS,
                stats_e, bn_e_g + (l - 1) * DD, bn_e_b + (l - 1) * DD, partial_e);

        agg_sorted_kernel<TH><<<GA_AGG, 256, 0, stream>>>(
            ehat, Bh, srcS, rowptr, Ah, hhat, partial_h);
        reduce_stats2_kernel<<<256, 256, 0, stream>>>(
            partial_e, GE_EDGE, stats_e, partial_h, GA_AGG, stats_h);
    }

    // final e update -> bf16 eorig in ORIGINAL edge order (uses eid; runs
    // before precompute_H clobbers Ah/Bh with Hs/Hd)
    if (fusedFinal) {
        bnfinal_scatter_kernel<TE, TH><<<8192, 256, 0, stream>>>(
            e, ehat, eid, stats_e, bn_e_g + 3 * DD, bn_e_b + 3 * DD, eorig);
    } else {
        bn_apply4_kernel<TE, TH><<<8192, 256, 0, stream>>>(
            e, ehat, stats_e, bn_e_g + 3 * DD, bn_e_b + 3 * DD, NEDGES);
        permute_e_kernel<TE><<<8192, 256, 0, stream>>>(e, eid, eorig);
    }

    // Hs/Hd precompute (bf16) with fused final h-update (no h writeback)
    precompute_H_kernel<<<391, 256, 0, stream>>>(
        h, hhat, stats_h, bn_h_g + 3 * DD, bn_h_b + 3 * DD, HT, b0, Hs, Hd);

    // streaming readout in original order
    readout_mfma2_kernel<<<2048, 256, 0, stream>>>(
        eorig, rev, Hs, Hd, src, dst, W0T, W1T, b1, W2, b2, out);
}

extern "C" void kernel_launch(void* const* d_in, const int* in_sizes, int n_in,
                              void* d_out, int out_size, void* d_ws, size_t ws_size,
                              hipStream_t stream)
{
    const size_t NH = (size_t)NNODES * DD;       // 1.6M floats
    const size_t NE = (size_t)NEDGES * DD;       // 25.6M elems
    const size_t baseB = (7 * NH + 256) * sizeof(float);   // 44.8 MB node region

    char* base = (char*)d_ws;
    char* edge = base + baseB;
    float* out = (float*)d_out;

    // main tier: fp32 e + bf16 ehat + dedicated bf16 eorig = 249.6 MB edge
    // region (same as R3's proven-fitting needA)
    const size_t needMain = baseB + NE * 4 + NE * 2 + NE * 2;
    const size_t needC    = baseB + NE * 2 * 2;    // bf16 e + bf16 ehat, 2-pass

    if (ws_size >= needMain) {
        float* e = (float*)edge;
        __hip_bfloat16* ehat  = (__hip_bfloat16*)(edge + NE * 4);
        __hip_bfloat16* eorig = (__hip_bfloat16*)(edge + NE * 6);
        run_net<float, __hip_bfloat16>(d_in, (float*)base, e, ehat, eorig,
                                       true, out, stream);
    } else if (ws_size >= needC) {
        __hip_bfloat16* e    = (__hip_bfloat16*)edge;
        __hip_bfloat16* ehat = (__hip_bfloat16*)(edge + NE * 2);
        // eorig overlays ehat (dead after bn_apply4), two-pass final
        run_net<__hip_bfloat16, __hip_bfloat16>(d_in, (float*)base, e, ehat,
                                                ehat, false, out, stream);
    } else {
        hipMemsetAsync(d_out, 0, (size_t)out_size * sizeof(float), stream);
    }
}

// Round 11
// 930.505 us; speedup vs baseline: 4.3357x; 1.0026x over previous
//
#include <hip/hip_runtime.h>
#include <hip/hip_bf16.h>

constexpr int NNODES = 25000;
constexpr int NEDGES = 400000;
constexpr int DD = 64;
constexpr float BNEPS = 1e-5f;
constexpr float AGGEPS = 1e-6f;

typedef __attribute__((ext_vector_type(8))) short short8_t;
typedef __attribute__((ext_vector_type(4))) short short4_t;
typedef __attribute__((ext_vector_type(4))) float float4_t;

// storage-type helpers (compute is always fp32)
__device__ __forceinline__ float ldv(const float* p, long i) { return p[i]; }
__device__ __forceinline__ float ldv(const __hip_bfloat16* p, long i) { return __bfloat162float(p[i]); }
__device__ __forceinline__ void stv(float* p, long i, float v) { p[i] = v; }
__device__ __forceinline__ void stv(__hip_bfloat16* p, long i, float v) { p[i] = __float2bfloat16(v); }

__device__ __forceinline__ short f2bs(float f) {
    union { float f; unsigned u; } x; x.f = f;
    unsigned r = x.u + 0x7FFFu + ((x.u >> 16) & 1u);
    return (short)(r >> 16);
}
__device__ __forceinline__ float bs2f(short s) {
    union { unsigned u; float f; } x; x.u = ((unsigned)(unsigned short)s) << 16; return x.f;
}

__device__ __forceinline__ float4_t ldv4(const float* p, long i) {
    return *(const float4_t*)(p + i);
}
__device__ __forceinline__ float4_t ldv4(const __hip_bfloat16* p, long i) {
    short4_t s = *(const short4_t*)(p + i);
    float4_t r;
    #pragma unroll
    for (int c = 0; c < 4; ++c) r[c] = bs2f(s[c]);
    return r;
}
__device__ __forceinline__ void stv4(float* p, long i, float4_t v) {
    *(float4_t*)(p + i) = v;
}
__device__ __forceinline__ void stv4(__hip_bfloat16* p, long i, float4_t v) {
    short4_t s;
    #pragma unroll
    for (int c = 0; c < 4; ++c) s[c] = f2bs(v[c]);
    *(short4_t*)(p + i) = s;
}

__device__ __forceinline__ void stage8(const __hip_bfloat16* s, short* d) {
    *(short8_t*)d = *(const short8_t*)s;
}
__device__ __forceinline__ void stage8(const float* s, short* d) {
    float4_t a = *(const float4_t*)s;
    float4_t b = *(const float4_t*)(s + 4);
    short8_t v;
    v[0] = f2bs(a[0]); v[1] = f2bs(a[1]); v[2] = f2bs(a[2]); v[3] = f2bs(a[3]);
    v[4] = f2bs(b[0]); v[5] = f2bs(b[1]); v[6] = f2bs(b[2]); v[7] = f2bs(b[3]);
    *(short8_t*)d = v;
}

// ---------------------------------------------------------------------------
// Generic LDS-tiled linear (embeddings), optional row-gather on X.
// ---------------------------------------------------------------------------
template<int K, int N, int JR, typename TX, typename TY>
__global__ __launch_bounds__(256) void linear_kernel(
    const TX* __restrict__ X, const float* __restrict__ W,
    const float* __restrict__ Bb, TY* __restrict__ Y,
    const int* __restrict__ gather, int rows)
{
    constexpr int SLOTS = 256 / N;
    constexpr int RPG = SLOTS * JR;
    __shared__ float wl[K * N];
    __shared__ float bl[N];
    __shared__ float xl[RPG * K];

    const int tid = threadIdx.x;
    for (int i = tid; i < K * N; i += 256) wl[i] = W[i];
    if (tid < N) bl[tid] = Bb[tid];

    const int col = tid % N;
    const int slot = tid / N;

    const int ngroups = (rows + RPG - 1) / RPG;
    for (int g = blockIdx.x; g < ngroups; g += gridDim.x) {
        const int rowBase = g * RPG;
        __syncthreads();
        for (int i = tid; i < RPG * K; i += 256) {
            int r = i / K, k = i - r * K;
            int row = rowBase + r;
            float v = 0.0f;
            if (row < rows) {
                int sr = gather ? gather[row] : row;
                v = ldv(X, (long)sr * K + k);
            }
            xl[i] = v;
        }
        __syncthreads();
        float acc[JR];
        #pragma unroll
        for (int j = 0; j < JR; ++j) acc[j] = bl[col];
        #pragma unroll 4
        for (int k = 0; k < K; ++k) {
            float w = wl[k * N + col];
            #pragma unroll
            for (int j = 0; j < JR; ++j)
                acc[j] += xl[(slot * JR + j) * K + k] * w;
        }
        #pragma unroll
        for (int j = 0; j < JR; ++j) {
            int row = rowBase + slot * JR + j;
            if (row < rows) stv(Y, (long)row * N + col, acc[j]);
        }
    }
}

// ---------------------------------------------------------------------------
// Quad node linear, MFMA: Ah (fp32) | Bh,Dh,Eh (bf16) = h @ {A,B,D,E} + b.
// If BNIN: h = h + relu(bn(hhat; stats_prev)) in place first (feeds matmul).
// ---------------------------------------------------------------------------
template<bool BNIN>
__global__ __launch_bounds__(256) void node_linear4_mfma_kernel(
    float* __restrict__ h, const float* __restrict__ hhat,
    const short* __restrict__ NT,
    const float* __restrict__ Ab, const float* __restrict__ Bb,
    const float* __restrict__ Db, const float* __restrict__ Eb,
    const float* __restrict__ stats_prev, const float* __restrict__ gprev,
    const float* __restrict__ bprev,
    float* __restrict__ Ah, __hip_bfloat16* __restrict__ Bh,
    __hip_bfloat16* __restrict__ Dh, __hip_bfloat16* __restrict__ Eh)
{
    __shared__ short wt[256 * 72];
    __shared__ short xs[64 * 72];
    __shared__ float bl[256];
    __shared__ float scale[64], shift[64];

    const int tid = threadIdx.x;
    const int wave = tid >> 6;
    const int lane = tid & 63;
    const int r = lane & 15;
    const int q = lane >> 4;

    for (int i = tid; i < 2048; i += 256) {
        int n = i >> 3, oct = i & 7;
        *(short8_t*)(wt + n * 72 + oct * 8) = *(const short8_t*)(NT + n * 64 + oct * 8);
    }
    if (tid < 64) bl[tid] = Ab[tid];
    else if (tid < 128) bl[tid] = Bb[tid - 64];
    else if (tid < 192) bl[tid] = Db[tid - 128];
    else bl[tid] = Eb[tid - 192];
    if (BNIN && tid < 64) {
        float inv = 1.0f / (float)NNODES;
        float mu = stats_prev[tid] * inv;
        float var = stats_prev[64 + tid] * inv - mu * mu;
        float rs = rsqrtf(var + BNEPS);
        float sc = rs * gprev[tid];
        scale[tid] = sc;
        shift[tid] = bprev[tid] - mu * sc;
    }

    const int ntiles = (NNODES + 63) / 64;        // 391
    for (int t = blockIdx.x; t < ntiles; t += gridDim.x) {
        const int rowBase = t * 64;
        __syncthreads();
        for (int i = tid; i < 512; i += 256) {
            int row = i >> 3, oct = i & 7;
            int nr = rowBase + row;
            if (nr < NNODES) {
                long idx = (long)nr * 64 + oct * 8;
                float4_t a = ldv4(h, idx), b = ldv4(h, idx + 4);
                if (BNIN) {
                    float4_t ha = ldv4(hhat, idx), hb = ldv4(hhat, idx + 4);
                    int k0 = oct * 8;
                    #pragma unroll
                    for (int c = 0; c < 4; ++c) {
                        a[c] += fmaxf(ha[c] * scale[k0 + c] + shift[k0 + c], 0.0f);
                        b[c] += fmaxf(hb[c] * scale[k0 + 4 + c] + shift[k0 + 4 + c], 0.0f);
                    }
                    stv4(h, idx, a); stv4(h, idx + 4, b);
                }
                short8_t v;
                v[0] = f2bs(a[0]); v[1] = f2bs(a[1]); v[2] = f2bs(a[2]); v[3] = f2bs(a[3]);
                v[4] = f2bs(b[0]); v[5] = f2bs(b[1]); v[6] = f2bs(b[2]); v[7] = f2bs(b[3]);
                *(short8_t*)(xs + row * 72 + oct * 8) = v;
            } else {
                *(short8_t*)(xs + row * 72 + oct * 8) = (short8_t)0;
            }
        }
        __syncthreads();
        float4_t acc[16];
        #pragma unroll
        for (int i = 0; i < 16; ++i) acc[i] = (float4_t)0.0f;
        #pragma unroll
        for (int kk = 0; kk < 2; ++kk) {
            short8_t a = *(const short8_t*)(xs + (wave * 16 + r) * 72 + kk * 32 + q * 8);
            #pragma unroll
            for (int nt = 0; nt < 16; ++nt) {
                short8_t b = *(const short8_t*)(wt + (nt * 16 + r) * 72 + kk * 32 + q * 8);
                acc[nt] = __builtin_amdgcn_mfma_f32_16x16x32_bf16(a, b, acc[nt], 0, 0, 0);
            }
        }
        #pragma unroll
        for (int nt = 0; nt < 16; ++nt) {
            int c = (nt & 3) * 16 + r;
            int n = nt * 16 + r;
            #pragma unroll
            for (int i2 = 0; i2 < 4; ++i2) {
                int row = rowBase + wave * 16 + q * 4 + i2;
                if (row < NNODES) {
                    float v = acc[nt][i2] + bl[n];
                    long idx = (long)row * 64 + c;
                    if (nt < 4)       Ah[idx] = v;
                    else if (nt < 8)  stv(Bh, idx, v);
                    else if (nt < 12) stv(Dh, idx, v);
                    else              stv(Eh, idx, v);
                }
            }
        }
    }
}

// ---------------------------------------------------------------------------
// MFMA edge update (edges in dst-sorted order); Dh/Eh are bf16 (L2-resident).
// BN stats are accumulated from fp32 values BEFORE ehat storage rounding.
// ---------------------------------------------------------------------------
template<bool BNIN, typename TE, typename TH>
__global__ __launch_bounds__(256) void edge_update_mfma_kernel(
    TE* __restrict__ e, TH* __restrict__ ehat,
    const short* __restrict__ CT, const float* __restrict__ Cb,
    const __hip_bfloat16* __restrict__ Dh, const int* __restrict__ srcS,
    const __hip_bfloat16* __restrict__ Eh, const int* __restrict__ dstS,
    const float* __restrict__ stats_prev, const float* __restrict__ gprev,
    const float* __restrict__ bprev, float* __restrict__ partial)
{
    __shared__ short ct[64 * 72];
    __shared__ short xs[64 * 72];
    __shared__ float bl[64], scale[64], shift[64];
    __shared__ float ps[128];

    const int tid = threadIdx.x;
    const int wave = tid >> 6;
    const int lane = tid & 63;
    const int r = lane & 15;
    const int q = lane >> 4;

    for (int i = tid; i < 512; i += 256) {
        int n = i >> 3, oct = i & 7;
        *(short8_t*)(ct + n * 72 + oct * 8) = *(const short8_t*)(CT + n * 64 + oct * 8);
    }
    if (tid < 64) {
        bl[tid] = Cb[tid];
        if (BNIN) {
            float inv = 1.0f / (float)NEDGES;
            float mu = stats_prev[tid] * inv;
            float var = stats_prev[64 + tid] * inv - mu * mu;
            float rs = rsqrtf(var + BNEPS);
            float sc = rs * gprev[tid];
            scale[tid] = sc;
            shift[tid] = bprev[tid] - mu * sc;
        }
    }
    if (tid < 128) ps[tid] = 0.0f;
    float lsum[4] = {0, 0, 0, 0}, lsum2[4] = {0, 0, 0, 0};

    constexpr int NTILES = NEDGES / 64;
    for (int t = blockIdx.x; t < NTILES; t += gridDim.x) {
        const int rowBase = t * 64;
        __syncthreads();
        for (int i = tid; i < 512; i += 256) {
            int row = i >> 3, oct = i & 7;
            long idx = (long)(rowBase + row) * 64 + oct * 8;
            float4_t a = ldv4(e, idx), b = ldv4(e, idx + 4);
            if (BNIN) {
                float4_t ha = ldv4(ehat, idx), hb = ldv4(ehat, idx + 4);
                int k0 = oct * 8;
                #pragma unroll
                for (int c = 0; c < 4; ++c) {
                    a[c] += fmaxf(ha[c] * scale[k0 + c] + shift[k0 + c], 0.0f);
                    b[c] += fmaxf(hb[c] * scale[k0 + 4 + c] + shift[k0 + 4 + c], 0.0f);
                }
                stv4(e, idx, a); stv4(e, idx + 4, b);
            }
            short8_t v;
            v[0] = f2bs(a[0]); v[1] = f2bs(a[1]); v[2] = f2bs(a[2]); v[3] = f2bs(a[3]);
            v[4] = f2bs(b[0]); v[5] = f2bs(b[1]); v[6] = f2bs(b[2]); v[7] = f2bs(b[3]);
            *(short8_t*)(xs + row * 72 + oct * 8) = v;
        }
        __syncthreads();
        float4_t acc[4];
        #pragma unroll
        for (int i = 0; i < 4; ++i) acc[i] = (float4_t)0.0f;
        #pragma unroll
        for (int kk = 0; kk < 2; ++kk) {
            short8_t a = *(const short8_t*)(xs + (wave * 16 + r) * 72 + kk * 32 + q * 8);
            #pragma unroll
            for (int nt = 0; nt < 4; ++nt) {
                short8_t b = *(const short8_t*)(ct + (nt * 16 + r) * 72 + kk * 32 + q * 8);
                acc[nt] = __builtin_amdgcn_mfma_f32_16x16x32_bf16(a, b, acc[nt], 0, 0, 0);
            }
        }
        #pragma unroll
        for (int i2 = 0; i2 < 4; ++i2) {
            int row = wave * 16 + q * 4 + i2;
            int er = rowBase + row;
            int s = srcS[er], d = dstS[er];
            #pragma unroll
            for (int nt = 0; nt < 4; ++nt) {
                int col = nt * 16 + r;
                float v = acc[nt][i2] + bl[col]
                        + ldv(Dh, (long)s * 64 + col) + ldv(Eh, (long)d * 64 + col);
                stv(ehat, (long)er * 64 + col, v);
                lsum[nt] += v; lsum2[nt] += v * v;
            }
        }
    }
    __syncthreads();
    #pragma unroll
    for (int nt = 0; nt < 4; ++nt) {
        atomicAdd(&ps[nt * 16 + r], lsum[nt]);
        atomicAdd(&ps[64 + nt * 16 + r], lsum2[nt]);
    }
    __syncthreads();
    if (tid < 128) partial[(long)blockIdx.x * 128 + tid] = ps[tid];
}

// ---------------------------------------------------------------------------
// CSR build + edge permutation
// ---------------------------------------------------------------------------
__global__ __launch_bounds__(256) void deg_hist_kernel(
    const int* __restrict__ dst, int* __restrict__ rowptr, int rows)
{
    int e = blockIdx.x * 256 + threadIdx.x;
    if (e < rows) atomicAdd(&rowptr[dst[e] + 1], 1);
}

__global__ __launch_bounds__(1024) void scan_kernel(int* __restrict__ data, int n)
{
    __shared__ int buf[1024];
    __shared__ int carry;
    if (threadIdx.x == 0) carry = 0;
    __syncthreads();
    for (int base = 0; base < n; base += 1024) {
        int i = base + threadIdx.x;
        int v = (i < n) ? data[i] : 0;
        buf[threadIdx.x] = v;
        __syncthreads();
        for (int off = 1; off < 1024; off <<= 1) {
            int t = (threadIdx.x >= off) ? buf[threadIdx.x - off] : 0;
            __syncthreads();
            buf[threadIdx.x] += t;
            __syncthreads();
        }
        if (i < n) data[i] = buf[threadIdx.x] + carry;
        __syncthreads();
        if (threadIdx.x == 0) carry += buf[1023];
        __syncthreads();
    }
}

__global__ __launch_bounds__(256) void scatter_kernel(
    const int* __restrict__ dst, const int* __restrict__ rowptr,
    int* __restrict__ cursor, int* __restrict__ eid, int rows)
{
    int e = blockIdx.x * 256 + threadIdx.x;
    if (e < rows) {
        int d = dst[e];
        int pos = atomicAdd(&cursor[d], 1);
        eid[rowptr[d] + pos] = e;
    }
}

__global__ __launch_bounds__(256) void remap1_kernel(
    const int* __restrict__ eid, const int* __restrict__ src,
    const int* __restrict__ dst, int* __restrict__ inv,
    int* __restrict__ srcS, int* __restrict__ dstS, int rows)
{
    int p = blockIdx.x * 256 + threadIdx.x;
    if (p < rows) {
        int orig = eid[p];
        inv[orig] = p;
        srcS[p] = src[orig];
        dstS[p] = dst[orig];
    }
}

// ---------------------------------------------------------------------------
// Sorted aggregation + fused hhat + BN partials; Bh is bf16 (L2-resident).
// ---------------------------------------------------------------------------
template<typename TH>
__global__ __launch_bounds__(256) void agg_sorted_kernel(
    const TH* __restrict__ ehat, const __hip_bfloat16* __restrict__ Bh,
    const int* __restrict__ srcS, const int* __restrict__ rowptr,
    const float* __restrict__ Ah, float* __restrict__ hhat,
    float* __restrict__ partial)
{
    __shared__ float ps[64], ps2[64];
    const int tid = threadIdx.x;
    if (tid < 64) { ps[tid] = 0.0f; ps2[tid] = 0.0f; }
    __syncthreads();

    const int node = blockIdx.x * 4 + (tid >> 6);
    const int lane = tid & 63;
    const int sub = lane >> 4;
    const int c4 = (lane & 15) * 4;
    const int s0 = rowptr[node], s1 = rowptr[node + 1];

    float4_t den = (float4_t)0.0f, num = (float4_t)0.0f;
    for (int p = s0 + sub; p < s1; p += 4) {
        float4_t v = ldv4(ehat, (long)p * 64 + c4);
        float4_t bh = ldv4(Bh, (long)srcS[p] * 64 + c4);
        #pragma unroll
        for (int c = 0; c < 4; ++c) {
            float s = 1.0f / (1.0f + __expf(-v[c]));
            den[c] += s;
            num[c] += s * bh[c];
        }
    }
    #pragma unroll
    for (int m = 16; m <= 32; m <<= 1) {
        #pragma unroll
        for (int c = 0; c < 4; ++c) {
            den[c] += __shfl_xor(den[c], m, 64);
            num[c] += __shfl_xor(num[c], m, 64);
        }
    }
    if (sub == 0) {
        float4_t av = ldv4(Ah, (long)node * 64 + c4);
        float4_t hh;
        #pragma unroll
        for (int c = 0; c < 4; ++c) {
            hh[c] = av[c] + num[c] / (den[c] + AGGEPS);
            atomicAdd(&ps[c4 + c], hh[c]);
            atomicAdd(&ps2[c4 + c], hh[c] * hh[c]);
        }
        stv4(hhat, (long)node * 64 + c4, hh);
    }
    __syncthreads();
    if (tid < 64) {
        partial[(long)blockIdx.x * 128 + tid] = ps[tid];
        partial[(long)blockIdx.x * 128 + 64 + tid] = ps2[tid];
    }
}

// merged stats reduce: blocks 0..127 -> stats_e, 128..255 -> stats_h
__global__ __launch_bounds__(256) void reduce_stats2_kernel(
    const float* __restrict__ pe, int ne, float* __restrict__ se,
    const float* __restrict__ ph, int nh, float* __restrict__ sh)
{
    __shared__ float sb[256];
    const float* partial; int nblk; float* stats; int col;
    if (blockIdx.x < 128) { partial = pe; nblk = ne; stats = se; col = blockIdx.x; }
    else                  { partial = ph; nblk = nh; stats = sh; col = blockIdx.x - 128; }
    int tid = threadIdx.x;
    float s = 0.0f;
    for (int i = tid; i < nblk; i += 256) s += partial[(long)i * 128 + col];
    sb[tid] = s;
    __syncthreads();
    for (int off = 128; off > 0; off >>= 1) {
        if (tid < off) sb[tid] += sb[tid + off];
        __syncthreads();
    }
    if (tid == 0) stats[col] = sb[0];
}

// base += relu((xhat-mu)*rstd*g + b), float4 per thread (in place)
template<typename TB, typename TX>
__global__ __launch_bounds__(256) void bn_apply4_kernel(
    TB* __restrict__ base, const TX* __restrict__ xhat,
    const float* __restrict__ stats, const float* __restrict__ g,
    const float* __restrict__ b, int rows)
{
    long total4 = (long)rows * 16;
    float inv = 1.0f / (float)rows;
    for (long q = (long)blockIdx.x * 256 + threadIdx.x; q < total4;
         q += (long)gridDim.x * 256) {
        long idx = q * 4;
        int c = (int)(idx & 63);
        float4_t x = ldv4(xhat, idx);
        float4_t bs = ldv4(base, idx);
        #pragma unroll
        for (int j = 0; j < 4; ++j) {
            float mu = stats[c + j] * inv;
            float var = stats[64 + c + j] * inv - mu * mu;
            float rs = rsqrtf(var + BNEPS);
            float v = (x[j] - mu) * rs * g[c + j] + b[c + j];
            bs[j] += fmaxf(v, 0.0f);
        }
        stv4(base, idx, bs);
    }
}

// fused final e update + scatter to original order:
// eorig[eid[p]] = bf16(e[p] + relu(bn(ehat[p])))
template<typename TE, typename TH>
__global__ __launch_bounds__(256) void bnfinal_scatter_kernel(
    const TE* __restrict__ e, const TH* __restrict__ ehat,
    const int* __restrict__ eid, const float* __restrict__ stats,
    const float* __restrict__ g, const float* __restrict__ b,
    __hip_bfloat16* __restrict__ eorig)
{
    __shared__ float scale[64], shift[64];
    const int tid = threadIdx.x;
    if (tid < 64) {
        float inv = 1.0f / (float)NEDGES;
        float mu = stats[tid] * inv;
        float var = stats[64 + tid] * inv - mu * mu;
        float rs = rsqrtf(var + BNEPS);
        float sc = rs * g[tid];
        scale[tid] = sc;
        shift[tid] = b[tid] - mu * sc;
    }
    __syncthreads();
    long total = (long)NEDGES * 8;
    for (long i = (long)blockIdx.x * 256 + tid; i < total; i += (long)gridDim.x * 256) {
        int p = (int)(i >> 3), oct = (int)(i & 7);
        int k0 = oct * 8;
        long idx = (long)p * 64 + k0;
        float4_t a = ldv4(e, idx), b4 = ldv4(e, idx + 4);
        float4_t ha = ldv4(ehat, idx), hb = ldv4(ehat, idx + 4);
        short8_t v;
        #pragma unroll
        for (int c = 0; c < 4; ++c) {
            v[c]     = f2bs(a[c]  + fmaxf(ha[c] * scale[k0 + c]     + shift[k0 + c], 0.0f));
            v[4 + c] = f2bs(b4[c] + fmaxf(hb[c] * scale[k0 + 4 + c] + shift[k0 + 4 + c], 0.0f));
        }
        *(short8_t*)((short*)eorig + (long)eid[p] * 64 + k0) = v;
    }
}

// two-pass fallback: permute updated e (sorted) -> bf16 eorig (original order)
template<typename TE>
__global__ __launch_bounds__(256) void permute_e_kernel(
    const TE* __restrict__ e, const int* __restrict__ eid,
    __hip_bfloat16* __restrict__ eorig)
{
    long total = (long)NEDGES * 8;
    for (long i = (long)blockIdx.x * 256 + threadIdx.x; i < total;
         i += (long)gridDim.x * 256) {
        int p = (int)(i >> 3), oct = (int)(i & 7);
        long idx = (long)p * 64 + oct * 8;
        float4_t a = ldv4(e, idx), b = ldv4(e, idx + 4);
        short8_t v;
        #pragma unroll
        for (int c = 0; c < 4; ++c) { v[c] = f2bs(a[c]); v[4 + c] = f2bs(b[c]); }
        *(short8_t*)((short*)eorig + (long)eid[p] * 64 + oct * 8) = v;
    }
}

// Hs = h_fin @ W0c + b0, Hd = h_fin @ W0d (bf16 outputs), with
// h_fin = h + relu(bn(hhat)) computed on the fly (no h writeback).
__global__ __launch_bounds__(256) void precompute_H_kernel(
    const float* __restrict__ h, const float* __restrict__ hhat,
    const float* __restrict__ stats, const float* __restrict__ g,
    const float* __restrict__ b,
    const short* __restrict__ HT, const float* __restrict__ b0,
    __hip_bfloat16* __restrict__ Hs, __hip_bfloat16* __restrict__ Hd)
{
    __shared__ short wt[256 * 72];
    __shared__ short xs[64 * 72];
    __shared__ float bl[256];
    __shared__ float scale[64], shift[64];

    const int tid = threadIdx.x;
    const int wave = tid >> 6;
    const int lane = tid & 63;
    const int r = lane & 15;
    const int q = lane >> 4;

    for (int i = tid; i < 2048; i += 256) {
        int n = i >> 3, oct = i & 7;
        *(short8_t*)(wt + n * 72 + oct * 8) = *(const short8_t*)(HT + n * 64 + oct * 8);
    }
    bl[tid] = (tid < 128) ? b0[tid] : 0.0f;
    if (tid < 64) {
        float inv = 1.0f / (float)NNODES;
        float mu = stats[tid] * inv;
        float var = stats[64 + tid] * inv - mu * mu;
        float rs = rsqrtf(var + BNEPS);
        float sc = rs * g[tid];
        scale[tid] = sc;
        shift[tid] = b[tid] - mu * sc;
    }

    const int ntiles = (NNODES + 63) / 64;
    for (int t = blockIdx.x; t < ntiles; t += gridDim.x) {
        const int rowBase = t * 64;
        __syncthreads();
        for (int i = tid; i < 512; i += 256) {
            int row = i >> 3, oct = i & 7;
            int nr = rowBase + row;
            if (nr < NNODES) {
                long idx = (long)nr * 64 + oct * 8;
                float4_t a = ldv4(h, idx), bb = ldv4(h, idx + 4);
                float4_t ha = ldv4(hhat, idx), hb = ldv4(hhat, idx + 4);
                int k0 = oct * 8;
                #pragma unroll
                for (int c = 0; c < 4; ++c) {
                    a[c]  += fmaxf(ha[c] * scale[k0 + c]     + shift[k0 + c], 0.0f);
                    bb[c] += fmaxf(hb[c] * scale[k0 + 4 + c] + shift[k0 + 4 + c], 0.0f);
                }
                short8_t v;
                v[0] = f2bs(a[0]); v[1] = f2bs(a[1]); v[2] = f2bs(a[2]); v[3] = f2bs(a[3]);
                v[4] = f2bs(bb[0]); v[5] = f2bs(bb[1]); v[6] = f2bs(bb[2]); v[7] = f2bs(bb[3]);
                *(short8_t*)(xs + row * 72 + oct * 8) = v;
            } else {
                *(short8_t*)(xs + row * 72 + oct * 8) = (short8_t)0;
            }
        }
        __syncthreads();
        float4_t acc[16];
        #pragma unroll
        for (int i = 0; i < 16; ++i) acc[i] = (float4_t)0.0f;
        #pragma unroll
        for (int kk = 0; kk < 2; ++kk) {
            short8_t a = *(const short8_t*)(xs + (wave * 16 + r) * 72 + kk * 32 + q * 8);
            #pragma unroll
            for (int nt = 0; nt < 16; ++nt) {
                short8_t b2 = *(const short8_t*)(wt + (nt * 16 + r) * 72 + kk * 32 + q * 8);
                acc[nt] = __builtin_amdgcn_mfma_f32_16x16x32_bf16(a, b2, acc[nt], 0, 0, 0);
            }
        }
        #pragma unroll
        for (int nt = 0; nt < 16; ++nt) {
            __hip_bfloat16* Y = (nt < 8) ? Hs : Hd;
            int c = (nt & 7) * 16 + r;
            int n = nt * 16 + r;
            #pragma unroll
            for (int i2 = 0; i2 < 4; ++i2) {
                int row = rowBase + wave * 16 + q * 4 + i2;
                if (row < NNODES) stv(Y, (long)row * 128 + c, acc[nt][i2] + bl[n]);
            }
        }
    }
}

// one-shot weight prep (bf16 [n][k]): W0T [128][256], W1T [64][128],
// CT [l][64][64], NT [l][256][64] (A|B|D|E), HT [256][64] (W0c|W0d)
__global__ __launch_bounds__(256) void transpose_w_kernel(
    const float* __restrict__ W0, const float* __restrict__ W1,
    const float* __restrict__ C_w,
    const float* __restrict__ A_w, const float* __restrict__ B_w,
    const float* __restrict__ D_w, const float* __restrict__ E_w,
    short* __restrict__ W0T, short* __restrict__ W1T,
    short* __restrict__ CT, short* __restrict__ NT, short* __restrict__ HT)
{
    int id = blockIdx.x * 256 + threadIdx.x;
    if (id < 256 * 128) {
        int k = id >> 7, n = id & 127;
        W0T[n * 256 + k] = f2bs(W0[id]);
    }
    if (id < 128 * 64) {
        int k = id >> 6, n = id & 63;
        W1T[n * 128 + k] = f2bs(W1[id]);
    }
    if (id < 4 * 64 * 64) {
        int l = id >> 12, rem = id & 4095, k = rem >> 6, n = rem & 63;
        CT[l * 4096 + n * 64 + k] = f2bs(C_w[l * 4096 + k * 64 + n]);
    }
    if (id < 4 * 256 * 64) {
        int l = id >> 14, rem = id & 16383, n = rem >> 6, k = rem & 63;
        int mat = n >> 6, c = n & 63;
        const float* Wm = (mat == 0) ? A_w : (mat == 1) ? B_w : (mat == 2) ? D_w : E_w;
        NT[l * 16384 + n * 64 + k] = f2bs(Wm[l * 4096 + k * 64 + c]);
    }
    if (id < 256 * 64) {
        int n = id >> 6, k = id & 63;
        int mat = n >> 7, col = n & 127;
        HT[n * 64 + k] = f2bs(W0[(128 + mat * 64 + k) * 128 + col]);
    }
}

// ---------------------------------------------------------------------------
// MFMA MLP readout v3 — original edge order; W1 fragments live in REGISTERS
// (loaded once per block); MFMA A-reads and x0t accesses are wave-private
// (row = wave*16 + lane&15), so no barrier is needed between epilogue-1,
// phase-2 and the x1 write (same-wave DS ops are in-order). 5 barriers/tile.
// ---------------------------------------------------------------------------
__global__ __launch_bounds__(256) void readout_mfma2_kernel(
    const __hip_bfloat16* __restrict__ eorig, const int* __restrict__ rev,
    const __hip_bfloat16* __restrict__ Hs, const __hip_bfloat16* __restrict__ Hd,
    const int* __restrict__ src, const int* __restrict__ dst,
    const short* __restrict__ W0T, const short* __restrict__ W1T,
    const float* __restrict__ b1, const float* __restrict__ W2,
    const float* __restrict__ b2, float* __restrict__ out)
{
    __shared__ short feat[64 * 72];    // e / e_rev tile; reused as x1 tile
    __shared__ short wtile[128 * 72];  // W0 slice [128][72]
    __shared__ short x0t[64 * 136];    // x0 tile bf16 (wave-private rows)
    __shared__ float smallb[194];      // b1[64] | W2[128] | b2[2]

    const int tid = threadIdx.x;
    const int wave = tid >> 6;
    const int lane = tid & 63;
    const int r = lane & 15;
    const int q = lane >> 4;

    if (tid < 64)  smallb[tid] = b1[tid];
    if (tid < 128) smallb[64 + tid] = W2[tid];
    if (tid < 2)   smallb[192 + tid] = b2[tid];

    // W1 B-fragments resident in registers (16 x short8 = 64 VGPRs)
    short8_t w1f[16];
    #pragma unroll
    for (int nt = 0; nt < 4; ++nt)
        #pragma unroll
        for (int kk = 0; kk < 4; ++kk)
            w1f[nt * 4 + kk] =
                *(const short8_t*)(W1T + (long)(nt * 16 + r) * 128 + kk * 32 + q * 8);

    constexpr int NTILES = NEDGES / 64;   // 6250
    for (int t = blockIdx.x; t < NTILES; t += gridDim.x) {
        const int rowBase = t * 64;
        float4_t acc0[8];
        #pragma unroll
        for (int i = 0; i < 8; ++i) acc0[i] = (float4_t)0.0f;

        for (int s = 0; s < 2; ++s) {
            __syncthreads();   // protect feat/wtile restage vs prior reads
            for (int i = tid; i < 512; i += 256) {
                int row = i >> 3, oct = i & 7;
                int er = rowBase + row;
                int srow = (s == 0) ? er : rev[er];   // sequential either way
                *(short8_t*)(feat + row * 72 + oct * 8) =
                    *(const short8_t*)((const short*)eorig + (long)srow * 64 + oct * 8);
            }
            for (int i = tid; i < 1024; i += 256) {
                int n = i >> 3, oct = i & 7;
                *(short8_t*)(wtile + n * 72 + oct * 8) =
                    *(const short8_t*)(W0T + (long)n * 256 + s * 64 + oct * 8);
            }
            __syncthreads();
            #pragma unroll
            for (int kk = 0; kk < 2; ++kk) {
                short8_t a = *(const short8_t*)(feat + (wave * 16 + r) * 72 + kk * 32 + q * 8);
                #pragma unroll
                for (int nt = 0; nt < 8; ++nt) {
                    short8_t b = *(const short8_t*)(wtile + (nt * 16 + r) * 72 + kk * 32 + q * 8);
                    acc0[nt] = __builtin_amdgcn_mfma_f32_16x16x32_bf16(a, b, acc0[nt], 0, 0, 0);
                }
            }
        }
        // epilogue 1: x0 = relu(acc0 + Hs[src] + Hd[dst]) -> x0t (wave-private)
        #pragma unroll
        for (int i2 = 0; i2 < 4; ++i2) {
            int row = wave * 16 + q * 4 + i2;
            int er = rowBase + row;
            int sN = src[er], dN = dst[er];
            #pragma unroll
            for (int nt = 0; nt < 8; ++nt) {
                int col = nt * 16 + r;
                float v = acc0[nt][i2] + ldv(Hs, (long)sN * 128 + col)
                                       + ldv(Hd, (long)dN * 128 + col);
                x0t[row * 136 + col] = f2bs(fmaxf(v, 0.0f));
            }
        }
        // phase 2 immediately (wave-private x0t reads + register W1 frags)
        float4_t acc1[4];
        #pragma unroll
        for (int i = 0; i < 4; ++i) acc1[i] = (float4_t)0.0f;
        #pragma unroll
        for (int kk = 0; kk < 4; ++kk) {
            short8_t a = *(const short8_t*)(x0t + (wave * 16 + r) * 136 + kk * 32 + q * 8);
            #pragma unroll
            for (int nt = 0; nt < 4; ++nt)
                acc1[nt] = __builtin_amdgcn_mfma_f32_16x16x32_bf16(a, w1f[nt * 4 + kk], acc1[nt], 0, 0, 0);
        }
        // x1 -> feat (wave-private rows; other waves only touch their own)
        #pragma unroll
        for (int nt = 0; nt < 4; ++nt) {
            int col = nt * 16 + r;
            #pragma unroll
            for (int i2 = 0; i2 < 4; ++i2) {
                int row = wave * 16 + q * 4 + i2;
                feat[row * 72 + col] = f2bs(fmaxf(acc1[nt][i2] + smallb[col], 0.0f));
            }
        }
        __syncthreads();   // x1 visible to all for phase 3
        if (tid < 128) {
            int row = tid >> 1, cls = tid & 1;
            float a = smallb[192 + cls];
            #pragma unroll 8
            for (int k = 0; k < 64; ++k)
                a += bs2f(feat[row * 72 + k]) * smallb[64 + k * 2 + cls];
            out[(long)(rowBase + row) * 2 + cls] = a;
        }
    }
}

// ---------------------------------------------------------------------------
static inline int igrid(long total, int block, int cap) {
    long g = (total + block - 1) / block;
    return (int)(g < cap ? g : cap);
}

constexpr int GE_EDGE = 2048;
constexpr int GA_AGG  = NNODES / 4;  // 6250
constexpr size_t NINTS_PAD = 25001 + 25000 + 4 * (size_t)NEDGES + 3;  // %4==0

template<typename TE, typename TH>
static void run_net(void* const* d_in, float* f, TE* e, TH* ehat,
                    __hip_bfloat16* eorig, bool fusedFinal,
                    float* out, hipStream_t stream)
{
    const float* h_in   = (const float*)d_in[0];
    const float* e_in   = (const float*)d_in[1];
    const int*   src    = (const int*)d_in[2];
    const int*   dst    = (const int*)d_in[3];
    const int*   rev    = (const int*)d_in[4];
    const float* emb_h_w = (const float*)d_in[5];
    const float* emb_h_b = (const float*)d_in[6];
    const float* emb_e_w = (const float*)d_in[7];
    const float* emb_e_b = (const float*)d_in[8];
    const float* A_w = (const float*)d_in[9];  const float* A_b = (const float*)d_in[10];
    const float* B_w = (const float*)d_in[11]; const float* B_b = (const float*)d_in[12];
    const float* C_w = (const float*)d_in[13]; const float* C_b = (const float*)d_in[14];
    const float* D_w = (const float*)d_in[15]; const float* D_b = (const float*)d_in[16];
    const float* E_w = (const float*)d_in[17]; const float* E_b = (const float*)d_in[18];
    // F/G (19..22) and bn_u (27,28) are dead: u never reaches the output.
    const float* bn_h_g = (const float*)d_in[23]; const float* bn_h_b = (const float*)d_in[24];
    const float* bn_e_g = (const float*)d_in[25]; const float* bn_e_b = (const float*)d_in[26];
    const float* W0 = (const float*)d_in[29]; const float* b0 = (const float*)d_in[30];
    const float* W1 = (const float*)d_in[31]; const float* b1 = (const float*)d_in[32];
    const float* W2 = (const float*)d_in[33]; const float* b2 = (const float*)d_in[34];

    const size_t NH = (size_t)NNODES * DD;   // 1.6M (even)
    float* h    = f;                         // NH fp32
    float* Ah   = f + NH;                    // NH fp32 (Hs overlays after layers)
    float* hhat = f + 2 * NH;                // NH fp32 (dedicated now)
    __hip_bfloat16* Bh16 = (__hip_bfloat16*)(f + 3 * NH);           // NH bf16
    __hip_bfloat16* Dh16 = (__hip_bfloat16*)(f + 3 * NH + NH / 2);  // NH bf16
    __hip_bfloat16* Eh16 = (__hip_bfloat16*)(f + 4 * NH);           // NH bf16
    float* scratch = f + 4 * NH + NH / 2;
    float* partial_e = scratch;                              // 2048*128
    float* partial_h = partial_e + (size_t)GE_EDGE * 128;    // 6250*128
    int*   rowptr = (int*)(partial_h + (size_t)GA_AGG * 128);
    int*   cursor = rowptr + NNODES + 1;
    int*   eid    = cursor + NNODES;
    int*   inv    = eid + NEDGES;
    int*   srcS   = inv + NEDGES;
    int*   dstS   = srcS + NEDGES;
    short* W0T = (short*)(rowptr + NINTS_PAD);   // 16B-aligned
    short* W1T = W0T + 256 * 128;
    short* CT  = W1T + 128 * 64;
    short* NT  = CT + 4 * 4096;
    short* HT  = NT + 4 * 16384;
    float* stats_h = (float*)(HT + 256 * 64);
    float* stats_e = stats_h + 128;
    // Hs: Ah region (NH fp32 = 3.2M bf16 = exactly 25000*128). Hd: Bh16+Dh16.
    __hip_bfloat16* Hs = (__hip_bfloat16*)(f + NH);
    __hip_bfloat16* Hd = (__hip_bfloat16*)(f + 3 * NH);

    const int GN = 1563;
    const int GEDGE = (NEDGES + 255) / 256;

    // CSR + permutation + weight prep (once per call; graph static)
    hipMemsetAsync(rowptr, 0, (2 * NNODES + 1) * sizeof(int), stream);
    deg_hist_kernel<<<GEDGE, 256, 0, stream>>>(dst, rowptr, NEDGES);
    scan_kernel<<<1, 1024, 0, stream>>>(rowptr, NNODES + 1);
    scatter_kernel<<<GEDGE, 256, 0, stream>>>(dst, rowptr, cursor, eid, NEDGES);
    remap1_kernel<<<GEDGE, 256, 0, stream>>>(eid, src, dst, inv, srcS, dstS, NEDGES);
    transpose_w_kernel<<<256, 256, 0, stream>>>(W0, W1, C_w, A_w, B_w, D_w, E_w,
                                                W0T, W1T, CT, NT, HT);

    // embeddings (e in dst-sorted order via eid gather)
    linear_kernel<64, 64, 4, float, float><<<GN, 256, 0, stream>>>(
        h_in, emb_h_w, emb_h_b, h, nullptr, NNODES);
    linear_kernel<16, 64, 4, float, TE><<<4096, 256, 0, stream>>>(
        e_in, emb_e_w, emb_e_b, e, eid, NEDGES);

    for (int l = 0; l < 4; ++l) {
        const size_t o = (size_t)l * DD * DD;
        if (l == 0)
            node_linear4_mfma_kernel<false><<<391, 256, 0, stream>>>(
                h, hhat, NT + (size_t)l * 16384,
                A_b + l * DD, B_b + l * DD, D_b + l * DD, E_b + l * DD,
                nullptr, nullptr, nullptr, Ah, Bh16, Dh16, Eh16);
        else
            node_linear4_mfma_kernel<true><<<391, 256, 0, stream>>>(
                h, hhat, NT + (size_t)l * 16384,
                A_b + l * DD, B_b + l * DD, D_b + l * DD, E_b + l * DD,
                stats_h, bn_h_g + (l - 1) * DD, bn_h_b + (l - 1) * DD,
                Ah, Bh16, Dh16, Eh16);

        if (l == 0)
            edge_update_mfma_kernel<false, TE, TH><<<GE_EDGE, 256, 0, stream>>>(
                e, ehat, CT + o, C_b + l * DD, Dh16, srcS, Eh16, dstS,
                nullptr, nullptr, nullptr, partial_e);
        else
            edge_update_mfma_kernel<true, TE, TH><<<GE_EDGE, 256, 0, stream>>>(
                e, ehat, CT + o, C_b + l * DD, Dh16, srcS, Eh16, dstS,
                stats_e, bn_e_g + (l - 1) * DD, bn_e_b + (l - 1) * DD, partial_e);

        agg_sorted_kernel<TH><<<GA_AGG, 256, 0, stream>>>(
            ehat, Bh16, srcS, rowptr, Ah, hhat, partial_h);
        reduce_stats2_kernel<<<256, 256, 0, stream>>>(
            partial_e, GE_EDGE, stats_e, partial_h, GA_AGG, stats_h);
    }

    // final e update -> bf16 eorig in ORIGINAL edge order (before precompute_H
    // clobbers Ah/Bh16/Dh16 with Hs/Hd)
    if (fusedFinal) {
        bnfinal_scatter_kernel<TE, TH><<<8192, 256, 0, stream>>>(
            e, ehat, eid, stats_e, bn_e_g + 3 * DD, bn_e_b + 3 * DD, eorig);
    } else {
        bn_apply4_kernel<TE, TH><<<8192, 256, 0, stream>>>(
            e, ehat, stats_e, bn_e_g + 3 * DD, bn_e_b + 3 * DD, NEDGES);
        permute_e_kernel<TE><<<8192, 256, 0, stream>>>(e, eid, eorig);
    }

    // Hs/Hd precompute (bf16) with fused final h-update (no h writeback)
    precompute_H_kernel<<<391, 256, 0, stream>>>(
        h, hhat, stats_h, bn_h_g + 3 * DD, bn_h_b + 3 * DD, HT, b0, Hs, Hd);

    // streaming readout in original order (register-resident W1)
    readout_mfma2_kernel<<<2048, 256, 0, stream>>>(
        eorig, rev, Hs, Hd, src, dst, W0T, W1T, b1, W2, b2, out);
}

extern "C" void kernel_launch(void* const* d_in, const int* in_sizes, int n_in,
                              void* d_out, int out_size, void* d_ws, size_t ws_size,
                              hipStream_t stream)
{
    const size_t NH = (size_t)NNODES * DD;       // 1.6M floats
    const size_t NE = (size_t)NEDGES * DD;       // 25.6M elems
    const size_t baseB = (7 * NH + 256) * sizeof(float);   // 44.8 MB node region

    char* base = (char*)d_ws;
    char* edge = base + baseB;
    float* out = (float*)d_out;

    // main tier: fp32 e + bf16 ehat + dedicated bf16 eorig (proven to fit)
    const size_t needMain = baseB + NE * 4 + NE * 2 + NE * 2;
    const size_t needC    = baseB + NE * 2 * 2;    // bf16 e + bf16 ehat, 2-pass

    if (ws_size >= needMain) {
        float* e = (float*)edge;
        __hip_bfloat16* ehat  = (__hip_bfloat16*)(edge + NE * 4);
        __hip_bfloat16* eorig = (__hip_bfloat16*)(edge + NE * 6);
        run_net<float, __hip_bfloat16>(d_in, (float*)base, e, ehat, eorig,
                                       true, out, stream);
    } else if (ws_size >= needC) {
        __hip_bfloat16* e    = (__hip_bfloat16*)edge;
        __hip_bfloat16* ehat = (__hip_bfloat16*)(edge + NE * 2);
        run_net<__hip_bfloat16, __hip_bfloat16>(d_in, (float*)base, e, ehat,
                                                ehat, false, out, stream);
    } else {
        hipMemsetAsync(d_out, 0, (size_t)out_size * sizeof(float), stream);
    }
}

// Round 12
// 900.833 us; speedup vs baseline: 4.4785x; 1.0329x over previous
//
#include <hip/hip_runtime.h>
#include <hip/hip_bf16.h>

constexpr int NNODES = 25000;
constexpr int NEDGES = 400000;
constexpr int DD = 64;
constexpr float BNEPS = 1e-5f;
constexpr float AGGEPS = 1e-6f;

typedef __attribute__((ext_vector_type(8))) short short8_t;
typedef __attribute__((ext_vector_type(4))) short short4_t;
typedef __attribute__((ext_vector_type(4))) float float4_t;

// storage-type helpers (compute is always fp32)
__device__ __forceinline__ float ldv(const float* p, long i) { return p[i]; }
__device__ __forceinline__ float ldv(const __hip_bfloat16* p, long i) { return __bfloat162float(p[i]); }
__device__ __forceinline__ void stv(float* p, long i, float v) { p[i] = v; }
__device__ __forceinline__ void stv(__hip_bfloat16* p, long i, float v) { p[i] = __float2bfloat16(v); }

__device__ __forceinline__ short f2bs(float f) {
    union { float f; unsigned u; } x; x.f = f;
    unsigned r = x.u + 0x7FFFu + ((x.u >> 16) & 1u);
    return (short)(r >> 16);
}
__device__ __forceinline__ float bs2f(short s) {
    union { unsigned u; float f; } x; x.u = ((unsigned)(unsigned short)s) << 16; return x.f;
}

__device__ __forceinline__ float4_t ldv4(const float* p, long i) {
    return *(const float4_t*)(p + i);
}
__device__ __forceinline__ float4_t ldv4(const __hip_bfloat16* p, long i) {
    short4_t s = *(const short4_t*)(p + i);
    float4_t r;
    #pragma unroll
    for (int c = 0; c < 4; ++c) r[c] = bs2f(s[c]);
    return r;
}
__device__ __forceinline__ void stv4(float* p, long i, float4_t v) {
    *(float4_t*)(p + i) = v;
}
__device__ __forceinline__ void stv4(__hip_bfloat16* p, long i, float4_t v) {
    short4_t s;
    #pragma unroll
    for (int c = 0; c < 4; ++c) s[c] = f2bs(v[c]);
    *(short4_t*)(p + i) = s;
}

__device__ __forceinline__ void stage8(const __hip_bfloat16* s, short* d) {
    *(short8_t*)d = *(const short8_t*)s;
}
__device__ __forceinline__ void stage8(const float* s, short* d) {
    float4_t a = *(const float4_t*)s;
    float4_t b = *(const float4_t*)(s + 4);
    short8_t v;
    v[0] = f2bs(a[0]); v[1] = f2bs(a[1]); v[2] = f2bs(a[2]); v[3] = f2bs(a[3]);
    v[4] = f2bs(b[0]); v[5] = f2bs(b[1]); v[6] = f2bs(b[2]); v[7] = f2bs(b[3]);
    *(short8_t*)d = v;
}

// ---------------------------------------------------------------------------
// Generic LDS-tiled linear (embeddings), optional row-gather on X.
// ---------------------------------------------------------------------------
template<int K, int N, int JR, typename TX, typename TY>
__global__ __launch_bounds__(256) void linear_kernel(
    const TX* __restrict__ X, const float* __restrict__ W,
    const float* __restrict__ Bb, TY* __restrict__ Y,
    const int* __restrict__ gather, int rows)
{
    constexpr int SLOTS = 256 / N;
    constexpr int RPG = SLOTS * JR;
    __shared__ float wl[K * N];
    __shared__ float bl[N];
    __shared__ float xl[RPG * K];

    const int tid = threadIdx.x;
    for (int i = tid; i < K * N; i += 256) wl[i] = W[i];
    if (tid < N) bl[tid] = Bb[tid];

    const int col = tid % N;
    const int slot = tid / N;

    const int ngroups = (rows + RPG - 1) / RPG;
    for (int g = blockIdx.x; g < ngroups; g += gridDim.x) {
        const int rowBase = g * RPG;
        __syncthreads();
        for (int i = tid; i < RPG * K; i += 256) {
            int r = i / K, k = i - r * K;
            int row = rowBase + r;
            float v = 0.0f;
            if (row < rows) {
                int sr = gather ? gather[row] : row;
                v = ldv(X, (long)sr * K + k);
            }
            xl[i] = v;
        }
        __syncthreads();
        float acc[JR];
        #pragma unroll
        for (int j = 0; j < JR; ++j) acc[j] = bl[col];
        #pragma unroll 4
        for (int k = 0; k < K; ++k) {
            float w = wl[k * N + col];
            #pragma unroll
            for (int j = 0; j < JR; ++j)
                acc[j] += xl[(slot * JR + j) * K + k] * w;
        }
        #pragma unroll
        for (int j = 0; j < JR; ++j) {
            int row = rowBase + slot * JR + j;
            if (row < rows) stv(Y, (long)row * N + col, acc[j]);
        }
    }
}

// ---------------------------------------------------------------------------
// Quad node linear, MFMA: Ah (fp32) | Bh,Dh,Eh (bf16) = h @ {A,B,D,E} + b.
// If BNIN: h = h + relu(bn(hhat; stats_prev)) in place first (feeds matmul).
// ---------------------------------------------------------------------------
template<bool BNIN>
__global__ __launch_bounds__(256) void node_linear4_mfma_kernel(
    float* __restrict__ h, const float* __restrict__ hhat,
    const short* __restrict__ NT,
    const float* __restrict__ Ab, const float* __restrict__ Bb,
    const float* __restrict__ Db, const float* __restrict__ Eb,
    const float* __restrict__ stats_prev, const float* __restrict__ gprev,
    const float* __restrict__ bprev,
    float* __restrict__ Ah, __hip_bfloat16* __restrict__ Bh,
    __hip_bfloat16* __restrict__ Dh, __hip_bfloat16* __restrict__ Eh)
{
    __shared__ short wt[256 * 72];
    __shared__ short xs[64 * 72];
    __shared__ float bl[256];
    __shared__ float scale[64], shift[64];

    const int tid = threadIdx.x;
    const int wave = tid >> 6;
    const int lane = tid & 63;
    const int r = lane & 15;
    const int q = lane >> 4;

    for (int i = tid; i < 2048; i += 256) {
        int n = i >> 3, oct = i & 7;
        *(short8_t*)(wt + n * 72 + oct * 8) = *(const short8_t*)(NT + n * 64 + oct * 8);
    }
    if (tid < 64) bl[tid] = Ab[tid];
    else if (tid < 128) bl[tid] = Bb[tid - 64];
    else if (tid < 192) bl[tid] = Db[tid - 128];
    else bl[tid] = Eb[tid - 192];
    if (BNIN && tid < 64) {
        float inv = 1.0f / (float)NNODES;
        float mu = stats_prev[tid] * inv;
        float var = stats_prev[64 + tid] * inv - mu * mu;
        float rs = rsqrtf(var + BNEPS);
        float sc = rs * gprev[tid];
        scale[tid] = sc;
        shift[tid] = bprev[tid] - mu * sc;
    }

    const int ntiles = (NNODES + 63) / 64;        // 391
    for (int t = blockIdx.x; t < ntiles; t += gridDim.x) {
        const int rowBase = t * 64;
        __syncthreads();
        for (int i = tid; i < 512; i += 256) {
            int row = i >> 3, oct = i & 7;
            int nr = rowBase + row;
            if (nr < NNODES) {
                long idx = (long)nr * 64 + oct * 8;
                float4_t a = ldv4(h, idx), b = ldv4(h, idx + 4);
                if (BNIN) {
                    float4_t ha = ldv4(hhat, idx), hb = ldv4(hhat, idx + 4);
                    int k0 = oct * 8;
                    #pragma unroll
                    for (int c = 0; c < 4; ++c) {
                        a[c] += fmaxf(ha[c] * scale[k0 + c] + shift[k0 + c], 0.0f);
                        b[c] += fmaxf(hb[c] * scale[k0 + 4 + c] + shift[k0 + 4 + c], 0.0f);
                    }
                    stv4(h, idx, a); stv4(h, idx + 4, b);
                }
                short8_t v;
                v[0] = f2bs(a[0]); v[1] = f2bs(a[1]); v[2] = f2bs(a[2]); v[3] = f2bs(a[3]);
                v[4] = f2bs(b[0]); v[5] = f2bs(b[1]); v[6] = f2bs(b[2]); v[7] = f2bs(b[3]);
                *(short8_t*)(xs + row * 72 + oct * 8) = v;
            } else {
                *(short8_t*)(xs + row * 72 + oct * 8) = (short8_t)0;
            }
        }
        __syncthreads();
        float4_t acc[16];
        #pragma unroll
        for (int i = 0; i < 16; ++i) acc[i] = (float4_t)0.0f;
        #pragma unroll
        for (int kk = 0; kk < 2; ++kk) {
            short8_t a = *(const short8_t*)(xs + (wave * 16 + r) * 72 + kk * 32 + q * 8);
            #pragma unroll
            for (int nt = 0; nt < 16; ++nt) {
                short8_t b = *(const short8_t*)(wt + (nt * 16 + r) * 72 + kk * 32 + q * 8);
                acc[nt] = __builtin_amdgcn_mfma_f32_16x16x32_bf16(a, b, acc[nt], 0, 0, 0);
            }
        }
        #pragma unroll
        for (int nt = 0; nt < 16; ++nt) {
            int c = (nt & 3) * 16 + r;
            int n = nt * 16 + r;
            #pragma unroll
            for (int i2 = 0; i2 < 4; ++i2) {
                int row = rowBase + wave * 16 + q * 4 + i2;
                if (row < NNODES) {
                    float v = acc[nt][i2] + bl[n];
                    long idx = (long)row * 64 + c;
                    if (nt < 4)       Ah[idx] = v;
                    else if (nt < 8)  stv(Bh, idx, v);
                    else if (nt < 12) stv(Dh, idx, v);
                    else              stv(Eh, idx, v);
                }
            }
        }
    }
}

// ---------------------------------------------------------------------------
// MFMA edge update (edges in dst-sorted order); Dh/Eh are bf16 (L2-resident).
// BN stats are accumulated from fp32 values BEFORE ehat storage rounding.
// ---------------------------------------------------------------------------
template<bool BNIN, typename TE, typename TH>
__global__ __launch_bounds__(256) void edge_update_mfma_kernel(
    TE* __restrict__ e, TH* __restrict__ ehat,
    const short* __restrict__ CT, const float* __restrict__ Cb,
    const __hip_bfloat16* __restrict__ Dh, const int* __restrict__ srcS,
    const __hip_bfloat16* __restrict__ Eh, const int* __restrict__ dstS,
    const float* __restrict__ stats_prev, const float* __restrict__ gprev,
    const float* __restrict__ bprev, float* __restrict__ partial)
{
    __shared__ short ct[64 * 72];
    __shared__ short xs[64 * 72];
    __shared__ float bl[64], scale[64], shift[64];
    __shared__ float ps[128];

    const int tid = threadIdx.x;
    const int wave = tid >> 6;
    const int lane = tid & 63;
    const int r = lane & 15;
    const int q = lane >> 4;

    for (int i = tid; i < 512; i += 256) {
        int n = i >> 3, oct = i & 7;
        *(short8_t*)(ct + n * 72 + oct * 8) = *(const short8_t*)(CT + n * 64 + oct * 8);
    }
    if (tid < 64) {
        bl[tid] = Cb[tid];
        if (BNIN) {
            float inv = 1.0f / (float)NEDGES;
            float mu = stats_prev[tid] * inv;
            float var = stats_prev[64 + tid] * inv - mu * mu;
            float rs = rsqrtf(var + BNEPS);
            float sc = rs * gprev[tid];
            scale[tid] = sc;
            shift[tid] = bprev[tid] - mu * sc;
        }
    }
    if (tid < 128) ps[tid] = 0.0f;
    float lsum[4] = {0, 0, 0, 0}, lsum2[4] = {0, 0, 0, 0};

    constexpr int NTILES = NEDGES / 64;
    for (int t = blockIdx.x; t < NTILES; t += gridDim.x) {
        const int rowBase = t * 64;
        __syncthreads();
        for (int i = tid; i < 512; i += 256) {
            int row = i >> 3, oct = i & 7;
            long idx = (long)(rowBase + row) * 64 + oct * 8;
            float4_t a = ldv4(e, idx), b = ldv4(e, idx + 4);
            if (BNIN) {
                float4_t ha = ldv4(ehat, idx), hb = ldv4(ehat, idx + 4);
                int k0 = oct * 8;
                #pragma unroll
                for (int c = 0; c < 4; ++c) {
                    a[c] += fmaxf(ha[c] * scale[k0 + c] + shift[k0 + c], 0.0f);
                    b[c] += fmaxf(hb[c] * scale[k0 + 4 + c] + shift[k0 + 4 + c], 0.0f);
                }
                stv4(e, idx, a); stv4(e, idx + 4, b);
            }
            short8_t v;
            v[0] = f2bs(a[0]); v[1] = f2bs(a[1]); v[2] = f2bs(a[2]); v[3] = f2bs(a[3]);
            v[4] = f2bs(b[0]); v[5] = f2bs(b[1]); v[6] = f2bs(b[2]); v[7] = f2bs(b[3]);
            *(short8_t*)(xs + row * 72 + oct * 8) = v;
        }
        __syncthreads();
        float4_t acc[4];
        #pragma unroll
        for (int i = 0; i < 4; ++i) acc[i] = (float4_t)0.0f;
        #pragma unroll
        for (int kk = 0; kk < 2; ++kk) {
            short8_t a = *(const short8_t*)(xs + (wave * 16 + r) * 72 + kk * 32 + q * 8);
            #pragma unroll
            for (int nt = 0; nt < 4; ++nt) {
                short8_t b = *(const short8_t*)(ct + (nt * 16 + r) * 72 + kk * 32 + q * 8);
                acc[nt] = __builtin_amdgcn_mfma_f32_16x16x32_bf16(a, b, acc[nt], 0, 0, 0);
            }
        }
        #pragma unroll
        for (int i2 = 0; i2 < 4; ++i2) {
            int row = wave * 16 + q * 4 + i2;
            int er = rowBase + row;
            int s = srcS[er], d = dstS[er];
            #pragma unroll
            for (int nt = 0; nt < 4; ++nt) {
                int col = nt * 16 + r;
                float v = acc[nt][i2] + bl[col]
                        + ldv(Dh, (long)s * 64 + col) + ldv(Eh, (long)d * 64 + col);
                stv(ehat, (long)er * 64 + col, v);
                lsum[nt] += v; lsum2[nt] += v * v;
            }
        }
    }
    __syncthreads();
    #pragma unroll
    for (int nt = 0; nt < 4; ++nt) {
        atomicAdd(&ps[nt * 16 + r], lsum[nt]);
        atomicAdd(&ps[64 + nt * 16 + r], lsum2[nt]);
    }
    __syncthreads();
    if (tid < 128) partial[(long)blockIdx.x * 128 + tid] = ps[tid];
}

// ---------------------------------------------------------------------------
// CSR build + edge permutation
// ---------------------------------------------------------------------------
__global__ __launch_bounds__(256) void deg_hist_kernel(
    const int* __restrict__ dst, int* __restrict__ rowptr, int rows)
{
    int e = blockIdx.x * 256 + threadIdx.x;
    if (e < rows) atomicAdd(&rowptr[dst[e] + 1], 1);
}

__global__ __launch_bounds__(1024) void scan_kernel(int* __restrict__ data, int n)
{
    __shared__ int buf[1024];
    __shared__ int carry;
    if (threadIdx.x == 0) carry = 0;
    __syncthreads();
    for (int base = 0; base < n; base += 1024) {
        int i = base + threadIdx.x;
        int v = (i < n) ? data[i] : 0;
        buf[threadIdx.x] = v;
        __syncthreads();
        for (int off = 1; off < 1024; off <<= 1) {
            int t = (threadIdx.x >= off) ? buf[threadIdx.x - off] : 0;
            __syncthreads();
            buf[threadIdx.x] += t;
            __syncthreads();
        }
        if (i < n) data[i] = buf[threadIdx.x] + carry;
        __syncthreads();
        if (threadIdx.x == 0) carry += buf[1023];
        __syncthreads();
    }
}

__global__ __launch_bounds__(256) void scatter_kernel(
    const int* __restrict__ dst, const int* __restrict__ rowptr,
    int* __restrict__ cursor, int* __restrict__ eid, int rows)
{
    int e = blockIdx.x * 256 + threadIdx.x;
    if (e < rows) {
        int d = dst[e];
        int pos = atomicAdd(&cursor[d], 1);
        eid[rowptr[d] + pos] = e;
    }
}

__global__ __launch_bounds__(256) void remap1_kernel(
    const int* __restrict__ eid, const int* __restrict__ src,
    const int* __restrict__ dst, int* __restrict__ inv,
    int* __restrict__ srcS, int* __restrict__ dstS, int rows)
{
    int p = blockIdx.x * 256 + threadIdx.x;
    if (p < rows) {
        int orig = eid[p];
        inv[orig] = p;
        srcS[p] = src[orig];
        dstS[p] = dst[orig];
    }
}

// ---------------------------------------------------------------------------
// Sorted aggregation + fused hhat + BN partials; Bh is bf16 (L2-resident).
// ---------------------------------------------------------------------------
template<typename TH>
__global__ __launch_bounds__(256) void agg_sorted_kernel(
    const TH* __restrict__ ehat, const __hip_bfloat16* __restrict__ Bh,
    const int* __restrict__ srcS, const int* __restrict__ rowptr,
    const float* __restrict__ Ah, float* __restrict__ hhat,
    float* __restrict__ partial)
{
    __shared__ float ps[64], ps2[64];
    const int tid = threadIdx.x;
    if (tid < 64) { ps[tid] = 0.0f; ps2[tid] = 0.0f; }
    __syncthreads();

    const int node = blockIdx.x * 4 + (tid >> 6);
    const int lane = tid & 63;
    const int sub = lane >> 4;
    const int c4 = (lane & 15) * 4;
    const int s0 = rowptr[node], s1 = rowptr[node + 1];

    float4_t den = (float4_t)0.0f, num = (float4_t)0.0f;
    for (int p = s0 + sub; p < s1; p += 4) {
        float4_t v = ldv4(ehat, (long)p * 64 + c4);
        float4_t bh = ldv4(Bh, (long)srcS[p] * 64 + c4);
        #pragma unroll
        for (int c = 0; c < 4; ++c) {
            float s = 1.0f / (1.0f + __expf(-v[c]));
            den[c] += s;
            num[c] += s * bh[c];
        }
    }
    #pragma unroll
    for (int m = 16; m <= 32; m <<= 1) {
        #pragma unroll
        for (int c = 0; c < 4; ++c) {
            den[c] += __shfl_xor(den[c], m, 64);
            num[c] += __shfl_xor(num[c], m, 64);
        }
    }
    if (sub == 0) {
        float4_t av = ldv4(Ah, (long)node * 64 + c4);
        float4_t hh;
        #pragma unroll
        for (int c = 0; c < 4; ++c) {
            hh[c] = av[c] + num[c] / (den[c] + AGGEPS);
            atomicAdd(&ps[c4 + c], hh[c]);
            atomicAdd(&ps2[c4 + c], hh[c] * hh[c]);
        }
        stv4(hhat, (long)node * 64 + c4, hh);
    }
    __syncthreads();
    if (tid < 64) {
        partial[(long)blockIdx.x * 128 + tid] = ps[tid];
        partial[(long)blockIdx.x * 128 + 64 + tid] = ps2[tid];
    }
}

// merged stats reduce: blocks 0..127 -> stats_e, 128..255 -> stats_h
__global__ __launch_bounds__(256) void reduce_stats2_kernel(
    const float* __restrict__ pe, int ne, float* __restrict__ se,
    const float* __restrict__ ph, int nh, float* __restrict__ sh)
{
    __shared__ float sb[256];
    const float* partial; int nblk; float* stats; int col;
    if (blockIdx.x < 128) { partial = pe; nblk = ne; stats = se; col = blockIdx.x; }
    else                  { partial = ph; nblk = nh; stats = sh; col = blockIdx.x - 128; }
    int tid = threadIdx.x;
    float s = 0.0f;
    for (int i = tid; i < nblk; i += 256) s += partial[(long)i * 128 + col];
    sb[tid] = s;
    __syncthreads();
    for (int off = 128; off > 0; off >>= 1) {
        if (tid < off) sb[tid] += sb[tid + off];
        __syncthreads();
    }
    if (tid == 0) stats[col] = sb[0];
}

// base += relu((xhat-mu)*rstd*g + b), float4 per thread (in place)
template<typename TB, typename TX>
__global__ __launch_bounds__(256) void bn_apply4_kernel(
    TB* __restrict__ base, const TX* __restrict__ xhat,
    const float* __restrict__ stats, const float* __restrict__ g,
    const float* __restrict__ b, int rows)
{
    long total4 = (long)rows * 16;
    float inv = 1.0f / (float)rows;
    for (long q = (long)blockIdx.x * 256 + threadIdx.x; q < total4;
         q += (long)gridDim.x * 256) {
        long idx = q * 4;
        int c = (int)(idx & 63);
        float4_t x = ldv4(xhat, idx);
        float4_t bs = ldv4(base, idx);
        #pragma unroll
        for (int j = 0; j < 4; ++j) {
            float mu = stats[c + j] * inv;
            float var = stats[64 + c + j] * inv - mu * mu;
            float rs = rsqrtf(var + BNEPS);
            float v = (x[j] - mu) * rs * g[c + j] + b[c + j];
            bs[j] += fmaxf(v, 0.0f);
        }
        stv4(base, idx, bs);
    }
}

// fused final e update + scatter to original order:
// eorig[eid[p]] = bf16(e[p] + relu(bn(ehat[p])))
template<typename TE, typename TH>
__global__ __launch_bounds__(256) void bnfinal_scatter_kernel(
    const TE* __restrict__ e, const TH* __restrict__ ehat,
    const int* __restrict__ eid, const float* __restrict__ stats,
    const float* __restrict__ g, const float* __restrict__ b,
    __hip_bfloat16* __restrict__ eorig)
{
    __shared__ float scale[64], shift[64];
    const int tid = threadIdx.x;
    if (tid < 64) {
        float inv = 1.0f / (float)NEDGES;
        float mu = stats[tid] * inv;
        float var = stats[64 + tid] * inv - mu * mu;
        float rs = rsqrtf(var + BNEPS);
        float sc = rs * g[tid];
        scale[tid] = sc;
        shift[tid] = b[tid] - mu * sc;
    }
    __syncthreads();
    long total = (long)NEDGES * 8;
    for (long i = (long)blockIdx.x * 256 + tid; i < total; i += (long)gridDim.x * 256) {
        int p = (int)(i >> 3), oct = (int)(i & 7);
        int k0 = oct * 8;
        long idx = (long)p * 64 + k0;
        float4_t a = ldv4(e, idx), b4 = ldv4(e, idx + 4);
        float4_t ha = ldv4(ehat, idx), hb = ldv4(ehat, idx + 4);
        short8_t v;
        #pragma unroll
        for (int c = 0; c < 4; ++c) {
            v[c]     = f2bs(a[c]  + fmaxf(ha[c] * scale[k0 + c]     + shift[k0 + c], 0.0f));
            v[4 + c] = f2bs(b4[c] + fmaxf(hb[c] * scale[k0 + 4 + c] + shift[k0 + 4 + c], 0.0f));
        }
        *(short8_t*)((short*)eorig + (long)eid[p] * 64 + k0) = v;
    }
}

// two-pass fallback: permute updated e (sorted) -> bf16 eorig (original order)
template<typename TE>
__global__ __launch_bounds__(256) void permute_e_kernel(
    const TE* __restrict__ e, const int* __restrict__ eid,
    __hip_bfloat16* __restrict__ eorig)
{
    long total = (long)NEDGES * 8;
    for (long i = (long)blockIdx.x * 256 + threadIdx.x; i < total;
         i += (long)gridDim.x * 256) {
        int p = (int)(i >> 3), oct = (int)(i & 7);
        long idx = (long)p * 64 + oct * 8;
        float4_t a = ldv4(e, idx), b = ldv4(e, idx + 4);
        short8_t v;
        #pragma unroll
        for (int c = 0; c < 4; ++c) { v[c] = f2bs(a[c]); v[4 + c] = f2bs(b[c]); }
        *(short8_t*)((short*)eorig + (long)eid[p] * 64 + oct * 8) = v;
    }
}

// Hs = h_fin @ W0c + b0, Hd = h_fin @ W0d (bf16 outputs), with
// h_fin = h + relu(bn(hhat)) computed on the fly (no h writeback).
__global__ __launch_bounds__(256) void precompute_H_kernel(
    const float* __restrict__ h, const float* __restrict__ hhat,
    const float* __restrict__ stats, const float* __restrict__ g,
    const float* __restrict__ b,
    const short* __restrict__ HT, const float* __restrict__ b0,
    __hip_bfloat16* __restrict__ Hs, __hip_bfloat16* __restrict__ Hd)
{
    __shared__ short wt[256 * 72];
    __shared__ short xs[64 * 72];
    __shared__ float bl[256];
    __shared__ float scale[64], shift[64];

    const int tid = threadIdx.x;
    const int wave = tid >> 6;
    const int lane = tid & 63;
    const int r = lane & 15;
    const int q = lane >> 4;

    for (int i = tid; i < 2048; i += 256) {
        int n = i >> 3, oct = i & 7;
        *(short8_t*)(wt + n * 72 + oct * 8) = *(const short8_t*)(HT + n * 64 + oct * 8);
    }
    bl[tid] = (tid < 128) ? b0[tid] : 0.0f;
    if (tid < 64) {
        float inv = 1.0f / (float)NNODES;
        float mu = stats[tid] * inv;
        float var = stats[64 + tid] * inv - mu * mu;
        float rs = rsqrtf(var + BNEPS);
        float sc = rs * g[tid];
        scale[tid] = sc;
        shift[tid] = b[tid] - mu * sc;
    }

    const int ntiles = (NNODES + 63) / 64;
    for (int t = blockIdx.x; t < ntiles; t += gridDim.x) {
        const int rowBase = t * 64;
        __syncthreads();
        for (int i = tid; i < 512; i += 256) {
            int row = i >> 3, oct = i & 7;
            int nr = rowBase + row;
            if (nr < NNODES) {
                long idx = (long)nr * 64 + oct * 8;
                float4_t a = ldv4(h, idx), bb = ldv4(h, idx + 4);
                float4_t ha = ldv4(hhat, idx), hb = ldv4(hhat, idx + 4);
                int k0 = oct * 8;
                #pragma unroll
                for (int c = 0; c < 4; ++c) {
                    a[c]  += fmaxf(ha[c] * scale[k0 + c]     + shift[k0 + c], 0.0f);
                    bb[c] += fmaxf(hb[c] * scale[k0 + 4 + c] + shift[k0 + 4 + c], 0.0f);
                }
                short8_t v;
                v[0] = f2bs(a[0]); v[1] = f2bs(a[1]); v[2] = f2bs(a[2]); v[3] = f2bs(a[3]);
                v[4] = f2bs(bb[0]); v[5] = f2bs(bb[1]); v[6] = f2bs(bb[2]); v[7] = f2bs(bb[3]);
                *(short8_t*)(xs + row * 72 + oct * 8) = v;
            } else {
                *(short8_t*)(xs + row * 72 + oct * 8) = (short8_t)0;
            }
        }
        __syncthreads();
        float4_t acc[16];
        #pragma unroll
        for (int i = 0; i < 16; ++i) acc[i] = (float4_t)0.0f;
        #pragma unroll
        for (int kk = 0; kk < 2; ++kk) {
            short8_t a = *(const short8_t*)(xs + (wave * 16 + r) * 72 + kk * 32 + q * 8);
            #pragma unroll
            for (int nt = 0; nt < 16; ++nt) {
                short8_t b2 = *(const short8_t*)(wt + (nt * 16 + r) * 72 + kk * 32 + q * 8);
                acc[nt] = __builtin_amdgcn_mfma_f32_16x16x32_bf16(a, b2, acc[nt], 0, 0, 0);
            }
        }
        #pragma unroll
        for (int nt = 0; nt < 16; ++nt) {
            __hip_bfloat16* Y = (nt < 8) ? Hs : Hd;
            int c = (nt & 7) * 16 + r;
            int n = nt * 16 + r;
            #pragma unroll
            for (int i2 = 0; i2 < 4; ++i2) {
                int row = rowBase + wave * 16 + q * 4 + i2;
                if (row < NNODES) stv(Y, (long)row * 128 + c, acc[nt][i2] + bl[n]);
            }
        }
    }
}

// one-shot weight prep (bf16 [n][k]): W0T [128][256], W1T [64][128],
// CT [l][64][64], NT [l][256][64] (A|B|D|E), HT [256][64] (W0c|W0d)
__global__ __launch_bounds__(256) void transpose_w_kernel(
    const float* __restrict__ W0, const float* __restrict__ W1,
    const float* __restrict__ C_w,
    const float* __restrict__ A_w, const float* __restrict__ B_w,
    const float* __restrict__ D_w, const float* __restrict__ E_w,
    short* __restrict__ W0T, short* __restrict__ W1T,
    short* __restrict__ CT, short* __restrict__ NT, short* __restrict__ HT)
{
    int id = blockIdx.x * 256 + threadIdx.x;
    if (id < 256 * 128) {
        int k = id >> 7, n = id & 127;
        W0T[n * 256 + k] = f2bs(W0[id]);
    }
    if (id < 128 * 64) {
        int k = id >> 6, n = id & 63;
        W1T[n * 128 + k] = f2bs(W1[id]);
    }
    if (id < 4 * 64 * 64) {
        int l = id >> 12, rem = id & 4095, k = rem >> 6, n = rem & 63;
        CT[l * 4096 + n * 64 + k] = f2bs(C_w[l * 4096 + k * 64 + n]);
    }
    if (id < 4 * 256 * 64) {
        int l = id >> 14, rem = id & 16383, n = rem >> 6, k = rem & 63;
        int mat = n >> 6, c = n & 63;
        const float* Wm = (mat == 0) ? A_w : (mat == 1) ? B_w : (mat == 2) ? D_w : E_w;
        NT[l * 16384 + n * 64 + k] = f2bs(Wm[l * 4096 + k * 64 + c]);
    }
    if (id < 256 * 64) {
        int n = id >> 6, k = id & 63;
        int mat = n >> 7, col = n & 127;
        HT[n * 64 + k] = f2bs(W0[(128 + mat * 64 + k) * 128 + col]);
    }
}

// ---------------------------------------------------------------------------
// MFMA MLP readout v2 (R10 form — proven fastest): original edge order,
// W0 slices and W1 staged in LDS, x0t separate buffer. 76 VGPR, 3 blocks/CU.
// ---------------------------------------------------------------------------
__global__ __launch_bounds__(256) void readout_mfma2_kernel(
    const __hip_bfloat16* __restrict__ eorig, const int* __restrict__ rev,
    const __hip_bfloat16* __restrict__ Hs, const __hip_bfloat16* __restrict__ Hd,
    const int* __restrict__ src, const int* __restrict__ dst,
    const short* __restrict__ W0T, const short* __restrict__ W1T,
    const float* __restrict__ b1, const float* __restrict__ W2,
    const float* __restrict__ b2, float* __restrict__ out)
{
    __shared__ short feat[64 * 72];    // e / e_rev tile; reused as x1 tile
    __shared__ short wtile[128 * 72];  // W0 slice [128][72]; reused as W1T [64][136]
    __shared__ short x0t[64 * 136];    // x0 tile bf16
    __shared__ float smallb[194];      // b1[64] | W2[128] | b2[2]

    const int tid = threadIdx.x;
    const int wave = tid >> 6;
    const int lane = tid & 63;
    const int r = lane & 15;
    const int q = lane >> 4;

    if (tid < 64)  smallb[tid] = b1[tid];
    if (tid < 128) smallb[64 + tid] = W2[tid];
    if (tid < 2)   smallb[192 + tid] = b2[tid];

    constexpr int NTILES = NEDGES / 64;   // 6250
    for (int t = blockIdx.x; t < NTILES; t += gridDim.x) {
        const int rowBase = t * 64;
        float4_t acc0[8];
        #pragma unroll
        for (int i = 0; i < 8; ++i) acc0[i] = (float4_t)0.0f;

        for (int s = 0; s < 2; ++s) {
            __syncthreads();
            for (int i = tid; i < 512; i += 256) {
                int row = i >> 3, oct = i & 7;
                int er = rowBase + row;
                int srow = (s == 0) ? er : rev[er];   // sequential either way
                *(short8_t*)(feat + row * 72 + oct * 8) =
                    *(const short8_t*)((const short*)eorig + (long)srow * 64 + oct * 8);
            }
            for (int i = tid; i < 1024; i += 256) {
                int n = i >> 3, oct = i & 7;
                *(short8_t*)(wtile + n * 72 + oct * 8) =
                    *(const short8_t*)(W0T + (long)n * 256 + s * 64 + oct * 8);
            }
            __syncthreads();
            #pragma unroll
            for (int kk = 0; kk < 2; ++kk) {
                short8_t a = *(const short8_t*)(feat + (wave * 16 + r) * 72 + kk * 32 + q * 8);
                #pragma unroll
                for (int nt = 0; nt < 8; ++nt) {
                    short8_t b = *(const short8_t*)(wtile + (nt * 16 + r) * 72 + kk * 32 + q * 8);
                    acc0[nt] = __builtin_amdgcn_mfma_f32_16x16x32_bf16(a, b, acc0[nt], 0, 0, 0);
                }
            }
        }
        // epilogue 1: x0 = relu(acc0 + Hs[src] + Hd[dst]) (b0 folded into Hs)
        #pragma unroll
        for (int i2 = 0; i2 < 4; ++i2) {
            int row = wave * 16 + q * 4 + i2;
            int er = rowBase + row;
            int sN = src[er], dN = dst[er];
            #pragma unroll
            for (int nt = 0; nt < 8; ++nt) {
                int col = nt * 16 + r;
                float v = acc0[nt][i2] + ldv(Hs, (long)sN * 128 + col)
                                       + ldv(Hd, (long)dN * 128 + col);
                x0t[row * 136 + col] = f2bs(fmaxf(v, 0.0f));
            }
        }
        __syncthreads();
        for (int i = tid; i < 1024; i += 256) {       // W1T -> wtile as [64][136]
            int n = i >> 4, oct = i & 15;
            *(short8_t*)(wtile + n * 136 + oct * 8) =
                *(const short8_t*)(W1T + (long)n * 128 + oct * 8);
        }
        __syncthreads();
        float4_t acc1[4];
        #pragma unroll
        for (int i = 0; i < 4; ++i) acc1[i] = (float4_t)0.0f;
        #pragma unroll
        for (int kk = 0; kk < 4; ++kk) {
            short8_t a = *(const short8_t*)(x0t + (wave * 16 + r) * 136 + kk * 32 + q * 8);
            #pragma unroll
            for (int nt = 0; nt < 4; ++nt) {
                short8_t b = *(const short8_t*)(wtile + (nt * 16 + r) * 136 + kk * 32 + q * 8);
                acc1[nt] = __builtin_amdgcn_mfma_f32_16x16x32_bf16(a, b, acc1[nt], 0, 0, 0);
            }
        }
        #pragma unroll
        for (int nt = 0; nt < 4; ++nt) {
            int col = nt * 16 + r;
            #pragma unroll
            for (int i2 = 0; i2 < 4; ++i2) {
                int row = wave * 16 + q * 4 + i2;
                feat[row * 72 + col] = f2bs(fmaxf(acc1[nt][i2] + smallb[col], 0.0f));
            }
        }
        __syncthreads();
        if (tid < 128) {
            int row = tid >> 1, cls = tid & 1;
            float a = smallb[192 + cls];
            #pragma unroll 8
            for (int k = 0; k < 64; ++k)
                a += bs2f(feat[row * 72 + k]) * smallb[64 + k * 2 + cls];
            out[(long)(rowBase + row) * 2 + cls] = a;
        }
    }
}

// ---------------------------------------------------------------------------
static inline int igrid(long total, int block, int cap) {
    long g = (total + block - 1) / block;
    return (int)(g < cap ? g : cap);
}

constexpr int GE_EDGE = 2048;
constexpr int GA_AGG  = NNODES / 4;  // 6250
constexpr size_t NINTS_PAD = 25001 + 25000 + 4 * (size_t)NEDGES + 3;  // %4==0

template<typename TE, typename TH>
static void run_net(void* const* d_in, float* f, TE* e, TH* ehat,
                    __hip_bfloat16* eorig, bool fusedFinal,
                    float* out, hipStream_t stream)
{
    const float* h_in   = (const float*)d_in[0];
    const float* e_in   = (const float*)d_in[1];
    const int*   src    = (const int*)d_in[2];
    const int*   dst    = (const int*)d_in[3];
    const int*   rev    = (const int*)d_in[4];
    const float* emb_h_w = (const float*)d_in[5];
    const float* emb_h_b = (const float*)d_in[6];
    const float* emb_e_w = (const float*)d_in[7];
    const float* emb_e_b = (const float*)d_in[8];
    const float* A_w = (const float*)d_in[9];  const float* A_b = (const float*)d_in[10];
    const float* B_w = (const float*)d_in[11]; const float* B_b = (const float*)d_in[12];
    const float* C_w = (const float*)d_in[13]; const float* C_b = (const float*)d_in[14];
    const float* D_w = (const float*)d_in[15]; const float* D_b = (const float*)d_in[16];
    const float* E_w = (const float*)d_in[17]; const float* E_b = (const float*)d_in[18];
    // F/G (19..22) and bn_u (27,28) are dead: u never reaches the output.
    const float* bn_h_g = (const float*)d_in[23]; const float* bn_h_b = (const float*)d_in[24];
    const float* bn_e_g = (const float*)d_in[25]; const float* bn_e_b = (const float*)d_in[26];
    const float* W0 = (const float*)d_in[29]; const float* b0 = (const float*)d_in[30];
    const float* W1 = (const float*)d_in[31]; const float* b1 = (const float*)d_in[32];
    const float* W2 = (const float*)d_in[33]; const float* b2 = (const float*)d_in[34];

    const size_t NH = (size_t)NNODES * DD;   // 1.6M (even)
    float* h    = f;                         // NH fp32
    float* Ah   = f + NH;                    // NH fp32 (Hs overlays after layers)
    float* hhat = f + 2 * NH;                // NH fp32 (dedicated)
    __hip_bfloat16* Bh16 = (__hip_bfloat16*)(f + 3 * NH);           // NH bf16
    __hip_bfloat16* Dh16 = (__hip_bfloat16*)(f + 3 * NH + NH / 2);  // NH bf16
    __hip_bfloat16* Eh16 = (__hip_bfloat16*)(f + 4 * NH);           // NH bf16
    float* scratch = f + 4 * NH + NH / 2;
    float* partial_e = scratch;                              // 2048*128
    float* partial_h = partial_e + (size_t)GE_EDGE * 128;    // 6250*128
    int*   rowptr = (int*)(partial_h + (size_t)GA_AGG * 128);
    int*   cursor = rowptr + NNODES + 1;
    int*   eid    = cursor + NNODES;
    int*   inv    = eid + NEDGES;
    int*   srcS   = inv + NEDGES;
    int*   dstS   = srcS + NEDGES;
    short* W0T = (short*)(rowptr + NINTS_PAD);   // 16B-aligned
    short* W1T = W0T + 256 * 128;
    short* CT  = W1T + 128 * 64;
    short* NT  = CT + 4 * 4096;
    short* HT  = NT + 4 * 16384;
    float* stats_h = (float*)(HT + 256 * 64);
    float* stats_e = stats_h + 128;
    // Hs: Ah region (NH fp32 = 25000*128 bf16). Hd: Bh16+Dh16 region.
    __hip_bfloat16* Hs = (__hip_bfloat16*)(f + NH);
    __hip_bfloat16* Hd = (__hip_bfloat16*)(f + 3 * NH);

    const int GN = 1563;
    const int GEDGE = (NEDGES + 255) / 256;

    // CSR + permutation + weight prep (once per call; graph static)
    hipMemsetAsync(rowptr, 0, (2 * NNODES + 1) * sizeof(int), stream);
    deg_hist_kernel<<<GEDGE, 256, 0, stream>>>(dst, rowptr, NEDGES);
    scan_kernel<<<1, 1024, 0, stream>>>(rowptr, NNODES + 1);
    scatter_kernel<<<GEDGE, 256, 0, stream>>>(dst, rowptr, cursor, eid, NEDGES);
    remap1_kernel<<<GEDGE, 256, 0, stream>>>(eid, src, dst, inv, srcS, dstS, NEDGES);
    transpose_w_kernel<<<256, 256, 0, stream>>>(W0, W1, C_w, A_w, B_w, D_w, E_w,
                                                W0T, W1T, CT, NT, HT);

    // embeddings (e in dst-sorted order via eid gather)
    linear_kernel<64, 64, 4, float, float><<<GN, 256, 0, stream>>>(
        h_in, emb_h_w, emb_h_b, h, nullptr, NNODES);
    linear_kernel<16, 64, 4, float, TE><<<4096, 256, 0, stream>>>(
        e_in, emb_e_w, emb_e_b, e, eid, NEDGES);

    for (int l = 0; l < 4; ++l) {
        const size_t o = (size_t)l * DD * DD;
        if (l == 0)
            node_linear4_mfma_kernel<false><<<391, 256, 0, stream>>>(
                h, hhat, NT + (size_t)l * 16384,
                A_b + l * DD, B_b + l * DD, D_b + l * DD, E_b + l * DD,
                nullptr, nullptr, nullptr, Ah, Bh16, Dh16, Eh16);
        else
            node_linear4_mfma_kernel<true><<<391, 256, 0, stream>>>(
                h, hhat, NT + (size_t)l * 16384,
                A_b + l * DD, B_b + l * DD, D_b + l * DD, E_b + l * DD,
                stats_h, bn_h_g + (l - 1) * DD, bn_h_b + (l - 1) * DD,
                Ah, Bh16, Dh16, Eh16);

        if (l == 0)
            edge_update_mfma_kernel<false, TE, TH><<<GE_EDGE, 256, 0, stream>>>(
                e, ehat, CT + o, C_b + l * DD, Dh16, srcS, Eh16, dstS,
                nullptr, nullptr, nullptr, partial_e);
        else
            edge_update_mfma_kernel<true, TE, TH><<<GE_EDGE, 256, 0, stream>>>(
                e, ehat, CT + o, C_b + l * DD, Dh16, srcS, Eh16, dstS,
                stats_e, bn_e_g + (l - 1) * DD, bn_e_b + (l - 1) * DD, partial_e);

        agg_sorted_kernel<TH><<<GA_AGG, 256, 0, stream>>>(
            ehat, Bh16, srcS, rowptr, Ah, hhat, partial_h);
        reduce_stats2_kernel<<<256, 256, 0, stream>>>(
            partial_e, GE_EDGE, stats_e, partial_h, GA_AGG, stats_h);
    }

    // final e update -> bf16 eorig in ORIGINAL edge order (before precompute_H
    // clobbers Ah/Bh16/Dh16 with Hs/Hd)
    if (fusedFinal) {
        bnfinal_scatter_kernel<TE, TH><<<8192, 256, 0, stream>>>(
            e, ehat, eid, stats_e, bn_e_g + 3 * DD, bn_e_b + 3 * DD, eorig);
    } else {
        bn_apply4_kernel<TE, TH><<<8192, 256, 0, stream>>>(
            e, ehat, stats_e, bn_e_g + 3 * DD, bn_e_b + 3 * DD, NEDGES);
        permute_e_kernel<TE><<<8192, 256, 0, stream>>>(e, eid, eorig);
    }

    // Hs/Hd precompute (bf16) with fused final h-update (no h writeback)
    precompute_H_kernel<<<391, 256, 0, stream>>>(
        h, hhat, stats_h, bn_h_g + 3 * DD, bn_h_b + 3 * DD, HT, b0, Hs, Hd);

    // streaming readout in original order (R10 form)
    readout_mfma2_kernel<<<2048, 256, 0, stream>>>(
        eorig, rev, Hs, Hd, src, dst, W0T, W1T, b1, W2, b2, out);
}

extern "C" void kernel_launch(void* const* d_in, const int* in_sizes, int n_in,
                              void* d_out, int out_size, void* d_ws, size_t ws_size,
                              hipStream_t stream)
{
    const size_t NH = (size_t)NNODES * DD;       // 1.6M floats
    const size_t NE = (size_t)NEDGES * DD;       // 25.6M elems
    const size_t baseB = (7 * NH + 256) * sizeof(float);   // 44.8 MB node region

    char* base = (char*)d_ws;
    char* edge = base + baseB;
    float* out = (float*)d_out;

    // main tier: fp32 e + bf16 ehat + dedicated bf16 eorig (proven to fit)
    const size_t needMain = baseB + NE * 4 + NE * 2 + NE * 2;
    const size_t needC    = baseB + NE * 2 * 2;    // bf16 e + bf16 ehat, 2-pass

    if (ws_size >= needMain) {
        float* e = (float*)edge;
        __hip_bfloat16* ehat  = (__hip_bfloat16*)(edge + NE * 4);
        __hip_bfloat16* eorig = (__hip_bfloat16*)(edge + NE * 6);
        run_net<float, __hip_bfloat16>(d_in, (float*)base, e, ehat, eorig,
                                       true, out, stream);
    } else if (ws_size >= needC) {
        __hip_bfloat16* e    = (__hip_bfloat16*)edge;
        __hip_bfloat16* ehat = (__hip_bfloat16*)(edge + NE * 2);
        run_net<__hip_bfloat16, __hip_bfloat16>(d_in, (float*)base, e, ehat,
                                                ehat, false, out, stream);
    } else {
        hipMemsetAsync(d_out, 0, (size_t)out_size * sizeof(float), stream);
    }
}

// Round 13
// 855.991 us; speedup vs baseline: 4.7131x; 1.0524x over previous
//
#include <hip/hip_runtime.h>
#include <hip/hip_bf16.h>

constexpr int NNODES = 25000;
constexpr int NEDGES = 400000;
constexpr int DD = 64;
constexpr float BNEPS = 1e-5f;
constexpr float AGGEPS = 1e-6f;

typedef __attribute__((ext_vector_type(8))) short short8_t;
typedef __attribute__((ext_vector_type(4))) short short4_t;
typedef __attribute__((ext_vector_type(4))) float float4_t;

// storage-type helpers (compute is always fp32)
__device__ __forceinline__ float ldv(const float* p, long i) { return p[i]; }
__device__ __forceinline__ float ldv(const __hip_bfloat16* p, long i) { return __bfloat162float(p[i]); }
__device__ __forceinline__ void stv(float* p, long i, float v) { p[i] = v; }
__device__ __forceinline__ void stv(__hip_bfloat16* p, long i, float v) { p[i] = __float2bfloat16(v); }

__device__ __forceinline__ short f2bs(float f) {
    union { float f; unsigned u; } x; x.f = f;
    unsigned r = x.u + 0x7FFFu + ((x.u >> 16) & 1u);
    return (short)(r >> 16);
}
__device__ __forceinline__ float bs2f(short s) {
    union { unsigned u; float f; } x; x.u = ((unsigned)(unsigned short)s) << 16; return x.f;
}

__device__ __forceinline__ float4_t ldv4(const float* p, long i) {
    return *(const float4_t*)(p + i);
}
__device__ __forceinline__ float4_t ldv4(const __hip_bfloat16* p, long i) {
    short4_t s = *(const short4_t*)(p + i);
    float4_t r;
    #pragma unroll
    for (int c = 0; c < 4; ++c) r[c] = bs2f(s[c]);
    return r;
}
__device__ __forceinline__ void stv4(float* p, long i, float4_t v) {
    *(float4_t*)(p + i) = v;
}
__device__ __forceinline__ void stv4(__hip_bfloat16* p, long i, float4_t v) {
    short4_t s;
    #pragma unroll
    for (int c = 0; c < 4; ++c) s[c] = f2bs(v[c]);
    *(short4_t*)(p + i) = s;
}

__device__ __forceinline__ void stage8(const __hip_bfloat16* s, short* d) {
    *(short8_t*)d = *(const short8_t*)s;
}
__device__ __forceinline__ void stage8(const float* s, short* d) {
    float4_t a = *(const float4_t*)s;
    float4_t b = *(const float4_t*)(s + 4);
    short8_t v;
    v[0] = f2bs(a[0]); v[1] = f2bs(a[1]); v[2] = f2bs(a[2]); v[3] = f2bs(a[3]);
    v[4] = f2bs(b[0]); v[5] = f2bs(b[1]); v[6] = f2bs(b[2]); v[7] = f2bs(b[3]);
    *(short8_t*)d = v;
}

// ---------------------------------------------------------------------------
// Generic LDS-tiled linear (embeddings), optional row-gather on X.
// ---------------------------------------------------------------------------
template<int K, int N, int JR, typename TX, typename TY>
__global__ __launch_bounds__(256) void linear_kernel(
    const TX* __restrict__ X, const float* __restrict__ W,
    const float* __restrict__ Bb, TY* __restrict__ Y,
    const int* __restrict__ gather, int rows)
{
    constexpr int SLOTS = 256 / N;
    constexpr int RPG = SLOTS * JR;
    __shared__ float wl[K * N];
    __shared__ float bl[N];
    __shared__ float xl[RPG * K];

    const int tid = threadIdx.x;
    for (int i = tid; i < K * N; i += 256) wl[i] = W[i];
    if (tid < N) bl[tid] = Bb[tid];

    const int col = tid % N;
    const int slot = tid / N;

    const int ngroups = (rows + RPG - 1) / RPG;
    for (int g = blockIdx.x; g < ngroups; g += gridDim.x) {
        const int rowBase = g * RPG;
        __syncthreads();
        for (int i = tid; i < RPG * K; i += 256) {
            int r = i / K, k = i - r * K;
            int row = rowBase + r;
            float v = 0.0f;
            if (row < rows) {
                int sr = gather ? gather[row] : row;
                v = ldv(X, (long)sr * K + k);
            }
            xl[i] = v;
        }
        __syncthreads();
        float acc[JR];
        #pragma unroll
        for (int j = 0; j < JR; ++j) acc[j] = bl[col];
        #pragma unroll 4
        for (int k = 0; k < K; ++k) {
            float w = wl[k * N + col];
            #pragma unroll
            for (int j = 0; j < JR; ++j)
                acc[j] += xl[(slot * JR + j) * K + k] * w;
        }
        #pragma unroll
        for (int j = 0; j < JR; ++j) {
            int row = rowBase + slot * JR + j;
            if (row < rows) stv(Y, (long)row * N + col, acc[j]);
        }
    }
}

// ---------------------------------------------------------------------------
// Quad node linear, MFMA: Ah (fp32) | Bh,Dh,Eh (bf16) = h @ {A,B,D,E} + b.
// If BNIN: h = h + relu(bn(hhat; stats_prev)) in place first (feeds matmul).
// ---------------------------------------------------------------------------
template<bool BNIN>
__global__ __launch_bounds__(256) void node_linear4_mfma_kernel(
    float* __restrict__ h, const float* __restrict__ hhat,
    const short* __restrict__ NT,
    const float* __restrict__ Ab, const float* __restrict__ Bb,
    const float* __restrict__ Db, const float* __restrict__ Eb,
    const float* __restrict__ stats_prev, const float* __restrict__ gprev,
    const float* __restrict__ bprev,
    float* __restrict__ Ah, __hip_bfloat16* __restrict__ Bh,
    __hip_bfloat16* __restrict__ Dh, __hip_bfloat16* __restrict__ Eh)
{
    __shared__ short wt[256 * 72];
    __shared__ short xs[64 * 72];
    __shared__ float bl[256];
    __shared__ float scale[64], shift[64];

    const int tid = threadIdx.x;
    const int wave = tid >> 6;
    const int lane = tid & 63;
    const int r = lane & 15;
    const int q = lane >> 4;

    for (int i = tid; i < 2048; i += 256) {
        int n = i >> 3, oct = i & 7;
        *(short8_t*)(wt + n * 72 + oct * 8) = *(const short8_t*)(NT + n * 64 + oct * 8);
    }
    if (tid < 64) bl[tid] = Ab[tid];
    else if (tid < 128) bl[tid] = Bb[tid - 64];
    else if (tid < 192) bl[tid] = Db[tid - 128];
    else bl[tid] = Eb[tid - 192];
    if (BNIN && tid < 64) {
        float inv = 1.0f / (float)NNODES;
        float mu = stats_prev[tid] * inv;
        float var = stats_prev[64 + tid] * inv - mu * mu;
        float rs = rsqrtf(var + BNEPS);
        float sc = rs * gprev[tid];
        scale[tid] = sc;
        shift[tid] = bprev[tid] - mu * sc;
    }

    const int ntiles = (NNODES + 63) / 64;        // 391
    for (int t = blockIdx.x; t < ntiles; t += gridDim.x) {
        const int rowBase = t * 64;
        __syncthreads();
        for (int i = tid; i < 512; i += 256) {
            int row = i >> 3, oct = i & 7;
            int nr = rowBase + row;
            if (nr < NNODES) {
                long idx = (long)nr * 64 + oct * 8;
                float4_t a = ldv4(h, idx), b = ldv4(h, idx + 4);
                if (BNIN) {
                    float4_t ha = ldv4(hhat, idx), hb = ldv4(hhat, idx + 4);
                    int k0 = oct * 8;
                    #pragma unroll
                    for (int c = 0; c < 4; ++c) {
                        a[c] += fmaxf(ha[c] * scale[k0 + c] + shift[k0 + c], 0.0f);
                        b[c] += fmaxf(hb[c] * scale[k0 + 4 + c] + shift[k0 + 4 + c], 0.0f);
                    }
                    stv4(h, idx, a); stv4(h, idx + 4, b);
                }
                short8_t v;
                v[0] = f2bs(a[0]); v[1] = f2bs(a[1]); v[2] = f2bs(a[2]); v[3] = f2bs(a[3]);
                v[4] = f2bs(b[0]); v[5] = f2bs(b[1]); v[6] = f2bs(b[2]); v[7] = f2bs(b[3]);
                *(short8_t*)(xs + row * 72 + oct * 8) = v;
            } else {
                *(short8_t*)(xs + row * 72 + oct * 8) = (short8_t)0;
            }
        }
        __syncthreads();
        float4_t acc[16];
        #pragma unroll
        for (int i = 0; i < 16; ++i) acc[i] = (float4_t)0.0f;
        #pragma unroll
        for (int kk = 0; kk < 2; ++kk) {
            short8_t a = *(const short8_t*)(xs + (wave * 16 + r) * 72 + kk * 32 + q * 8);
            #pragma unroll
            for (int nt = 0; nt < 16; ++nt) {
                short8_t b = *(const short8_t*)(wt + (nt * 16 + r) * 72 + kk * 32 + q * 8);
                acc[nt] = __builtin_amdgcn_mfma_f32_16x16x32_bf16(a, b, acc[nt], 0, 0, 0);
            }
        }
        #pragma unroll
        for (int nt = 0; nt < 16; ++nt) {
            int c = (nt & 3) * 16 + r;
            int n = nt * 16 + r;
            #pragma unroll
            for (int i2 = 0; i2 < 4; ++i2) {
                int row = rowBase + wave * 16 + q * 4 + i2;
                if (row < NNODES) {
                    float v = acc[nt][i2] + bl[n];
                    long idx = (long)row * 64 + c;
                    if (nt < 4)       Ah[idx] = v;
                    else if (nt < 8)  stv(Bh, idx, v);
                    else if (nt < 12) stv(Dh, idx, v);
                    else              stv(Eh, idx, v);
                }
            }
        }
    }
}

// ---------------------------------------------------------------------------
// MFMA edge update (edges in dst-sorted order); Dh/Eh are bf16 (L2-resident).
// BN stats are accumulated from fp32 values BEFORE ehat storage rounding.
// ---------------------------------------------------------------------------
template<bool BNIN, typename TE, typename TH>
__global__ __launch_bounds__(256) void edge_update_mfma_kernel(
    TE* __restrict__ e, TH* __restrict__ ehat,
    const short* __restrict__ CT, const float* __restrict__ Cb,
    const __hip_bfloat16* __restrict__ Dh, const int* __restrict__ srcS,
    const __hip_bfloat16* __restrict__ Eh, const int* __restrict__ dstS,
    const float* __restrict__ stats_prev, const float* __restrict__ gprev,
    const float* __restrict__ bprev, float* __restrict__ partial)
{
    __shared__ short ct[64 * 72];
    __shared__ short xs[64 * 72];
    __shared__ float bl[64], scale[64], shift[64];
    __shared__ float ps[128];

    const int tid = threadIdx.x;
    const int wave = tid >> 6;
    const int lane = tid & 63;
    const int r = lane & 15;
    const int q = lane >> 4;

    for (int i = tid; i < 512; i += 256) {
        int n = i >> 3, oct = i & 7;
        *(short8_t*)(ct + n * 72 + oct * 8) = *(const short8_t*)(CT + n * 64 + oct * 8);
    }
    if (tid < 64) {
        bl[tid] = Cb[tid];
        if (BNIN) {
            float inv = 1.0f / (float)NEDGES;
            float mu = stats_prev[tid] * inv;
            float var = stats_prev[64 + tid] * inv - mu * mu;
            float rs = rsqrtf(var + BNEPS);
            float sc = rs * gprev[tid];
            scale[tid] = sc;
            shift[tid] = bprev[tid] - mu * sc;
        }
    }
    if (tid < 128) ps[tid] = 0.0f;
    float lsum[4] = {0, 0, 0, 0}, lsum2[4] = {0, 0, 0, 0};

    constexpr int NTILES = NEDGES / 64;
    for (int t = blockIdx.x; t < NTILES; t += gridDim.x) {
        const int rowBase = t * 64;
        __syncthreads();
        for (int i = tid; i < 512; i += 256) {
            int row = i >> 3, oct = i & 7;
            long idx = (long)(rowBase + row) * 64 + oct * 8;
            float4_t a = ldv4(e, idx), b = ldv4(e, idx + 4);
            if (BNIN) {
                float4_t ha = ldv4(ehat, idx), hb = ldv4(ehat, idx + 4);
                int k0 = oct * 8;
                #pragma unroll
                for (int c = 0; c < 4; ++c) {
                    a[c] += fmaxf(ha[c] * scale[k0 + c] + shift[k0 + c], 0.0f);
                    b[c] += fmaxf(hb[c] * scale[k0 + 4 + c] + shift[k0 + 4 + c], 0.0f);
                }
                stv4(e, idx, a); stv4(e, idx + 4, b);
            }
            short8_t v;
            v[0] = f2bs(a[0]); v[1] = f2bs(a[1]); v[2] = f2bs(a[2]); v[3] = f2bs(a[3]);
            v[4] = f2bs(b[0]); v[5] = f2bs(b[1]); v[6] = f2bs(b[2]); v[7] = f2bs(b[3]);
            *(short8_t*)(xs + row * 72 + oct * 8) = v;
        }
        __syncthreads();
        float4_t acc[4];
        #pragma unroll
        for (int i = 0; i < 4; ++i) acc[i] = (float4_t)0.0f;
        #pragma unroll
        for (int kk = 0; kk < 2; ++kk) {
            short8_t a = *(const short8_t*)(xs + (wave * 16 + r) * 72 + kk * 32 + q * 8);
            #pragma unroll
            for (int nt = 0; nt < 4; ++nt) {
                short8_t b = *(const short8_t*)(ct + (nt * 16 + r) * 72 + kk * 32 + q * 8);
                acc[nt] = __builtin_amdgcn_mfma_f32_16x16x32_bf16(a, b, acc[nt], 0, 0, 0);
            }
        }
        #pragma unroll
        for (int i2 = 0; i2 < 4; ++i2) {
            int row = wave * 16 + q * 4 + i2;
            int er = rowBase + row;
            int s = srcS[er], d = dstS[er];
            #pragma unroll
            for (int nt = 0; nt < 4; ++nt) {
                int col = nt * 16 + r;
                float v = acc[nt][i2] + bl[col]
                        + ldv(Dh, (long)s * 64 + col) + ldv(Eh, (long)d * 64 + col);
                stv(ehat, (long)er * 64 + col, v);
                lsum[nt] += v; lsum2[nt] += v * v;
            }
        }
    }
    __syncthreads();
    #pragma unroll
    for (int nt = 0; nt < 4; ++nt) {
        atomicAdd(&ps[nt * 16 + r], lsum[nt]);
        atomicAdd(&ps[64 + nt * 16 + r], lsum2[nt]);
    }
    __syncthreads();
    if (tid < 128) partial[(long)blockIdx.x * 128 + tid] = ps[tid];
}

// ---------------------------------------------------------------------------
// CSR build + edge permutation
// ---------------------------------------------------------------------------
__global__ __launch_bounds__(256) void deg_hist_kernel(
    const int* __restrict__ dst, int* __restrict__ rowptr, int rows)
{
    int e = blockIdx.x * 256 + threadIdx.x;
    if (e < rows) atomicAdd(&rowptr[dst[e] + 1], 1);
}

__global__ __launch_bounds__(1024) void scan_kernel(int* __restrict__ data, int n)
{
    __shared__ int buf[1024];
    __shared__ int carry;
    if (threadIdx.x == 0) carry = 0;
    __syncthreads();
    for (int base = 0; base < n; base += 1024) {
        int i = base + threadIdx.x;
        int v = (i < n) ? data[i] : 0;
        buf[threadIdx.x] = v;
        __syncthreads();
        for (int off = 1; off < 1024; off <<= 1) {
            int t = (threadIdx.x >= off) ? buf[threadIdx.x - off] : 0;
            __syncthreads();
            buf[threadIdx.x] += t;
            __syncthreads();
        }
        if (i < n) data[i] = buf[threadIdx.x] + carry;
        __syncthreads();
        if (threadIdx.x == 0) carry += buf[1023];
        __syncthreads();
    }
}

__global__ __launch_bounds__(256) void scatter_kernel(
    const int* __restrict__ dst, const int* __restrict__ rowptr,
    int* __restrict__ cursor, int* __restrict__ eid, int rows)
{
    int e = blockIdx.x * 256 + threadIdx.x;
    if (e < rows) {
        int d = dst[e];
        int pos = atomicAdd(&cursor[d], 1);
        eid[rowptr[d] + pos] = e;
    }
}

__global__ __launch_bounds__(256) void remap1_kernel(
    const int* __restrict__ eid, const int* __restrict__ src,
    const int* __restrict__ dst, int* __restrict__ inv,
    int* __restrict__ srcS, int* __restrict__ dstS, int rows)
{
    int p = blockIdx.x * 256 + threadIdx.x;
    if (p < rows) {
        int orig = eid[p];
        inv[orig] = p;
        srcS[p] = src[orig];
        dstS[p] = dst[orig];
    }
}

// ---------------------------------------------------------------------------
// Sorted aggregation + fused hhat + BN partials; Bh is bf16 (L2-resident).
// ---------------------------------------------------------------------------
template<typename TH>
__global__ __launch_bounds__(256) void agg_sorted_kernel(
    const TH* __restrict__ ehat, const __hip_bfloat16* __restrict__ Bh,
    const int* __restrict__ srcS, const int* __restrict__ rowptr,
    const float* __restrict__ Ah, float* __restrict__ hhat,
    float* __restrict__ partial)
{
    __shared__ float ps[64], ps2[64];
    const int tid = threadIdx.x;
    if (tid < 64) { ps[tid] = 0.0f; ps2[tid] = 0.0f; }
    __syncthreads();

    const int node = blockIdx.x * 4 + (tid >> 6);
    const int lane = tid & 63;
    const int sub = lane >> 4;
    const int c4 = (lane & 15) * 4;
    const int s0 = rowptr[node], s1 = rowptr[node + 1];

    float4_t den = (float4_t)0.0f, num = (float4_t)0.0f;
    for (int p = s0 + sub; p < s1; p += 4) {
        float4_t v = ldv4(ehat, (long)p * 64 + c4);
        float4_t bh = ldv4(Bh, (long)srcS[p] * 64 + c4);
        #pragma unroll
        for (int c = 0; c < 4; ++c) {
            float s = 1.0f / (1.0f + __expf(-v[c]));
            den[c] += s;
            num[c] += s * bh[c];
        }
    }
    #pragma unroll
    for (int m = 16; m <= 32; m <<= 1) {
        #pragma unroll
        for (int c = 0; c < 4; ++c) {
            den[c] += __shfl_xor(den[c], m, 64);
            num[c] += __shfl_xor(num[c], m, 64);
        }
    }
    if (sub == 0) {
        float4_t av = ldv4(Ah, (long)node * 64 + c4);
        float4_t hh;
        #pragma unroll
        for (int c = 0; c < 4; ++c) {
            hh[c] = av[c] + num[c] / (den[c] + AGGEPS);
            atomicAdd(&ps[c4 + c], hh[c]);
            atomicAdd(&ps2[c4 + c], hh[c] * hh[c]);
        }
        stv4(hhat, (long)node * 64 + c4, hh);
    }
    __syncthreads();
    if (tid < 64) {
        partial[(long)blockIdx.x * 128 + tid] = ps[tid];
        partial[(long)blockIdx.x * 128 + 64 + tid] = ps2[tid];
    }
}

// merged stats reduce: blocks 0..127 -> stats_e, 128..255 -> stats_h
__global__ __launch_bounds__(256) void reduce_stats2_kernel(
    const float* __restrict__ pe, int ne, float* __restrict__ se,
    const float* __restrict__ ph, int nh, float* __restrict__ sh)
{
    __shared__ float sb[256];
    const float* partial; int nblk; float* stats; int col;
    if (blockIdx.x < 128) { partial = pe; nblk = ne; stats = se; col = blockIdx.x; }
    else                  { partial = ph; nblk = nh; stats = sh; col = blockIdx.x - 128; }
    int tid = threadIdx.x;
    float s = 0.0f;
    for (int i = tid; i < nblk; i += 256) s += partial[(long)i * 128 + col];
    sb[tid] = s;
    __syncthreads();
    for (int off = 128; off > 0; off >>= 1) {
        if (tid < off) sb[tid] += sb[tid + off];
        __syncthreads();
    }
    if (tid == 0) stats[col] = sb[0];
}

// base += relu((xhat-mu)*rstd*g + b), float4 per thread (in place)
template<typename TB, typename TX>
__global__ __launch_bounds__(256) void bn_apply4_kernel(
    TB* __restrict__ base, const TX* __restrict__ xhat,
    const float* __restrict__ stats, const float* __restrict__ g,
    const float* __restrict__ b, int rows)
{
    long total4 = (long)rows * 16;
    float inv = 1.0f / (float)rows;
    for (long q = (long)blockIdx.x * 256 + threadIdx.x; q < total4;
         q += (long)gridDim.x * 256) {
        long idx = q * 4;
        int c = (int)(idx & 63);
        float4_t x = ldv4(xhat, idx);
        float4_t bs = ldv4(base, idx);
        #pragma unroll
        for (int j = 0; j < 4; ++j) {
            float mu = stats[c + j] * inv;
            float var = stats[64 + c + j] * inv - mu * mu;
            float rs = rsqrtf(var + BNEPS);
            float v = (x[j] - mu) * rs * g[c + j] + b[c + j];
            bs[j] += fmaxf(v, 0.0f);
        }
        stv4(base, idx, bs);
    }
}

// fused final e update + scatter to original order:
// eorig[eid[p]] = bf16(e[p] + relu(bn(ehat[p])))
template<typename TE, typename TH>
__global__ __launch_bounds__(256) void bnfinal_scatter_kernel(
    const TE* __restrict__ e, const TH* __restrict__ ehat,
    const int* __restrict__ eid, const float* __restrict__ stats,
    const float* __restrict__ g, const float* __restrict__ b,
    __hip_bfloat16* __restrict__ eorig)
{
    __shared__ float scale[64], shift[64];
    const int tid = threadIdx.x;
    if (tid < 64) {
        float inv = 1.0f / (float)NEDGES;
        float mu = stats[tid] * inv;
        float var = stats[64 + tid] * inv - mu * mu;
        float rs = rsqrtf(var + BNEPS);
        float sc = rs * g[tid];
        scale[tid] = sc;
        shift[tid] = b[tid] - mu * sc;
    }
    __syncthreads();
    long total = (long)NEDGES * 8;
    for (long i = (long)blockIdx.x * 256 + tid; i < total; i += (long)gridDim.x * 256) {
        int p = (int)(i >> 3), oct = (int)(i & 7);
        int k0 = oct * 8;
        long idx = (long)p * 64 + k0;
        float4_t a = ldv4(e, idx), b4 = ldv4(e, idx + 4);
        float4_t ha = ldv4(ehat, idx), hb = ldv4(ehat, idx + 4);
        short8_t v;
        #pragma unroll
        for (int c = 0; c < 4; ++c) {
            v[c]     = f2bs(a[c]  + fmaxf(ha[c] * scale[k0 + c]     + shift[k0 + c], 0.0f));
            v[4 + c] = f2bs(b4[c] + fmaxf(hb[c] * scale[k0 + 4 + c] + shift[k0 + 4 + c], 0.0f));
        }
        *(short8_t*)((short*)eorig + (long)eid[p] * 64 + k0) = v;
    }
}

// two-pass fallback: permute updated e (sorted) -> bf16 eorig (original order)
template<typename TE>
__global__ __launch_bounds__(256) void permute_e_kernel(
    const TE* __restrict__ e, const int* __restrict__ eid,
    __hip_bfloat16* __restrict__ eorig)
{
    long total = (long)NEDGES * 8;
    for (long i = (long)blockIdx.x * 256 + threadIdx.x; i < total;
         i += (long)gridDim.x * 256) {
        int p = (int)(i >> 3), oct = (int)(i & 7);
        long idx = (long)p * 64 + oct * 8;
        float4_t a = ldv4(e, idx), b = ldv4(e, idx + 4);
        short8_t v;
        #pragma unroll
        for (int c = 0; c < 4; ++c) { v[c] = f2bs(a[c]); v[4 + c] = f2bs(b[c]); }
        *(short8_t*)((short*)eorig + (long)eid[p] * 64 + oct * 8) = v;
    }
}

// Hs = h_fin @ W0c + b0, Hd = h_fin @ W0d (bf16 outputs), with
// h_fin = h + relu(bn(hhat)) computed on the fly (no h writeback).
__global__ __launch_bounds__(256) void precompute_H_kernel(
    const float* __restrict__ h, const float* __restrict__ hhat,
    const float* __restrict__ stats, const float* __restrict__ g,
    const float* __restrict__ b,
    const short* __restrict__ HT, const float* __restrict__ b0,
    __hip_bfloat16* __restrict__ Hs, __hip_bfloat16* __restrict__ Hd)
{
    __shared__ short wt[256 * 72];
    __shared__ short xs[64 * 72];
    __shared__ float bl[256];
    __shared__ float scale[64], shift[64];

    const int tid = threadIdx.x;
    const int wave = tid >> 6;
    const int lane = tid & 63;
    const int r = lane & 15;
    const int q = lane >> 4;

    for (int i = tid; i < 2048; i += 256) {
        int n = i >> 3, oct = i & 7;
        *(short8_t*)(wt + n * 72 + oct * 8) = *(const short8_t*)(HT + n * 64 + oct * 8);
    }
    bl[tid] = (tid < 128) ? b0[tid] : 0.0f;
    if (tid < 64) {
        float inv = 1.0f / (float)NNODES;
        float mu = stats[tid] * inv;
        float var = stats[64 + tid] * inv - mu * mu;
        float rs = rsqrtf(var + BNEPS);
        float sc = rs * g[tid];
        scale[tid] = sc;
        shift[tid] = b[tid] - mu * sc;
    }

    const int ntiles = (NNODES + 63) / 64;
    for (int t = blockIdx.x; t < ntiles; t += gridDim.x) {
        const int rowBase = t * 64;
        __syncthreads();
        for (int i = tid; i < 512; i += 256) {
            int row = i >> 3, oct = i & 7;
            int nr = rowBase + row;
            if (nr < NNODES) {
                long idx = (long)nr * 64 + oct * 8;
                float4_t a = ldv4(h, idx), bb = ldv4(h, idx + 4);
                float4_t ha = ldv4(hhat, idx), hb = ldv4(hhat, idx + 4);
                int k0 = oct * 8;
                #pragma unroll
                for (int c = 0; c < 4; ++c) {
                    a[c]  += fmaxf(ha[c] * scale[k0 + c]     + shift[k0 + c], 0.0f);
                    bb[c] += fmaxf(hb[c] * scale[k0 + 4 + c] + shift[k0 + 4 + c], 0.0f);
                }
                short8_t v;
                v[0] = f2bs(a[0]); v[1] = f2bs(a[1]); v[2] = f2bs(a[2]); v[3] = f2bs(a[3]);
                v[4] = f2bs(bb[0]); v[5] = f2bs(bb[1]); v[6] = f2bs(bb[2]); v[7] = f2bs(bb[3]);
                *(short8_t*)(xs + row * 72 + oct * 8) = v;
            } else {
                *(short8_t*)(xs + row * 72 + oct * 8) = (short8_t)0;
            }
        }
        __syncthreads();
        float4_t acc[16];
        #pragma unroll
        for (int i = 0; i < 16; ++i) acc[i] = (float4_t)0.0f;
        #pragma unroll
        for (int kk = 0; kk < 2; ++kk) {
            short8_t a = *(const short8_t*)(xs + (wave * 16 + r) * 72 + kk * 32 + q * 8);
            #pragma unroll
            for (int nt = 0; nt < 16; ++nt) {
                short8_t b2 = *(const short8_t*)(wt + (nt * 16 + r) * 72 + kk * 32 + q * 8);
                acc[nt] = __builtin_amdgcn_mfma_f32_16x16x32_bf16(a, b2, acc[nt], 0, 0, 0);
            }
        }
        #pragma unroll
        for (int nt = 0; nt < 16; ++nt) {
            __hip_bfloat16* Y = (nt < 8) ? Hs : Hd;
            int c = (nt & 7) * 16 + r;
            int n = nt * 16 + r;
            #pragma unroll
            for (int i2 = 0; i2 < 4; ++i2) {
                int row = rowBase + wave * 16 + q * 4 + i2;
                if (row < NNODES) stv(Y, (long)row * 128 + c, acc[nt][i2] + bl[n]);
            }
        }
    }
}

// one-shot weight prep (bf16 [n][k]): W0T [128][256], W1T [64][128],
// CT [l][64][64], NT [l][256][64] (A|B|D|E), HT [256][64] (W0c|W0d)
__global__ __launch_bounds__(256) void transpose_w_kernel(
    const float* __restrict__ W0, const float* __restrict__ W1,
    const float* __restrict__ C_w,
    const float* __restrict__ A_w, const float* __restrict__ B_w,
    const float* __restrict__ D_w, const float* __restrict__ E_w,
    short* __restrict__ W0T, short* __restrict__ W1T,
    short* __restrict__ CT, short* __restrict__ NT, short* __restrict__ HT)
{
    int id = blockIdx.x * 256 + threadIdx.x;
    if (id < 256 * 128) {
        int k = id >> 7, n = id & 127;
        W0T[n * 256 + k] = f2bs(W0[id]);
    }
    if (id < 128 * 64) {
        int k = id >> 6, n = id & 63;
        W1T[n * 128 + k] = f2bs(W1[id]);
    }
    if (id < 4 * 64 * 64) {
        int l = id >> 12, rem = id & 4095, k = rem >> 6, n = rem & 63;
        CT[l * 4096 + n * 64 + k] = f2bs(C_w[l * 4096 + k * 64 + n]);
    }
    if (id < 4 * 256 * 64) {
        int l = id >> 14, rem = id & 16383, n = rem >> 6, k = rem & 63;
        int mat = n >> 6, c = n & 63;
        const float* Wm = (mat == 0) ? A_w : (mat == 1) ? B_w : (mat == 2) ? D_w : E_w;
        NT[l * 16384 + n * 64 + k] = f2bs(Wm[l * 4096 + k * 64 + c]);
    }
    if (id < 256 * 64) {
        int n = id >> 6, k = id & 63;
        int mat = n >> 7, col = n & 127;
        HT[n * 64 + k] = f2bs(W0[(128 + mat * 64 + k) * 128 + col]);
    }
}

// ---------------------------------------------------------------------------
// MFMA MLP readout v2 (R10 form — proven fastest): original edge order,
// W0 slices and W1 staged in LDS, x0t separate buffer. 76 VGPR, 3 blocks/CU.
// ---------------------------------------------------------------------------
__global__ __launch_bounds__(256) void readout_mfma2_kernel(
    const __hip_bfloat16* __restrict__ eorig, const int* __restrict__ rev,
    const __hip_bfloat16* __restrict__ Hs, const __hip_bfloat16* __restrict__ Hd,
    const int* __restrict__ src, const int* __restrict__ dst,
    const short* __restrict__ W0T, const short* __restrict__ W1T,
    const float* __restrict__ b1, const float* __restrict__ W2,
    const float* __restrict__ b2, float* __restrict__ out)
{
    __shared__ short feat[64 * 72];    // e / e_rev tile; reused as x1 tile
    __shared__ short wtile[128 * 72];  // W0 slice [128][72]; reused as W1T [64][136]
    __shared__ short x0t[64 * 136];    // x0 tile bf16
    __shared__ float smallb[194];      // b1[64] | W2[128] | b2[2]

    const int tid = threadIdx.x;
    const int wave = tid >> 6;
    const int lane = tid & 63;
    const int r = lane & 15;
    const int q = lane >> 4;

    if (tid < 64)  smallb[tid] = b1[tid];
    if (tid < 128) smallb[64 + tid] = W2[tid];
    if (tid < 2)   smallb[192 + tid] = b2[tid];

    constexpr int NTILES = NEDGES / 64;   // 6250
    for (int t = blockIdx.x; t < NTILES; t += gridDim.x) {
        const int rowBase = t * 64;
        float4_t acc0[8];
        #pragma unroll
        for (int i = 0; i < 8; ++i) acc0[i] = (float4_t)0.0f;

        for (int s = 0; s < 2; ++s) {
            __syncthreads();
            for (int i = tid; i < 512; i += 256) {
                int row = i >> 3, oct = i & 7;
                int er = rowBase + row;
                int srow = (s == 0) ? er : rev[er];   // sequential either way
                *(short8_t*)(feat + row * 72 + oct * 8) =
                    *(const short8_t*)((const short*)eorig + (long)srow * 64 + oct * 8);
            }
            for (int i = tid; i < 1024; i += 256) {
                int n = i >> 3, oct = i & 7;
                *(short8_t*)(wtile + n * 72 + oct * 8) =
                    *(const short8_t*)(W0T + (long)n * 256 + s * 64 + oct * 8);
            }
            __syncthreads();
            #pragma unroll
            for (int kk = 0; kk < 2; ++kk) {
                short8_t a = *(const short8_t*)(feat + (wave * 16 + r) * 72 + kk * 32 + q * 8);
                #pragma unroll
                for (int nt = 0; nt < 8; ++nt) {
                    short8_t b = *(const short8_t*)(wtile + (nt * 16 + r) * 72 + kk * 32 + q * 8);
                    acc0[nt] = __builtin_amdgcn_mfma_f32_16x16x32_bf16(a, b, acc0[nt], 0, 0, 0);
                }
            }
        }
        // epilogue 1: x0 = relu(acc0 + Hs[src] + Hd[dst]) (b0 folded into Hs)
        #pragma unroll
        for (int i2 = 0; i2 < 4; ++i2) {
            int row = wave * 16 + q * 4 + i2;
            int er = rowBase + row;
            int sN = src[er], dN = dst[er];
            #pragma unroll
            for (int nt = 0; nt < 8; ++nt) {
                int col = nt * 16 + r;
                float v = acc0[nt][i2] + ldv(Hs, (long)sN * 128 + col)
                                       + ldv(Hd, (long)dN * 128 + col);
                x0t[row * 136 + col] = f2bs(fmaxf(v, 0.0f));
            }
        }
        __syncthreads();
        for (int i = tid; i < 1024; i += 256) {       // W1T -> wtile as [64][136]
            int n = i >> 4, oct = i & 15;
            *(short8_t*)(wtile + n * 136 + oct * 8) =
                *(const short8_t*)(W1T + (long)n * 128 + oct * 8);
        }
        __syncthreads();
        float4_t acc1[4];
        #pragma unroll
        for (int i = 0; i < 4; ++i) acc1[i] = (float4_t)0.0f;
        #pragma unroll
        for (int kk = 0; kk < 4; ++kk) {
            short8_t a = *(const short8_t*)(x0t + (wave * 16 + r) * 136 + kk * 32 + q * 8);
            #pragma unroll
            for (int nt = 0; nt < 4; ++nt) {
                short8_t b = *(const short8_t*)(wtile + (nt * 16 + r) * 136 + kk * 32 + q * 8);
                acc1[nt] = __builtin_amdgcn_mfma_f32_16x16x32_bf16(a, b, acc1[nt], 0, 0, 0);
            }
        }
        #pragma unroll
        for (int nt = 0; nt < 4; ++nt) {
            int col = nt * 16 + r;
            #pragma unroll
            for (int i2 = 0; i2 < 4; ++i2) {
                int row = wave * 16 + q * 4 + i2;
                feat[row * 72 + col] = f2bs(fmaxf(acc1[nt][i2] + smallb[col], 0.0f));
            }
        }
        __syncthreads();
        if (tid < 128) {
            int row = tid >> 1, cls = tid & 1;
            float a = smallb[192 + cls];
            #pragma unroll 8
            for (int k = 0; k < 64; ++k)
                a += bs2f(feat[row * 72 + k]) * smallb[64 + k * 2 + cls];
            out[(long)(rowBase + row) * 2 + cls] = a;
        }
    }
}

// ---------------------------------------------------------------------------
static inline int igrid(long total, int block, int cap) {
    long g = (total + block - 1) / block;
    return (int)(g < cap ? g : cap);
}

constexpr int GE_EDGE = 2048;
constexpr int GA_AGG  = NNODES / 4;  // 6250
constexpr size_t NINTS_PAD = 25001 + 25000 + 4 * (size_t)NEDGES + 3;  // %4==0

template<typename TE, typename TH>
static void run_net(void* const* d_in, float* f, TE* e, TH* ehat,
                    __hip_bfloat16* eorig, bool fusedFinal,
                    float* out, hipStream_t stream)
{
    const float* h_in   = (const float*)d_in[0];
    const float* e_in   = (const float*)d_in[1];
    const int*   src    = (const int*)d_in[2];
    const int*   dst    = (const int*)d_in[3];
    const int*   rev    = (const int*)d_in[4];
    const float* emb_h_w = (const float*)d_in[5];
    const float* emb_h_b = (const float*)d_in[6];
    const float* emb_e_w = (const float*)d_in[7];
    const float* emb_e_b = (const float*)d_in[8];
    const float* A_w = (const float*)d_in[9];  const float* A_b = (const float*)d_in[10];
    const float* B_w = (const float*)d_in[11]; const float* B_b = (const float*)d_in[12];
    const float* C_w = (const float*)d_in[13]; const float* C_b = (const float*)d_in[14];
    const float* D_w = (const float*)d_in[15]; const float* D_b = (const float*)d_in[16];
    const float* E_w = (const float*)d_in[17]; const float* E_b = (const float*)d_in[18];
    // F/G (19..22) and bn_u (27,28) are dead: u never reaches the output.
    const float* bn_h_g = (const float*)d_in[23]; const float* bn_h_b = (const float*)d_in[24];
    const float* bn_e_g = (const float*)d_in[25]; const float* bn_e_b = (const float*)d_in[26];
    const float* W0 = (const float*)d_in[29]; const float* b0 = (const float*)d_in[30];
    const float* W1 = (const float*)d_in[31]; const float* b1 = (const float*)d_in[32];
    const float* W2 = (const float*)d_in[33]; const float* b2 = (const float*)d_in[34];

    const size_t NH = (size_t)NNODES * DD;   // 1.6M (even)
    float* h    = f;                         // NH fp32
    float* Ah   = f + NH;                    // NH fp32 (Hs overlays after layers)
    float* hhat = f + 2 * NH;                // NH fp32 (dedicated)
    __hip_bfloat16* Bh16 = (__hip_bfloat16*)(f + 3 * NH);           // NH bf16
    __hip_bfloat16* Dh16 = (__hip_bfloat16*)(f + 3 * NH + NH / 2);  // NH bf16
    __hip_bfloat16* Eh16 = (__hip_bfloat16*)(f + 4 * NH);           // NH bf16
    float* scratch = f + 4 * NH + NH / 2;
    float* partial_e = scratch;                              // 2048*128
    float* partial_h = partial_e + (size_t)GE_EDGE * 128;    // 6250*128
    int*   rowptr = (int*)(partial_h + (size_t)GA_AGG * 128);
    int*   cursor = rowptr + NNODES + 1;
    int*   eid    = cursor + NNODES;
    int*   inv    = eid + NEDGES;
    int*   srcS   = inv + NEDGES;
    int*   dstS   = srcS + NEDGES;
    short* W0T = (short*)(rowptr + NINTS_PAD);   // 16B-aligned
    short* W1T = W0T + 256 * 128;
    short* CT  = W1T + 128 * 64;
    short* NT  = CT + 4 * 4096;
    short* HT  = NT + 4 * 16384;
    float* stats_h = (float*)(HT + 256 * 64);
    float* stats_e = stats_h + 128;
    // Hs: Ah region (NH fp32 = 25000*128 bf16). Hd: Bh16+Dh16 region.
    __hip_bfloat16* Hs = (__hip_bfloat16*)(f + NH);
    __hip_bfloat16* Hd = (__hip_bfloat16*)(f + 3 * NH);

    const int GN = 1563;
    const int GEDGE = (NEDGES + 255) / 256;

    // CSR + permutation + weight prep (once per call; graph static)
    hipMemsetAsync(rowptr, 0, (2 * NNODES + 1) * sizeof(int), stream);
    deg_hist_kernel<<<GEDGE, 256, 0, stream>>>(dst, rowptr, NEDGES);
    scan_kernel<<<1, 1024, 0, stream>>>(rowptr, NNODES + 1);
    scatter_kernel<<<GEDGE, 256, 0, stream>>>(dst, rowptr, cursor, eid, NEDGES);
    remap1_kernel<<<GEDGE, 256, 0, stream>>>(eid, src, dst, inv, srcS, dstS, NEDGES);
    transpose_w_kernel<<<256, 256, 0, stream>>>(W0, W1, C_w, A_w, B_w, D_w, E_w,
                                                W0T, W1T, CT, NT, HT);

    // embeddings (e in dst-sorted order via eid gather)
    linear_kernel<64, 64, 4, float, float><<<GN, 256, 0, stream>>>(
        h_in, emb_h_w, emb_h_b, h, nullptr, NNODES);
    linear_kernel<16, 64, 4, float, TE><<<4096, 256, 0, stream>>>(
        e_in, emb_e_w, emb_e_b, e, eid, NEDGES);

    for (int l = 0; l < 4; ++l) {
        const size_t o = (size_t)l * DD * DD;
        if (l == 0)
            node_linear4_mfma_kernel<false><<<391, 256, 0, stream>>>(
                h, hhat, NT + (size_t)l * 16384,
                A_b + l * DD, B_b + l * DD, D_b + l * DD, E_b + l * DD,
                nullptr, nullptr, nullptr, Ah, Bh16, Dh16, Eh16);
        else
            node_linear4_mfma_kernel<true><<<391, 256, 0, stream>>>(
                h, hhat, NT + (size_t)l * 16384,
                A_b + l * DD, B_b + l * DD, D_b + l * DD, E_b + l * DD,
                stats_h, bn_h_g + (l - 1) * DD, bn_h_b + (l - 1) * DD,
                Ah, Bh16, Dh16, Eh16);

        if (l == 0)
            edge_update_mfma_kernel<false, TE, TH><<<GE_EDGE, 256, 0, stream>>>(
                e, ehat, CT + o, C_b + l * DD, Dh16, srcS, Eh16, dstS,
                nullptr, nullptr, nullptr, partial_e);
        else
            edge_update_mfma_kernel<true, TE, TH><<<GE_EDGE, 256, 0, stream>>>(
                e, ehat, CT + o, C_b + l * DD, Dh16, srcS, Eh16, dstS,
                stats_e, bn_e_g + (l - 1) * DD, bn_e_b + (l - 1) * DD, partial_e);

        agg_sorted_kernel<TH><<<GA_AGG, 256, 0, stream>>>(
            ehat, Bh16, srcS, rowptr, Ah, hhat, partial_h);
        reduce_stats2_kernel<<<256, 256, 0, stream>>>(
            partial_e, GE_EDGE, stats_e, partial_h, GA_AGG, stats_h);
    }

    // final e update -> bf16 eorig in ORIGINAL edge order (before precompute_H
    // clobbers Ah/Bh16/Dh16 with Hs/Hd)
    if (fusedFinal) {
        bnfinal_scatter_kernel<TE, TH><<<8192, 256, 0, stream>>>(
            e, ehat, eid, stats_e, bn_e_g + 3 * DD, bn_e_b + 3 * DD, eorig);
    } else {
        bn_apply4_kernel<TE, TH><<<8192, 256, 0, stream>>>(
            e, ehat, stats_e, bn_e_g + 3 * DD, bn_e_b + 3 * DD, NEDGES);
        permute_e_kernel<TE><<<8192, 256, 0, stream>>>(e, eid, eorig);
    }

    // Hs/Hd precompute (bf16) with fused final h-update (no h writeback)
    precompute_H_kernel<<<391, 256, 0, stream>>>(
        h, hhat, stats_h, bn_h_g + 3 * DD, bn_h_b + 3 * DD, HT, b0, Hs, Hd);

    // streaming readout in original order (R10 form)
    readout_mfma2_kernel<<<2048, 256, 0, stream>>>(
        eorig, rev, Hs, Hd, src, dst, W0T, W1T, b1, W2, b2, out);
}

extern "C" void kernel_launch(void* const* d_in, const int* in_sizes, int n_in,
                              void* d_out, int out_size, void* d_ws, size_t ws_size,
                              hipStream_t stream)
{
    const size_t NH = (size_t)NNODES * DD;       // 1.6M floats
    const size_t NE = (size_t)NEDGES * DD;       // 25.6M elems
    const size_t baseB = (7 * NH + 256) * sizeof(float);   // 44.8 MB node region

    char* base = (char*)d_ws;
    char* edge = base + baseB;
    float* out = (float*)d_out;

    // main tier (R13): bf16 e + bf16 ehat + dedicated bf16 eorig = 153.6 MB
    // edge region (well under the 249.6 MB proven to fit in R3)
    const size_t needMain = baseB + NE * 2 * 3;

    if (ws_size >= needMain) {
        __hip_bfloat16* e     = (__hip_bfloat16*)edge;
        __hip_bfloat16* ehat  = (__hip_bfloat16*)(edge + NE * 2);
        __hip_bfloat16* eorig = (__hip_bfloat16*)(edge + NE * 4);
        run_net<__hip_bfloat16, __hip_bfloat16>(d_in, (float*)base, e, ehat,
                                                eorig, true, out, stream);
    } else {
        // diagnostic fallback: workspace too small — emit zeros, don't fault
        hipMemsetAsync(d_out, 0, (size_t)out_size * sizeof(float), stream);
    }
}

// Round 14
// 845.163 us; speedup vs baseline: 4.7735x; 1.0128x over previous
//
#include <hip/hip_runtime.h>
#include <hip/hip_bf16.h>

constexpr int NNODES = 25000;
constexpr int NEDGES = 400000;
constexpr int DD = 64;
constexpr float BNEPS = 1e-5f;
constexpr float AGGEPS = 1e-6f;

typedef __attribute__((ext_vector_type(8))) short short8_t;
typedef __attribute__((ext_vector_type(4))) short short4_t;
typedef __attribute__((ext_vector_type(2))) short short2_t;
typedef __attribute__((ext_vector_type(4))) float float4_t;

// storage-type helpers (compute is always fp32)
__device__ __forceinline__ float ldv(const float* p, long i) { return p[i]; }
__device__ __forceinline__ float ldv(const __hip_bfloat16* p, long i) { return __bfloat162float(p[i]); }
__device__ __forceinline__ void stv(float* p, long i, float v) { p[i] = v; }
__device__ __forceinline__ void stv(__hip_bfloat16* p, long i, float v) { p[i] = __float2bfloat16(v); }

__device__ __forceinline__ short f2bs(float f) {
    union { float f; unsigned u; } x; x.f = f;
    unsigned r = x.u + 0x7FFFu + ((x.u >> 16) & 1u);
    return (short)(r >> 16);
}
__device__ __forceinline__ float bs2f(short s) {
    union { unsigned u; float f; } x; x.u = ((unsigned)(unsigned short)s) << 16; return x.f;
}

__device__ __forceinline__ float4_t ldv4(const float* p, long i) {
    return *(const float4_t*)(p + i);
}
__device__ __forceinline__ float4_t ldv4(const __hip_bfloat16* p, long i) {
    short4_t s = *(const short4_t*)(p + i);
    float4_t r;
    #pragma unroll
    for (int c = 0; c < 4; ++c) r[c] = bs2f(s[c]);
    return r;
}
__device__ __forceinline__ void stv4(float* p, long i, float4_t v) {
    *(float4_t*)(p + i) = v;
}
__device__ __forceinline__ void stv4(__hip_bfloat16* p, long i, float4_t v) {
    short4_t s;
    #pragma unroll
    for (int c = 0; c < 4; ++c) s[c] = f2bs(v[c]);
    *(short4_t*)(p + i) = s;
}

__device__ __forceinline__ void stage8(const __hip_bfloat16* s, short* d) {
    *(short8_t*)d = *(const short8_t*)s;
}
__device__ __forceinline__ void stage8(const float* s, short* d) {
    float4_t a = *(const float4_t*)s;
    float4_t b = *(const float4_t*)(s + 4);
    short8_t v;
    v[0] = f2bs(a[0]); v[1] = f2bs(a[1]); v[2] = f2bs(a[2]); v[3] = f2bs(a[3]);
    v[4] = f2bs(b[0]); v[5] = f2bs(b[1]); v[6] = f2bs(b[2]); v[7] = f2bs(b[3]);
    *(short8_t*)d = v;
}

// ---------------------------------------------------------------------------
// Generic LDS-tiled linear (embeddings), optional row-gather on X.
// ---------------------------------------------------------------------------
template<int K, int N, int JR, typename TX, typename TY>
__global__ __launch_bounds__(256) void linear_kernel(
    const TX* __restrict__ X, const float* __restrict__ W,
    const float* __restrict__ Bb, TY* __restrict__ Y,
    const int* __restrict__ gather, int rows)
{
    constexpr int SLOTS = 256 / N;
    constexpr int RPG = SLOTS * JR;
    __shared__ float wl[K * N];
    __shared__ float bl[N];
    __shared__ float xl[RPG * K];

    const int tid = threadIdx.x;
    for (int i = tid; i < K * N; i += 256) wl[i] = W[i];
    if (tid < N) bl[tid] = Bb[tid];

    const int col = tid % N;
    const int slot = tid / N;

    const int ngroups = (rows + RPG - 1) / RPG;
    for (int g = blockIdx.x; g < ngroups; g += gridDim.x) {
        const int rowBase = g * RPG;
        __syncthreads();
        for (int i = tid; i < RPG * K; i += 256) {
            int r = i / K, k = i - r * K;
            int row = rowBase + r;
            float v = 0.0f;
            if (row < rows) {
                int sr = gather ? gather[row] : row;
                v = ldv(X, (long)sr * K + k);
            }
            xl[i] = v;
        }
        __syncthreads();
        float acc[JR];
        #pragma unroll
        for (int j = 0; j < JR; ++j) acc[j] = bl[col];
        #pragma unroll 4
        for (int k = 0; k < K; ++k) {
            float w = wl[k * N + col];
            #pragma unroll
            for (int j = 0; j < JR; ++j)
                acc[j] += xl[(slot * JR + j) * K + k] * w;
        }
        #pragma unroll
        for (int j = 0; j < JR; ++j) {
            int row = rowBase + slot * JR + j;
            if (row < rows) stv(Y, (long)row * N + col, acc[j]);
        }
    }
}

// ---------------------------------------------------------------------------
// Quad node linear, MFMA: Ah (fp32) | Bh,Dh,Eh (bf16) = h @ {A,B,D,E} + b.
// If BNIN: h = h + relu(bn(hhat; stats_prev)) in place first (feeds matmul).
// ---------------------------------------------------------------------------
template<bool BNIN>
__global__ __launch_bounds__(256) void node_linear4_mfma_kernel(
    float* __restrict__ h, const float* __restrict__ hhat,
    const short* __restrict__ NT,
    const float* __restrict__ Ab, const float* __restrict__ Bb,
    const float* __restrict__ Db, const float* __restrict__ Eb,
    const float* __restrict__ stats_prev, const float* __restrict__ gprev,
    const float* __restrict__ bprev,
    float* __restrict__ Ah, __hip_bfloat16* __restrict__ Bh,
    __hip_bfloat16* __restrict__ Dh, __hip_bfloat16* __restrict__ Eh)
{
    __shared__ short wt[256 * 72];
    __shared__ short xs[64 * 72];
    __shared__ float bl[256];
    __shared__ float scale[64], shift[64];

    const int tid = threadIdx.x;
    const int wave = tid >> 6;
    const int lane = tid & 63;
    const int r = lane & 15;
    const int q = lane >> 4;

    for (int i = tid; i < 2048; i += 256) {
        int n = i >> 3, oct = i & 7;
        *(short8_t*)(wt + n * 72 + oct * 8) = *(const short8_t*)(NT + n * 64 + oct * 8);
    }
    if (tid < 64) bl[tid] = Ab[tid];
    else if (tid < 128) bl[tid] = Bb[tid - 64];
    else if (tid < 192) bl[tid] = Db[tid - 128];
    else bl[tid] = Eb[tid - 192];
    if (BNIN && tid < 64) {
        float inv = 1.0f / (float)NNODES;
        float mu = stats_prev[tid] * inv;
        float var = stats_prev[64 + tid] * inv - mu * mu;
        float rs = rsqrtf(var + BNEPS);
        float sc = rs * gprev[tid];
        scale[tid] = sc;
        shift[tid] = bprev[tid] - mu * sc;
    }

    const int ntiles = (NNODES + 63) / 64;        // 391
    for (int t = blockIdx.x; t < ntiles; t += gridDim.x) {
        const int rowBase = t * 64;
        __syncthreads();
        for (int i = tid; i < 512; i += 256) {
            int row = i >> 3, oct = i & 7;
            int nr = rowBase + row;
            if (nr < NNODES) {
                long idx = (long)nr * 64 + oct * 8;
                float4_t a = ldv4(h, idx), b = ldv4(h, idx + 4);
                if (BNIN) {
                    float4_t ha = ldv4(hhat, idx), hb = ldv4(hhat, idx + 4);
                    int k0 = oct * 8;
                    #pragma unroll
                    for (int c = 0; c < 4; ++c) {
                        a[c] += fmaxf(ha[c] * scale[k0 + c] + shift[k0 + c], 0.0f);
                        b[c] += fmaxf(hb[c] * scale[k0 + 4 + c] + shift[k0 + 4 + c], 0.0f);
                    }
                    stv4(h, idx, a); stv4(h, idx + 4, b);
                }
                short8_t v;
                v[0] = f2bs(a[0]); v[1] = f2bs(a[1]); v[2] = f2bs(a[2]); v[3] = f2bs(a[3]);
                v[4] = f2bs(b[0]); v[5] = f2bs(b[1]); v[6] = f2bs(b[2]); v[7] = f2bs(b[3]);
                *(short8_t*)(xs + row * 72 + oct * 8) = v;
            } else {
                *(short8_t*)(xs + row * 72 + oct * 8) = (short8_t)0;
            }
        }
        __syncthreads();
        float4_t acc[16];
        #pragma unroll
        for (int i = 0; i < 16; ++i) acc[i] = (float4_t)0.0f;
        #pragma unroll
        for (int kk = 0; kk < 2; ++kk) {
            short8_t a = *(const short8_t*)(xs + (wave * 16 + r) * 72 + kk * 32 + q * 8);
            #pragma unroll
            for (int nt = 0; nt < 16; ++nt) {
                short8_t b = *(const short8_t*)(wt + (nt * 16 + r) * 72 + kk * 32 + q * 8);
                acc[nt] = __builtin_amdgcn_mfma_f32_16x16x32_bf16(a, b, acc[nt], 0, 0, 0);
            }
        }
        #pragma unroll
        for (int nt = 0; nt < 16; ++nt) {
            int c = (nt & 3) * 16 + r;
            int n = nt * 16 + r;
            #pragma unroll
            for (int i2 = 0; i2 < 4; ++i2) {
                int row = rowBase + wave * 16 + q * 4 + i2;
                if (row < NNODES) {
                    float v = acc[nt][i2] + bl[n];
                    long idx = (long)row * 64 + c;
                    if (nt < 4)       Ah[idx] = v;
                    else if (nt < 8)  stv(Bh, idx, v);
                    else if (nt < 12) stv(Dh, idx, v);
                    else              stv(Eh, idx, v);
                }
            }
        }
    }
}

// ---------------------------------------------------------------------------
// MFMA edge update (edges in dst-sorted order); Dh/Eh bf16 (L2-resident).
// R14: epilogue restructured — acc spilled to xs (wave-private rows), then a
// per-row pass with lane==col does fully-coalesced Dh/Eh gathers (128 B/row)
// and coalesced ehat row stores. BN stats accumulated in fp32 post-gather.
// ---------------------------------------------------------------------------
template<bool BNIN, typename TE, typename TH>
__global__ __launch_bounds__(256) void edge_update_mfma_kernel(
    TE* __restrict__ e, TH* __restrict__ ehat,
    const short* __restrict__ CT, const float* __restrict__ Cb,
    const __hip_bfloat16* __restrict__ Dh, const int* __restrict__ srcS,
    const __hip_bfloat16* __restrict__ Eh, const int* __restrict__ dstS,
    const float* __restrict__ stats_prev, const float* __restrict__ gprev,
    const float* __restrict__ bprev, float* __restrict__ partial)
{
    __shared__ short ct[64 * 72];
    __shared__ short xs[64 * 72];
    __shared__ float bl[64], scale[64], shift[64];
    __shared__ float ps[128];

    const int tid = threadIdx.x;
    const int wave = tid >> 6;
    const int lane = tid & 63;
    const int r = lane & 15;
    const int q = lane >> 4;

    for (int i = tid; i < 512; i += 256) {
        int n = i >> 3, oct = i & 7;
        *(short8_t*)(ct + n * 72 + oct * 8) = *(const short8_t*)(CT + n * 64 + oct * 8);
    }
    if (tid < 64) {
        bl[tid] = Cb[tid];
        if (BNIN) {
            float inv = 1.0f / (float)NEDGES;
            float mu = stats_prev[tid] * inv;
            float var = stats_prev[64 + tid] * inv - mu * mu;
            float rs = rsqrtf(var + BNEPS);
            float sc = rs * gprev[tid];
            scale[tid] = sc;
            shift[tid] = bprev[tid] - mu * sc;
        }
    }
    if (tid < 128) ps[tid] = 0.0f;
    float ls = 0.0f, ls2 = 0.0f;    // col == lane in the row pass

    constexpr int NTILES = NEDGES / 64;
    for (int t = blockIdx.x; t < NTILES; t += gridDim.x) {
        const int rowBase = t * 64;
        __syncthreads();
        for (int i = tid; i < 512; i += 256) {
            int row = i >> 3, oct = i & 7;
            long idx = (long)(rowBase + row) * 64 + oct * 8;
            float4_t a = ldv4(e, idx), b = ldv4(e, idx + 4);
            if (BNIN) {
                float4_t ha = ldv4(ehat, idx), hb = ldv4(ehat, idx + 4);
                int k0 = oct * 8;
                #pragma unroll
                for (int c = 0; c < 4; ++c) {
                    a[c] += fmaxf(ha[c] * scale[k0 + c] + shift[k0 + c], 0.0f);
                    b[c] += fmaxf(hb[c] * scale[k0 + 4 + c] + shift[k0 + 4 + c], 0.0f);
                }
                stv4(e, idx, a); stv4(e, idx + 4, b);
            }
            short8_t v;
            v[0] = f2bs(a[0]); v[1] = f2bs(a[1]); v[2] = f2bs(a[2]); v[3] = f2bs(a[3]);
            v[4] = f2bs(b[0]); v[5] = f2bs(b[1]); v[6] = f2bs(b[2]); v[7] = f2bs(b[3]);
            *(short8_t*)(xs + row * 72 + oct * 8) = v;
        }
        __syncthreads();
        float4_t acc[4];
        #pragma unroll
        for (int i = 0; i < 4; ++i) acc[i] = (float4_t)0.0f;
        #pragma unroll
        for (int kk = 0; kk < 2; ++kk) {
            short8_t a = *(const short8_t*)(xs + (wave * 16 + r) * 72 + kk * 32 + q * 8);
            #pragma unroll
            for (int nt = 0; nt < 4; ++nt) {
                short8_t b = *(const short8_t*)(ct + (nt * 16 + r) * 72 + kk * 32 + q * 8);
                acc[nt] = __builtin_amdgcn_mfma_f32_16x16x32_bf16(a, b, acc[nt], 0, 0, 0);
            }
        }
        // spill acc+bias into xs (wave-private rows: A-reads were wave-private)
        #pragma unroll
        for (int nt = 0; nt < 4; ++nt) {
            int col = nt * 16 + r;
            #pragma unroll
            for (int i2 = 0; i2 < 4; ++i2) {
                int row = wave * 16 + q * 4 + i2;
                xs[row * 72 + col] = f2bs(acc[nt][i2] + bl[col]);
            }
        }
        // row pass (wave-private rows; lane == col): coalesced gather + store
        #pragma unroll 4
        for (int i = 0; i < 16; ++i) {
            int row = wave * 16 + i;
            int er = rowBase + row;
            int s = srcS[er], d = dstS[er];
            float v = bs2f(xs[row * 72 + lane])
                    + ldv(Dh, (long)s * 64 + lane)
                    + ldv(Eh, (long)d * 64 + lane);
            stv(ehat, (long)er * 64 + lane, v);
            ls += v; ls2 += v * v;
        }
    }
    __syncthreads();
    atomicAdd(&ps[lane], ls);
    atomicAdd(&ps[64 + lane], ls2);
    __syncthreads();
    if (tid < 128) partial[(long)blockIdx.x * 128 + tid] = ps[tid];
}

// ---------------------------------------------------------------------------
// CSR build + edge permutation
// ---------------------------------------------------------------------------
__global__ __launch_bounds__(256) void deg_hist_kernel(
    const int* __restrict__ dst, int* __restrict__ rowptr, int rows)
{
    int e = blockIdx.x * 256 + threadIdx.x;
    if (e < rows) atomicAdd(&rowptr[dst[e] + 1], 1);
}

__global__ __launch_bounds__(1024) void scan_kernel(int* __restrict__ data, int n)
{
    __shared__ int buf[1024];
    __shared__ int carry;
    if (threadIdx.x == 0) carry = 0;
    __syncthreads();
    for (int base = 0; base < n; base += 1024) {
        int i = base + threadIdx.x;
        int v = (i < n) ? data[i] : 0;
        buf[threadIdx.x] = v;
        __syncthreads();
        for (int off = 1; off < 1024; off <<= 1) {
            int t = (threadIdx.x >= off) ? buf[threadIdx.x - off] : 0;
            __syncthreads();
            buf[threadIdx.x] += t;
            __syncthreads();
        }
        if (i < n) data[i] = buf[threadIdx.x] + carry;
        __syncthreads();
        if (threadIdx.x == 0) carry += buf[1023];
        __syncthreads();
    }
}

__global__ __launch_bounds__(256) void scatter_kernel(
    const int* __restrict__ dst, const int* __restrict__ rowptr,
    int* __restrict__ cursor, int* __restrict__ eid, int rows)
{
    int e = blockIdx.x * 256 + threadIdx.x;
    if (e < rows) {
        int d = dst[e];
        int pos = atomicAdd(&cursor[d], 1);
        eid[rowptr[d] + pos] = e;
    }
}

__global__ __launch_bounds__(256) void remap1_kernel(
    const int* __restrict__ eid, const int* __restrict__ src,
    const int* __restrict__ dst, int* __restrict__ inv,
    int* __restrict__ srcS, int* __restrict__ dstS, int rows)
{
    int p = blockIdx.x * 256 + threadIdx.x;
    if (p < rows) {
        int orig = eid[p];
        inv[orig] = p;
        srcS[p] = src[orig];
        dstS[p] = dst[orig];
    }
}

// ---------------------------------------------------------------------------
// Sorted aggregation + fused hhat + BN partials; Bh is bf16 (L2-resident).
// ---------------------------------------------------------------------------
template<typename TH>
__global__ __launch_bounds__(256) void agg_sorted_kernel(
    const TH* __restrict__ ehat, const __hip_bfloat16* __restrict__ Bh,
    const int* __restrict__ srcS, const int* __restrict__ rowptr,
    const float* __restrict__ Ah, float* __restrict__ hhat,
    float* __restrict__ partial)
{
    __shared__ float ps[64], ps2[64];
    const int tid = threadIdx.x;
    if (tid < 64) { ps[tid] = 0.0f; ps2[tid] = 0.0f; }
    __syncthreads();

    const int node = blockIdx.x * 4 + (tid >> 6);
    const int lane = tid & 63;
    const int sub = lane >> 4;
    const int c4 = (lane & 15) * 4;
    const int s0 = rowptr[node], s1 = rowptr[node + 1];

    float4_t den = (float4_t)0.0f, num = (float4_t)0.0f;
    for (int p = s0 + sub; p < s1; p += 4) {
        float4_t v = ldv4(ehat, (long)p * 64 + c4);
        float4_t bh = ldv4(Bh, (long)srcS[p] * 64 + c4);
        #pragma unroll
        for (int c = 0; c < 4; ++c) {
            float s = 1.0f / (1.0f + __expf(-v[c]));
            den[c] += s;
            num[c] += s * bh[c];
        }
    }
    #pragma unroll
    for (int m = 16; m <= 32; m <<= 1) {
        #pragma unroll
        for (int c = 0; c < 4; ++c) {
            den[c] += __shfl_xor(den[c], m, 64);
            num[c] += __shfl_xor(num[c], m, 64);
        }
    }
    if (sub == 0) {
        float4_t av = ldv4(Ah, (long)node * 64 + c4);
        float4_t hh;
        #pragma unroll
        for (int c = 0; c < 4; ++c) {
            hh[c] = av[c] + num[c] / (den[c] + AGGEPS);
            atomicAdd(&ps[c4 + c], hh[c]);
            atomicAdd(&ps2[c4 + c], hh[c] * hh[c]);
        }
        stv4(hhat, (long)node * 64 + c4, hh);
    }
    __syncthreads();
    if (tid < 64) {
        partial[(long)blockIdx.x * 128 + tid] = ps[tid];
        partial[(long)blockIdx.x * 128 + 64 + tid] = ps2[tid];
    }
}

// merged stats reduce: blocks 0..127 -> stats_e, 128..255 -> stats_h
__global__ __launch_bounds__(256) void reduce_stats2_kernel(
    const float* __restrict__ pe, int ne, float* __restrict__ se,
    const float* __restrict__ ph, int nh, float* __restrict__ sh)
{
    __shared__ float sb[256];
    const float* partial; int nblk; float* stats; int col;
    if (blockIdx.x < 128) { partial = pe; nblk = ne; stats = se; col = blockIdx.x; }
    else                  { partial = ph; nblk = nh; stats = sh; col = blockIdx.x - 128; }
    int tid = threadIdx.x;
    float s = 0.0f;
    for (int i = tid; i < nblk; i += 256) s += partial[(long)i * 128 + col];
    sb[tid] = s;
    __syncthreads();
    for (int off = 128; off > 0; off >>= 1) {
        if (tid < off) sb[tid] += sb[tid + off];
        __syncthreads();
    }
    if (tid == 0) stats[col] = sb[0];
}

// base += relu((xhat-mu)*rstd*g + b), float4 per thread (in place)
template<typename TB, typename TX>
__global__ __launch_bounds__(256) void bn_apply4_kernel(
    TB* __restrict__ base, const TX* __restrict__ xhat,
    const float* __restrict__ stats, const float* __restrict__ g,
    const float* __restrict__ b, int rows)
{
    long total4 = (long)rows * 16;
    float inv = 1.0f / (float)rows;
    for (long q = (long)blockIdx.x * 256 + threadIdx.x; q < total4;
         q += (long)gridDim.x * 256) {
        long idx = q * 4;
        int c = (int)(idx & 63);
        float4_t x = ldv4(xhat, idx);
        float4_t bs = ldv4(base, idx);
        #pragma unroll
        for (int j = 0; j < 4; ++j) {
            float mu = stats[c + j] * inv;
            float var = stats[64 + c + j] * inv - mu * mu;
            float rs = rsqrtf(var + BNEPS);
            float v = (x[j] - mu) * rs * g[c + j] + b[c + j];
            bs[j] += fmaxf(v, 0.0f);
        }
        stv4(base, idx, bs);
    }
}

// fused final e update + scatter to original order:
// eorig[eid[p]] = bf16(e[p] + relu(bn(ehat[p])))
template<typename TE, typename TH>
__global__ __launch_bounds__(256) void bnfinal_scatter_kernel(
    const TE* __restrict__ e, const TH* __restrict__ ehat,
    const int* __restrict__ eid, const float* __restrict__ stats,
    const float* __restrict__ g, const float* __restrict__ b,
    __hip_bfloat16* __restrict__ eorig)
{
    __shared__ float scale[64], shift[64];
    const int tid = threadIdx.x;
    if (tid < 64) {
        float inv = 1.0f / (float)NEDGES;
        float mu = stats[tid] * inv;
        float var = stats[64 + tid] * inv - mu * mu;
        float rs = rsqrtf(var + BNEPS);
        float sc = rs * g[tid];
        scale[tid] = sc;
        shift[tid] = b[tid] - mu * sc;
    }
    __syncthreads();
    long total = (long)NEDGES * 8;
    for (long i = (long)blockIdx.x * 256 + tid; i < total; i += (long)gridDim.x * 256) {
        int p = (int)(i >> 3), oct = (int)(i & 7);
        int k0 = oct * 8;
        long idx = (long)p * 64 + k0;
        float4_t a = ldv4(e, idx), b4 = ldv4(e, idx + 4);
        float4_t ha = ldv4(ehat, idx), hb = ldv4(ehat, idx + 4);
        short8_t v;
        #pragma unroll
        for (int c = 0; c < 4; ++c) {
            v[c]     = f2bs(a[c]  + fmaxf(ha[c] * scale[k0 + c]     + shift[k0 + c], 0.0f));
            v[4 + c] = f2bs(b4[c] + fmaxf(hb[c] * scale[k0 + 4 + c] + shift[k0 + 4 + c], 0.0f));
        }
        *(short8_t*)((short*)eorig + (long)eid[p] * 64 + k0) = v;
    }
}

// Hs = h_fin @ W0c + b0, Hd = h_fin @ W0d (bf16 outputs), with
// h_fin = h + relu(bn(hhat)) computed on the fly (no h writeback).
__global__ __launch_bounds__(256) void precompute_H_kernel(
    const float* __restrict__ h, const float* __restrict__ hhat,
    const float* __restrict__ stats, const float* __restrict__ g,
    const float* __restrict__ b,
    const short* __restrict__ HT, const float* __restrict__ b0,
    __hip_bfloat16* __restrict__ Hs, __hip_bfloat16* __restrict__ Hd)
{
    __shared__ short wt[256 * 72];
    __shared__ short xs[64 * 72];
    __shared__ float bl[256];
    __shared__ float scale[64], shift[64];

    const int tid = threadIdx.x;
    const int wave = tid >> 6;
    const int lane = tid & 63;
    const int r = lane & 15;
    const int q = lane >> 4;

    for (int i = tid; i < 2048; i += 256) {
        int n = i >> 3, oct = i & 7;
        *(short8_t*)(wt + n * 72 + oct * 8) = *(const short8_t*)(HT + n * 64 + oct * 8);
    }
    bl[tid] = (tid < 128) ? b0[tid] : 0.0f;
    if (tid < 64) {
        float inv = 1.0f / (float)NNODES;
        float mu = stats[tid] * inv;
        float var = stats[64 + tid] * inv - mu * mu;
        float rs = rsqrtf(var + BNEPS);
        float sc = rs * g[tid];
        scale[tid] = sc;
        shift[tid] = b[tid] - mu * sc;
    }

    const int ntiles = (NNODES + 63) / 64;
    for (int t = blockIdx.x; t < ntiles; t += gridDim.x) {
        const int rowBase = t * 64;
        __syncthreads();
        for (int i = tid; i < 512; i += 256) {
            int row = i >> 3, oct = i & 7;
            int nr = rowBase + row;
            if (nr < NNODES) {
                long idx = (long)nr * 64 + oct * 8;
                float4_t a = ldv4(h, idx), bb = ldv4(h, idx + 4);
                float4_t ha = ldv4(hhat, idx), hb = ldv4(hhat, idx + 4);
                int k0 = oct * 8;
                #pragma unroll
                for (int c = 0; c < 4; ++c) {
                    a[c]  += fmaxf(ha[c] * scale[k0 + c]     + shift[k0 + c], 0.0f);
                    bb[c] += fmaxf(hb[c] * scale[k0 + 4 + c] + shift[k0 + 4 + c], 0.0f);
                }
                short8_t v;
                v[0] = f2bs(a[0]); v[1] = f2bs(a[1]); v[2] = f2bs(a[2]); v[3] = f2bs(a[3]);
                v[4] = f2bs(bb[0]); v[5] = f2bs(bb[1]); v[6] = f2bs(bb[2]); v[7] = f2bs(bb[3]);
                *(short8_t*)(xs + row * 72 + oct * 8) = v;
            } else {
                *(short8_t*)(xs + row * 72 + oct * 8) = (short8_t)0;
            }
        }
        __syncthreads();
        float4_t acc[16];
        #pragma unroll
        for (int i = 0; i < 16; ++i) acc[i] = (float4_t)0.0f;
        #pragma unroll
        for (int kk = 0; kk < 2; ++kk) {
            short8_t a = *(const short8_t*)(xs + (wave * 16 + r) * 72 + kk * 32 + q * 8);
            #pragma unroll
            for (int nt = 0; nt < 16; ++nt) {
                short8_t b2 = *(const short8_t*)(wt + (nt * 16 + r) * 72 + kk * 32 + q * 8);
                acc[nt] = __builtin_amdgcn_mfma_f32_16x16x32_bf16(a, b2, acc[nt], 0, 0, 0);
            }
        }
        #pragma unroll
        for (int nt = 0; nt < 16; ++nt) {
            __hip_bfloat16* Y = (nt < 8) ? Hs : Hd;
            int c = (nt & 7) * 16 + r;
            int n = nt * 16 + r;
            #pragma unroll
            for (int i2 = 0; i2 < 4; ++i2) {
                int row = rowBase + wave * 16 + q * 4 + i2;
                if (row < NNODES) stv(Y, (long)row * 128 + c, acc[nt][i2] + bl[n]);
            }
        }
    }
}

// one-shot weight prep (bf16 [n][k]): W0T [128][256], W1T [64][128],
// CT [l][64][64], NT [l][256][64] (A|B|D|E), HT [256][64] (W0c|W0d)
__global__ __launch_bounds__(256) void transpose_w_kernel(
    const float* __restrict__ W0, const float* __restrict__ W1,
    const float* __restrict__ C_w,
    const float* __restrict__ A_w, const float* __restrict__ B_w,
    const float* __restrict__ D_w, const float* __restrict__ E_w,
    short* __restrict__ W0T, short* __restrict__ W1T,
    short* __restrict__ CT, short* __restrict__ NT, short* __restrict__ HT)
{
    int id = blockIdx.x * 256 + threadIdx.x;
    if (id < 256 * 128) {
        int k = id >> 7, n = id & 127;
        W0T[n * 256 + k] = f2bs(W0[id]);
    }
    if (id < 128 * 64) {
        int k = id >> 6, n = id & 63;
        W1T[n * 128 + k] = f2bs(W1[id]);
    }
    if (id < 4 * 64 * 64) {
        int l = id >> 12, rem = id & 4095, k = rem >> 6, n = rem & 63;
        CT[l * 4096 + n * 64 + k] = f2bs(C_w[l * 4096 + k * 64 + n]);
    }
    if (id < 4 * 256 * 64) {
        int l = id >> 14, rem = id & 16383, n = rem >> 6, k = rem & 63;
        int mat = n >> 6, c = n & 63;
        const float* Wm = (mat == 0) ? A_w : (mat == 1) ? B_w : (mat == 2) ? D_w : E_w;
        NT[l * 16384 + n * 64 + k] = f2bs(Wm[l * 4096 + k * 64 + c]);
    }
    if (id < 256 * 64) {
        int n = id >> 6, k = id & 63;
        int mat = n >> 7, col = n & 127;
        HT[n * 64 + k] = f2bs(W0[(128 + mat * 64 + k) * 128 + col]);
    }
}

// ---------------------------------------------------------------------------
// MFMA MLP readout (R14): original edge order; epilogue-1 restructured —
// raw acc spilled to x0t (wave-private rows), then per-row pass with
// lane-contiguous short2 so Hs/Hd gathers are one coalesced 256 B read/row.
// ---------------------------------------------------------------------------
__global__ __launch_bounds__(256) void readout_mfma2_kernel(
    const __hip_bfloat16* __restrict__ eorig, const int* __restrict__ rev,
    const __hip_bfloat16* __restrict__ Hs, const __hip_bfloat16* __restrict__ Hd,
    const int* __restrict__ src, const int* __restrict__ dst,
    const short* __restrict__ W0T, const short* __restrict__ W1T,
    const float* __restrict__ b1, const float* __restrict__ W2,
    const float* __restrict__ b2, float* __restrict__ out)
{
    __shared__ short feat[64 * 72];    // e / e_rev tile; reused as x1 tile
    __shared__ short wtile[128 * 72];  // W0 slice [128][72]; reused as W1T [64][136]
    __shared__ short x0t[64 * 136];    // x0 tile bf16 (wave-private rows)
    __shared__ float smallb[194];      // b1[64] | W2[128] | b2[2]

    const int tid = threadIdx.x;
    const int wave = tid >> 6;
    const int lane = tid & 63;
    const int r = lane & 15;
    const int q = lane >> 4;

    if (tid < 64)  smallb[tid] = b1[tid];
    if (tid < 128) smallb[64 + tid] = W2[tid];
    if (tid < 2)   smallb[192 + tid] = b2[tid];

    constexpr int NTILES = NEDGES / 64;   // 6250
    for (int t = blockIdx.x; t < NTILES; t += gridDim.x) {
        const int rowBase = t * 64;
        float4_t acc0[8];
        #pragma unroll
        for (int i = 0; i < 8; ++i) acc0[i] = (float4_t)0.0f;

        for (int s = 0; s < 2; ++s) {
            __syncthreads();
            for (int i = tid; i < 512; i += 256) {
                int row = i >> 3, oct = i & 7;
                int er = rowBase + row;
                int srow = (s == 0) ? er : rev[er];   // sequential either way
                *(short8_t*)(feat + row * 72 + oct * 8) =
                    *(const short8_t*)((const short*)eorig + (long)srow * 64 + oct * 8);
            }
            for (int i = tid; i < 1024; i += 256) {
                int n = i >> 3, oct = i & 7;
                *(short8_t*)(wtile + n * 72 + oct * 8) =
                    *(const short8_t*)(W0T + (long)n * 256 + s * 64 + oct * 8);
            }
            __syncthreads();
            #pragma unroll
            for (int kk = 0; kk < 2; ++kk) {
                short8_t a = *(const short8_t*)(feat + (wave * 16 + r) * 72 + kk * 32 + q * 8);
                #pragma unroll
                for (int nt = 0; nt < 8; ++nt) {
                    short8_t b = *(const short8_t*)(wtile + (nt * 16 + r) * 72 + kk * 32 + q * 8);
                    acc0[nt] = __builtin_amdgcn_mfma_f32_16x16x32_bf16(a, b, acc0[nt], 0, 0, 0);
                }
            }
        }
        // spill raw acc0 -> x0t (wave-private rows)
        #pragma unroll
        for (int nt = 0; nt < 8; ++nt) {
            int col = nt * 16 + r;
            #pragma unroll
            for (int i2 = 0; i2 < 4; ++i2) {
                int row = wave * 16 + q * 4 + i2;
                x0t[row * 136 + col] = f2bs(acc0[nt][i2]);
            }
        }
        // row pass: coalesced Hs/Hd adds, lane handles cols {2l, 2l+1}
        #pragma unroll 4
        for (int i = 0; i < 16; ++i) {
            int row = wave * 16 + i;
            int er = rowBase + row;
            int sN = src[er], dN = dst[er];
            short2_t hs = *(const short2_t*)((const short*)Hs + (long)sN * 128 + 2 * lane);
            short2_t hd = *(const short2_t*)((const short*)Hd + (long)dN * 128 + 2 * lane);
            short2_t x = *(short2_t*)(x0t + row * 136 + 2 * lane);
            short2_t o;
            o[0] = f2bs(fmaxf(bs2f(x[0]) + bs2f(hs[0]) + bs2f(hd[0]), 0.0f));
            o[1] = f2bs(fmaxf(bs2f(x[1]) + bs2f(hs[1]) + bs2f(hd[1]), 0.0f));
            *(short2_t*)(x0t + row * 136 + 2 * lane) = o;
        }
        __syncthreads();
        for (int i = tid; i < 1024; i += 256) {       // W1T -> wtile as [64][136]
            int n = i >> 4, oct = i & 15;
            *(short8_t*)(wtile + n * 136 + oct * 8) =
                *(const short8_t*)(W1T + (long)n * 128 + oct * 8);
        }
        __syncthreads();
        float4_t acc1[4];
        #pragma unroll
        for (int i = 0; i < 4; ++i) acc1[i] = (float4_t)0.0f;
        #pragma unroll
        for (int kk = 0; kk < 4; ++kk) {
            short8_t a = *(const short8_t*)(x0t + (wave * 16 + r) * 136 + kk * 32 + q * 8);
            #pragma unroll
            for (int nt = 0; nt < 4; ++nt) {
                short8_t b = *(const short8_t*)(wtile + (nt * 16 + r) * 136 + kk * 32 + q * 8);
                acc1[nt] = __builtin_amdgcn_mfma_f32_16x16x32_bf16(a, b, acc1[nt], 0, 0, 0);
            }
        }
        #pragma unroll
        for (int nt = 0; nt < 4; ++nt) {
            int col = nt * 16 + r;
            #pragma unroll
            for (int i2 = 0; i2 < 4; ++i2) {
                int row = wave * 16 + q * 4 + i2;
                feat[row * 72 + col] = f2bs(fmaxf(acc1[nt][i2] + smallb[col], 0.0f));
            }
        }
        __syncthreads();
        if (tid < 128) {
            int row = tid >> 1, cls = tid & 1;
            float a = smallb[192 + cls];
            #pragma unroll 8
            for (int k = 0; k < 64; ++k)
                a += bs2f(feat[row * 72 + k]) * smallb[64 + k * 2 + cls];
            out[(long)(rowBase + row) * 2 + cls] = a;
        }
    }
}

// ---------------------------------------------------------------------------
static inline int igrid(long total, int block, int cap) {
    long g = (total + block - 1) / block;
    return (int)(g < cap ? g : cap);
}

constexpr int GE_EDGE = 2048;
constexpr int GA_AGG  = NNODES / 4;  // 6250
constexpr size_t NINTS_PAD = 25001 + 25000 + 4 * (size_t)NEDGES + 3;  // %4==0

template<typename TE, typename TH>
static void run_net(void* const* d_in, float* f, TE* e, TH* ehat,
                    __hip_bfloat16* eorig, float* out, hipStream_t stream)
{
    const float* h_in   = (const float*)d_in[0];
    const float* e_in   = (const float*)d_in[1];
    const int*   src    = (const int*)d_in[2];
    const int*   dst    = (const int*)d_in[3];
    const int*   rev    = (const int*)d_in[4];
    const float* emb_h_w = (const float*)d_in[5];
    const float* emb_h_b = (const float*)d_in[6];
    const float* emb_e_w = (const float*)d_in[7];
    const float* emb_e_b = (const float*)d_in[8];
    const float* A_w = (const float*)d_in[9];  const float* A_b = (const float*)d_in[10];
    const float* B_w = (const float*)d_in[11]; const float* B_b = (const float*)d_in[12];
    const float* C_w = (const float*)d_in[13]; const float* C_b = (const float*)d_in[14];
    const float* D_w = (const float*)d_in[15]; const float* D_b = (const float*)d_in[16];
    const float* E_w = (const float*)d_in[17]; const float* E_b = (const float*)d_in[18];
    // F/G (19..22) and bn_u (27,28) are dead: u never reaches the output.
    const float* bn_h_g = (const float*)d_in[23]; const float* bn_h_b = (const float*)d_in[24];
    const float* bn_e_g = (const float*)d_in[25]; const float* bn_e_b = (const float*)d_in[26];
    const float* W0 = (const float*)d_in[29]; const float* b0 = (const float*)d_in[30];
    const float* W1 = (const float*)d_in[31]; const float* b1 = (const float*)d_in[32];
    const float* W2 = (const float*)d_in[33]; const float* b2 = (const float*)d_in[34];

    const size_t NH = (size_t)NNODES * DD;   // 1.6M (even)
    float* h    = f;                         // NH fp32
    float* Ah   = f + NH;                    // NH fp32 (Hs overlays after layers)
    float* hhat = f + 2 * NH;                // NH fp32 (dedicated)
    __hip_bfloat16* Bh16 = (__hip_bfloat16*)(f + 3 * NH);           // NH bf16
    __hip_bfloat16* Dh16 = (__hip_bfloat16*)(f + 3 * NH + NH / 2);  // NH bf16
    __hip_bfloat16* Eh16 = (__hip_bfloat16*)(f + 4 * NH);           // NH bf16
    float* scratch = f + 4 * NH + NH / 2;
    float* partial_e = scratch;                              // 2048*128
    float* partial_h = partial_e + (size_t)GE_EDGE * 128;    // 6250*128
    int*   rowptr = (int*)(partial_h + (size_t)GA_AGG * 128);
    int*   cursor = rowptr + NNODES + 1;
    int*   eid    = cursor + NNODES;
    int*   inv    = eid + NEDGES;
    int*   srcS   = inv + NEDGES;
    int*   dstS   = srcS + NEDGES;
    short* W0T = (short*)(rowptr + NINTS_PAD);   // 16B-aligned
    short* W1T = W0T + 256 * 128;
    short* CT  = W1T + 128 * 64;
    short* NT  = CT + 4 * 4096;
    short* HT  = NT + 4 * 16384;
    float* stats_h = (float*)(HT + 256 * 64);
    float* stats_e = stats_h + 128;
    // Hs: Ah region (NH fp32 = 25000*128 bf16). Hd: Bh16+Dh16 region.
    __hip_bfloat16* Hs = (__hip_bfloat16*)(f + NH);
    __hip_bfloat16* Hd = (__hip_bfloat16*)(f + 3 * NH);

    const int GN = 1563;
    const int GEDGE = (NEDGES + 255) / 256;

    // CSR + permutation + weight prep (once per call; graph static)
    hipMemsetAsync(rowptr, 0, (2 * NNODES + 1) * sizeof(int), stream);
    deg_hist_kernel<<<GEDGE, 256, 0, stream>>>(dst, rowptr, NEDGES);
    scan_kernel<<<1, 1024, 0, stream>>>(rowptr, NNODES + 1);
    scatter_kernel<<<GEDGE, 256, 0, stream>>>(dst, rowptr, cursor, eid, NEDGES);
    remap1_kernel<<<GEDGE, 256, 0, stream>>>(eid, src, dst, inv, srcS, dstS, NEDGES);
    transpose_w_kernel<<<256, 256, 0, stream>>>(W0, W1, C_w, A_w, B_w, D_w, E_w,
                                                W0T, W1T, CT, NT, HT);

    // embeddings (e in dst-sorted order via eid gather)
    linear_kernel<64, 64, 4, float, float><<<GN, 256, 0, stream>>>(
        h_in, emb_h_w, emb_h_b, h, nullptr, NNODES);
    linear_kernel<16, 64, 4, float, TE><<<4096, 256, 0, stream>>>(
        e_in, emb_e_w, emb_e_b, e, eid, NEDGES);

    for (int l = 0; l < 4; ++l) {
        const size_t o = (size_t)l * DD * DD;
        if (l == 0)
            node_linear4_mfma_kernel<false><<<391, 256, 0, stream>>>(
                h, hhat, NT + (size_t)l * 16384,
                A_b + l * DD, B_b + l * DD, D_b + l * DD, E_b + l * DD,
                nullptr, nullptr, nullptr, Ah, Bh16, Dh16, Eh16);
        else
            node_linear4_mfma_kernel<true><<<391, 256, 0, stream>>>(
                h, hhat, NT + (size_t)l * 16384,
                A_b + l * DD, B_b + l * DD, D_b + l * DD, E_b + l * DD,
                stats_h, bn_h_g + (l - 1) * DD, bn_h_b + (l - 1) * DD,
                Ah, Bh16, Dh16, Eh16);

        if (l == 0)
            edge_update_mfma_kernel<false, TE, TH><<<GE_EDGE, 256, 0, stream>>>(
                e, ehat, CT + o, C_b + l * DD, Dh16, srcS, Eh16, dstS,
                nullptr, nullptr, nullptr, partial_e);
        else
            edge_update_mfma_kernel<true, TE, TH><<<GE_EDGE, 256, 0, stream>>>(
                e, ehat, CT + o, C_b + l * DD, Dh16, srcS, Eh16, dstS,
                stats_e, bn_e_g + (l - 1) * DD, bn_e_b + (l - 1) * DD, partial_e);

        agg_sorted_kernel<TH><<<GA_AGG, 256, 0, stream>>>(
            ehat, Bh16, srcS, rowptr, Ah, hhat, partial_h);
        reduce_stats2_kernel<<<256, 256, 0, stream>>>(
            partial_e, GE_EDGE, stats_e, partial_h, GA_AGG, stats_h);
    }

    // final e update -> bf16 eorig in ORIGINAL edge order (before precompute_H
    // clobbers Ah/Bh16/Dh16 with Hs/Hd)
    bnfinal_scatter_kernel<TE, TH><<<8192, 256, 0, stream>>>(
        e, ehat, eid, stats_e, bn_e_g + 3 * DD, bn_e_b + 3 * DD, eorig);

    // Hs/Hd precompute (bf16) with fused final h-update (no h writeback)
    precompute_H_kernel<<<391, 256, 0, stream>>>(
        h, hhat, stats_h, bn_h_g + 3 * DD, bn_h_b + 3 * DD, HT, b0, Hs, Hd);

    // streaming readout in original order (coalesced Hs/Hd row adds)
    readout_mfma2_kernel<<<2048, 256, 0, stream>>>(
        eorig, rev, Hs, Hd, src, dst, W0T, W1T, b1, W2, b2, out);
}

extern "C" void kernel_launch(void* const* d_in, const int* in_sizes, int n_in,
                              void* d_out, int out_size, void* d_ws, size_t ws_size,
                              hipStream_t stream)
{
    const size_t NH = (size_t)NNODES * DD;       // 1.6M floats
    const size_t NE = (size_t)NEDGES * DD;       // 25.6M elems
    const size_t baseB = (7 * NH + 256) * sizeof(float);   // 44.8 MB node region

    char* base = (char*)d_ws;
    char* edge = base + baseB;
    float* out = (float*)d_out;

    // bf16 e + bf16 ehat + dedicated bf16 eorig = 153.6 MB edge region
    const size_t needMain = baseB + NE * 2 * 3;

    if (ws_size >= needMain) {
        __hip_bfloat16* e     = (__hip_bfloat16*)edge;
        __hip_bfloat16* ehat  = (__hip_bfloat16*)(edge + NE * 2);
        __hip_bfloat16* eorig = (__hip_bfloat16*)(edge + NE * 4);
        run_net<__hip_bfloat16, __hip_bfloat16>(d_in, (float*)base, e, ehat,
                                                eorig, out, stream);
    } else {
        // diagnostic fallback: workspace too small — emit zeros, don't fault
        hipMemsetAsync(d_out, 0, (size_t)out_size * sizeof(float), stream);
    }
}